// Round 1
// baseline (6985.004 us; speedup 1.0000x reference)
//
#include <hip/hip_runtime.h>
#include <math.h>

#define DEVI __device__ __forceinline__

namespace {

constexpr int Bn   = 2048;
constexpr int En   = 6;
constexpr int Hn   = 4;
constexpr int Dn   = 128;
constexpr int DHn  = 32;
constexpr int LTn  = 24;   // text length
constexpr int CSn  = 20;   // chunk (decoder query) length
constexpr int JDn  = 7;
constexpr int SDn  = 16;
constexpr int NLBn = 4;
constexpr int NLDn = 3;
constexpr int DFFn = 512;
constexpr float INV_SQRT_DH = 0.17677669529663687f;  // 1/sqrt(32)

DEVI float geluf(float x) { return 0.5f * x * (1.0f + erff(x * 0.70710678118654752f)); }

// ---------------------------------------------------------------------------
// out[r][c] = OP(sum_k X[r][k]*W[k*wstr+c] + b[c]) for c in [0,N), 256 threads,
// column-per-thread, all R rows in registers. X is LDS (broadcast float4 reads).
template<int R, int KD, int N, int OP>  // OP: 0 none, 1 gelu, 2 relu
DEVI void mmwide(const float* __restrict__ W, const int wstr,
                 const float* __restrict__ bias,
                 const float* X, const int xstr,
                 float* O, const int ostr)
{
#pragma unroll
  for (int c0 = 0; c0 < N; c0 += 256) {
    const int c = c0 + (int)threadIdx.x;
    if ((N % 256 == 0) || (c < N)) {
      float acc[R];
#pragma unroll
      for (int r = 0; r < R; ++r) acc[r] = 0.f;
#pragma unroll 2
      for (int k = 0; k < KD; k += 4) {
        const float w0 = W[(k + 0) * wstr + c];
        const float w1 = W[(k + 1) * wstr + c];
        const float w2 = W[(k + 2) * wstr + c];
        const float w3 = W[(k + 3) * wstr + c];
#pragma unroll
        for (int r = 0; r < R; ++r) {
          const float4 xv = *reinterpret_cast<const float4*>(X + r * xstr + k);
          acc[r] = fmaf(xv.x, w0, acc[r]);
          acc[r] = fmaf(xv.y, w1, acc[r]);
          acc[r] = fmaf(xv.z, w2, acc[r]);
          acc[r] = fmaf(xv.w, w3, acc[r]);
        }
      }
      const float bb = bias[c];
#pragma unroll
      for (int r = 0; r < R; ++r) {
        float v = acc[r] + bb;
        if (OP == 1) v = geluf(v);
        else if (OP == 2) v = fmaxf(v, 0.f);
        O[r * ostr + c] = v;
      }
    }
  }
}

// N=128 variant: 256 threads as 2 groups of 128 cols, each group R/2 rows.
template<int R, int KD, int OP, bool ACC, bool HASB>
DEVI void mm128(const float* __restrict__ W, const int wstr,
                const float* __restrict__ bias,
                const float* X, const int xstr,
                float* O, const int ostr)
{
  static_assert(R % 2 == 0, "R must be even");
  constexpr int RH = R / 2;
  const int g = (int)threadIdx.x >> 7;
  const int c = (int)threadIdx.x & 127;
  const float* Xg = X + g * RH * xstr;
  float acc[RH];
#pragma unroll
  for (int r = 0; r < RH; ++r) acc[r] = 0.f;
#pragma unroll 2
  for (int k = 0; k < KD; k += 4) {
    const float w0 = W[(k + 0) * wstr + c];
    const float w1 = W[(k + 1) * wstr + c];
    const float w2 = W[(k + 2) * wstr + c];
    const float w3 = W[(k + 3) * wstr + c];
#pragma unroll
    for (int r = 0; r < RH; ++r) {
      const float4 xv = *reinterpret_cast<const float4*>(Xg + r * xstr + k);
      acc[r] = fmaf(xv.x, w0, acc[r]);
      acc[r] = fmaf(xv.y, w1, acc[r]);
      acc[r] = fmaf(xv.z, w2, acc[r]);
      acc[r] = fmaf(xv.w, w3, acc[r]);
    }
  }
  const float bb = HASB ? bias[c] : 0.f;
  float* Og = O + g * RH * ostr;
#pragma unroll
  for (int r = 0; r < RH; ++r) {
    float v = acc[r] + bb;
    if (OP == 1) v = geluf(v);
    else if (OP == 2) v = fmaxf(v, 0.f);
    if (ACC) Og[r * ostr + c] += v;
    else     Og[r * ostr + c] = v;
  }
}

// LayerNorm over 128 cols, one wave per row (blockDim must be 256).
template<int R>
DEVI void ln_rows(float* X, const float* gs, const float* gb, float* O)
{
  const int wid  = (int)threadIdx.x >> 6;
  const int lane = (int)threadIdx.x & 63;
  for (int r = wid; r < R; r += 4) {
    const float a0 = X[r * 128 + lane];
    const float a1 = X[r * 128 + lane + 64];
    float s1 = a0 + a1, s2 = a0 * a0 + a1 * a1;
#pragma unroll
    for (int o = 32; o > 0; o >>= 1) { s1 += __shfl_xor(s1, o); s2 += __shfl_xor(s2, o); }
    const float m  = s1 * (1.f / 128.f);
    const float rs = rsqrtf(s2 * (1.f / 128.f) - m * m + 1e-5f);
    O[r * 128 + lane]      = (a0 - m) * rs * gs[lane]      + gb[lane];
    O[r * 128 + lane + 64] = (a1 - m) * rs * gs[lane + 64] + gb[lane + 64];
  }
}

// scores: att[h*L*L + i*L + j] = (q_i . k_j) / sqrt(32), optional key-pad mask.
template<int L, bool MASK>
DEVI void attn_scores(const float* qkv /*stride 384*/, float* att, const int* pad)
{
  for (int e = (int)threadIdx.x; e < Hn * L * L; e += 256) {
    const int h = e / (L * L);
    const int rem = e % (L * L);
    const int i = rem / L, j = rem % L;
    const float* qp = qkv + i * 384 + h * DHn;
    const float* kp = qkv + j * 384 + 128 + h * DHn;
    float acc = 0.f;
#pragma unroll
    for (int d = 0; d < DHn; d += 4) {
      const float4 qa = *reinterpret_cast<const float4*>(qp + d);
      const float4 kb = *reinterpret_cast<const float4*>(kp + d);
      acc += qa.x * kb.x + qa.y * kb.y + qa.z * kb.z + qa.w * kb.w;
    }
    acc *= INV_SQRT_DH;
    if (MASK && pad[j]) acc = -1e9f;
    att[e] = acc;
  }
}

template<int L>
DEVI void softmax_rows(float* att)
{
  for (int r = (int)threadIdx.x; r < Hn * L; r += 256) {
    float* row = att + r * L;
    float m = row[0];
#pragma unroll 4
    for (int j = 1; j < L; ++j) m = fmaxf(m, row[j]);
    float s = 0.f;
#pragma unroll 4
    for (int j = 0; j < L; ++j) { const float ex = expf(row[j] - m); row[j] = ex; s += ex; }
    const float inv = 1.f / s;
#pragma unroll 4
    for (int j = 0; j < L; ++j) row[j] *= inv;
  }
}

// o[i][c] = sum_j a[h][i][j] * v[j][c]   (v = qkv cols 256..383)
template<int L>
DEVI void attn_av(const float* qkv, const float* att, float* o, const int ostr)
{
  for (int e = (int)threadIdx.x; e < L * Dn; e += 256) {
    const int i = e >> 7, c = e & 127, h = c >> 5;
    const float* arow = att + (h * L + i) * L;
    const float* vp = qkv + 256 + c;
    float acc = 0.f;
#pragma unroll 4
    for (int j = 0; j < L; ++j) acc = fmaf(arow[j], vp[j * 384], acc);
    o[i * ostr + c] = acc;
  }
}

// ---------------------------------------------------------------------------
struct BertP {
  const int* ids; const float* tok; const float* pos;
  const float* Wqkv; const float* bqkv; const float* Wo; const float* bo;
  const float* W1; const float* b1; const float* W2; const float* b2;
  const float* ln_s; const float* ln_b; const float* lnf_s; const float* lnf_b;
  float* intent;
};

__global__ __launch_bounds__(256) void bert_kernel(BertP p)
{
  __shared__ float xs[LTn * Dn];            // 3072 floats
  __shared__ float scr[LTn * 384 + Hn * LTn * LTn];  // qkv(9216) + att(2304) = 11520
  __shared__ int   pad_s[LTn];
  const int b = blockIdx.x;
  const int tid = (int)threadIdx.x;

  for (int e = tid; e < LTn * Dn; e += 256) {
    const int i = e >> 7, c = e & 127;
    const int id = p.ids[b * LTn + i];
    xs[e] = p.tok[id * Dn + c] + p.pos[e];
  }
  for (int i = tid; i < LTn; i += 256) pad_s[i] = (p.ids[b * LTn + i] == 0) ? 1 : 0;
  __syncthreads();

  float* att = scr + LTn * 384;
  for (int l = 0; l < NLBn; ++l) {
    const float* Wqkv = p.Wqkv + l * Dn * 3 * Dn;
    const float* bqkv = p.bqkv + l * 3 * Dn;
    const float* Wo   = p.Wo   + l * Dn * Dn;
    const float* bo   = p.bo   + l * Dn;
    const float* W1   = p.W1   + l * Dn * DFFn;
    const float* b1   = p.b1   + l * DFFn;
    const float* W2   = p.W2   + l * DFFn * Dn;
    const float* b2   = p.b2   + l * Dn;

    // ---- self-attention (post-LN: input is xs directly)
    mmwide<LTn, Dn, 3 * Dn, 0>(Wqkv, 3 * Dn, bqkv, xs, Dn, scr, 3 * Dn);
    __syncthreads();
    attn_scores<LTn, true>(scr, att, pad_s);
    __syncthreads();
    softmax_rows<LTn>(att);
    __syncthreads();
    attn_av<LTn>(scr, att, scr, 384);   // o overwrites the (consumed) q slots
    __syncthreads();
    mm128<LTn, Dn, 0, true, true>(Wo, Dn, bo, scr, 384, xs, Dn);  // xs += o@Wo+bo
    __syncthreads();
    ln_rows<LTn>(xs, p.ln_s + l * 2 * Dn, p.ln_b + l * 2 * Dn, xs);
    __syncthreads();

    // ---- FFN (chunked in two 256-col halves; xin copy since xs is mutated)
    for (int e = tid; e < LTn * Dn; e += 256) scr[e] = xs[e];
    __syncthreads();
    float* xin  = scr;
    float* hbuf = scr + LTn * Dn;
    mmwide<LTn, Dn, 256, 1>(W1, DFFn, b1, xin, Dn, hbuf, 256);
    __syncthreads();
    mm128<LTn, 256, 0, true, true>(W2, Dn, b2, hbuf, 256, xs, Dn);
    __syncthreads();
    mmwide<LTn, Dn, 256, 1>(W1 + 256, DFFn, b1 + 256, xin, Dn, hbuf, 256);
    __syncthreads();
    mm128<LTn, 256, 0, true, false>(W2 + 256 * Dn, Dn, nullptr, hbuf, 256, xs, Dn);
    __syncthreads();
    ln_rows<LTn>(xs, p.ln_s + l * 2 * Dn + Dn, p.ln_b + l * 2 * Dn + Dn, xs);
    __syncthreads();
  }

  // intent = LN(row 0, lnf)
  if (tid < 64) {
    const float a0 = xs[tid], a1 = xs[tid + 64];
    float s1 = a0 + a1, s2 = a0 * a0 + a1 * a1;
#pragma unroll
    for (int o = 32; o > 0; o >>= 1) { s1 += __shfl_xor(s1, o); s2 += __shfl_xor(s2, o); }
    const float m  = s1 * (1.f / 128.f);
    const float rs = rsqrtf(s2 * (1.f / 128.f) - m * m + 1e-5f);
    p.intent[b * Dn + tid]      = (a0 - m) * rs * p.lnf_s[tid]      + p.lnf_b[tid];
    p.intent[b * Dn + tid + 64] = (a1 - m) * rs * p.lnf_s[tid + 64] + p.lnf_b[tid + 64];
  }
}

// ---------------------------------------------------------------------------
struct RouterP {
  const float* state; const float* intent;
  const float* se_W1; const float* se_b1; const float* se_W2; const float* se_b2;
  const float* se_ln_s; const float* se_ln_b;
  const float* r_W1; const float* r_b1; const float* r_W2; const float* r_b2;
  const float* r_ln_s; const float* r_ln_b;
  const float* gate_W; const float* gate_b;
  int* ridx; float* rwgt;
};

DEVI void ln128(float* x, const float* gs, const float* gb, float* red)
{
  const int c = (int)threadIdx.x;      // blockDim == 128
  const float a = x[c];
  float s1 = a, s2 = a * a;
#pragma unroll
  for (int o = 32; o > 0; o >>= 1) { s1 += __shfl_xor(s1, o); s2 += __shfl_xor(s2, o); }
  const int wid = c >> 6;
  if ((c & 63) == 0) { red[wid * 2] = s1; red[wid * 2 + 1] = s2; }
  __syncthreads();
  s1 = red[0] + red[2]; s2 = red[1] + red[3];
  const float m  = s1 * (1.f / 128.f);
  const float rs = rsqrtf(s2 * (1.f / 128.f) - m * m + 1e-5f);
  __syncthreads();
  x[c] = (a - m) * rs * gs[c] + gb[c];
}

__global__ __launch_bounds__(128) void router_kernel(RouterP p)
{
  __shared__ float sstate[SDn];
  __shared__ float h1[Dn];
  __shared__ float vv[Dn];
  __shared__ float red[4];
  __shared__ float slog[En];
  const int b = blockIdx.x;
  const int c = (int)threadIdx.x;

  if (c < SDn) sstate[c] = p.state[b * SDn + c];
  __syncthreads();
  { // state encoder hidden
    float acc = p.se_b1[c];
#pragma unroll
    for (int k = 0; k < SDn; ++k) acc = fmaf(sstate[k], p.se_W1[k * Dn + c], acc);
    h1[c] = geluf(acc);
  }
  __syncthreads();
  {
    float acc = p.se_b2[c];
#pragma unroll 4
    for (int k = 0; k < Dn; ++k) acc = fmaf(h1[k], p.se_W2[k * Dn + c], acc);
    vv[c] = acc;
  }
  __syncthreads();
  ln128(vv, p.se_ln_s, p.se_ln_b, red);  // vv = semb
  __syncthreads();
  { // fusion hidden: concat([intent, semb])
    float acc = p.r_b1[c];
    const float* ib = p.intent + b * Dn;
#pragma unroll 4
    for (int k = 0; k < Dn; ++k) acc = fmaf(ib[k], p.r_W1[k * Dn + c], acc);
#pragma unroll 4
    for (int k = 0; k < Dn; ++k) acc = fmaf(vv[k], p.r_W1[(Dn + k) * Dn + c], acc);
    h1[c] = geluf(acc);
  }
  __syncthreads();
  {
    float acc = p.r_b2[c];
#pragma unroll 4
    for (int k = 0; k < Dn; ++k) acc = fmaf(h1[k], p.r_W2[k * Dn + c], acc);
    vv[c] = acc;
  }
  __syncthreads();
  ln128(vv, p.r_ln_s, p.r_ln_b, red);    // vv = fused
  __syncthreads();
  if (c < En) {
    float acc = p.gate_b[c];
#pragma unroll 4
    for (int k = 0; k < Dn; ++k) acc = fmaf(vv[k], p.gate_W[k * En + c], acc);
    slog[c] = acc;
  }
  __syncthreads();
  if (c == 0) {
    int i0 = 0; float v0 = slog[0];
#pragma unroll
    for (int e2 = 1; e2 < En; ++e2) if (slog[e2] > v0) { v0 = slog[e2]; i0 = e2; }
    int i1 = -1; float v1 = -3.4e38f;
#pragma unroll
    for (int e2 = 0; e2 < En; ++e2) if (e2 != i0 && slog[e2] > v1) { v1 = slog[e2]; i1 = e2; }
    const float e1  = expf(v1 - v0);
    const float inv = 1.f / (1.f + e1);
    p.ridx[b * 2 + 0] = i0; p.ridx[b * 2 + 1] = i1;
    p.rwgt[b * 2 + 0] = inv; p.rwgt[b * 2 + 1] = e1 * inv;
  }
}

// ---------------------------------------------------------------------------
struct ExpertP {
  const float* state; const float* qpe; const int* ridx; const float* rwgt;
  const float* sp_W; const float* sp_b; const float* zp_b;
  const float* aW; const float* ab; const float* aWo; const float* abo;
  const float* ln_s; const float* ln_b;
  const float* fW1; const float* fb1; const float* fW2; const float* fb2;
  const float* hW; const float* hb;
  float* out;
};

__global__ __launch_bounds__(256) void expert_kernel(ExpertP p)
{
  __shared__ float xs[CSn * Dn];                       // 2560
  __shared__ float xn[CSn * Dn];                       // 2560
  __shared__ float scr[CSn * 384 + Hn * CSn * CSn];    // 7680 + 1600 = 9280
  __shared__ float mem[2 * Dn];
  __shared__ float memkv[2 * 256];
  __shared__ float outacc[CSn * JDn];
  const int b = blockIdx.x;
  const int tid = (int)threadIdx.x;

  for (int e = tid; e < CSn * JDn; e += 256) outacc[e] = 0.f;

  for (int slot = 0; slot < 2; ++slot) {
    const int   ex  = p.ridx[b * 2 + slot];
    const float wgt = p.rwgt[b * 2 + slot];

    // mem[0] = state @ sp_W + sp_b ; mem[1] = zp_b (z == 0)
    if (tid < Dn) {
      float acc = p.sp_b[ex * Dn + tid];
      const float* spw = p.sp_W + ex * SDn * Dn;
#pragma unroll
      for (int k = 0; k < SDn; ++k) acc = fmaf(p.state[b * SDn + k], spw[k * Dn + tid], acc);
      mem[tid] = acc;
    } else {
      mem[Dn + (tid - Dn)] = p.zp_b[ex * Dn + (tid - Dn)];
    }
    for (int e = tid; e < CSn * Dn; e += 256) xs[e] = p.qpe[e];
    __syncthreads();

    for (int l = 0; l < NLDn; ++l) {
      const int li = ex * NLDn + l;
      const float* aW0 = p.aW  + (li * 2 + 0) * Dn * 3 * Dn;
      const float* ab0 = p.ab  + (li * 2 + 0) * 3 * Dn;
      const float* aW1 = p.aW  + (li * 2 + 1) * Dn * 3 * Dn;
      const float* ab1 = p.ab  + (li * 2 + 1) * 3 * Dn;
      const float* Wo0 = p.aWo + (li * 2 + 0) * Dn * Dn;
      const float* bo0 = p.abo + (li * 2 + 0) * Dn;
      const float* Wo1 = p.aWo + (li * 2 + 1) * Dn * Dn;
      const float* bo1 = p.abo + (li * 2 + 1) * Dn;
      const float* lns = p.ln_s + li * 3 * Dn;
      const float* lnb = p.ln_b + li * 3 * Dn;
      const float* fW1 = p.fW1 + li * Dn * DFFn;
      const float* fb1 = p.fb1 + li * DFFn;
      const float* fW2 = p.fW2 + li * DFFn * Dn;
      const float* fb2 = p.fb2 + li * Dn;

      // ---- self-attention (norm_first)
      ln_rows<CSn>(xs, lns + 0 * Dn, lnb + 0 * Dn, xn);
      __syncthreads();
      mmwide<CSn, Dn, 3 * Dn, 0>(aW0, 3 * Dn, ab0, xn, Dn, scr, 3 * Dn);
      __syncthreads();
      float* att = scr + CSn * 384;
      attn_scores<CSn, false>(scr, att, nullptr);
      __syncthreads();
      softmax_rows<CSn>(att);
      __syncthreads();
      attn_av<CSn>(scr, att, xn, Dn);
      __syncthreads();
      mm128<CSn, Dn, 0, true, true>(Wo0, Dn, bo0, xn, Dn, xs, Dn);
      __syncthreads();

      // ---- cross-attention with mem (2 keys)
      ln_rows<CSn>(xs, lns + 1 * Dn, lnb + 1 * Dn, xn);
      __syncthreads();
      mm128<CSn, Dn, 0, false, true>(aW1, 3 * Dn, ab1, xn, Dn, scr, Dn);  // q -> scr[0..2560)
      for (int e = tid; e < 2 * 256; e += 256) {   // k,v of mem
        const int j = e >> 8, c2 = e & 255;
        float acc = ab1[Dn + c2];
        const float* wp = aW1 + Dn + c2;
#pragma unroll 4
        for (int k = 0; k < Dn; ++k) acc = fmaf(mem[j * Dn + k], wp[k * 3 * Dn], acc);
        memkv[j * 256 + c2] = acc;
      }
      __syncthreads();
      float* catt = scr + CSn * Dn;  // [2560, 2720)
      for (int e = tid; e < Hn * CSn; e += 256) {
        const int h = e / CSn, i = e % CSn;
        const float* qp = scr + i * Dn + h * DHn;
        float s0 = 0.f, s1 = 0.f;
#pragma unroll
        for (int d = 0; d < DHn; d += 4) {
          const float4 q4 = *reinterpret_cast<const float4*>(qp + d);
          const float4 k0 = *reinterpret_cast<const float4*>(memkv + 0 * 256 + h * DHn + d);
          const float4 k1 = *reinterpret_cast<const float4*>(memkv + 1 * 256 + h * DHn + d);
          s0 += q4.x * k0.x + q4.y * k0.y + q4.z * k0.z + q4.w * k0.w;
          s1 += q4.x * k1.x + q4.y * k1.y + q4.z * k1.z + q4.w * k1.w;
        }
        s0 *= INV_SQRT_DH; s1 *= INV_SQRT_DH;
        const float m = fmaxf(s0, s1);
        const float e0 = expf(s0 - m), e1 = expf(s1 - m);
        const float inv = 1.f / (e0 + e1);
        catt[e * 2] = e0 * inv; catt[e * 2 + 1] = e1 * inv;
      }
      __syncthreads();
      for (int e = tid; e < CSn * Dn; e += 256) {
        const int i = e >> 7, c = e & 127, h = c >> 5;
        const int a = (h * CSn + i) * 2;
        xn[e] = catt[a] * memkv[0 * 256 + Dn + c] + catt[a + 1] * memkv[1 * 256 + Dn + c];
      }
      __syncthreads();
      mm128<CSn, Dn, 0, true, true>(Wo1, Dn, bo1, xn, Dn, xs, Dn);
      __syncthreads();

      // ---- FFN (relu), chunked halves; input xn is stable
      ln_rows<CSn>(xs, lns + 2 * Dn, lnb + 2 * Dn, xn);
      __syncthreads();
      mmwide<CSn, Dn, 256, 2>(fW1, DFFn, fb1, xn, Dn, scr, 256);
      __syncthreads();
      mm128<CSn, 256, 0, true, true>(fW2, Dn, fb2, scr, 256, xs, Dn);
      __syncthreads();
      mmwide<CSn, Dn, 256, 2>(fW1 + 256, DFFn, fb1 + 256, xn, Dn, scr, 256);
      __syncthreads();
      mm128<CSn, 256, 0, true, false>(fW2 + 256 * Dn, Dn, nullptr, scr, 256, xs, Dn);
      __syncthreads();
    }

    // head + weighted accumulate
    const float* hw = p.hW + ex * Dn * JDn;
    for (int e = tid; e < CSn * JDn; e += 256) {
      const int t = e / JDn, j = e % JDn;
      float acc = p.hb[ex * JDn + j];
#pragma unroll 4
      for (int k = 0; k < Dn; ++k) acc = fmaf(xs[t * Dn + k], hw[k * JDn + j], acc);
      outacc[e] = fmaf(wgt, acc, outacc[e]);
    }
    __syncthreads();
  }

  for (int e = tid; e < CSn * JDn; e += 256) p.out[b * CSn * JDn + e] = outacc[e];
}

// ---------------------------------------------------------------------------
__global__ void qpe_kernel(float* qpe)
{
  const int e = (int)blockIdx.x * 256 + (int)threadIdx.x;
  if (e < CSn * Dn) {
    const int t = e >> 7, d = e & 127;
    const float j  = (float)(d & ~1);
    const float dv = expf(j * (-logf(10000.f) / 128.f));
    const float a  = (float)t * dv;
    qpe[e] = (d & 1) ? cosf(a) : sinf(a);
  }
}

} // namespace

// ---------------------------------------------------------------------------
extern "C" void kernel_launch(void* const* d_in, const int* in_sizes, int n_in,
                              void* d_out, int out_size, void* d_ws, size_t ws_size,
                              hipStream_t stream)
{
  (void)in_sizes; (void)n_in; (void)out_size; (void)ws_size;

  const int*   ids     = (const int*)  d_in[0];
  const float* state   = (const float*)d_in[1];
  const float* tok_emb = (const float*)d_in[2];
  const float* pos_emb = (const float*)d_in[3];

  // workspace layout (floats)
  float* ws     = (float*)d_ws;
  float* qpe    = ws;                       // 2560 (pad to 4096)
  float* intent = ws + 4096;                // 2048*128 = 262144
  int*   ridx   = (int*)(ws + 4096 + 262144);  // 4096 ints
  float* rwgt   = ws + 4096 + 262144 + 4096;   // 4096 floats

  qpe_kernel<<<dim3(10), dim3(256), 0, stream>>>(qpe);

  BertP bp;
  bp.ids  = ids; bp.tok = tok_emb; bp.pos = pos_emb;
  bp.Wqkv = (const float*)d_in[4];  bp.bqkv = (const float*)d_in[5];
  bp.Wo   = (const float*)d_in[6];  bp.bo   = (const float*)d_in[7];
  bp.W1   = (const float*)d_in[8];  bp.b1   = (const float*)d_in[9];
  bp.W2   = (const float*)d_in[10]; bp.b2   = (const float*)d_in[11];
  bp.ln_s = (const float*)d_in[12]; bp.ln_b = (const float*)d_in[13];
  bp.lnf_s= (const float*)d_in[14]; bp.lnf_b= (const float*)d_in[15];
  bp.intent = intent;
  bert_kernel<<<dim3(Bn), dim3(256), 0, stream>>>(bp);

  RouterP rp;
  rp.state = state; rp.intent = intent;
  rp.se_W1 = (const float*)d_in[16]; rp.se_b1 = (const float*)d_in[17];
  rp.se_W2 = (const float*)d_in[18]; rp.se_b2 = (const float*)d_in[19];
  rp.se_ln_s = (const float*)d_in[20]; rp.se_ln_b = (const float*)d_in[21];
  rp.r_W1 = (const float*)d_in[22]; rp.r_b1 = (const float*)d_in[23];
  rp.r_W2 = (const float*)d_in[24]; rp.r_b2 = (const float*)d_in[25];
  rp.r_ln_s = (const float*)d_in[26]; rp.r_ln_b = (const float*)d_in[27];
  rp.gate_W = (const float*)d_in[28]; rp.gate_b = (const float*)d_in[29];
  rp.ridx = ridx; rp.rwgt = rwgt;
  router_kernel<<<dim3(Bn), dim3(128), 0, stream>>>(rp);

  ExpertP ep;
  ep.state = state; ep.qpe = qpe; ep.ridx = ridx; ep.rwgt = rwgt;
  ep.sp_W = (const float*)d_in[30]; ep.sp_b = (const float*)d_in[31];
  // d_in[32] (exp_zp_W) unused: z == 0 so z @ zp_W == 0
  ep.zp_b = (const float*)d_in[33];
  ep.aW   = (const float*)d_in[34]; ep.ab   = (const float*)d_in[35];
  ep.aWo  = (const float*)d_in[36]; ep.abo  = (const float*)d_in[37];
  ep.ln_s = (const float*)d_in[38]; ep.ln_b = (const float*)d_in[39];
  ep.fW1  = (const float*)d_in[40]; ep.fb1  = (const float*)d_in[41];
  ep.fW2  = (const float*)d_in[42]; ep.fb2  = (const float*)d_in[43];
  ep.hW   = (const float*)d_in[44]; ep.hb   = (const float*)d_in[45];
  ep.out  = (float*)d_out;
  expert_kernel<<<dim3(Bn), dim3(256), 0, stream>>>(ep);
}

// Round 2
// 4964.897 us; speedup vs baseline: 1.4069x; 1.4069x over previous
//
#include <hip/hip_runtime.h>
#include <math.h>

#define DEVI __device__ __forceinline__

namespace {

constexpr int Bn   = 2048;
constexpr int En   = 6;
constexpr int Hn   = 4;
constexpr int Dn   = 128;
constexpr int DHn  = 32;
constexpr int LTn  = 24;   // text length
constexpr int CSn  = 20;   // chunk (decoder query) length
constexpr int JDn  = 7;
constexpr int SDn  = 16;
constexpr int NLBn = 4;
constexpr int NLDn = 3;
constexpr int DFFn = 512;
constexpr float INV_SQRT_DH = 0.17677669529663687f;  // 1/sqrt(32)

typedef float f32x4v __attribute__((ext_vector_type(4)));
typedef short short8 __attribute__((ext_vector_type(8)));

DEVI float geluf(float x) { return 0.5f * x * (1.0f + erff(x * 0.70710678118654752f)); }

DEVI short f2bf(float f) {  // fp32 -> bf16 bits, round-to-nearest-even
  unsigned u = __float_as_uint(f);
  return (short)((u + 0x7FFFu + ((u >> 16) & 1u)) >> 16);
}

// swizzled bf16 writes: row-stride-K LDS tile, 16B slot XORed with row&7
DEVI void xbW128(short* xb, int r, int c, float v) {
  xb[r * 128 + ((((c >> 3) ^ (r & 7)) << 3) | (c & 7))] = f2bf(v);
}
DEVI void hbW256(short* hb, int r, int c, float v) {
  hb[r * 256 + ((((c >> 3) ^ (r & 7)) << 3) | (c & 7))] = f2bf(v);
}

// ---------------------------------------------------------------------------
// fp32 column-per-thread matmuls (used by BERT / router / fallback expert)
template<int R, int KD, int N, int OP>  // OP: 0 none, 1 gelu, 2 relu
DEVI void mmwide(const float* __restrict__ W, const int wstr,
                 const float* __restrict__ bias,
                 const float* X, const int xstr,
                 float* O, const int ostr)
{
#pragma unroll
  for (int c0 = 0; c0 < N; c0 += 256) {
    const int c = c0 + (int)threadIdx.x;
    if ((N % 256 == 0) || (c < N)) {
      float acc[R];
#pragma unroll
      for (int r = 0; r < R; ++r) acc[r] = 0.f;
#pragma unroll 2
      for (int k = 0; k < KD; k += 4) {
        const float w0 = W[(k + 0) * wstr + c];
        const float w1 = W[(k + 1) * wstr + c];
        const float w2 = W[(k + 2) * wstr + c];
        const float w3 = W[(k + 3) * wstr + c];
#pragma unroll
        for (int r = 0; r < R; ++r) {
          const float4 xv = *reinterpret_cast<const float4*>(X + r * xstr + k);
          acc[r] = fmaf(xv.x, w0, acc[r]);
          acc[r] = fmaf(xv.y, w1, acc[r]);
          acc[r] = fmaf(xv.z, w2, acc[r]);
          acc[r] = fmaf(xv.w, w3, acc[r]);
        }
      }
      const float bb = bias[c];
#pragma unroll
      for (int r = 0; r < R; ++r) {
        float v = acc[r] + bb;
        if (OP == 1) v = geluf(v);
        else if (OP == 2) v = fmaxf(v, 0.f);
        O[r * ostr + c] = v;
      }
    }
  }
}

template<int R, int KD, int OP, bool ACC, bool HASB>
DEVI void mm128(const float* __restrict__ W, const int wstr,
                const float* __restrict__ bias,
                const float* X, const int xstr,
                float* O, const int ostr)
{
  static_assert(R % 2 == 0, "R must be even");
  constexpr int RH = R / 2;
  const int g = (int)threadIdx.x >> 7;
  const int c = (int)threadIdx.x & 127;
  const float* Xg = X + g * RH * xstr;
  float acc[RH];
#pragma unroll
  for (int r = 0; r < RH; ++r) acc[r] = 0.f;
#pragma unroll 2
  for (int k = 0; k < KD; k += 4) {
    const float w0 = W[(k + 0) * wstr + c];
    const float w1 = W[(k + 1) * wstr + c];
    const float w2 = W[(k + 2) * wstr + c];
    const float w3 = W[(k + 3) * wstr + c];
#pragma unroll
    for (int r = 0; r < RH; ++r) {
      const float4 xv = *reinterpret_cast<const float4*>(Xg + r * xstr + k);
      acc[r] = fmaf(xv.x, w0, acc[r]);
      acc[r] = fmaf(xv.y, w1, acc[r]);
      acc[r] = fmaf(xv.z, w2, acc[r]);
      acc[r] = fmaf(xv.w, w3, acc[r]);
    }
  }
  const float bb = HASB ? bias[c] : 0.f;
  float* Og = O + g * RH * ostr;
#pragma unroll
  for (int r = 0; r < RH; ++r) {
    float v = acc[r] + bb;
    if (OP == 1) v = geluf(v);
    else if (OP == 2) v = fmaxf(v, 0.f);
    if (ACC) Og[r * ostr + c] += v;
    else     Og[r * ostr + c] = v;
  }
}

// LayerNorm over 128 cols, one wave per row (blockDim must be 256).
template<int R>
DEVI void ln_rows(float* X, const float* gs, const float* gb, float* O)
{
  const int wid  = (int)threadIdx.x >> 6;
  const int lane = (int)threadIdx.x & 63;
  for (int r = wid; r < R; r += 4) {
    const float a0 = X[r * 128 + lane];
    const float a1 = X[r * 128 + lane + 64];
    float s1 = a0 + a1, s2 = a0 * a0 + a1 * a1;
#pragma unroll
    for (int o = 32; o > 0; o >>= 1) { s1 += __shfl_xor(s1, o); s2 += __shfl_xor(s2, o); }
    const float m  = s1 * (1.f / 128.f);
    const float rs = rsqrtf(s2 * (1.f / 128.f) - m * m + 1e-5f);
    O[r * 128 + lane]      = (a0 - m) * rs * gs[lane]      + gb[lane];
    O[r * 128 + lane + 64] = (a1 - m) * rs * gs[lane + 64] + gb[lane + 64];
  }
}

// LayerNorm xs -> bf16 swizzled xb (rows 0..CSn-1 only)
DEVI void ln_rows_bf(const float* X, const float* gs, const float* gb, short* xb)
{
  const int wid  = (int)threadIdx.x >> 6;
  const int lane = (int)threadIdx.x & 63;
  for (int r = wid; r < CSn; r += 4) {
    const float a0 = X[r * 128 + lane];
    const float a1 = X[r * 128 + lane + 64];
    float s1 = a0 + a1, s2 = a0 * a0 + a1 * a1;
#pragma unroll
    for (int o = 32; o > 0; o >>= 1) { s1 += __shfl_xor(s1, o); s2 += __shfl_xor(s2, o); }
    const float m  = s1 * (1.f / 128.f);
    const float rs = rsqrtf(s2 * (1.f / 128.f) - m * m + 1e-5f);
    xbW128(xb, r, lane,      (a0 - m) * rs * gs[lane]      + gb[lane]);
    xbW128(xb, r, lane + 64, (a1 - m) * rs * gs[lane + 64] + gb[lane + 64]);
  }
}

// scores: att[h*L*L + i*L + j] = (q_i . k_j) / sqrt(32), optional key-pad mask.
template<int L, bool MASK>
DEVI void attn_scores(const float* qkv /*stride 384*/, float* att, const int* pad)
{
  for (int e = (int)threadIdx.x; e < Hn * L * L; e += 256) {
    const int h = e / (L * L);
    const int rem = e % (L * L);
    const int i = rem / L, j = rem % L;
    const float* qp = qkv + i * 384 + h * DHn;
    const float* kp = qkv + j * 384 + 128 + h * DHn;
    float acc = 0.f;
#pragma unroll
    for (int d = 0; d < DHn; d += 4) {
      const float4 qa = *reinterpret_cast<const float4*>(qp + d);
      const float4 kb = *reinterpret_cast<const float4*>(kp + d);
      acc += qa.x * kb.x + qa.y * kb.y + qa.z * kb.z + qa.w * kb.w;
    }
    acc *= INV_SQRT_DH;
    if (MASK && pad[j]) acc = -1e9f;
    att[e] = acc;
  }
}

template<int L>
DEVI void softmax_rows(float* att)
{
  for (int r = (int)threadIdx.x; r < Hn * L; r += 256) {
    float* row = att + r * L;
    float m = row[0];
#pragma unroll 4
    for (int j = 1; j < L; ++j) m = fmaxf(m, row[j]);
    float s = 0.f;
#pragma unroll 4
    for (int j = 0; j < L; ++j) { const float ex = expf(row[j] - m); row[j] = ex; s += ex; }
    const float inv = 1.f / s;
#pragma unroll 4
    for (int j = 0; j < L; ++j) row[j] *= inv;
  }
}

template<int L>
DEVI void attn_av(const float* qkv, const float* att, float* o, const int ostr)
{
  for (int e = (int)threadIdx.x; e < L * Dn; e += 256) {
    const int i = e >> 7, c = e & 127, h = c >> 5;
    const float* arow = att + (h * L + i) * L;
    const float* vp = qkv + 256 + c;
    float acc = 0.f;
#pragma unroll 4
    for (int j = 0; j < L; ++j) acc = fmaf(arow[j], vp[j * 384], acc);
    o[i * ostr + c] = acc;
  }
}

// ---------------------------------------------------------------------------
// MFMA GEMM: A = LDS bf16 [32][K] (rows >= 20 zero, XOR-swizzled),
// B = packed tiles (tile = (ntG*KTtot + kt), 64 lanes x 8 bf16 each).
// EPI: 0 = store O fp32 (+bias), 1 = accumulate O fp32 (+bias),
//      2 = relu(+bias) -> bf16 swizzled hb (stride 256).
template<int K, int KTn, int NTW, int EPI, bool HASB>
DEVI void mfma_gemm(const short* A, const short* Bp, const int ntOff, const int kt0B,
                    const int KTtot, const float* __restrict__ bias,
                    float* O, const int ostr, short* hb)
{
  const int tid  = (int)threadIdx.x;
  const int lane = tid & 63, wv = tid >> 6;
  const int r0 = lane & 15, g = lane >> 4;
  short8 a[2][KTn];
#pragma unroll
  for (int mt = 0; mt < 2; ++mt) {
    const int row = mt * 16 + r0;
#pragma unroll
    for (int kk = 0; kk < KTn; ++kk) {
      const int slot = (kk * 4 + g) ^ (row & 7);
      a[mt][kk] = *reinterpret_cast<const short8*>(A + row * K + slot * 8);
    }
  }
#pragma unroll
  for (int i = 0; i < NTW; ++i) {
    const int ntL = wv * NTW + i;
    const int ntG = ntOff + ntL;
    f32x4v c0 = {0.f, 0.f, 0.f, 0.f}, c1 = {0.f, 0.f, 0.f, 0.f};
#pragma unroll
    for (int kk = 0; kk < KTn; ++kk) {
      const short8 bfr = *reinterpret_cast<const short8*>(
          Bp + ((size_t)(ntG * KTtot + kt0B + kk) * 64 + lane) * 8);
      c0 = __builtin_amdgcn_mfma_f32_16x16x32_bf16(a[0][kk], bfr, c0, 0, 0, 0);
      c1 = __builtin_amdgcn_mfma_f32_16x16x32_bf16(a[1][kk], bfr, c1, 0, 0, 0);
    }
    const int col = ntL * 16 + r0;
    const float bb = HASB ? bias[col] : 0.f;
    const int rb = g * 4;
#pragma unroll
    for (int q = 0; q < 4; ++q) {
      const int r = rb + q;           // tile0 row (0..15, always < 20)
      const float v0 = c0[q] + bb;
      const float v1 = c1[q] + bb;
      if (EPI == 0) {
        O[r * ostr + col] = v0;
        if (16 + r < CSn) O[(16 + r) * ostr + col] = v1;
      } else if (EPI == 1) {
        O[r * ostr + col] += v0;
        if (16 + r < CSn) O[(16 + r) * ostr + col] += v1;
      } else {
        hbW256(hb, r, col, fmaxf(v0, 0.f));
        if (16 + r < CSn) hbW256(hb, 16 + r, col, fmaxf(v1, 0.f));
      }
    }
  }
}

// ---------------------------------------------------------------------------
// pack fp32 [K][N] (nmat matrices) into B-fragment bf16 tiles:
// out[((m*KN/8) + (nt*KT + kt)*64 + lane)*8 + j]
//   = bf16( W[m][kt*32 + (lane>>4)*8 + j][nt*16 + (lane&15)] )
__global__ void pack_kernel(const float* __restrict__ W, short* __restrict__ out,
                            const int K, const int N, const int total)
{
  const int p = (int)blockIdx.x * 256 + (int)threadIdx.x;
  if (p >= total) return;
  const int perMat = (K * N) >> 3;
  const int m = p / perMat, r = p - m * perMat;
  const int t = r >> 6, lane = r & 63;
  const int KT = K >> 5;
  const int nt = t / KT, kt = t - nt * KT;
  const int row0 = kt * 32 + (lane >> 4) * 8;
  const int col  = nt * 16 + (lane & 15);
  const float* src = W + (size_t)m * K * N;
  short8 v;
#pragma unroll
  for (int j = 0; j < 8; ++j) v[j] = f2bf(src[(size_t)(row0 + j) * N + col]);
  *reinterpret_cast<short8*>(out + (size_t)p * 8) = v;
}

// ---------------------------------------------------------------------------
struct BertP {
  const int* ids; const float* tok; const float* pos;
  const float* Wqkv; const float* bqkv; const float* Wo; const float* bo;
  const float* W1; const float* b1; const float* W2; const float* b2;
  const float* ln_s; const float* ln_b; const float* lnf_s; const float* lnf_b;
  float* intent;
};

__global__ __launch_bounds__(256) void bert_kernel(BertP p)
{
  __shared__ float xs[LTn * Dn];
  __shared__ float scr[LTn * 384 + Hn * LTn * LTn];
  __shared__ int   pad_s[LTn];
  const int b = blockIdx.x;
  const int tid = (int)threadIdx.x;

  for (int e = tid; e < LTn * Dn; e += 256) {
    const int i = e >> 7, c = e & 127;
    const int id = p.ids[b * LTn + i];
    xs[e] = p.tok[id * Dn + c] + p.pos[e];
  }
  for (int i = tid; i < LTn; i += 256) pad_s[i] = (p.ids[b * LTn + i] == 0) ? 1 : 0;
  __syncthreads();

  float* att = scr + LTn * 384;
  for (int l = 0; l < NLBn; ++l) {
    const float* Wqkv = p.Wqkv + l * Dn * 3 * Dn;
    const float* bqkv = p.bqkv + l * 3 * Dn;
    const float* Wo   = p.Wo   + l * Dn * Dn;
    const float* bo   = p.bo   + l * Dn;
    const float* W1   = p.W1   + l * Dn * DFFn;
    const float* b1   = p.b1   + l * DFFn;
    const float* W2   = p.W2   + l * DFFn * Dn;
    const float* b2   = p.b2   + l * Dn;

    mmwide<LTn, Dn, 3 * Dn, 0>(Wqkv, 3 * Dn, bqkv, xs, Dn, scr, 3 * Dn);
    __syncthreads();
    attn_scores<LTn, true>(scr, att, pad_s);
    __syncthreads();
    softmax_rows<LTn>(att);
    __syncthreads();
    attn_av<LTn>(scr, att, scr, 384);
    __syncthreads();
    mm128<LTn, Dn, 0, true, true>(Wo, Dn, bo, scr, 384, xs, Dn);
    __syncthreads();
    ln_rows<LTn>(xs, p.ln_s + l * 2 * Dn, p.ln_b + l * 2 * Dn, xs);
    __syncthreads();

    for (int e = tid; e < LTn * Dn; e += 256) scr[e] = xs[e];
    __syncthreads();
    float* xin  = scr;
    float* hbuf = scr + LTn * Dn;
    mmwide<LTn, Dn, 256, 1>(W1, DFFn, b1, xin, Dn, hbuf, 256);
    __syncthreads();
    mm128<LTn, 256, 0, true, true>(W2, Dn, b2, hbuf, 256, xs, Dn);
    __syncthreads();
    mmwide<LTn, Dn, 256, 1>(W1 + 256, DFFn, b1 + 256, xin, Dn, hbuf, 256);
    __syncthreads();
    mm128<LTn, 256, 0, true, false>(W2 + 256 * Dn, Dn, nullptr, hbuf, 256, xs, Dn);
    __syncthreads();
    ln_rows<LTn>(xs, p.ln_s + l * 2 * Dn + Dn, p.ln_b + l * 2 * Dn + Dn, xs);
    __syncthreads();
  }

  if (tid < 64) {
    const float a0 = xs[tid], a1 = xs[tid + 64];
    float s1 = a0 + a1, s2 = a0 * a0 + a1 * a1;
#pragma unroll
    for (int o = 32; o > 0; o >>= 1) { s1 += __shfl_xor(s1, o); s2 += __shfl_xor(s2, o); }
    const float m  = s1 * (1.f / 128.f);
    const float rs = rsqrtf(s2 * (1.f / 128.f) - m * m + 1e-5f);
    p.intent[b * Dn + tid]      = (a0 - m) * rs * p.lnf_s[tid]      + p.lnf_b[tid];
    p.intent[b * Dn + tid + 64] = (a1 - m) * rs * p.lnf_s[tid + 64] + p.lnf_b[tid + 64];
  }
}

// ---------------------------------------------------------------------------
struct RouterP {
  const float* state; const float* intent;
  const float* se_W1; const float* se_b1; const float* se_W2; const float* se_b2;
  const float* se_ln_s; const float* se_ln_b;
  const float* r_W1; const float* r_b1; const float* r_W2; const float* r_b2;
  const float* r_ln_s; const float* r_ln_b;
  const float* gate_W; const float* gate_b;
  int* ridx; float* rwgt;
};

DEVI void ln128(float* x, const float* gs, const float* gb, float* red)
{
  const int c = (int)threadIdx.x;      // blockDim == 128
  const float a = x[c];
  float s1 = a, s2 = a * a;
#pragma unroll
  for (int o = 32; o > 0; o >>= 1) { s1 += __shfl_xor(s1, o); s2 += __shfl_xor(s2, o); }
  const int wid = c >> 6;
  if ((c & 63) == 0) { red[wid * 2] = s1; red[wid * 2 + 1] = s2; }
  __syncthreads();
  s1 = red[0] + red[2]; s2 = red[1] + red[3];
  const float m  = s1 * (1.f / 128.f);
  const float rs = rsqrtf(s2 * (1.f / 128.f) - m * m + 1e-5f);
  __syncthreads();
  x[c] = (a - m) * rs * gs[c] + gb[c];
}

__global__ __launch_bounds__(128) void router_kernel(RouterP p)
{
  __shared__ float sstate[SDn];
  __shared__ float h1[Dn];
  __shared__ float vv[Dn];
  __shared__ float red[4];
  __shared__ float slog[En];
  const int b = blockIdx.x;
  const int c = (int)threadIdx.x;

  if (c < SDn) sstate[c] = p.state[b * SDn + c];
  __syncthreads();
  {
    float acc = p.se_b1[c];
#pragma unroll
    for (int k = 0; k < SDn; ++k) acc = fmaf(sstate[k], p.se_W1[k * Dn + c], acc);
    h1[c] = geluf(acc);
  }
  __syncthreads();
  {
    float acc = p.se_b2[c];
#pragma unroll 4
    for (int k = 0; k < Dn; ++k) acc = fmaf(h1[k], p.se_W2[k * Dn + c], acc);
    vv[c] = acc;
  }
  __syncthreads();
  ln128(vv, p.se_ln_s, p.se_ln_b, red);
  __syncthreads();
  {
    float acc = p.r_b1[c];
    const float* ib = p.intent + b * Dn;
#pragma unroll 4
    for (int k = 0; k < Dn; ++k) acc = fmaf(ib[k], p.r_W1[k * Dn + c], acc);
#pragma unroll 4
    for (int k = 0; k < Dn; ++k) acc = fmaf(vv[k], p.r_W1[(Dn + k) * Dn + c], acc);
    h1[c] = geluf(acc);
  }
  __syncthreads();
  {
    float acc = p.r_b2[c];
#pragma unroll 4
    for (int k = 0; k < Dn; ++k) acc = fmaf(h1[k], p.r_W2[k * Dn + c], acc);
    vv[c] = acc;
  }
  __syncthreads();
  ln128(vv, p.r_ln_s, p.r_ln_b, red);
  __syncthreads();
  if (c < En) {
    float acc = p.gate_b[c];
#pragma unroll 4
    for (int k = 0; k < Dn; ++k) acc = fmaf(vv[k], p.gate_W[k * En + c], acc);
    slog[c] = acc;
  }
  __syncthreads();
  if (c == 0) {
    int i0 = 0; float v0 = slog[0];
#pragma unroll
    for (int e2 = 1; e2 < En; ++e2) if (slog[e2] > v0) { v0 = slog[e2]; i0 = e2; }
    int i1 = -1; float v1 = -3.4e38f;
#pragma unroll
    for (int e2 = 0; e2 < En; ++e2) if (e2 != i0 && slog[e2] > v1) { v1 = slog[e2]; i1 = e2; }
    const float e1  = expf(v1 - v0);
    const float inv = 1.f / (1.f + e1);
    p.ridx[b * 2 + 0] = i0; p.ridx[b * 2 + 1] = i1;
    p.rwgt[b * 2 + 0] = inv; p.rwgt[b * 2 + 1] = e1 * inv;
  }
}

// ---------------------------------------------------------------------------
// MFMA expert kernel
struct ExpertMP {
  const float* state; const float* qpe; const int* ridx; const float* rwgt;
  const float* sp_W; const float* sp_b; const float* zp_b;
  const float* aW;   // fp32 cross-attn weights (for the 2-row kv projection)
  const float* ab; const float* abo;
  const float* ln_s; const float* ln_b;
  const float* fb1; const float* fb2;
  const float* headW; const float* headB;
  const short* pQ; const short* pO; const short* pF1; const short* pF2;
  float* out;
};

__global__ __launch_bounds__(256, 3) void expert_mfma_kernel(ExpertMP p)
{
  __shared__ float xs[CSn * Dn];                 // 2560 f : residual stream
  __shared__ __align__(16) short xb[32 * 128];   // 4096 sh: bf16 A-tile (att aliases)
  __shared__ float scr[CSn * 384];               // 7680 f : qkv / q+catt / hb(bf16)
  __shared__ float mem[2 * Dn];
  __shared__ float memkv[2 * 256];
  __shared__ float outacc[CSn * JDn];
  const int b = blockIdx.x;
  const int tid = (int)threadIdx.x;

  for (int e = tid; e < CSn * JDn; e += 256) outacc[e] = 0.f;
  for (int e = tid; e < 12 * 128; e += 256) xb[CSn * 128 + e] = 0;  // zero pad rows 20..31

  for (int slot = 0; slot < 2; ++slot) {
    const int   ex  = p.ridx[b * 2 + slot];
    const float wgt = p.rwgt[b * 2 + slot];

    if (tid < Dn) {
      float acc = p.sp_b[ex * Dn + tid];
      const float* spw = p.sp_W + ex * SDn * Dn;
#pragma unroll
      for (int k = 0; k < SDn; ++k) acc = fmaf(p.state[b * SDn + k], spw[k * Dn + tid], acc);
      mem[tid] = acc;
    } else {
      mem[Dn + (tid - Dn)] = p.zp_b[ex * Dn + (tid - Dn)];
    }
    for (int e = tid; e < CSn * Dn; e += 256) xs[e] = p.qpe[e];
    __syncthreads();

    for (int l = 0; l < NLDn; ++l) {
      const int li = ex * NLDn + l;
      const short* wq0 = p.pQ + (size_t)(li * 2 + 0) * 49152;
      const short* wq1 = p.pQ + (size_t)(li * 2 + 1) * 49152;
      const short* wo0 = p.pO + (size_t)(li * 2 + 0) * 16384;
      const short* wo1 = p.pO + (size_t)(li * 2 + 1) * 16384;
      const short* w1p = p.pF1 + (size_t)li * 65536;
      const short* w2p = p.pF2 + (size_t)li * 65536;
      const float* ab0 = p.ab  + (size_t)(li * 2 + 0) * 384;
      const float* ab1 = p.ab  + (size_t)(li * 2 + 1) * 384;
      const float* bo0 = p.abo + (li * 2 + 0) * Dn;
      const float* bo1 = p.abo + (li * 2 + 1) * Dn;
      const float* lns = p.ln_s + li * 3 * Dn;
      const float* lnb = p.ln_b + li * 3 * Dn;
      const float* fb1 = p.fb1 + li * DFFn;
      const float* fb2 = p.fb2 + li * Dn;
      const float* aW1f = p.aW + (size_t)(li * 2 + 1) * Dn * 384;

      // ---- self-attention (norm_first)
      ln_rows_bf(xs, lns, lnb, xb);
      __syncthreads();
      mfma_gemm<128, 4, 6, 0, true>(xb, wq0, 0, 0, 4, ab0, scr, 384, nullptr);
      __syncthreads();
      attn_scores<CSn, false>(scr, (float*)xb, nullptr);
      __syncthreads();
      softmax_rows<CSn>((float*)xb);
      __syncthreads();
      attn_av<CSn>(scr, (float*)xb, scr, 384);   // o -> q slots of scr
      __syncthreads();
      for (int e = tid; e < CSn * Dn; e += 256) {  // o -> bf16 swizzled xb
        const int i = e >> 7, c = e & 127;
        xbW128(xb, i, c, scr[i * 384 + c]);
      }
      for (int e = tid; e < 12 * 128; e += 256) xb[CSn * 128 + e] = 0;  // re-zero pads (att garbage)
      __syncthreads();
      mfma_gemm<128, 4, 2, 1, true>(xb, wo0, 0, 0, 4, bo0, xs, 128, nullptr);
      __syncthreads();

      // ---- cross-attention (2 keys)
      ln_rows_bf(xs, lns + Dn, lnb + Dn, xb);
      __syncthreads();
      mfma_gemm<128, 4, 2, 0, true>(xb, wq1, 0, 0, 4, ab1, scr, 128, nullptr);  // q
      for (int e = tid; e < 2 * 256; e += 256) {   // k,v of mem (VALU, fp32 weights)
        const int j = e >> 8, c2 = e & 255;
        float acc = ab1[Dn + c2];
        const float* wp = aW1f + Dn + c2;
#pragma unroll 4
        for (int k = 0; k < Dn; ++k) acc = fmaf(mem[j * Dn + k], wp[k * 384], acc);
        memkv[j * 256 + c2] = acc;
      }
      __syncthreads();
      float* catt = scr + CSn * Dn;
      for (int e = tid; e < Hn * CSn; e += 256) {
        const int h = e / CSn, i = e % CSn;
        const float* qp = scr + i * Dn + h * DHn;
        float s0 = 0.f, s1 = 0.f;
#pragma unroll
        for (int d = 0; d < DHn; d += 4) {
          const float4 q4 = *reinterpret_cast<const float4*>(qp + d);
          const float4 k0 = *reinterpret_cast<const float4*>(memkv + 0 * 256 + h * DHn + d);
          const float4 k1 = *reinterpret_cast<const float4*>(memkv + 1 * 256 + h * DHn + d);
          s0 += q4.x * k0.x + q4.y * k0.y + q4.z * k0.z + q4.w * k0.w;
          s1 += q4.x * k1.x + q4.y * k1.y + q4.z * k1.z + q4.w * k1.w;
        }
        s0 *= INV_SQRT_DH; s1 *= INV_SQRT_DH;
        const float m = fmaxf(s0, s1);
        const float e0 = expf(s0 - m), e1 = expf(s1 - m);
        const float inv = 1.f / (e0 + e1);
        catt[e * 2] = e0 * inv; catt[e * 2 + 1] = e1 * inv;
      }
      __syncthreads();
      for (int e = tid; e < CSn * Dn; e += 256) {
        const int i = e >> 7, c = e & 127, h = c >> 5;
        const int a = (h * CSn + i) * 2;
        const float v = catt[a]     * memkv[0 * 256 + Dn + c]
                      + catt[a + 1] * memkv[1 * 256 + Dn + c];
        xbW128(xb, i, c, v);
      }
      __syncthreads();
      mfma_gemm<128, 4, 2, 1, true>(xb, wo1, 0, 0, 4, bo1, xs, 128, nullptr);
      __syncthreads();

      // ---- FFN (relu), two 256-col halves through bf16 hb
      ln_rows_bf(xs, lns + 2 * Dn, lnb + 2 * Dn, xb);
      short* hb = (short*)scr;                    // [32][256] bf16 swizzled
      for (int e = tid; e < 12 * 256; e += 256) hb[CSn * 256 + e] = 0;  // pad rows
      __syncthreads();
      mfma_gemm<128, 4, 4, 2, true>(xb, w1p, 0, 0, 4, fb1, nullptr, 0, hb);
      __syncthreads();
      mfma_gemm<256, 8, 2, 1, true>(hb, w2p, 0, 0, 16, fb2, xs, 128, nullptr);
      __syncthreads();
      mfma_gemm<128, 4, 4, 2, true>(xb, w1p, 16, 0, 4, fb1 + 256, nullptr, 0, hb);
      __syncthreads();
      mfma_gemm<256, 8, 2, 1, false>(hb, w2p, 0, 8, 16, nullptr, xs, 128, nullptr);
      __syncthreads();
    }

    // head + weighted accumulate
    const float* hw = p.headW + ex * Dn * JDn;
    for (int e = tid; e < CSn * JDn; e += 256) {
      const int t = e / JDn, j = e % JDn;
      float acc = p.headB[ex * JDn + j];
#pragma unroll 4
      for (int k = 0; k < Dn; ++k) acc = fmaf(xs[t * Dn + k], hw[k * JDn + j], acc);
      outacc[e] = fmaf(wgt, acc, outacc[e]);
    }
    __syncthreads();
  }

  for (int e = tid; e < CSn * JDn; e += 256) p.out[b * CSn * JDn + e] = outacc[e];
}

// ---------------------------------------------------------------------------
// fp32 fallback expert kernel (used only if ws_size can't hold packed weights)
struct ExpertP {
  const float* state; const float* qpe; const int* ridx; const float* rwgt;
  const float* sp_W; const float* sp_b; const float* zp_b;
  const float* aW; const float* ab; const float* aWo; const float* abo;
  const float* ln_s; const float* ln_b;
  const float* fW1; const float* fb1; const float* fW2; const float* fb2;
  const float* hW; const float* hb;
  float* out;
};

__global__ __launch_bounds__(256) void expert_kernel(ExpertP p)
{
  __shared__ float xs[CSn * Dn];
  __shared__ float xn[CSn * Dn];
  __shared__ float scr[CSn * 384 + Hn * CSn * CSn];
  __shared__ float mem[2 * Dn];
  __shared__ float memkv[2 * 256];
  __shared__ float outacc[CSn * JDn];
  const int b = blockIdx.x;
  const int tid = (int)threadIdx.x;

  for (int e = tid; e < CSn * JDn; e += 256) outacc[e] = 0.f;

  for (int slot = 0; slot < 2; ++slot) {
    const int   ex  = p.ridx[b * 2 + slot];
    const float wgt = p.rwgt[b * 2 + slot];

    if (tid < Dn) {
      float acc = p.sp_b[ex * Dn + tid];
      const float* spw = p.sp_W + ex * SDn * Dn;
#pragma unroll
      for (int k = 0; k < SDn; ++k) acc = fmaf(p.state[b * SDn + k], spw[k * Dn + tid], acc);
      mem[tid] = acc;
    } else {
      mem[Dn + (tid - Dn)] = p.zp_b[ex * Dn + (tid - Dn)];
    }
    for (int e = tid; e < CSn * Dn; e += 256) xs[e] = p.qpe[e];
    __syncthreads();

    for (int l = 0; l < NLDn; ++l) {
      const int li = ex * NLDn + l;
      const float* aW0 = p.aW  + (size_t)(li * 2 + 0) * Dn * 3 * Dn;
      const float* ab0 = p.ab  + (li * 2 + 0) * 3 * Dn;
      const float* aW1 = p.aW  + (size_t)(li * 2 + 1) * Dn * 3 * Dn;
      const float* ab1 = p.ab  + (li * 2 + 1) * 3 * Dn;
      const float* Wo0 = p.aWo + (size_t)(li * 2 + 0) * Dn * Dn;
      const float* bo0 = p.abo + (li * 2 + 0) * Dn;
      const float* Wo1 = p.aWo + (size_t)(li * 2 + 1) * Dn * Dn;
      const float* bo1 = p.abo + (li * 2 + 1) * Dn;
      const float* lns = p.ln_s + li * 3 * Dn;
      const float* lnb = p.ln_b + li * 3 * Dn;
      const float* fW1 = p.fW1 + (size_t)li * Dn * DFFn;
      const float* fb1 = p.fb1 + li * DFFn;
      const float* fW2 = p.fW2 + (size_t)li * DFFn * Dn;
      const float* fb2 = p.fb2 + li * Dn;

      ln_rows<CSn>(xs, lns + 0 * Dn, lnb + 0 * Dn, xn);
      __syncthreads();
      mmwide<CSn, Dn, 3 * Dn, 0>(aW0, 3 * Dn, ab0, xn, Dn, scr, 3 * Dn);
      __syncthreads();
      float* att = scr + CSn * 384;
      attn_scores<CSn, false>(scr, att, nullptr);
      __syncthreads();
      softmax_rows<CSn>(att);
      __syncthreads();
      attn_av<CSn>(scr, att, xn, Dn);
      __syncthreads();
      mm128<CSn, Dn, 0, true, true>(Wo0, Dn, bo0, xn, Dn, xs, Dn);
      __syncthreads();

      ln_rows<CSn>(xs, lns + 1 * Dn, lnb + 1 * Dn, xn);
      __syncthreads();
      mm128<CSn, Dn, 0, false, true>(aW1, 3 * Dn, ab1, xn, Dn, scr, Dn);
      for (int e = tid; e < 2 * 256; e += 256) {
        const int j = e >> 8, c2 = e & 255;
        float acc = ab1[Dn + c2];
        const float* wp = aW1 + Dn + c2;
#pragma unroll 4
        for (int k = 0; k < Dn; ++k) acc = fmaf(mem[j * Dn + k], wp[k * 3 * Dn], acc);
        memkv[j * 256 + c2] = acc;
      }
      __syncthreads();
      float* catt = scr + CSn * Dn;
      for (int e = tid; e < Hn * CSn; e += 256) {
        const int h = e / CSn, i = e % CSn;
        const float* qp = scr + i * Dn + h * DHn;
        float s0 = 0.f, s1 = 0.f;
#pragma unroll
        for (int d = 0; d < DHn; d += 4) {
          const float4 q4 = *reinterpret_cast<const float4*>(qp + d);
          const float4 k0 = *reinterpret_cast<const float4*>(memkv + 0 * 256 + h * DHn + d);
          const float4 k1 = *reinterpret_cast<const float4*>(memkv + 1 * 256 + h * DHn + d);
          s0 += q4.x * k0.x + q4.y * k0.y + q4.z * k0.z + q4.w * k0.w;
          s1 += q4.x * k1.x + q4.y * k1.y + q4.z * k1.z + q4.w * k1.w;
        }
        s0 *= INV_SQRT_DH; s1 *= INV_SQRT_DH;
        const float m = fmaxf(s0, s1);
        const float e0 = expf(s0 - m), e1 = expf(s1 - m);
        const float inv = 1.f / (e0 + e1);
        catt[e * 2] = e0 * inv; catt[e * 2 + 1] = e1 * inv;
      }
      __syncthreads();
      for (int e = tid; e < CSn * Dn; e += 256) {
        const int i = e >> 7, c = e & 127, h = c >> 5;
        const int a = (h * CSn + i) * 2;
        xn[e] = catt[a] * memkv[0 * 256 + Dn + c] + catt[a + 1] * memkv[1 * 256 + Dn + c];
      }
      __syncthreads();
      mm128<CSn, Dn, 0, true, true>(Wo1, Dn, bo1, xn, Dn, xs, Dn);
      __syncthreads();

      ln_rows<CSn>(xs, lns + 2 * Dn, lnb + 2 * Dn, xn);
      __syncthreads();
      mmwide<CSn, Dn, 256, 2>(fW1, DFFn, fb1, xn, Dn, scr, 256);
      __syncthreads();
      mm128<CSn, 256, 0, true, true>(fW2, Dn, fb2, scr, 256, xs, Dn);
      __syncthreads();
      mmwide<CSn, Dn, 256, 2>(fW1 + 256, DFFn, fb1 + 256, xn, Dn, scr, 256);
      __syncthreads();
      mm128<CSn, 256, 0, true, false>(fW2 + 256 * Dn, Dn, nullptr, scr, 256, xs, Dn);
      __syncthreads();
    }

    const float* hw = p.hW + ex * Dn * JDn;
    for (int e = tid; e < CSn * JDn; e += 256) {
      const int t = e / JDn, j = e % JDn;
      float acc = p.hb[ex * JDn + j];
#pragma unroll 4
      for (int k = 0; k < Dn; ++k) acc = fmaf(xs[t * Dn + k], hw[k * JDn + j], acc);
      outacc[e] = fmaf(wgt, acc, outacc[e]);
    }
    __syncthreads();
  }

  for (int e = tid; e < CSn * JDn; e += 256) p.out[b * CSn * JDn + e] = outacc[e];
}

// ---------------------------------------------------------------------------
__global__ void qpe_kernel(float* qpe)
{
  const int e = (int)blockIdx.x * 256 + (int)threadIdx.x;
  if (e < CSn * Dn) {
    const int t = e >> 7, d = e & 127;
    const float j  = (float)(d & ~1);
    const float dv = expf(j * (-logf(10000.f) / 128.f));
    const float a  = (float)t * dv;
    qpe[e] = (d & 1) ? cosf(a) : sinf(a);
  }
}

} // namespace

// ---------------------------------------------------------------------------
extern "C" void kernel_launch(void* const* d_in, const int* in_sizes, int n_in,
                              void* d_out, int out_size, void* d_ws, size_t ws_size,
                              hipStream_t stream)
{
  (void)in_sizes; (void)n_in; (void)out_size;

  const int*   ids     = (const int*)  d_in[0];
  const float* state   = (const float*)d_in[1];
  const float* tok_emb = (const float*)d_in[2];
  const float* pos_emb = (const float*)d_in[3];

  // workspace layout
  float* qpe    = (float*)d_ws;                  // 4096 f
  float* intent = qpe + 4096;                    // 262144 f
  int*   ridx   = (int*)(intent + 262144);       // 4096 i
  float* rwgt   = (float*)(ridx + 4096);         // 4096 f
  short* pQ     = (short*)(rwgt + 4096);         // 36*49152 sh
  short* pO     = pQ  + (size_t)36 * 49152;      // 36*16384 sh
  short* pF1    = pO  + (size_t)36 * 16384;      // 18*65536 sh
  short* pF2    = pF1 + (size_t)18 * 65536;      // 18*65536 sh
  const size_t NEEDED = (size_t)((char*)(pF2 + (size_t)18 * 65536) - (char*)d_ws);
  const bool use_mfma = (ws_size >= NEEDED);

  qpe_kernel<<<dim3(10), dim3(256), 0, stream>>>(qpe);

  if (use_mfma) {
    // pack expert weights to bf16 B-fragment tiles
    {
      const int tq = 36 * 6144;
      pack_kernel<<<dim3((tq + 255) / 256), dim3(256), 0, stream>>>(
          (const float*)d_in[34], pQ, 128, 384, tq);
      const int to = 36 * 2048;
      pack_kernel<<<dim3((to + 255) / 256), dim3(256), 0, stream>>>(
          (const float*)d_in[36], pO, 128, 128, to);
      const int t1 = 18 * 8192;
      pack_kernel<<<dim3((t1 + 255) / 256), dim3(256), 0, stream>>>(
          (const float*)d_in[40], pF1, 128, 512, t1);
      const int t2 = 18 * 8192;
      pack_kernel<<<dim3((t2 + 255) / 256), dim3(256), 0, stream>>>(
          (const float*)d_in[42], pF2, 512, 128, t2);
    }
  }

  BertP bp;
  bp.ids  = ids; bp.tok = tok_emb; bp.pos = pos_emb;
  bp.Wqkv = (const float*)d_in[4];  bp.bqkv = (const float*)d_in[5];
  bp.Wo   = (const float*)d_in[6];  bp.bo   = (const float*)d_in[7];
  bp.W1   = (const float*)d_in[8];  bp.b1   = (const float*)d_in[9];
  bp.W2   = (const float*)d_in[10]; bp.b2   = (const float*)d_in[11];
  bp.ln_s = (const float*)d_in[12]; bp.ln_b = (const float*)d_in[13];
  bp.lnf_s= (const float*)d_in[14]; bp.lnf_b= (const float*)d_in[15];
  bp.intent = intent;
  bert_kernel<<<dim3(Bn), dim3(256), 0, stream>>>(bp);

  RouterP rp;
  rp.state = state; rp.intent = intent;
  rp.se_W1 = (const float*)d_in[16]; rp.se_b1 = (const float*)d_in[17];
  rp.se_W2 = (const float*)d_in[18]; rp.se_b2 = (const float*)d_in[19];
  rp.se_ln_s = (const float*)d_in[20]; rp.se_ln_b = (const float*)d_in[21];
  rp.r_W1 = (const float*)d_in[22]; rp.r_b1 = (const float*)d_in[23];
  rp.r_W2 = (const float*)d_in[24]; rp.r_b2 = (const float*)d_in[25];
  rp.r_ln_s = (const float*)d_in[26]; rp.r_ln_b = (const float*)d_in[27];
  rp.gate_W = (const float*)d_in[28]; rp.gate_b = (const float*)d_in[29];
  rp.ridx = ridx; rp.rwgt = rwgt;
  router_kernel<<<dim3(Bn), dim3(128), 0, stream>>>(rp);

  if (use_mfma) {
    ExpertMP ep;
    ep.state = state; ep.qpe = qpe; ep.ridx = ridx; ep.rwgt = rwgt;
    ep.sp_W = (const float*)d_in[30]; ep.sp_b = (const float*)d_in[31];
    ep.zp_b = (const float*)d_in[33];
    ep.aW   = (const float*)d_in[34]; ep.ab = (const float*)d_in[35];
    ep.abo  = (const float*)d_in[37];
    ep.ln_s = (const float*)d_in[38]; ep.ln_b = (const float*)d_in[39];
    ep.fb1  = (const float*)d_in[41]; ep.fb2 = (const float*)d_in[43];
    ep.headW= (const float*)d_in[44]; ep.headB = (const float*)d_in[45];
    ep.pQ = pQ; ep.pO = pO; ep.pF1 = pF1; ep.pF2 = pF2;
    ep.out  = (float*)d_out;
    expert_mfma_kernel<<<dim3(Bn), dim3(256), 0, stream>>>(ep);
  } else {
    ExpertP ep;
    ep.state = state; ep.qpe = qpe; ep.ridx = ridx; ep.rwgt = rwgt;
    ep.sp_W = (const float*)d_in[30]; ep.sp_b = (const float*)d_in[31];
    ep.zp_b = (const float*)d_in[33];
    ep.aW   = (const float*)d_in[34]; ep.ab   = (const float*)d_in[35];
    ep.aWo  = (const float*)d_in[36]; ep.abo  = (const float*)d_in[37];
    ep.ln_s = (const float*)d_in[38]; ep.ln_b = (const float*)d_in[39];
    ep.fW1  = (const float*)d_in[40]; ep.fb1  = (const float*)d_in[41];
    ep.fW2  = (const float*)d_in[42]; ep.fb2  = (const float*)d_in[43];
    ep.hW   = (const float*)d_in[44]; ep.hb   = (const float*)d_in[45];
    ep.out  = (float*)d_out;
    expert_kernel<<<dim3(Bn), dim3(256), 0, stream>>>(ep);
  }
}

// Round 3
// 3102.554 us; speedup vs baseline: 2.2514x; 1.6003x over previous
//
#include <hip/hip_runtime.h>
#include <math.h>

#define DEVI __device__ __forceinline__

namespace {

constexpr int Bn   = 2048;
constexpr int En   = 6;
constexpr int Hn   = 4;
constexpr int Dn   = 128;
constexpr int DHn  = 32;
constexpr int LTn  = 24;   // text length
constexpr int CSn  = 20;   // chunk (decoder query) length
constexpr int JDn  = 7;
constexpr int SDn  = 16;
constexpr int NLBn = 4;
constexpr int NLDn = 3;
constexpr int DFFn = 512;
constexpr int QSTR = 388;  // qkv LDS row stride (388 mod 32 = 4 -> no 32-way bank conflicts)
constexpr float INV_SQRT_DH = 0.17677669529663687f;  // 1/sqrt(32)

typedef float f32x4v __attribute__((ext_vector_type(4)));
typedef short short8 __attribute__((ext_vector_type(8)));

DEVI float geluf(float x) { return 0.5f * x * (1.0f + erff(x * 0.70710678118654752f)); }

DEVI short f2bf(float f) {  // fp32 -> bf16 bits, round-to-nearest-even
  unsigned u = __float_as_uint(f);
  return (short)((u + 0x7FFFu + ((u >> 16) & 1u)) >> 16);
}
DEVI float bf2f(short s) { return __uint_as_float(((unsigned)(unsigned short)s) << 16); }
DEVI void split2(float v, short& h, short& l) {  // v ~= hi + lo to ~2^-16 rel
  h = f2bf(v);
  l = f2bf(v - bf2f(h));
}

// swizzled bf16 writes: row-stride-K LDS tile, 16B slot XORed with row&7
DEVI void xbW128(short* xb, int r, int c, float v) {
  xb[r * 128 + ((((c >> 3) ^ (r & 7)) << 3) | (c & 7))] = f2bf(v);
}
DEVI int swz128(int r, int c) { return r * 128 + ((((c >> 3) ^ (r & 7)) << 3) | (c & 7)); }
DEVI int swz256(int r, int c) { return r * 256 + ((((c >> 3) ^ (r & 7)) << 3) | (c & 7)); }
DEVI void hbW256(short* hb, int r, int c, float v) { hb[swz256(r, c)] = f2bf(v); }

// ---------------------------------------------------------------------------
// fp32 column-per-thread matmuls (router / fallback kernels)
template<int R, int KD, int N, int OP>  // OP: 0 none, 1 gelu, 2 relu
DEVI void mmwide(const float* __restrict__ W, const int wstr,
                 const float* __restrict__ bias,
                 const float* X, const int xstr,
                 float* O, const int ostr)
{
#pragma unroll
  for (int c0 = 0; c0 < N; c0 += 256) {
    const int c = c0 + (int)threadIdx.x;
    if ((N % 256 == 0) || (c < N)) {
      float acc[R];
#pragma unroll
      for (int r = 0; r < R; ++r) acc[r] = 0.f;
#pragma unroll 2
      for (int k = 0; k < KD; k += 4) {
        const float w0 = W[(k + 0) * wstr + c];
        const float w1 = W[(k + 1) * wstr + c];
        const float w2 = W[(k + 2) * wstr + c];
        const float w3 = W[(k + 3) * wstr + c];
#pragma unroll
        for (int r = 0; r < R; ++r) {
          const float4 xv = *reinterpret_cast<const float4*>(X + r * xstr + k);
          acc[r] = fmaf(xv.x, w0, acc[r]);
          acc[r] = fmaf(xv.y, w1, acc[r]);
          acc[r] = fmaf(xv.z, w2, acc[r]);
          acc[r] = fmaf(xv.w, w3, acc[r]);
        }
      }
      const float bb = bias[c];
#pragma unroll
      for (int r = 0; r < R; ++r) {
        float v = acc[r] + bb;
        if (OP == 1) v = geluf(v);
        else if (OP == 2) v = fmaxf(v, 0.f);
        O[r * ostr + c] = v;
      }
    }
  }
}

template<int R, int KD, int OP, bool ACC, bool HASB>
DEVI void mm128(const float* __restrict__ W, const int wstr,
                const float* __restrict__ bias,
                const float* X, const int xstr,
                float* O, const int ostr)
{
  static_assert(R % 2 == 0, "R must be even");
  constexpr int RH = R / 2;
  const int g = (int)threadIdx.x >> 7;
  const int c = (int)threadIdx.x & 127;
  const float* Xg = X + g * RH * xstr;
  float acc[RH];
#pragma unroll
  for (int r = 0; r < RH; ++r) acc[r] = 0.f;
#pragma unroll 2
  for (int k = 0; k < KD; k += 4) {
    const float w0 = W[(k + 0) * wstr + c];
    const float w1 = W[(k + 1) * wstr + c];
    const float w2 = W[(k + 2) * wstr + c];
    const float w3 = W[(k + 3) * wstr + c];
#pragma unroll
    for (int r = 0; r < RH; ++r) {
      const float4 xv = *reinterpret_cast<const float4*>(Xg + r * xstr + k);
      acc[r] = fmaf(xv.x, w0, acc[r]);
      acc[r] = fmaf(xv.y, w1, acc[r]);
      acc[r] = fmaf(xv.z, w2, acc[r]);
      acc[r] = fmaf(xv.w, w3, acc[r]);
    }
  }
  const float bb = HASB ? bias[c] : 0.f;
  float* Og = O + g * RH * ostr;
#pragma unroll
  for (int r = 0; r < RH; ++r) {
    float v = acc[r] + bb;
    if (OP == 1) v = geluf(v);
    else if (OP == 2) v = fmaxf(v, 0.f);
    if (ACC) Og[r * ostr + c] += v;
    else     Og[r * ostr + c] = v;
  }
}

// LayerNorm over 128 cols, one wave per row (blockDim must be 256).
template<int R>
DEVI void ln_rows(float* X, const float* gs, const float* gb, float* O)
{
  const int wid  = (int)threadIdx.x >> 6;
  const int lane = (int)threadIdx.x & 63;
  for (int r = wid; r < R; r += 4) {
    const float a0 = X[r * 128 + lane];
    const float a1 = X[r * 128 + lane + 64];
    float s1 = a0 + a1, s2 = a0 * a0 + a1 * a1;
#pragma unroll
    for (int o = 32; o > 0; o >>= 1) { s1 += __shfl_xor(s1, o); s2 += __shfl_xor(s2, o); }
    const float m  = s1 * (1.f / 128.f);
    const float rs = rsqrtf(s2 * (1.f / 128.f) - m * m + 1e-5f);
    O[r * 128 + lane]      = (a0 - m) * rs * gs[lane]      + gb[lane];
    O[r * 128 + lane + 64] = (a1 - m) * rs * gs[lane + 64] + gb[lane + 64];
  }
}

// LayerNorm xs -> bf16 swizzled xb (rows 0..CSn-1 only) — expert kernel
DEVI void ln_rows_bf(const float* X, const float* gs, const float* gb, short* xb)
{
  const int wid  = (int)threadIdx.x >> 6;
  const int lane = (int)threadIdx.x & 63;
  for (int r = wid; r < CSn; r += 4) {
    const float a0 = X[r * 128 + lane];
    const float a1 = X[r * 128 + lane + 64];
    float s1 = a0 + a1, s2 = a0 * a0 + a1 * a1;
#pragma unroll
    for (int o = 32; o > 0; o >>= 1) { s1 += __shfl_xor(s1, o); s2 += __shfl_xor(s2, o); }
    const float m  = s1 * (1.f / 128.f);
    const float rs = rsqrtf(s2 * (1.f / 128.f) - m * m + 1e-5f);
    xbW128(xb, r, lane,      (a0 - m) * rs * gs[lane]      + gb[lane]);
    xbW128(xb, r, lane + 64, (a1 - m) * rs * gs[lane + 64] + gb[lane + 64]);
  }
}

// scores: att[h*L*L + i*L + j] = (q_i . k_j) / sqrt(32), optional key-pad mask.
template<int L, int STR, bool MASK>
DEVI void attn_scores(const float* qkv, float* att, const int* pad)
{
  for (int e = (int)threadIdx.x; e < Hn * L * L; e += 256) {
    const int h = e / (L * L);
    const int rem = e % (L * L);
    const int i = rem / L, j = rem % L;
    const float* qp = qkv + i * STR + h * DHn;
    const float* kp = qkv + j * STR + 128 + h * DHn;
    float acc = 0.f;
#pragma unroll
    for (int d = 0; d < DHn; d += 4) {
      const float4 qa = *reinterpret_cast<const float4*>(qp + d);
      const float4 kb = *reinterpret_cast<const float4*>(kp + d);
      acc += qa.x * kb.x + qa.y * kb.y + qa.z * kb.z + qa.w * kb.w;
    }
    acc *= INV_SQRT_DH;
    if (MASK && pad[j]) acc = -1e9f;
    att[e] = acc;
  }
}

template<int L>
DEVI void softmax_rows(float* att)
{
  for (int r = (int)threadIdx.x; r < Hn * L; r += 256) {
    float* row = att + r * L;
    float m = row[0];
#pragma unroll 4
    for (int j = 1; j < L; ++j) m = fmaxf(m, row[j]);
    float s = 0.f;
#pragma unroll 4
    for (int j = 0; j < L; ++j) { const float ex = expf(row[j] - m); row[j] = ex; s += ex; }
    const float inv = 1.f / s;
#pragma unroll 4
    for (int j = 0; j < L; ++j) row[j] *= inv;
  }
}

template<int L, int STR>
DEVI void attn_av(const float* qkv, const float* att, float* o, const int ostr)
{
  for (int e = (int)threadIdx.x; e < L * Dn; e += 256) {
    const int i = e >> 7, c = e & 127, h = c >> 5;
    const float* arow = att + (h * L + i) * L;
    const float* vp = qkv + 256 + c;
    float acc = 0.f;
#pragma unroll 4
    for (int j = 0; j < L; ++j) acc = fmaf(arow[j], vp[j * STR], acc);
    o[i * ostr + c] = acc;
  }
}

// ---------------------------------------------------------------------------
// single-bf16 MFMA GEMM (expert kernel). B tiles: 512 shorts each.
template<int K, int KTn, int NTW, int EPI, bool HASB>
DEVI void mfma_gemm(const short* A, const short* Bp, const int ntOff, const int kt0B,
                    const int KTtot, const float* __restrict__ bias,
                    float* O, const int ostr, short* hb)
{
  const int tid  = (int)threadIdx.x;
  const int lane = tid & 63, wv = tid >> 6;
  const int r0 = lane & 15, g = lane >> 4;
  short8 a[2][KTn];
#pragma unroll
  for (int mt = 0; mt < 2; ++mt) {
    const int row = mt * 16 + r0;
#pragma unroll
    for (int kk = 0; kk < KTn; ++kk) {
      const int slot = (kk * 4 + g) ^ (row & 7);
      a[mt][kk] = *reinterpret_cast<const short8*>(A + row * K + slot * 8);
    }
  }
#pragma unroll
  for (int i = 0; i < NTW; ++i) {
    const int ntL = wv * NTW + i;
    const int ntG = ntOff + ntL;
    f32x4v c0 = {0.f, 0.f, 0.f, 0.f}, c1 = {0.f, 0.f, 0.f, 0.f};
#pragma unroll
    for (int kk = 0; kk < KTn; ++kk) {
      const short8 bfr = *reinterpret_cast<const short8*>(
          Bp + ((size_t)(ntG * KTtot + kt0B + kk) * 64 + lane) * 8);
      c0 = __builtin_amdgcn_mfma_f32_16x16x32_bf16(a[0][kk], bfr, c0, 0, 0, 0);
      c1 = __builtin_amdgcn_mfma_f32_16x16x32_bf16(a[1][kk], bfr, c1, 0, 0, 0);
    }
    const int col = ntL * 16 + r0;
    const float bb = HASB ? bias[col] : 0.f;
    const int rb = g * 4;
#pragma unroll
    for (int q = 0; q < 4; ++q) {
      const int r = rb + q;
      const float v0 = c0[q] + bb;
      const float v1 = c1[q] + bb;
      if (EPI == 0) {
        O[r * ostr + col] = v0;
        if (16 + r < CSn) O[(16 + r) * ostr + col] = v1;
      } else if (EPI == 1) {
        O[r * ostr + col] += v0;
        if (16 + r < CSn) O[(16 + r) * ostr + col] += v1;
      } else {
        hbW256(hb, r, col, fmaxf(v0, 0.f));
        if (16 + r < CSn) hbW256(hb, 16 + r, col, fmaxf(v1, 0.f));
      }
    }
  }
}

// ---------------------------------------------------------------------------
// split-bf16 MFMA GEMM (BERT): A = hi+lo LDS tiles, B = packed hi+lo tiles
// (tile = 1024 shorts: 512 hi then 512 lo). 3 MFMA per (tile, row-tile) gives
// ~1e-5 relative accuracy (hi*hi + lo*hi + hi*lo).
// EPI: 0 store fp32 (+bias), 1 accumulate fp32 (+bias), 2 gelu -> split bf16 H.
template<int K, int KTn, int NTW, int EPI, bool HASB>
DEVI void bgemm(const short* Ah, const short* Al, const short* Bp,
                const int ntOff, const int kt0B, const int KTtot,
                const float* __restrict__ bias,
                float* O, const int ostr, short* Hh, short* Hl)
{
  const int tid  = (int)threadIdx.x;
  const int lane = tid & 63, wv = tid >> 6;
  const int r0 = lane & 15, g = lane >> 4;
  short8 ah[2][KTn], al[2][KTn];
#pragma unroll
  for (int mt = 0; mt < 2; ++mt) {
    const int row = mt * 16 + r0;
#pragma unroll
    for (int kk = 0; kk < KTn; ++kk) {
      const int slot = (kk * 4 + g) ^ (row & 7);
      ah[mt][kk] = *reinterpret_cast<const short8*>(Ah + row * K + slot * 8);
      al[mt][kk] = *reinterpret_cast<const short8*>(Al + row * K + slot * 8);
    }
  }
#pragma unroll
  for (int i = 0; i < NTW; ++i) {
    const int ntL = wv * NTW + i;
    const int ntG = ntOff + ntL;
    f32x4v c0 = {0.f, 0.f, 0.f, 0.f}, c1 = {0.f, 0.f, 0.f, 0.f};
#pragma unroll
    for (int kk = 0; kk < KTn; ++kk) {
      const size_t tb = (size_t)(ntG * KTtot + kt0B + kk) * 1024;
      const short8 bh = *reinterpret_cast<const short8*>(Bp + tb + lane * 8);
      const short8 bl = *reinterpret_cast<const short8*>(Bp + tb + 512 + lane * 8);
      c0 = __builtin_amdgcn_mfma_f32_16x16x32_bf16(ah[0][kk], bh, c0, 0, 0, 0);
      c0 = __builtin_amdgcn_mfma_f32_16x16x32_bf16(al[0][kk], bh, c0, 0, 0, 0);
      c0 = __builtin_amdgcn_mfma_f32_16x16x32_bf16(ah[0][kk], bl, c0, 0, 0, 0);
      c1 = __builtin_amdgcn_mfma_f32_16x16x32_bf16(ah[1][kk], bh, c1, 0, 0, 0);
      c1 = __builtin_amdgcn_mfma_f32_16x16x32_bf16(al[1][kk], bh, c1, 0, 0, 0);
      c1 = __builtin_amdgcn_mfma_f32_16x16x32_bf16(ah[1][kk], bl, c1, 0, 0, 0);
    }
    const int col = ntL * 16 + r0;
    const float bb = HASB ? bias[col] : 0.f;
#pragma unroll
    for (int q = 0; q < 4; ++q) {
      const int r = g * 4 + q;
      const float v0 = c0[q] + bb;
      const float v1 = c1[q] + bb;
      if (EPI == 0) {
        O[r * ostr + col] = v0;
        if (16 + r < LTn) O[(16 + r) * ostr + col] = v1;
      } else if (EPI == 1) {
        O[r * ostr + col] += v0;
        if (16 + r < LTn) O[(16 + r) * ostr + col] += v1;
      } else {
        short hh, ll;
        split2(geluf(v0), hh, ll);
        const int s0 = swz256(r, col);
        Hh[s0] = hh; Hl[s0] = ll;
        if (16 + r < LTn) {
          split2(geluf(v1), hh, ll);
          const int s1 = swz256(16 + r, col);
          Hh[s1] = hh; Hl[s1] = ll;
        }
      }
    }
  }
}

// ---------------------------------------------------------------------------
// pack fp32 [K][N] into single-bf16 B tiles (512 shorts/tile)
__global__ void pack_kernel(const float* __restrict__ W, short* __restrict__ out,
                            const int K, const int N, const int total)
{
  const int p = (int)blockIdx.x * 256 + (int)threadIdx.x;
  if (p >= total) return;
  const int perMat = (K * N) >> 3;
  const int m = p / perMat, r = p - m * perMat;
  const int t = r >> 6, lane = r & 63;
  const int KT = K >> 5;
  const int nt = t / KT, kt = t - nt * KT;
  const int row0 = kt * 32 + (lane >> 4) * 8;
  const int col  = nt * 16 + (lane & 15);
  const float* src = W + (size_t)m * K * N;
  short8 v;
#pragma unroll
  for (int j = 0; j < 8; ++j) v[j] = f2bf(src[(size_t)(row0 + j) * N + col]);
  *reinterpret_cast<short8*>(out + (size_t)p * 8) = v;
}

// pack fp32 [K][N] into split hi/lo B tiles (1024 shorts/tile: 512 hi, 512 lo)
__global__ void pack2_kernel(const float* __restrict__ W, short* __restrict__ out,
                             const int K, const int N, const int total)
{
  const int p = (int)blockIdx.x * 256 + (int)threadIdx.x;
  if (p >= total) return;
  const int perMat = (K * N) >> 3;
  const int m = p / perMat, r = p - m * perMat;
  const int t = r >> 6, lane = r & 63;
  const int KT = K >> 5;
  const int nt = t / KT, kt = t - nt * KT;
  const int row0 = kt * 32 + (lane >> 4) * 8;
  const int col  = nt * 16 + (lane & 15);
  const float* src = W + (size_t)m * K * N;
  short8 vh, vl;
#pragma unroll
  for (int j = 0; j < 8; ++j) {
    short hh, ll;
    split2(src[(size_t)(row0 + j) * N + col], hh, ll);
    vh[j] = hh; vl[j] = ll;
  }
  const size_t T  = (size_t)(perMat >> 6);
  const size_t tg = (size_t)m * T + t;
  *reinterpret_cast<short8*>(out + tg * 1024 + lane * 8)       = vh;
  *reinterpret_cast<short8*>(out + tg * 1024 + 512 + lane * 8) = vl;
}

// ---------------------------------------------------------------------------
// split-bf16 MFMA BERT kernel
struct BertMP {
  const int* ids; const float* tok; const float* pos;
  const float* bqkv; const float* bo; const float* b1; const float* b2;
  const float* ln_s; const float* ln_b; const float* lnf_s; const float* lnf_b;
  const short* pQ; const short* pO; const short* pW1; const short* pW2;
  float* intent;
};

__global__ __launch_bounds__(256, 2) void bert_mfma_kernel(BertMP p)
{
  __shared__ float xs[LTn * Dn];                 // 12288 B : residual
  __shared__ __align__(16) short xah[32 * 128];  // 8192 B : A hi (swizzled)
  __shared__ __align__(16) short xal[32 * 128];  // 8192 B : A lo
  __shared__ __align__(16) float S[LTn * QSTR];  // 37248 B: qkv fp32 / FFN h (aliased)
  __shared__ float att[Hn * LTn * LTn];          // 9216 B
  __shared__ int pad_s[LTn];
  const int b = blockIdx.x;
  const int tid = (int)threadIdx.x;

  for (int e = tid; e < LTn * Dn; e += 256) {
    const int i = e >> 7, c = e & 127;
    const int id = p.ids[b * LTn + i];
    xs[e] = p.tok[id * Dn + c] + p.pos[e];
  }
  for (int i = tid; i < LTn; i += 256) pad_s[i] = (p.ids[b * LTn + i] == 0) ? 1 : 0;
  for (int e = tid; e < 8 * 128; e += 256) {      // zero pad rows 24..31
    xah[LTn * 128 + e] = 0; xal[LTn * 128 + e] = 0;
  }
  __syncthreads();

  short* Hh = (short*)S;                          // FFN hidden split tiles [32][256]
  short* Hl = Hh + 32 * 256;

  for (int l = 0; l < NLBn; ++l) {
    const short* pQ_l  = p.pQ  + (size_t)l * 98304;
    const short* pO_l  = p.pO  + (size_t)l * 32768;
    const short* pW1_l = p.pW1 + (size_t)l * 131072;
    const short* pW2_l = p.pW2 + (size_t)l * 131072;
    const float* bqkv = p.bqkv + l * 384;
    const float* bo   = p.bo   + l * Dn;
    const float* b1   = p.b1   + l * DFFn;
    const float* b2   = p.b2   + l * Dn;
    const float* lns  = p.ln_s + l * 2 * Dn;
    const float* lnb  = p.ln_b + l * 2 * Dn;

    // ---- self-attention (post-LN: input = xs)
    for (int e = tid; e < LTn * Dn; e += 256) {   // xs -> split A tiles
      const int r = e >> 7, c = e & 127;
      short hh, ll; split2(xs[e], hh, ll);
      const int s = swz128(r, c);
      xah[s] = hh; xal[s] = ll;
    }
    __syncthreads();
    bgemm<128, 4, 6, 0, true>(xah, xal, pQ_l, 0, 0, 4, bqkv, S, QSTR, nullptr, nullptr);
    __syncthreads();
    attn_scores<LTn, QSTR, true>(S, att, pad_s);
    __syncthreads();
    softmax_rows<LTn>(att);
    __syncthreads();
    for (int e = tid; e < LTn * Dn; e += 256) {   // o = att@v -> split A tiles
      const int i = e >> 7, c = e & 127, h = c >> 5;
      const float* arow = att + (h * LTn + i) * LTn;
      const float* vp = S + 256 + c;
      float acc = 0.f;
#pragma unroll 4
      for (int j = 0; j < LTn; ++j) acc = fmaf(arow[j], vp[j * QSTR], acc);
      short hh, ll; split2(acc, hh, ll);
      const int s = swz128(i, c);
      xah[s] = hh; xal[s] = ll;
    }
    __syncthreads();
    bgemm<128, 4, 2, 1, true>(xah, xal, pO_l, 0, 0, 4, bo, xs, 128, nullptr, nullptr);
    __syncthreads();
    ln_rows<LTn>(xs, lns, lnb, xs);
    __syncthreads();

    // ---- FFN (gelu), two 256-col halves through split bf16 H
    for (int e = tid; e < LTn * Dn; e += 256) {   // xs -> split A tiles
      const int r = e >> 7, c = e & 127;
      short hh, ll; split2(xs[e], hh, ll);
      const int s = swz128(r, c);
      xah[s] = hh; xal[s] = ll;
    }
    for (int e = tid; e < 8 * 256; e += 256) {    // zero H pad rows 24..31
      Hh[LTn * 256 + e] = 0; Hl[LTn * 256 + e] = 0;
    }
    __syncthreads();
    bgemm<128, 4, 4, 2, true>(xah, xal, pW1_l, 0, 0, 4, b1, nullptr, 0, Hh, Hl);
    __syncthreads();
    bgemm<256, 8, 2, 1, true>(Hh, Hl, pW2_l, 0, 0, 16, b2, xs, 128, nullptr, nullptr);
    __syncthreads();
    bgemm<128, 4, 4, 2, true>(xah, xal, pW1_l, 16, 0, 4, b1 + 256, nullptr, 0, Hh, Hl);
    __syncthreads();
    bgemm<256, 8, 2, 1, false>(Hh, Hl, pW2_l, 0, 8, 16, nullptr, xs, 128, nullptr, nullptr);
    __syncthreads();
    ln_rows<LTn>(xs, lns + Dn, lnb + Dn, xs);
    __syncthreads();
  }

  if (tid < 64) {
    const float a0 = xs[tid], a1 = xs[tid + 64];
    float s1 = a0 + a1, s2 = a0 * a0 + a1 * a1;
#pragma unroll
    for (int o = 32; o > 0; o >>= 1) { s1 += __shfl_xor(s1, o); s2 += __shfl_xor(s2, o); }
    const float m  = s1 * (1.f / 128.f);
    const float rs = rsqrtf(s2 * (1.f / 128.f) - m * m + 1e-5f);
    p.intent[b * Dn + tid]      = (a0 - m) * rs * p.lnf_s[tid]      + p.lnf_b[tid];
    p.intent[b * Dn + tid + 64] = (a1 - m) * rs * p.lnf_s[tid + 64] + p.lnf_b[tid + 64];
  }
}

// ---------------------------------------------------------------------------
// fp32 fallback BERT
struct BertP {
  const int* ids; const float* tok; const float* pos;
  const float* Wqkv; const float* bqkv; const float* Wo; const float* bo;
  const float* W1; const float* b1; const float* W2; const float* b2;
  const float* ln_s; const float* ln_b; const float* lnf_s; const float* lnf_b;
  float* intent;
};

__global__ __launch_bounds__(256) void bert_kernel(BertP p)
{
  __shared__ float xs[LTn * Dn];
  __shared__ float scr[LTn * 384 + Hn * LTn * LTn];
  __shared__ int   pad_s[LTn];
  const int b = blockIdx.x;
  const int tid = (int)threadIdx.x;

  for (int e = tid; e < LTn * Dn; e += 256) {
    const int i = e >> 7, c = e & 127;
    const int id = p.ids[b * LTn + i];
    xs[e] = p.tok[id * Dn + c] + p.pos[e];
  }
  for (int i = tid; i < LTn; i += 256) pad_s[i] = (p.ids[b * LTn + i] == 0) ? 1 : 0;
  __syncthreads();

  float* att = scr + LTn * 384;
  for (int l = 0; l < NLBn; ++l) {
    const float* Wqkv = p.Wqkv + l * Dn * 3 * Dn;
    const float* bqkv = p.bqkv + l * 3 * Dn;
    const float* Wo   = p.Wo   + l * Dn * Dn;
    const float* bo   = p.bo   + l * Dn;
    const float* W1   = p.W1   + l * Dn * DFFn;
    const float* b1   = p.b1   + l * DFFn;
    const float* W2   = p.W2   + l * DFFn * Dn;
    const float* b2   = p.b2   + l * Dn;

    mmwide<LTn, Dn, 3 * Dn, 0>(Wqkv, 3 * Dn, bqkv, xs, Dn, scr, 3 * Dn);
    __syncthreads();
    attn_scores<LTn, 384, true>(scr, att, pad_s);
    __syncthreads();
    softmax_rows<LTn>(att);
    __syncthreads();
    attn_av<LTn, 384>(scr, att, scr, 384);
    __syncthreads();
    mm128<LTn, Dn, 0, true, true>(Wo, Dn, bo, scr, 384, xs, Dn);
    __syncthreads();
    ln_rows<LTn>(xs, p.ln_s + l * 2 * Dn, p.ln_b + l * 2 * Dn, xs);
    __syncthreads();

    for (int e = tid; e < LTn * Dn; e += 256) scr[e] = xs[e];
    __syncthreads();
    float* xin  = scr;
    float* hbuf = scr + LTn * Dn;
    mmwide<LTn, Dn, 256, 1>(W1, DFFn, b1, xin, Dn, hbuf, 256);
    __syncthreads();
    mm128<LTn, 256, 0, true, true>(W2, Dn, b2, hbuf, 256, xs, Dn);
    __syncthreads();
    mmwide<LTn, Dn, 256, 1>(W1 + 256, DFFn, b1 + 256, xin, Dn, hbuf, 256);
    __syncthreads();
    mm128<LTn, 256, 0, true, false>(W2 + 256 * Dn, Dn, nullptr, hbuf, 256, xs, Dn);
    __syncthreads();
    ln_rows<LTn>(xs, p.ln_s + l * 2 * Dn + Dn, p.ln_b + l * 2 * Dn + Dn, xs);
    __syncthreads();
  }

  if (tid < 64) {
    const float a0 = xs[tid], a1 = xs[tid + 64];
    float s1 = a0 + a1, s2 = a0 * a0 + a1 * a1;
#pragma unroll
    for (int o = 32; o > 0; o >>= 1) { s1 += __shfl_xor(s1, o); s2 += __shfl_xor(s2, o); }
    const float m  = s1 * (1.f / 128.f);
    const float rs = rsqrtf(s2 * (1.f / 128.f) - m * m + 1e-5f);
    p.intent[b * Dn + tid]      = (a0 - m) * rs * p.lnf_s[tid]      + p.lnf_b[tid];
    p.intent[b * Dn + tid + 64] = (a1 - m) * rs * p.lnf_s[tid + 64] + p.lnf_b[tid + 64];
  }
}

// ---------------------------------------------------------------------------
struct RouterP {
  const float* state; const float* intent;
  const float* se_W1; const float* se_b1; const float* se_W2; const float* se_b2;
  const float* se_ln_s; const float* se_ln_b;
  const float* r_W1; const float* r_b1; const float* r_W2; const float* r_b2;
  const float* r_ln_s; const float* r_ln_b;
  const float* gate_W; const float* gate_b;
  int* ridx; float* rwgt;
};

DEVI void ln128(float* x, const float* gs, const float* gb, float* red)
{
  const int c = (int)threadIdx.x;      // blockDim == 128
  const float a = x[c];
  float s1 = a, s2 = a * a;
#pragma unroll
  for (int o = 32; o > 0; o >>= 1) { s1 += __shfl_xor(s1, o); s2 += __shfl_xor(s2, o); }
  const int wid = c >> 6;
  if ((c & 63) == 0) { red[wid * 2] = s1; red[wid * 2 + 1] = s2; }
  __syncthreads();
  s1 = red[0] + red[2]; s2 = red[1] + red[3];
  const float m  = s1 * (1.f / 128.f);
  const float rs = rsqrtf(s2 * (1.f / 128.f) - m * m + 1e-5f);
  __syncthreads();
  x[c] = (a - m) * rs * gs[c] + gb[c];
}

__global__ __launch_bounds__(128) void router_kernel(RouterP p)
{
  __shared__ float sstate[SDn];
  __shared__ float h1[Dn];
  __shared__ float vv[Dn];
  __shared__ float red[4];
  __shared__ float slog[En];
  const int b = blockIdx.x;
  const int c = (int)threadIdx.x;

  if (c < SDn) sstate[c] = p.state[b * SDn + c];
  __syncthreads();
  {
    float acc = p.se_b1[c];
#pragma unroll
    for (int k = 0; k < SDn; ++k) acc = fmaf(sstate[k], p.se_W1[k * Dn + c], acc);
    h1[c] = geluf(acc);
  }
  __syncthreads();
  {
    float acc = p.se_b2[c];
#pragma unroll 4
    for (int k = 0; k < Dn; ++k) acc = fmaf(h1[k], p.se_W2[k * Dn + c], acc);
    vv[c] = acc;
  }
  __syncthreads();
  ln128(vv, p.se_ln_s, p.se_ln_b, red);
  __syncthreads();
  {
    float acc = p.r_b1[c];
    const float* ib = p.intent + b * Dn;
#pragma unroll 4
    for (int k = 0; k < Dn; ++k) acc = fmaf(ib[k], p.r_W1[k * Dn + c], acc);
#pragma unroll 4
    for (int k = 0; k < Dn; ++k) acc = fmaf(vv[k], p.r_W1[(Dn + k) * Dn + c], acc);
    h1[c] = geluf(acc);
  }
  __syncthreads();
  {
    float acc = p.r_b2[c];
#pragma unroll 4
    for (int k = 0; k < Dn; ++k) acc = fmaf(h1[k], p.r_W2[k * Dn + c], acc);
    vv[c] = acc;
  }
  __syncthreads();
  ln128(vv, p.r_ln_s, p.r_ln_b, red);
  __syncthreads();
  if (c < En) {
    float acc = p.gate_b[c];
#pragma unroll 4
    for (int k = 0; k < Dn; ++k) acc = fmaf(vv[k], p.gate_W[k * En + c], acc);
    slog[c] = acc;
  }
  __syncthreads();
  if (c == 0) {
    int i0 = 0; float v0 = slog[0];
#pragma unroll
    for (int e2 = 1; e2 < En; ++e2) if (slog[e2] > v0) { v0 = slog[e2]; i0 = e2; }
    int i1 = -1; float v1 = -3.4e38f;
#pragma unroll
    for (int e2 = 0; e2 < En; ++e2) if (e2 != i0 && slog[e2] > v1) { v1 = slog[e2]; i1 = e2; }
    const float e1  = expf(v1 - v0);
    const float inv = 1.f / (1.f + e1);
    p.ridx[b * 2 + 0] = i0; p.ridx[b * 2 + 1] = i1;
    p.rwgt[b * 2 + 0] = inv; p.rwgt[b * 2 + 1] = e1 * inv;
  }
}

// ---------------------------------------------------------------------------
// MFMA expert kernel
struct ExpertMP {
  const float* state; const float* qpe; const int* ridx; const float* rwgt;
  const float* sp_W; const float* sp_b; const float* zp_b;
  const float* aW;   // fp32 cross-attn weights (2-row kv projection)
  const float* ab; const float* abo;
  const float* ln_s; const float* ln_b;
  const float* fb1; const float* fb2;
  const float* headW; const float* headB;
  const short* pQ; const short* pO; const short* pF1; const short* pF2;
  float* out;
};

__global__ __launch_bounds__(256, 3) void expert_mfma_kernel(ExpertMP p)
{
  __shared__ float xs[CSn * Dn];                 // residual stream
  __shared__ __align__(16) short xb[32 * 128];   // bf16 A-tile (att aliases)
  __shared__ float scr[CSn * QSTR];              // qkv / q+catt / hb(bf16)
  __shared__ float mem[2 * Dn];
  __shared__ float memkv[2 * 256];
  __shared__ float outacc[CSn * JDn];
  const int b = blockIdx.x;
  const int tid = (int)threadIdx.x;

  for (int e = tid; e < CSn * JDn; e += 256) outacc[e] = 0.f;
  for (int e = tid; e < 12 * 128; e += 256) xb[CSn * 128 + e] = 0;  // zero pad rows 20..31

  for (int slot = 0; slot < 2; ++slot) {
    const int   ex  = p.ridx[b * 2 + slot];
    const float wgt = p.rwgt[b * 2 + slot];

    if (tid < Dn) {
      float acc = p.sp_b[ex * Dn + tid];
      const float* spw = p.sp_W + ex * SDn * Dn;
#pragma unroll
      for (int k = 0; k < SDn; ++k) acc = fmaf(p.state[b * SDn + k], spw[k * Dn + tid], acc);
      mem[tid] = acc;
    } else {
      mem[Dn + (tid - Dn)] = p.zp_b[ex * Dn + (tid - Dn)];
    }
    for (int e = tid; e < CSn * Dn; e += 256) xs[e] = p.qpe[e];
    __syncthreads();

    for (int l = 0; l < NLDn; ++l) {
      const int li = ex * NLDn + l;
      const short* wq0 = p.pQ + (size_t)(li * 2 + 0) * 49152;
      const short* wq1 = p.pQ + (size_t)(li * 2 + 1) * 49152;
      const short* wo0 = p.pO + (size_t)(li * 2 + 0) * 16384;
      const short* wo1 = p.pO + (size_t)(li * 2 + 1) * 16384;
      const short* w1p = p.pF1 + (size_t)li * 65536;
      const short* w2p = p.pF2 + (size_t)li * 65536;
      const float* ab0 = p.ab  + (size_t)(li * 2 + 0) * 384;
      const float* ab1 = p.ab  + (size_t)(li * 2 + 1) * 384;
      const float* bo0 = p.abo + (li * 2 + 0) * Dn;
      const float* bo1 = p.abo + (li * 2 + 1) * Dn;
      const float* lns = p.ln_s + li * 3 * Dn;
      const float* lnb = p.ln_b + li * 3 * Dn;
      const float* fb1 = p.fb1 + li * DFFn;
      const float* fb2 = p.fb2 + li * Dn;
      const float* aW1f = p.aW + (size_t)(li * 2 + 1) * Dn * 384;

      // ---- self-attention (norm_first)
      ln_rows_bf(xs, lns, lnb, xb);
      __syncthreads();
      mfma_gemm<128, 4, 6, 0, true>(xb, wq0, 0, 0, 4, ab0, scr, QSTR, nullptr);
      __syncthreads();
      attn_scores<CSn, QSTR, false>(scr, (float*)xb, nullptr);
      __syncthreads();
      softmax_rows<CSn>((float*)xb);
      __syncthreads();
      attn_av<CSn, QSTR>(scr, (float*)xb, scr, QSTR);   // o -> q slots of scr
      __syncthreads();
      for (int e = tid; e < CSn * Dn; e += 256) {  // o -> bf16 swizzled xb
        const int i = e >> 7, c = e & 127;
        xbW128(xb, i, c, scr[i * QSTR + c]);
      }
      for (int e = tid; e < 12 * 128; e += 256) xb[CSn * 128 + e] = 0;  // re-zero pads
      __syncthreads();
      mfma_gemm<128, 4, 2, 1, true>(xb, wo0, 0, 0, 4, bo0, xs, 128, nullptr);
      __syncthreads();

      // ---- cross-attention (2 keys)
      ln_rows_bf(xs, lns + Dn, lnb + Dn, xb);
      __syncthreads();
      mfma_gemm<128, 4, 2, 0, true>(xb, wq1, 0, 0, 4, ab1, scr, 128, nullptr);  // q
      for (int e = tid; e < 2 * 256; e += 256) {   // k,v of mem (VALU, fp32 weights)
        const int j = e >> 8, c2 = e & 255;
        float acc = ab1[Dn + c2];
        const float* wp = aW1f + Dn + c2;
#pragma unroll 4
        for (int k = 0; k < Dn; ++k) acc = fmaf(mem[j * Dn + k], wp[k * 384], acc);
        memkv[j * 256 + c2] = acc;
      }
      __syncthreads();
      float* catt = scr + CSn * Dn;
      for (int e = tid; e < Hn * CSn; e += 256) {
        const int h = e / CSn, i = e % CSn;
        const float* qp = scr + i * Dn + h * DHn;
        float s0 = 0.f, s1 = 0.f;
#pragma unroll
        for (int d = 0; d < DHn; d += 4) {
          const float4 q4 = *reinterpret_cast<const float4*>(qp + d);
          const float4 k0 = *reinterpret_cast<const float4*>(memkv + 0 * 256 + h * DHn + d);
          const float4 k1 = *reinterpret_cast<const float4*>(memkv + 1 * 256 + h * DHn + d);
          s0 += q4.x * k0.x + q4.y * k0.y + q4.z * k0.z + q4.w * k0.w;
          s1 += q4.x * k1.x + q4.y * k1.y + q4.z * k1.z + q4.w * k1.w;
        }
        s0 *= INV_SQRT_DH; s1 *= INV_SQRT_DH;
        const float m = fmaxf(s0, s1);
        const float e0 = expf(s0 - m), e1 = expf(s1 - m);
        const float inv = 1.f / (e0 + e1);
        catt[e * 2] = e0 * inv; catt[e * 2 + 1] = e1 * inv;
      }
      __syncthreads();
      for (int e = tid; e < CSn * Dn; e += 256) {
        const int i = e >> 7, c = e & 127, h = c >> 5;
        const int a = (h * CSn + i) * 2;
        const float v = catt[a]     * memkv[0 * 256 + Dn + c]
                      + catt[a + 1] * memkv[1 * 256 + Dn + c];
        xbW128(xb, i, c, v);
      }
      __syncthreads();
      mfma_gemm<128, 4, 2, 1, true>(xb, wo1, 0, 0, 4, bo1, xs, 128, nullptr);
      __syncthreads();

      // ---- FFN (relu), two 256-col halves through bf16 hb
      ln_rows_bf(xs, lns + 2 * Dn, lnb + 2 * Dn, xb);
      short* hb = (short*)scr;                    // [32][256] bf16 swizzled
      for (int e = tid; e < 12 * 256; e += 256) hb[CSn * 256 + e] = 0;  // pad rows
      __syncthreads();
      mfma_gemm<128, 4, 4, 2, true>(xb, w1p, 0, 0, 4, fb1, nullptr, 0, hb);
      __syncthreads();
      mfma_gemm<256, 8, 2, 1, true>(hb, w2p, 0, 0, 16, fb2, xs, 128, nullptr);
      __syncthreads();
      mfma_gemm<128, 4, 4, 2, true>(xb, w1p, 16, 0, 4, fb1 + 256, nullptr, 0, hb);
      __syncthreads();
      mfma_gemm<256, 8, 2, 1, false>(hb, w2p, 0, 8, 16, nullptr, xs, 128, nullptr);
      __syncthreads();
    }

    // head + weighted accumulate
    const float* hw = p.headW + ex * Dn * JDn;
    for (int e = tid; e < CSn * JDn; e += 256) {
      const int t = e / JDn, j = e % JDn;
      float acc = p.headB[ex * JDn + j];
#pragma unroll 4
      for (int k = 0; k < Dn; ++k) acc = fmaf(xs[t * Dn + k], hw[k * JDn + j], acc);
      outacc[e] = fmaf(wgt, acc, outacc[e]);
    }
    __syncthreads();
  }

  for (int e = tid; e < CSn * JDn; e += 256) p.out[b * CSn * JDn + e] = outacc[e];
}

// ---------------------------------------------------------------------------
// fp32 fallback expert kernel
struct ExpertP {
  const float* state; const float* qpe; const int* ridx; const float* rwgt;
  const float* sp_W; const float* sp_b; const float* zp_b;
  const float* aW; const float* ab; const float* aWo; const float* abo;
  const float* ln_s; const float* ln_b;
  const float* fW1; const float* fb1; const float* fW2; const float* fb2;
  const float* hW; const float* hb;
  float* out;
};

__global__ __launch_bounds__(256) void expert_kernel(ExpertP p)
{
  __shared__ float xs[CSn * Dn];
  __shared__ float xn[CSn * Dn];
  __shared__ float scr[CSn * 384 + Hn * CSn * CSn];
  __shared__ float mem[2 * Dn];
  __shared__ float memkv[2 * 256];
  __shared__ float outacc[CSn * JDn];
  const int b = blockIdx.x;
  const int tid = (int)threadIdx.x;

  for (int e = tid; e < CSn * JDn; e += 256) outacc[e] = 0.f;

  for (int slot = 0; slot < 2; ++slot) {
    const int   ex  = p.ridx[b * 2 + slot];
    const float wgt = p.rwgt[b * 2 + slot];

    if (tid < Dn) {
      float acc = p.sp_b[ex * Dn + tid];
      const float* spw = p.sp_W + ex * SDn * Dn;
#pragma unroll
      for (int k = 0; k < SDn; ++k) acc = fmaf(p.state[b * SDn + k], spw[k * Dn + tid], acc);
      mem[tid] = acc;
    } else {
      mem[Dn + (tid - Dn)] = p.zp_b[ex * Dn + (tid - Dn)];
    }
    for (int e = tid; e < CSn * Dn; e += 256) xs[e] = p.qpe[e];
    __syncthreads();

    for (int l = 0; l < NLDn; ++l) {
      const int li = ex * NLDn + l;
      const float* aW0 = p.aW  + (size_t)(li * 2 + 0) * Dn * 3 * Dn;
      const float* ab0 = p.ab  + (li * 2 + 0) * 3 * Dn;
      const float* aW1 = p.aW  + (size_t)(li * 2 + 1) * Dn * 3 * Dn;
      const float* ab1 = p.ab  + (li * 2 + 1) * 3 * Dn;
      const float* Wo0 = p.aWo + (size_t)(li * 2 + 0) * Dn * Dn;
      const float* bo0 = p.abo + (li * 2 + 0) * Dn;
      const float* Wo1 = p.aWo + (size_t)(li * 2 + 1) * Dn * Dn;
      const float* bo1 = p.abo + (li * 2 + 1) * Dn;
      const float* lns = p.ln_s + li * 3 * Dn;
      const float* lnb = p.ln_b + li * 3 * Dn;
      const float* fW1 = p.fW1 + (size_t)li * Dn * DFFn;
      const float* fb1 = p.fb1 + li * DFFn;
      const float* fW2 = p.fW2 + (size_t)li * DFFn * Dn;
      const float* fb2 = p.fb2 + li * Dn;

      ln_rows<CSn>(xs, lns + 0 * Dn, lnb + 0 * Dn, xn);
      __syncthreads();
      mmwide<CSn, Dn, 3 * Dn, 0>(aW0, 3 * Dn, ab0, xn, Dn, scr, 3 * Dn);
      __syncthreads();
      float* att = scr + CSn * 384;
      attn_scores<CSn, 384, false>(scr, att, nullptr);
      __syncthreads();
      softmax_rows<CSn>(att);
      __syncthreads();
      attn_av<CSn, 384>(scr, att, xn, Dn);
      __syncthreads();
      mm128<CSn, Dn, 0, true, true>(Wo0, Dn, bo0, xn, Dn, xs, Dn);
      __syncthreads();

      ln_rows<CSn>(xs, lns + 1 * Dn, lnb + 1 * Dn, xn);
      __syncthreads();
      mm128<CSn, Dn, 0, false, true>(aW1, 3 * Dn, ab1, xn, Dn, scr, Dn);
      for (int e = tid; e < 2 * 256; e += 256) {
        const int j = e >> 8, c2 = e & 255;
        float acc = ab1[Dn + c2];
        const float* wp = aW1 + Dn + c2;
#pragma unroll 4
        for (int k = 0; k < Dn; ++k) acc = fmaf(mem[j * Dn + k], wp[k * 3 * Dn], acc);
        memkv[j * 256 + c2] = acc;
      }
      __syncthreads();
      float* catt = scr + CSn * Dn;
      for (int e = tid; e < Hn * CSn; e += 256) {
        const int h = e / CSn, i = e % CSn;
        const float* qp = scr + i * Dn + h * DHn;
        float s0 = 0.f, s1 = 0.f;
#pragma unroll
        for (int d = 0; d < DHn; d += 4) {
          const float4 q4 = *reinterpret_cast<const float4*>(qp + d);
          const float4 k0 = *reinterpret_cast<const float4*>(memkv + 0 * 256 + h * DHn + d);
          const float4 k1 = *reinterpret_cast<const float4*>(memkv + 1 * 256 + h * DHn + d);
          s0 += q4.x * k0.x + q4.y * k0.y + q4.z * k0.z + q4.w * k0.w;
          s1 += q4.x * k1.x + q4.y * k1.y + q4.z * k1.z + q4.w * k1.w;
        }
        s0 *= INV_SQRT_DH; s1 *= INV_SQRT_DH;
        const float m = fmaxf(s0, s1);
        const float e0 = expf(s0 - m), e1 = expf(s1 - m);
        const float inv = 1.f / (e0 + e1);
        catt[e * 2] = e0 * inv; catt[e * 2 + 1] = e1 * inv;
      }
      __syncthreads();
      for (int e = tid; e < CSn * Dn; e += 256) {
        const int i = e >> 7, c = e & 127, h = c >> 5;
        const int a = (h * CSn + i) * 2;
        xn[e] = catt[a] * memkv[0 * 256 + Dn + c] + catt[a + 1] * memkv[1 * 256 + Dn + c];
      }
      __syncthreads();
      mm128<CSn, Dn, 0, true, true>(Wo1, Dn, bo1, xn, Dn, xs, Dn);
      __syncthreads();

      ln_rows<CSn>(xs, lns + 2 * Dn, lnb + 2 * Dn, xn);
      __syncthreads();
      mmwide<CSn, Dn, 256, 2>(fW1, DFFn, fb1, xn, Dn, scr, 256);
      __syncthreads();
      mm128<CSn, 256, 0, true, true>(fW2, Dn, fb2, scr, 256, xs, Dn);
      __syncthreads();
      mmwide<CSn, Dn, 256, 2>(fW1 + 256, DFFn, fb1 + 256, xn, Dn, scr, 256);
      __syncthreads();
      mm128<CSn, 256, 0, true, false>(fW2 + 256 * Dn, Dn, nullptr, scr, 256, xs, Dn);
      __syncthreads();
    }

    const float* hw = p.hW + ex * Dn * JDn;
    for (int e = tid; e < CSn * JDn; e += 256) {
      const int t = e / JDn, j = e % JDn;
      float acc = p.hb[ex * JDn + j];
#pragma unroll 4
      for (int k = 0; k < Dn; ++k) acc = fmaf(xs[t * Dn + k], hw[k * JDn + j], acc);
      outacc[e] = fmaf(wgt, acc, outacc[e]);
    }
    __syncthreads();
  }

  for (int e = tid; e < CSn * JDn; e += 256) p.out[b * CSn * JDn + e] = outacc[e];
}

// ---------------------------------------------------------------------------
__global__ void qpe_kernel(float* qpe)
{
  const int e = (int)blockIdx.x * 256 + (int)threadIdx.x;
  if (e < CSn * Dn) {
    const int t = e >> 7, d = e & 127;
    const float j  = (float)(d & ~1);
    const float dv = expf(j * (-logf(10000.f) / 128.f));
    const float a  = (float)t * dv;
    qpe[e] = (d & 1) ? cosf(a) : sinf(a);
  }
}

} // namespace

// ---------------------------------------------------------------------------
extern "C" void kernel_launch(void* const* d_in, const int* in_sizes, int n_in,
                              void* d_out, int out_size, void* d_ws, size_t ws_size,
                              hipStream_t stream)
{
  (void)in_sizes; (void)n_in; (void)out_size;

  const int*   ids     = (const int*)  d_in[0];
  const float* state   = (const float*)d_in[1];
  const float* tok_emb = (const float*)d_in[2];
  const float* pos_emb = (const float*)d_in[3];

  // workspace layout
  float* qpe    = (float*)d_ws;                  // 4096 f
  float* intent = qpe + 4096;                    // 262144 f
  int*   ridx   = (int*)(intent + 262144);       // 4096 i
  float* rwgt   = (float*)(ridx + 4096);         // 4096 f
  short* pQ     = (short*)(rwgt + 4096);         // expert packs (single bf16)
  short* pO     = pQ  + (size_t)36 * 49152;
  short* pF1    = pO  + (size_t)36 * 16384;
  short* pF2    = pF1 + (size_t)18 * 65536;
  short* pbQ    = pF2 + (size_t)18 * 65536;      // BERT packs (split hi/lo)
  short* pbO    = pbQ + (size_t)4 * 98304;
  short* pbW1   = pbO + (size_t)4 * 32768;
  short* pbW2   = pbW1 + (size_t)4 * 131072;
  const size_t NEEDED = (size_t)((char*)(pbW2 + (size_t)4 * 131072) - (char*)d_ws);
  const bool use_mfma = (ws_size >= NEEDED);

  qpe_kernel<<<dim3(10), dim3(256), 0, stream>>>(qpe);

  if (use_mfma) {
    // expert weights -> single-bf16 B tiles
    const int tq = 36 * 6144;
    pack_kernel<<<dim3((tq + 255) / 256), dim3(256), 0, stream>>>(
        (const float*)d_in[34], pQ, 128, 384, tq);
    const int to = 36 * 2048;
    pack_kernel<<<dim3((to + 255) / 256), dim3(256), 0, stream>>>(
        (const float*)d_in[36], pO, 128, 128, to);
    const int t1 = 18 * 8192;
    pack_kernel<<<dim3((t1 + 255) / 256), dim3(256), 0, stream>>>(
        (const float*)d_in[40], pF1, 128, 512, t1);
    const int t2 = 18 * 8192;
    pack_kernel<<<dim3((t2 + 255) / 256), dim3(256), 0, stream>>>(
        (const float*)d_in[42], pF2, 512, 128, t2);
    // BERT weights -> split hi/lo B tiles
    const int bq = 4 * 6144;
    pack2_kernel<<<dim3((bq + 255) / 256), dim3(256), 0, stream>>>(
        (const float*)d_in[4], pbQ, 128, 384, bq);
    const int bo = 4 * 2048;
    pack2_kernel<<<dim3((bo + 255) / 256), dim3(256), 0, stream>>>(
        (const float*)d_in[6], pbO, 128, 128, bo);
    const int bw1 = 4 * 8192;
    pack2_kernel<<<dim3((bw1 + 255) / 256), dim3(256), 0, stream>>>(
        (const float*)d_in[8], pbW1, 128, 512, bw1);
    const int bw2 = 4 * 8192;
    pack2_kernel<<<dim3((bw2 + 255) / 256), dim3(256), 0, stream>>>(
        (const float*)d_in[10], pbW2, 512, 128, bw2);
  }

  if (use_mfma) {
    BertMP bp;
    bp.ids  = ids; bp.tok = tok_emb; bp.pos = pos_emb;
    bp.bqkv = (const float*)d_in[5];  bp.bo = (const float*)d_in[7];
    bp.b1   = (const float*)d_in[9];  bp.b2 = (const float*)d_in[11];
    bp.ln_s = (const float*)d_in[12]; bp.ln_b = (const float*)d_in[13];
    bp.lnf_s= (const float*)d_in[14]; bp.lnf_b= (const float*)d_in[15];
    bp.pQ = pbQ; bp.pO = pbO; bp.pW1 = pbW1; bp.pW2 = pbW2;
    bp.intent = intent;
    bert_mfma_kernel<<<dim3(Bn), dim3(256), 0, stream>>>(bp);
  } else {
    BertP bp;
    bp.ids  = ids; bp.tok = tok_emb; bp.pos = pos_emb;
    bp.Wqkv = (const float*)d_in[4];  bp.bqkv = (const float*)d_in[5];
    bp.Wo   = (const float*)d_in[6];  bp.bo   = (const float*)d_in[7];
    bp.W1   = (const float*)d_in[8];  bp.b1   = (const float*)d_in[9];
    bp.W2   = (const float*)d_in[10]; bp.b2   = (const float*)d_in[11];
    bp.ln_s = (const float*)d_in[12]; bp.ln_b = (const float*)d_in[13];
    bp.lnf_s= (const float*)d_in[14]; bp.lnf_b= (const float*)d_in[15];
    bp.intent = intent;
    bert_kernel<<<dim3(Bn), dim3(256), 0, stream>>>(bp);
  }

  RouterP rp;
  rp.state = state; rp.intent = intent;
  rp.se_W1 = (const float*)d_in[16]; rp.se_b1 = (const float*)d_in[17];
  rp.se_W2 = (const float*)d_in[18]; rp.se_b2 = (const float*)d_in[19];
  rp.se_ln_s = (const float*)d_in[20]; rp.se_ln_b = (const float*)d_in[21];
  rp.r_W1 = (const float*)d_in[22]; rp.r_b1 = (const float*)d_in[23];
  rp.r_W2 = (const float*)d_in[24]; rp.r_b2 = (const float*)d_in[25];
  rp.r_ln_s = (const float*)d_in[26]; rp.r_ln_b = (const float*)d_in[27];
  rp.gate_W = (const float*)d_in[28]; rp.gate_b = (const float*)d_in[29];
  rp.ridx = ridx; rp.rwgt = rwgt;
  router_kernel<<<dim3(Bn), dim3(128), 0, stream>>>(rp);

  if (use_mfma) {
    ExpertMP ep;
    ep.state = state; ep.qpe = qpe; ep.ridx = ridx; ep.rwgt = rwgt;
    ep.sp_W = (const float*)d_in[30]; ep.sp_b = (const float*)d_in[31];
    ep.zp_b = (const float*)d_in[33];
    ep.aW   = (const float*)d_in[34]; ep.ab = (const float*)d_in[35];
    ep.abo  = (const float*)d_in[37];
    ep.ln_s = (const float*)d_in[38]; ep.ln_b = (const float*)d_in[39];
    ep.fb1  = (const float*)d_in[41]; ep.fb2 = (const float*)d_in[43];
    ep.headW= (const float*)d_in[44]; ep.headB = (const float*)d_in[45];
    ep.pQ = pQ; ep.pO = pO; ep.pF1 = pF1; ep.pF2 = pF2;
    ep.out  = (float*)d_out;
    expert_mfma_kernel<<<dim3(Bn), dim3(256), 0, stream>>>(ep);
  } else {
    ExpertP ep;
    ep.state = state; ep.qpe = qpe; ep.ridx = ridx; ep.rwgt = rwgt;
    ep.sp_W = (const float*)d_in[30]; ep.sp_b = (const float*)d_in[31];
    ep.zp_b = (const float*)d_in[33];
    ep.aW   = (const float*)d_in[34]; ep.ab   = (const float*)d_in[35];
    ep.aWo  = (const float*)d_in[36]; ep.abo  = (const float*)d_in[37];
    ep.ln_s = (const float*)d_in[38]; ep.ln_b = (const float*)d_in[39];
    ep.fW1  = (const float*)d_in[40]; ep.fb1  = (const float*)d_in[41];
    ep.fW2  = (const float*)d_in[42]; ep.fb2  = (const float*)d_in[43];
    ep.hW   = (const float*)d_in[44]; ep.hb   = (const float*)d_in[45];
    ep.out  = (float*)d_out;
    expert_kernel<<<dim3(Bn), dim3(256), 0, stream>>>(ep);
  }
}

// Round 4
// 2085.624 us; speedup vs baseline: 3.3491x; 1.4876x over previous
//
#include <hip/hip_runtime.h>
#include <math.h>

#define DEVI __device__ __forceinline__

namespace {

constexpr int Bn   = 2048;
constexpr int En   = 6;
constexpr int Hn   = 4;
constexpr int Dn   = 128;
constexpr int DHn  = 32;
constexpr int LTn  = 24;   // text length
constexpr int CSn  = 20;   // chunk (decoder query) length
constexpr int JDn  = 7;
constexpr int SDn  = 16;
constexpr int NLBn = 4;
constexpr int NLDn = 3;
constexpr int DFFn = 512;
constexpr int QSTR = 388;  // qkv LDS row stride (388 mod 32 = 4 -> no 32-way bank conflicts)
constexpr float INV_SQRT_DH = 0.17677669529663687f;  // 1/sqrt(32)

// phase-pipeline geometry
constexpr int PAIRS  = 4096;                 // 2048 items x top-2
constexpr int MPMAX  = PAIRS * 20 + En * 128; // padded rows (per-expert 128-aligned)
constexpr int NBGMAX = PAIRS * 20 / 128 + En; // 646 grouped-GEMM blocks max
constexpr int GEXP_OFF = 64;
constexpr int GMT_OFF  = 64 + NBGMAX;

typedef float f32x4v __attribute__((ext_vector_type(4)));
typedef short short8 __attribute__((ext_vector_type(8)));

DEVI float geluf(float x) { return 0.5f * x * (1.0f + erff(x * 0.70710678118654752f)); }

DEVI short f2bf(float f) {  // fp32 -> bf16 bits, round-to-nearest-even
  unsigned u = __float_as_uint(f);
  return (short)((u + 0x7FFFu + ((u >> 16) & 1u)) >> 16);
}
DEVI float bf2f(short s) { return __uint_as_float(((unsigned)(unsigned short)s) << 16); }
DEVI void split2(float v, short& h, short& l) {  // v ~= hi + lo to ~2^-16 rel
  h = f2bf(v);
  l = f2bf(v - bf2f(h));
}

// swizzled bf16 writes: row-stride-K LDS tile, 16B slot XORed with row&7
DEVI void xbW128(short* xb, int r, int c, float v) {
  xb[r * 128 + ((((c >> 3) ^ (r & 7)) << 3) | (c & 7))] = f2bf(v);
}
DEVI int swz128(int r, int c) { return r * 128 + ((((c >> 3) ^ (r & 7)) << 3) | (c & 7)); }
DEVI int swz256(int r, int c) { return r * 256 + ((((c >> 3) ^ (r & 7)) << 3) | (c & 7)); }
DEVI void hbW256(short* hb, int r, int c, float v) { hb[swz256(r, c)] = f2bf(v); }

// LayerNorm over 128 cols, one wave per row (blockDim must be 256).
template<int R>
DEVI void ln_rows(float* X, const float* gs, const float* gb, float* O)
{
  const int wid  = (int)threadIdx.x >> 6;
  const int lane = (int)threadIdx.x & 63;
  for (int r = wid; r < R; r += 4) {
    const float a0 = X[r * 128 + lane];
    const float a1 = X[r * 128 + lane + 64];
    float s1 = a0 + a1, s2 = a0 * a0 + a1 * a1;
#pragma unroll
    for (int o = 32; o > 0; o >>= 1) { s1 += __shfl_xor(s1, o); s2 += __shfl_xor(s2, o); }
    const float m  = s1 * (1.f / 128.f);
    const float rs = rsqrtf(s2 * (1.f / 128.f) - m * m + 1e-5f);
    O[r * 128 + lane]      = (a0 - m) * rs * gs[lane]      + gb[lane];
    O[r * 128 + lane + 64] = (a1 - m) * rs * gs[lane + 64] + gb[lane + 64];
  }
}

// LayerNorm xs -> bf16 swizzled xb (rows 0..CSn-1 only) — T1 expert kernel
DEVI void ln_rows_bf(const float* X, const float* gs, const float* gb, short* xb)
{
  const int wid  = (int)threadIdx.x >> 6;
  const int lane = (int)threadIdx.x & 63;
  for (int r = wid; r < CSn; r += 4) {
    const float a0 = X[r * 128 + lane];
    const float a1 = X[r * 128 + lane + 64];
    float s1 = a0 + a1, s2 = a0 * a0 + a1 * a1;
#pragma unroll
    for (int o = 32; o > 0; o >>= 1) { s1 += __shfl_xor(s1, o); s2 += __shfl_xor(s2, o); }
    const float m  = s1 * (1.f / 128.f);
    const float rs = rsqrtf(s2 * (1.f / 128.f) - m * m + 1e-5f);
    xbW128(xb, r, lane,      (a0 - m) * rs * gs[lane]      + gb[lane]);
    xbW128(xb, r, lane + 64, (a1 - m) * rs * gs[lane + 64] + gb[lane + 64]);
  }
}

// scores: att[h*L*L + i*L + j] = (q_i . k_j) / sqrt(32), optional key-pad mask.
template<int L, int STR, bool MASK>
DEVI void attn_scores(const float* qkv, float* att, const int* pad)
{
  for (int e = (int)threadIdx.x; e < Hn * L * L; e += 256) {
    const int h = e / (L * L);
    const int rem = e % (L * L);
    const int i = rem / L, j = rem % L;
    const float* qp = qkv + i * STR + h * DHn;
    const float* kp = qkv + j * STR + 128 + h * DHn;
    float acc = 0.f;
#pragma unroll
    for (int d = 0; d < DHn; d += 4) {
      const float4 qa = *reinterpret_cast<const float4*>(qp + d);
      const float4 kb = *reinterpret_cast<const float4*>(kp + d);
      acc += qa.x * kb.x + qa.y * kb.y + qa.z * kb.z + qa.w * kb.w;
    }
    acc *= INV_SQRT_DH;
    if (MASK && pad[j]) acc = -1e9f;
    att[e] = acc;
  }
}

template<int L>
DEVI void softmax_rows(float* att)
{
  for (int r = (int)threadIdx.x; r < Hn * L; r += 256) {
    float* row = att + r * L;
    float m = row[0];
#pragma unroll 4
    for (int j = 1; j < L; ++j) m = fmaxf(m, row[j]);
    float s = 0.f;
#pragma unroll 4
    for (int j = 0; j < L; ++j) { const float ex = expf(row[j] - m); row[j] = ex; s += ex; }
    const float inv = 1.f / s;
#pragma unroll 4
    for (int j = 0; j < L; ++j) row[j] *= inv;
  }
}

template<int L, int STR>
DEVI void attn_av(const float* qkv, const float* att, float* o, const int ostr)
{
  for (int e = (int)threadIdx.x; e < L * Dn; e += 256) {
    const int i = e >> 7, c = e & 127, h = c >> 5;
    const float* arow = att + (h * L + i) * L;
    const float* vp = qkv + 256 + c;
    float acc = 0.f;
#pragma unroll 4
    for (int j = 0; j < L; ++j) acc = fmaf(arow[j], vp[j * STR], acc);
    o[i * ostr + c] = acc;
  }
}

// ---------------------------------------------------------------------------
// single-bf16 MFMA GEMM (T1 expert kernel). B tiles: 512 shorts each.
template<int K, int KTn, int NTW, int EPI, bool HASB>
DEVI void mfma_gemm(const short* A, const short* Bp, const int ntOff, const int kt0B,
                    const int KTtot, const float* __restrict__ bias,
                    float* O, const int ostr, short* hb)
{
  const int tid  = (int)threadIdx.x;
  const int lane = tid & 63, wv = tid >> 6;
  const int r0 = lane & 15, g = lane >> 4;
  short8 a[2][KTn];
#pragma unroll
  for (int mt = 0; mt < 2; ++mt) {
    const int row = mt * 16 + r0;
#pragma unroll
    for (int kk = 0; kk < KTn; ++kk) {
      const int slot = (kk * 4 + g) ^ (row & 7);
      a[mt][kk] = *reinterpret_cast<const short8*>(A + row * K + slot * 8);
    }
  }
#pragma unroll
  for (int i = 0; i < NTW; ++i) {
    const int ntL = wv * NTW + i;
    const int ntG = ntOff + ntL;
    f32x4v c0 = {0.f, 0.f, 0.f, 0.f}, c1 = {0.f, 0.f, 0.f, 0.f};
#pragma unroll
    for (int kk = 0; kk < KTn; ++kk) {
      const short8 bfr = *reinterpret_cast<const short8*>(
          Bp + ((size_t)(ntG * KTtot + kt0B + kk) * 64 + lane) * 8);
      c0 = __builtin_amdgcn_mfma_f32_16x16x32_bf16(a[0][kk], bfr, c0, 0, 0, 0);
      c1 = __builtin_amdgcn_mfma_f32_16x16x32_bf16(a[1][kk], bfr, c1, 0, 0, 0);
    }
    const int col = ntL * 16 + r0;
    const float bb = HASB ? bias[col] : 0.f;
    const int rb = g * 4;
#pragma unroll
    for (int q = 0; q < 4; ++q) {
      const int r = rb + q;
      const float v0 = c0[q] + bb;
      const float v1 = c1[q] + bb;
      if (EPI == 0) {
        O[r * ostr + col] = v0;
        if (16 + r < CSn) O[(16 + r) * ostr + col] = v1;
      } else if (EPI == 1) {
        O[r * ostr + col] += v0;
        if (16 + r < CSn) O[(16 + r) * ostr + col] += v1;
      } else {
        hbW256(hb, r, col, fmaxf(v0, 0.f));
        if (16 + r < CSn) hbW256(hb, 16 + r, col, fmaxf(v1, 0.f));
      }
    }
  }
}

// ---------------------------------------------------------------------------
// split-bf16 MFMA GEMM (BERT).
template<int K, int KTn, int NTW, int EPI, bool HASB>
DEVI void bgemm(const short* Ah, const short* Al, const short* Bp,
                const int ntOff, const int kt0B, const int KTtot,
                const float* __restrict__ bias,
                float* O, const int ostr, short* Hh, short* Hl)
{
  const int tid  = (int)threadIdx.x;
  const int lane = tid & 63, wv = tid >> 6;
  const int r0 = lane & 15, g = lane >> 4;
  short8 ah[2][KTn], al[2][KTn];
#pragma unroll
  for (int mt = 0; mt < 2; ++mt) {
    const int row = mt * 16 + r0;
#pragma unroll
    for (int kk = 0; kk < KTn; ++kk) {
      const int slot = (kk * 4 + g) ^ (row & 7);
      ah[mt][kk] = *reinterpret_cast<const short8*>(Ah + row * K + slot * 8);
      al[mt][kk] = *reinterpret_cast<const short8*>(Al + row * K + slot * 8);
    }
  }
#pragma unroll
  for (int i = 0; i < NTW; ++i) {
    const int ntL = wv * NTW + i;
    const int ntG = ntOff + ntL;
    f32x4v c0 = {0.f, 0.f, 0.f, 0.f}, c1 = {0.f, 0.f, 0.f, 0.f};
#pragma unroll
    for (int kk = 0; kk < KTn; ++kk) {
      const size_t tb = (size_t)(ntG * KTtot + kt0B + kk) * 1024;
      const short8 bh = *reinterpret_cast<const short8*>(Bp + tb + lane * 8);
      const short8 bl = *reinterpret_cast<const short8*>(Bp + tb + 512 + lane * 8);
      c0 = __builtin_amdgcn_mfma_f32_16x16x32_bf16(ah[0][kk], bh, c0, 0, 0, 0);
      c0 = __builtin_amdgcn_mfma_f32_16x16x32_bf16(al[0][kk], bh, c0, 0, 0, 0);
      c0 = __builtin_amdgcn_mfma_f32_16x16x32_bf16(ah[0][kk], bl, c0, 0, 0, 0);
      c1 = __builtin_amdgcn_mfma_f32_16x16x32_bf16(ah[1][kk], bh, c1, 0, 0, 0);
      c1 = __builtin_amdgcn_mfma_f32_16x16x32_bf16(al[1][kk], bh, c1, 0, 0, 0);
      c1 = __builtin_amdgcn_mfma_f32_16x16x32_bf16(ah[1][kk], bl, c1, 0, 0, 0);
    }
    const int col = ntL * 16 + r0;
    const float bb = HASB ? bias[col] : 0.f;
#pragma unroll
    for (int q = 0; q < 4; ++q) {
      const int r = g * 4 + q;
      const float v0 = c0[q] + bb;
      const float v1 = c1[q] + bb;
      if (EPI == 0) {
        O[r * ostr + col] = v0;
        if (16 + r < LTn) O[(16 + r) * ostr + col] = v1;
      } else if (EPI == 1) {
        O[r * ostr + col] += v0;
        if (16 + r < LTn) O[(16 + r) * ostr + col] += v1;
      } else {
        short hh, ll;
        split2(geluf(v0), hh, ll);
        const int s0 = swz256(r, col);
        Hh[s0] = hh; Hl[s0] = ll;
        if (16 + r < LTn) {
          split2(geluf(v1), hh, ll);
          const int s1 = swz256(16 + r, col);
          Hh[s1] = hh; Hl[s1] = ll;
        }
      }
    }
  }
}

// ---------------------------------------------------------------------------
// pack fp32 [K][N] into single-bf16 B tiles (512 shorts/tile)
__global__ void pack_kernel(const float* __restrict__ W, short* __restrict__ out,
                            const int K, const int N, const int total)
{
  const int p = (int)blockIdx.x * 256 + (int)threadIdx.x;
  if (p >= total) return;
  const int perMat = (K * N) >> 3;
  const int m = p / perMat, r = p - m * perMat;
  const int t = r >> 6, lane = r & 63;
  const int KT = K >> 5;
  const int nt = t / KT, kt = t - nt * KT;
  const int row0 = kt * 32 + (lane >> 4) * 8;
  const int col  = nt * 16 + (lane & 15);
  const float* src = W + (size_t)m * K * N;
  short8 v;
#pragma unroll
  for (int j = 0; j < 8; ++j) v[j] = f2bf(src[(size_t)(row0 + j) * N + col]);
  *reinterpret_cast<short8*>(out + (size_t)p * 8) = v;
}

// pack fp32 [K][N] into split hi/lo B tiles (1024 shorts/tile)
__global__ void pack2_kernel(const float* __restrict__ W, short* __restrict__ out,
                             const int K, const int N, const int total)
{
  const int p = (int)blockIdx.x * 256 + (int)threadIdx.x;
  if (p >= total) return;
  const int perMat = (K * N) >> 3;
  const int m = p / perMat, r = p - m * perMat;
  const int t = r >> 6, lane = r & 63;
  const int KT = K >> 5;
  const int nt = t / KT, kt = t - nt * KT;
  const int row0 = kt * 32 + (lane >> 4) * 8;
  const int col  = nt * 16 + (lane & 15);
  const float* src = W + (size_t)m * K * N;
  short8 vh, vl;
#pragma unroll
  for (int j = 0; j < 8; ++j) {
    short hh, ll;
    split2(src[(size_t)(row0 + j) * N + col], hh, ll);
    vh[j] = hh; vl[j] = ll;
  }
  const size_t T  = (size_t)(perMat >> 6);
  const size_t tg = (size_t)m * T + t;
  *reinterpret_cast<short8*>(out + tg * 1024 + lane * 8)       = vh;
  *reinterpret_cast<short8*>(out + tg * 1024 + 512 + lane * 8) = vl;
}

// ---------------------------------------------------------------------------
// split-bf16 MFMA BERT kernel
struct BertMP {
  const int* ids; const float* tok; const float* pos;
  const float* bqkv; const float* bo; const float* b1; const float* b2;
  const float* ln_s; const float* ln_b; const float* lnf_s; const float* lnf_b;
  const short* pQ; const short* pO; const short* pW1; const short* pW2;
  float* intent;
};

__global__ __launch_bounds__(256, 2) void bert_mfma_kernel(BertMP p)
{
  __shared__ float xs[LTn * Dn];
  __shared__ __align__(16) short xah[32 * 128];
  __shared__ __align__(16) short xal[32 * 128];
  __shared__ __align__(16) float S[LTn * QSTR];
  __shared__ float att[Hn * LTn * LTn];
  __shared__ int pad_s[LTn];
  const int b = blockIdx.x;
  const int tid = (int)threadIdx.x;

  for (int e = tid; e < LTn * Dn; e += 256) {
    const int i = e >> 7, c = e & 127;
    const int id = p.ids[b * LTn + i];
    xs[e] = p.tok[id * Dn + c] + p.pos[e];
  }
  for (int i = tid; i < LTn; i += 256) pad_s[i] = (p.ids[b * LTn + i] == 0) ? 1 : 0;
  for (int e = tid; e < 8 * 128; e += 256) {
    xah[LTn * 128 + e] = 0; xal[LTn * 128 + e] = 0;
  }
  __syncthreads();

  short* Hh = (short*)S;
  short* Hl = Hh + 32 * 256;

  for (int l = 0; l < NLBn; ++l) {
    const short* pQ_l  = p.pQ  + (size_t)l * 98304;
    const short* pO_l  = p.pO  + (size_t)l * 32768;
    const short* pW1_l = p.pW1 + (size_t)l * 131072;
    const short* pW2_l = p.pW2 + (size_t)l * 131072;
    const float* bqkv = p.bqkv + l * 384;
    const float* bo   = p.bo   + l * Dn;
    const float* b1   = p.b1   + l * DFFn;
    const float* b2   = p.b2   + l * Dn;
    const float* lns  = p.ln_s + l * 2 * Dn;
    const float* lnb  = p.ln_b + l * 2 * Dn;

    for (int e = tid; e < LTn * Dn; e += 256) {
      const int r = e >> 7, c = e & 127;
      short hh, ll; split2(xs[e], hh, ll);
      const int s = swz128(r, c);
      xah[s] = hh; xal[s] = ll;
    }
    __syncthreads();
    bgemm<128, 4, 6, 0, true>(xah, xal, pQ_l, 0, 0, 4, bqkv, S, QSTR, nullptr, nullptr);
    __syncthreads();
    attn_scores<LTn, QSTR, true>(S, att, pad_s);
    __syncthreads();
    softmax_rows<LTn>(att);
    __syncthreads();
    for (int e = tid; e < LTn * Dn; e += 256) {
      const int i = e >> 7, c = e & 127, h = c >> 5;
      const float* arow = att + (h * LTn + i) * LTn;
      const float* vp = S + 256 + c;
      float acc = 0.f;
#pragma unroll 4
      for (int j = 0; j < LTn; ++j) acc = fmaf(arow[j], vp[j * QSTR], acc);
      short hh, ll; split2(acc, hh, ll);
      const int s = swz128(i, c);
      xah[s] = hh; xal[s] = ll;
    }
    __syncthreads();
    bgemm<128, 4, 2, 1, true>(xah, xal, pO_l, 0, 0, 4, bo, xs, 128, nullptr, nullptr);
    __syncthreads();
    ln_rows<LTn>(xs, lns, lnb, xs);
    __syncthreads();

    for (int e = tid; e < LTn * Dn; e += 256) {
      const int r = e >> 7, c = e & 127;
      short hh, ll; split2(xs[e], hh, ll);
      const int s = swz128(r, c);
      xah[s] = hh; xal[s] = ll;
    }
    for (int e = tid; e < 8 * 256; e += 256) {
      Hh[LTn * 256 + e] = 0; Hl[LTn * 256 + e] = 0;
    }
    __syncthreads();
    bgemm<128, 4, 4, 2, true>(xah, xal, pW1_l, 0, 0, 4, b1, nullptr, 0, Hh, Hl);
    __syncthreads();
    bgemm<256, 8, 2, 1, true>(Hh, Hl, pW2_l, 0, 0, 16, b2, xs, 128, nullptr, nullptr);
    __syncthreads();
    bgemm<128, 4, 4, 2, true>(xah, xal, pW1_l, 16, 0, 4, b1 + 256, nullptr, 0, Hh, Hl);
    __syncthreads();
    bgemm<256, 8, 2, 1, false>(Hh, Hl, pW2_l, 0, 8, 16, nullptr, xs, 128, nullptr, nullptr);
    __syncthreads();
    ln_rows<LTn>(xs, lns + Dn, lnb + Dn, xs);
    __syncthreads();
  }

  if (tid < 64) {
    const float a0 = xs[tid], a1 = xs[tid + 64];
    float s1 = a0 + a1, s2 = a0 * a0 + a1 * a1;
#pragma unroll
    for (int o = 32; o > 0; o >>= 1) { s1 += __shfl_xor(s1, o); s2 += __shfl_xor(s2, o); }
    const float m  = s1 * (1.f / 128.f);
    const float rs = rsqrtf(s2 * (1.f / 128.f) - m * m + 1e-5f);
    p.intent[b * Dn + tid]      = (a0 - m) * rs * p.lnf_s[tid]      + p.lnf_b[tid];
    p.intent[b * Dn + tid + 64] = (a1 - m) * rs * p.lnf_s[tid + 64] + p.lnf_b[tid + 64];
  }
}

// ---------------------------------------------------------------------------
struct RouterP {
  const float* state; const float* intent;
  const float* se_W1; const float* se_b1; const float* se_W2; const float* se_b2;
  const float* se_ln_s; const float* se_ln_b;
  const float* r_W1; const float* r_b1; const float* r_W2; const float* r_b2;
  const float* r_ln_s; const float* r_ln_b;
  const float* gate_W; const float* gate_b;
  int* ridx; float* rwgt;
};

DEVI void ln128(float* x, const float* gs, const float* gb, float* red)
{
  const int c = (int)threadIdx.x;      // blockDim == 128
  const float a = x[c];
  float s1 = a, s2 = a * a;
#pragma unroll
  for (int o = 32; o > 0; o >>= 1) { s1 += __shfl_xor(s1, o); s2 += __shfl_xor(s2, o); }
  const int wid = c >> 6;
  if ((c & 63) == 0) { red[wid * 2] = s1; red[wid * 2 + 1] = s2; }
  __syncthreads();
  s1 = red[0] + red[2]; s2 = red[1] + red[3];
  const float m  = s1 * (1.f / 128.f);
  const float rs = rsqrtf(s2 * (1.f / 128.f) - m * m + 1e-5f);
  __syncthreads();
  x[c] = (a - m) * rs * gs[c] + gb[c];
}

__global__ __launch_bounds__(128) void router_kernel(RouterP p)
{
  __shared__ float sstate[SDn];
  __shared__ float h1[Dn];
  __shared__ float vv[Dn];
  __shared__ float red[4];
  __shared__ float slog[En];
  const int b = blockIdx.x;
  const int c = (int)threadIdx.x;

  if (c < SDn) sstate[c] = p.state[b * SDn + c];
  __syncthreads();
  {
    float acc = p.se_b1[c];
#pragma unroll
    for (int k = 0; k < SDn; ++k) acc = fmaf(sstate[k], p.se_W1[k * Dn + c], acc);
    h1[c] = geluf(acc);
  }
  __syncthreads();
  {
    float acc = p.se_b2[c];
#pragma unroll 4
    for (int k = 0; k < Dn; ++k) acc = fmaf(h1[k], p.se_W2[k * Dn + c], acc);
    vv[c] = acc;
  }
  __syncthreads();
  ln128(vv, p.se_ln_s, p.se_ln_b, red);
  __syncthreads();
  {
    float acc = p.r_b1[c];
    const float* ib = p.intent + b * Dn;
#pragma unroll 4
    for (int k = 0; k < Dn; ++k) acc = fmaf(ib[k], p.r_W1[k * Dn + c], acc);
#pragma unroll 4
    for (int k = 0; k < Dn; ++k) acc = fmaf(vv[k], p.r_W1[(Dn + k) * Dn + c], acc);
    h1[c] = geluf(acc);
  }
  __syncthreads();
  {
    float acc = p.r_b2[c];
#pragma unroll 4
    for (int k = 0; k < Dn; ++k) acc = fmaf(h1[k], p.r_W2[k * Dn + c], acc);
    vv[c] = acc;
  }
  __syncthreads();
  ln128(vv, p.r_ln_s, p.r_ln_b, red);
  __syncthreads();
  if (c < En) {
    float acc = p.gate_b[c];
#pragma unroll 4
    for (int k = 0; k < Dn; ++k) acc = fmaf(vv[k], p.gate_W[k * En + c], acc);
    slog[c] = acc;
  }
  __syncthreads();
  if (c == 0) {
    int i0 = 0; float v0 = slog[0];
#pragma unroll
    for (int e2 = 1; e2 < En; ++e2) if (slog[e2] > v0) { v0 = slog[e2]; i0 = e2; }
    int i1 = -1; float v1 = -3.4e38f;
#pragma unroll
    for (int e2 = 0; e2 < En; ++e2) if (e2 != i0 && slog[e2] > v1) { v1 = slog[e2]; i1 = e2; }
    const float e1  = expf(v1 - v0);
    const float inv = 1.f / (1.f + e1);
    p.ridx[b * 2 + 0] = i0; p.ridx[b * 2 + 1] = i1;
    p.rwgt[b * 2 + 0] = inv; p.rwgt[b * 2 + 1] = e1 * inv;
  }
}

// ===========================================================================
// PHASE PIPELINE (tier 2): sorted-by-expert grouped GEMMs + per-pair attention
// ===========================================================================

// counting sort of pairs by expert + block schedule. 1 block, 256 threads.
__global__ void sched_kernel(const int* __restrict__ ridx, int* __restrict__ sch,
                             int* plist, int* prow, int* pexp, int* ppos)
{
  __shared__ int scnt[En], scur[En], soff[En], srb[En + 1];
  const int t = (int)threadIdx.x;
  if (t < En) { scnt[t] = 0; scur[t] = 0; }
  __syncthreads();
  for (int p = t; p < PAIRS; p += 256) atomicAdd(&scnt[ridx[p]], 1);
  __syncthreads();
  if (t == 0) {
    int off = 0, rb = 0, k = 0;
    for (int e = 0; e < En; ++e) {
      soff[e] = off; srb[e] = rb;
      const int rows = scnt[e] * 20;
      const int nb = (rows + 127) >> 7;
      for (int q = 0; q < nb; ++q) {
        sch[GEXP_OFF + k] = e;
        sch[GMT_OFF + k]  = (rb >> 4) + q * 8;
        ++k;
      }
      off += scnt[e];
      rb += nb * 128;
    }
    srb[En] = rb;
    sch[0] = k;
    for (int e = 0; e < En; ++e) { sch[1 + e] = scnt[e]; sch[7 + e] = soff[e]; }
    for (int e = 0; e <= En; ++e) sch[13 + e] = srb[e];
  }
  __syncthreads();
  for (int p = t; p < PAIRS; p += 256) {
    const int e = ridx[p];
    const int pos = atomicAdd(&scur[e], 1);
    const int i = soff[e] + pos;
    plist[i] = p; ppos[p] = i; pexp[i] = e; prow[i] = srb[e] + pos * 20;
  }
}

// X init: real rows = qpe, padded rows = 0
__global__ void xinit_kernel(const float* __restrict__ qpe, const int* __restrict__ sch,
                             float* __restrict__ X)
{
  const int idx = (int)blockIdx.x * 256 + (int)threadIdx.x;  // quad index
  const int row = idx >> 5;
  if (row >= MPMAX) return;
  const int c4 = (idx & 31) * 4;
  const int* RB = sch + 13;
  float4 v = {0.f, 0.f, 0.f, 0.f};
  int e = 0;
  while (e < En && row >= RB[e + 1]) ++e;
  if (e < En) {
    const int local = row - RB[e];
    if (local < sch[1 + e] * 20) {
      const int r = local - (local / 20) * 20;
      v = *reinterpret_cast<const float4*>(qpe + r * 128 + c4);
    }
  }
  *reinterpret_cast<float4*>(X + (size_t)row * 128 + c4) = v;
}

// LN over X rows -> packed bf16 A-fragments. 16 rows/block.
__global__ __launch_bounds__(256) void ln_pack_kernel(
    const float* __restrict__ X, short* __restrict__ XnP,
    const float* __restrict__ lns_all, const float* __restrict__ lnb_all,
    const int subOff, const int* __restrict__ sch)
{
  const int* RB = sch + 13;
  const int mt = (int)blockIdx.x;
  const int row0 = mt << 4;
  if (row0 >= RB[En]) return;
  int e = 0;
  while (e < En - 1 && row0 >= RB[e + 1]) ++e;
  const float* gs = lns_all + e * (NLDn * 3 * 128) + subOff;
  const float* gb = lnb_all + e * (NLDn * 3 * 128) + subOff;
  const int t = (int)threadIdx.x;
  const int rl = t >> 4, j = t & 15;
  const int row = row0 + rl;
  float x[8];
  {
    const float4 a = *reinterpret_cast<const float4*>(X + (size_t)row * 128 + j * 8);
    const float4 bq = *reinterpret_cast<const float4*>(X + (size_t)row * 128 + j * 8 + 4);
    x[0] = a.x; x[1] = a.y; x[2] = a.z; x[3] = a.w;
    x[4] = bq.x; x[5] = bq.y; x[6] = bq.z; x[7] = bq.w;
  }
  float s1 = 0.f, s2 = 0.f;
#pragma unroll
  for (int u = 0; u < 8; ++u) { s1 += x[u]; s2 += x[u] * x[u]; }
#pragma unroll
  for (int o = 1; o < 16; o <<= 1) { s1 += __shfl_xor(s1, o); s2 += __shfl_xor(s2, o); }
  const float m  = s1 * (1.f / 128.f);
  const float rs = rsqrtf(s2 * (1.f / 128.f) - m * m + 1e-5f);
  short8 pk;
#pragma unroll
  for (int u = 0; u < 8; ++u)
    pk[u] = f2bf((x[u] - m) * rs * gs[j * 8 + u] + gb[j * 8 + u]);
  const int kt = j >> 2, g = j & 3, lp = g * 16 + rl;
  *reinterpret_cast<short8*>(XnP + (((size_t)mt * 4 + kt) * 64 + lp) * 8) = pk;
}

// grouped GEMM, K=128 (packed A, 4 k-tiles). EPI: 0 QKV f32 stride 384,
// 1 X += (stride 128), 2 store f32 stride 128, 3 relu -> packed bf16 K=256.
template<int NTW, int EPI, bool HASB>
__global__ __launch_bounds__(256) void gemm_k128(
    const short* __restrict__ A, const short* __restrict__ Bb, const int strideB,
    const float* __restrict__ biasb, const int strideBias, const int ntOff,
    float* __restrict__ OutF, short* __restrict__ OutP, const int* __restrict__ sch)
{
  const int k = (int)blockIdx.x;
  if (k >= sch[0]) return;
  const int ex  = sch[GEXP_OFF + k];
  const int mt0 = sch[GMT_OFF + k];
  const short* Bp = Bb + (size_t)ex * strideB;
  const float* bias = biasb + (size_t)ex * strideBias;
  const int lane = (int)threadIdx.x & 63, wv = (int)threadIdx.x >> 6;
  const int r0 = lane & 15, g = lane >> 4;
  short8 bf[NTW][4];
#pragma unroll
  for (int i = 0; i < NTW; ++i)
#pragma unroll
    for (int kt = 0; kt < 4; ++kt)
      bf[i][kt] = *reinterpret_cast<const short8*>(
          Bp + (((size_t)(ntOff + wv * NTW + i) * 4 + kt) * 64 + lane) * 8);
#pragma unroll 2
  for (int mt = 0; mt < 8; ++mt) {
    short8 a[4];
#pragma unroll
    for (int kt = 0; kt < 4; ++kt)
      a[kt] = *reinterpret_cast<const short8*>(
          A + (((size_t)(mt0 + mt) * 4 + kt) * 64 + lane) * 8);
#pragma unroll
    for (int i = 0; i < NTW; ++i) {
      f32x4v c = {0.f, 0.f, 0.f, 0.f};
#pragma unroll
      for (int kt = 0; kt < 4; ++kt)
        c = __builtin_amdgcn_mfma_f32_16x16x32_bf16(a[kt], bf[i][kt], c, 0, 0, 0);
      const int colL = (wv * NTW + i) * 16 + r0;
      const float bb = HASB ? bias[colL] : 0.f;
      const int rowB = (mt0 + mt) * 16 + g * 4;
#pragma unroll
      for (int q = 0; q < 4; ++q) {
        const int row = rowB + q;
        const float v = c[q] + bb;
        if (EPI == 0)      OutF[(size_t)row * 384 + colL] = v;
        else if (EPI == 1) OutF[(size_t)row * 128 + colL] += v;
        else if (EPI == 2) OutF[(size_t)row * 128 + colL] = v;
        else {
          const float rv = fmaxf(v, 0.f);
          const int j = colL >> 3, kt2 = j >> 2, g2 = j & 3;
          const int lp = g2 * 16 + (row & 15);
          OutP[(((size_t)(row >> 4) * 8 + kt2) * 64 + lp) * 8 + (colL & 7)] = f2bf(rv);
        }
      }
    }
  }
}

// grouped GEMM, K=256 half of 512 (packed A: 8 k-tiles). X += (+bias if HASB).
template<bool HASB>
__global__ __launch_bounds__(256) void gemm_k256(
    const short* __restrict__ A, const short* __restrict__ Bb, const int strideB,
    const float* __restrict__ biasb, const int strideBias, const int ktOff,
    float* __restrict__ X, const int* __restrict__ sch)
{
  const int k = (int)blockIdx.x;
  if (k >= sch[0]) return;
  const int ex  = sch[GEXP_OFF + k];
  const int mt0 = sch[GMT_OFF + k];
  const short* Bp = Bb + (size_t)ex * strideB;
  const float* bias = biasb + (size_t)ex * strideBias;
  const int lane = (int)threadIdx.x & 63, wv = (int)threadIdx.x >> 6;
  const int r0 = lane & 15, g = lane >> 4;
  short8 bf[2][8];
#pragma unroll
  for (int i = 0; i < 2; ++i)
#pragma unroll
    for (int kk = 0; kk < 8; ++kk)
      bf[i][kk] = *reinterpret_cast<const short8*>(
          Bp + (((size_t)(wv * 2 + i) * 16 + ktOff + kk) * 64 + lane) * 8);
#pragma unroll 2
  for (int mt = 0; mt < 8; ++mt) {
    short8 a[8];
#pragma unroll
    for (int kk = 0; kk < 8; ++kk)
      a[kk] = *reinterpret_cast<const short8*>(
          A + (((size_t)(mt0 + mt) * 8 + kk) * 64 + lane) * 8);
#pragma unroll
    for (int i = 0; i < 2; ++i) {
      f32x4v c = {0.f, 0.f, 0.f, 0.f};
#pragma unroll
      for (int kk = 0; kk < 8; ++kk)
        c = __builtin_amdgcn_mfma_f32_16x16x32_bf16(a[kk], bf[i][kk], c, 0, 0, 0);
      const int colL = (wv * 2 + i) * 16 + r0;
      const float bb = HASB ? bias[colL] : 0.f;
      const int rowB = (mt0 + mt) * 16 + g * 4;
#pragma unroll
      for (int q = 0; q < 4; ++q)
        X[(size_t)(rowB + q) * 128 + colL] += c[q] + bb;
    }
  }
}

// per-pair self-attention: QKV f32 -> O packed bf16
__global__ __launch_bounds__(256) void sattn_kernel(
    const float* __restrict__ QKV, const int* __restrict__ prow,
    short* __restrict__ ANP)
{
  __shared__ float qkv[CSn * QSTR];
  __shared__ float att[Hn * CSn * CSn];
  const int i = (int)blockIdx.x;
  const int row0 = prow[i];
  for (int e4 = (int)threadIdx.x; e4 < CSn * 96; e4 += 256) {
    const int il = e4 / 96, c4 = e4 - il * 96;
    *reinterpret_cast<float4*>(qkv + il * QSTR + c4 * 4) =
        *reinterpret_cast<const float4*>(QKV + (size_t)(row0 + il) * 384 + c4 * 4);
  }
  __syncthreads();
  attn_scores<CSn, QSTR, false>(qkv, att, nullptr);
  __syncthreads();
  softmax_rows<CSn>(att);
  __syncthreads();
  for (int e = (int)threadIdx.x; e < CSn * Dn; e += 256) {
    const int il = e >> 7, c = e & 127, h = c >> 5;
    const float* arow = att + (h * CSn + il) * CSn;
    const float* vp = qkv + 256 + c;
    float acc = 0.f;
#pragma unroll 4
    for (int j = 0; j < CSn; ++j) acc = fmaf(arow[j], vp[j * QSTR], acc);
    const int row = row0 + il;
    const int j2 = c >> 3, kt = j2 >> 2, g2 = j2 & 3;
    const int lp = g2 * 16 + (row & 15);
    ANP[(((size_t)(row >> 4) * 4 + kt) * 64 + lp) * 8 + (c & 7)] = f2bf(acc);
  }
}

// per-pair cross-attention (2 keys): Qc f32 -> co packed bf16
__global__ __launch_bounds__(256) void cattn_kernel(
    const float* __restrict__ Qc, const float* __restrict__ state,
    const float* __restrict__ sp_W, const float* __restrict__ sp_b,
    const float* __restrict__ zp_b, const float* __restrict__ aW,
    const float* __restrict__ ab, const int layer,
    const int* __restrict__ plist, const int* __restrict__ prow,
    const int* __restrict__ pexp, short* __restrict__ ANP)
{
  __shared__ float q[CSn * Dn];
  __shared__ float mem[2 * Dn];
  __shared__ float memkv[2 * 256];
  __shared__ float catt[2 * Hn * CSn];
  const int i = (int)blockIdx.x;
  const int ex = pexp[i];
  const int orig = plist[i];
  const int b = orig >> 1;
  const int row0 = prow[i];
  const int li = ex * NLDn + layer;
  const float* aW1f = aW + (size_t)(li * 2 + 1) * Dn * 384;
  const float* ab1  = ab + (size_t)(li * 2 + 1) * 384;
  const int tid = (int)threadIdx.x;

  if (tid < Dn) {
    float acc = sp_b[ex * Dn + tid];
    const float* spw = sp_W + ex * SDn * Dn;
#pragma unroll
    for (int kk = 0; kk < SDn; ++kk) acc = fmaf(state[b * SDn + kk], spw[kk * Dn + tid], acc);
    mem[tid] = acc;
  } else {
    mem[Dn + (tid - Dn)] = zp_b[ex * Dn + (tid - Dn)];
  }
  for (int e4 = tid; e4 < CSn * 32; e4 += 256) {
    const int il = e4 >> 5, c4 = (e4 & 31) * 4;
    *reinterpret_cast<float4*>(q + il * Dn + c4) =
        *reinterpret_cast<const float4*>(Qc + (size_t)(row0 + il) * 128 + c4);
  }
  __syncthreads();
  for (int e = tid; e < 2 * 256; e += 256) {
    const int j = e >> 8, c2 = e & 255;
    float acc = ab1[Dn + c2];
    const float* wp = aW1f + Dn + c2;
#pragma unroll 4
    for (int kk = 0; kk < Dn; ++kk) acc = fmaf(mem[j * Dn + kk], wp[kk * 384], acc);
    memkv[j * 256 + c2] = acc;
  }
  __syncthreads();
  for (int e = tid; e < Hn * CSn; e += 256) {
    const int h = e / CSn, il = e % CSn;
    const float* qp = q + il * Dn + h * DHn;
    float s0 = 0.f, s1 = 0.f;
#pragma unroll
    for (int d = 0; d < DHn; d += 4) {
      const float4 q4 = *reinterpret_cast<const float4*>(qp + d);
      const float4 k0 = *reinterpret_cast<const float4*>(memkv + 0 * 256 + h * DHn + d);
      const float4 k1 = *reinterpret_cast<const float4*>(memkv + 1 * 256 + h * DHn + d);
      s0 += q4.x * k0.x + q4.y * k0.y + q4.z * k0.z + q4.w * k0.w;
      s1 += q4.x * k1.x + q4.y * k1.y + q4.z * k1.z + q4.w * k1.w;
    }
    s0 *= INV_SQRT_DH; s1 *= INV_SQRT_DH;
    const float m = fmaxf(s0, s1);
    const float e0 = expf(s0 - m), e1 = expf(s1 - m);
    const float inv = 1.f / (e0 + e1);
    catt[e * 2] = e0 * inv; catt[e * 2 + 1] = e1 * inv;
  }
  __syncthreads();
  for (int e = tid; e < CSn * Dn; e += 256) {
    const int il = e >> 7, c = e & 127, h = c >> 5;
    const int a = (h * CSn + il) * 2;
    const float v = catt[a]     * memkv[0 * 256 + Dn + c]
                  + catt[a + 1] * memkv[1 * 256 + Dn + c];
    const int row = row0 + il;
    const int j2 = c >> 3, kt = j2 >> 2, g2 = j2 & 3;
    const int lp = g2 * 16 + (row & 15);
    ANP[(((size_t)(row >> 4) * 4 + kt) * 64 + lp) * 8 + (c & 7)] = f2bf(v);
  }
}

// per-pair head: Rbuf[i] = wgt * (X_rows @ headW + headB)
__global__ __launch_bounds__(256) void head_kernel(
    const float* __restrict__ X, const int* __restrict__ plist,
    const int* __restrict__ prow, const int* __restrict__ pexp,
    const float* __restrict__ rwgt, const float* __restrict__ hW,
    const float* __restrict__ hb, float* __restrict__ Rbuf)
{
  __shared__ float xr[CSn * Dn];
  const int i = (int)blockIdx.x;
  const int ex = pexp[i];
  const int orig = plist[i];
  const int row0 = prow[i];
  const float wgt = rwgt[orig];
  for (int e4 = (int)threadIdx.x; e4 < CSn * 32; e4 += 256) {
    const int il = e4 >> 5, c4 = (e4 & 31) * 4;
    *reinterpret_cast<float4*>(xr + il * Dn + c4) =
        *reinterpret_cast<const float4*>(X + (size_t)(row0 + il) * 128 + c4);
  }
  __syncthreads();
  const int e = (int)threadIdx.x;
  if (e < CSn * JDn) {
    const int t = e / JDn, j = e - t * JDn;
    const float* w = hW + ex * Dn * JDn + j;
    float acc = hb[ex * JDn + j];
#pragma unroll 4
    for (int kk = 0; kk < Dn; ++kk) acc = fmaf(xr[t * Dn + kk], w[kk * JDn], acc);
    Rbuf[(size_t)i * 140 + e] = wgt * acc;
  }
}

__global__ void combine_kernel(const float* __restrict__ Rbuf,
                               const int* __restrict__ ppos, float* __restrict__ out)
{
  const int idx = (int)blockIdx.x * 256 + (int)threadIdx.x;
  if (idx >= Bn * 140) return;
  const int b = idx / 140, e = idx - b * 140;
  out[idx] = Rbuf[(size_t)ppos[2 * b] * 140 + e] + Rbuf[(size_t)ppos[2 * b + 1] * 140 + e];
}

// ---------------------------------------------------------------------------
// tier-1 monolithic MFMA expert kernel (fallback when ws too small for tier 2)
struct ExpertMP {
  const float* state; const float* qpe; const int* ridx; const float* rwgt;
  const float* sp_W; const float* sp_b; const float* zp_b;
  const float* aW; const float* ab; const float* abo;
  const float* ln_s; const float* ln_b;
  const float* fb1; const float* fb2;
  const float* headW; const float* headB;
  const short* pQ; const short* pO; const short* pF1; const short* pF2;
  float* out;
};

__global__ __launch_bounds__(256, 3) void expert_mfma_kernel(ExpertMP p)
{
  __shared__ float xs[CSn * Dn];
  __shared__ __align__(16) short xb[32 * 128];
  __shared__ float scr[CSn * QSTR];
  __shared__ float mem[2 * Dn];
  __shared__ float memkv[2 * 256];
  __shared__ float outacc[CSn * JDn];
  const int b = blockIdx.x;
  const int tid = (int)threadIdx.x;

  for (int e = tid; e < CSn * JDn; e += 256) outacc[e] = 0.f;
  for (int e = tid; e < 12 * 128; e += 256) xb[CSn * 128 + e] = 0;

  for (int slot = 0; slot < 2; ++slot) {
    const int   ex  = p.ridx[b * 2 + slot];
    const float wgt = p.rwgt[b * 2 + slot];

    if (tid < Dn) {
      float acc = p.sp_b[ex * Dn + tid];
      const float* spw = p.sp_W + ex * SDn * Dn;
#pragma unroll
      for (int k = 0; k < SDn; ++k) acc = fmaf(p.state[b * SDn + k], spw[k * Dn + tid], acc);
      mem[tid] = acc;
    } else {
      mem[Dn + (tid - Dn)] = p.zp_b[ex * Dn + (tid - Dn)];
    }
    for (int e = tid; e < CSn * Dn; e += 256) xs[e] = p.qpe[e];
    __syncthreads();

    for (int l = 0; l < NLDn; ++l) {
      const int li = ex * NLDn + l;
      const short* wq0 = p.pQ + (size_t)(li * 2 + 0) * 49152;
      const short* wq1 = p.pQ + (size_t)(li * 2 + 1) * 49152;
      const short* wo0 = p.pO + (size_t)(li * 2 + 0) * 16384;
      const short* wo1 = p.pO + (size_t)(li * 2 + 1) * 16384;
      const short* w1p = p.pF1 + (size_t)li * 65536;
      const short* w2p = p.pF2 + (size_t)li * 65536;
      const float* ab0 = p.ab  + (size_t)(li * 2 + 0) * 384;
      const float* ab1 = p.ab  + (size_t)(li * 2 + 1) * 384;
      const float* bo0 = p.abo + (li * 2 + 0) * Dn;
      const float* bo1 = p.abo + (li * 2 + 1) * Dn;
      const float* lns = p.ln_s + li * 3 * Dn;
      const float* lnb = p.ln_b + li * 3 * Dn;
      const float* fb1 = p.fb1 + li * DFFn;
      const float* fb2 = p.fb2 + li * Dn;
      const float* aW1f = p.aW + (size_t)(li * 2 + 1) * Dn * 384;

      ln_rows_bf(xs, lns, lnb, xb);
      __syncthreads();
      mfma_gemm<128, 4, 6, 0, true>(xb, wq0, 0, 0, 4, ab0, scr, QSTR, nullptr);
      __syncthreads();
      attn_scores<CSn, QSTR, false>(scr, (float*)xb, nullptr);
      __syncthreads();
      softmax_rows<CSn>((float*)xb);
      __syncthreads();
      attn_av<CSn, QSTR>(scr, (float*)xb, scr, QSTR);
      __syncthreads();
      for (int e = tid; e < CSn * Dn; e += 256) {
        const int i = e >> 7, c = e & 127;
        xbW128(xb, i, c, scr[i * QSTR + c]);
      }
      for (int e = tid; e < 12 * 128; e += 256) xb[CSn * 128 + e] = 0;
      __syncthreads();
      mfma_gemm<128, 4, 2, 1, true>(xb, wo0, 0, 0, 4, bo0, xs, 128, nullptr);
      __syncthreads();

      ln_rows_bf(xs, lns + Dn, lnb + Dn, xb);
      __syncthreads();
      mfma_gemm<128, 4, 2, 0, true>(xb, wq1, 0, 0, 4, ab1, scr, 128, nullptr);
      for (int e = tid; e < 2 * 256; e += 256) {
        const int j = e >> 8, c2 = e & 255;
        float acc = ab1[Dn + c2];
        const float* wp = aW1f + Dn + c2;
#pragma unroll 4
        for (int k = 0; k < Dn; ++k) acc = fmaf(mem[j * Dn + k], wp[k * 384], acc);
        memkv[j * 256 + c2] = acc;
      }
      __syncthreads();
      float* catt = scr + CSn * Dn;
      for (int e = tid; e < Hn * CSn; e += 256) {
        const int h = e / CSn, i = e % CSn;
        const float* qp = scr + i * Dn + h * DHn;
        float s0 = 0.f, s1 = 0.f;
#pragma unroll
        for (int d = 0; d < DHn; d += 4) {
          const float4 q4 = *reinterpret_cast<const float4*>(qp + d);
          const float4 k0 = *reinterpret_cast<const float4*>(memkv + 0 * 256 + h * DHn + d);
          const float4 k1 = *reinterpret_cast<const float4*>(memkv + 1 * 256 + h * DHn + d);
          s0 += q4.x * k0.x + q4.y * k0.y + q4.z * k0.z + q4.w * k0.w;
          s1 += q4.x * k1.x + q4.y * k1.y + q4.z * k1.z + q4.w * k1.w;
        }
        s0 *= INV_SQRT_DH; s1 *= INV_SQRT_DH;
        const float m = fmaxf(s0, s1);
        const float e0 = expf(s0 - m), e1 = expf(s1 - m);
        const float inv = 1.f / (e0 + e1);
        catt[e * 2] = e0 * inv; catt[e * 2 + 1] = e1 * inv;
      }
      __syncthreads();
      for (int e = tid; e < CSn * Dn; e += 256) {
        const int i = e >> 7, c = e & 127, h = c >> 5;
        const int a = (h * CSn + i) * 2;
        const float v = catt[a]     * memkv[0 * 256 + Dn + c]
                      + catt[a + 1] * memkv[1 * 256 + Dn + c];
        xbW128(xb, i, c, v);
      }
      __syncthreads();
      mfma_gemm<128, 4, 2, 1, true>(xb, wo1, 0, 0, 4, bo1, xs, 128, nullptr);
      __syncthreads();

      ln_rows_bf(xs, lns + 2 * Dn, lnb + 2 * Dn, xb);
      short* hbuf = (short*)scr;
      for (int e = tid; e < 12 * 256; e += 256) hbuf[CSn * 256 + e] = 0;
      __syncthreads();
      mfma_gemm<128, 4, 4, 2, true>(xb, w1p, 0, 0, 4, fb1, nullptr, 0, hbuf);
      __syncthreads();
      mfma_gemm<256, 8, 2, 1, true>(hbuf, w2p, 0, 0, 16, fb2, xs, 128, nullptr);
      __syncthreads();
      mfma_gemm<128, 4, 4, 2, true>(xb, w1p, 16, 0, 4, fb1 + 256, nullptr, 0, hbuf);
      __syncthreads();
      mfma_gemm<256, 8, 2, 1, false>(hbuf, w2p, 0, 8, 16, nullptr, xs, 128, nullptr);
      __syncthreads();
    }

    const float* hw = p.headW + ex * Dn * JDn;
    for (int e = tid; e < CSn * JDn; e += 256) {
      const int t = e / JDn, j = e % JDn;
      float acc = p.headB[ex * JDn + j];
#pragma unroll 4
      for (int k = 0; k < Dn; ++k) acc = fmaf(xs[t * Dn + k], hw[k * JDn + j], acc);
      outacc[e] = fmaf(wgt, acc, outacc[e]);
    }
    __syncthreads();
  }

  for (int e = tid; e < CSn * JDn; e += 256) p.out[b * CSn * JDn + e] = outacc[e];
}

// ---------------------------------------------------------------------------
__global__ void qpe_kernel(float* qpe)
{
  const int e = (int)blockIdx.x * 256 + (int)threadIdx.x;
  if (e < CSn * Dn) {
    const int t = e >> 7, d = e & 127;
    const float j  = (float)(d & ~1);
    const float dv = expf(j * (-logf(10000.f) / 128.f));
    const float a  = (float)t * dv;
    qpe[e] = (d & 1) ? cosf(a) : sinf(a);
  }
}

} // namespace

// ---------------------------------------------------------------------------
extern "C" void kernel_launch(void* const* d_in, const int* in_sizes, int n_in,
                              void* d_out, int out_size, void* d_ws, size_t ws_size,
                              hipStream_t stream)
{
  (void)in_sizes; (void)n_in; (void)out_size;

  const int*   ids     = (const int*)  d_in[0];
  const float* state   = (const float*)d_in[1];
  const float* tok_emb = (const float*)d_in[2];
  const float* pos_emb = (const float*)d_in[3];

  // workspace layout (256B-aligned cursor)
  char* cur = (char*)d_ws;
  auto alloc = [&cur](size_t bytes) -> char* {
    char* p = cur; cur += (bytes + 255) & ~(size_t)255; return p;
  };
  float* qpe    = (float*)alloc(4096 * 4);
  float* intent = (float*)alloc((size_t)Bn * Dn * 4);
  int*   ridx   = (int*)  alloc(PAIRS * 4);
  float* rwgt   = (float*)alloc(PAIRS * 4);
  short* pQ     = (short*)alloc((size_t)36 * 49152 * 2);
  short* pO     = (short*)alloc((size_t)36 * 16384 * 2);
  short* pF1    = (short*)alloc((size_t)18 * 65536 * 2);
  short* pF2    = (short*)alloc((size_t)18 * 65536 * 2);
  short* pbQ    = (short*)alloc((size_t)4 * 98304 * 2);
  short* pbO    = (short*)alloc((size_t)4 * 32768 * 2);
  short* pbW1   = (short*)alloc((size_t)4 * 131072 * 2);
  short* pbW2   = (short*)alloc((size_t)4 * 131072 * 2);
  const size_t NEEDED1 = (size_t)(cur - (char*)d_ws);
  int*   sch    = (int*)  alloc(2048 * 4);
  int*   plist  = (int*)  alloc(PAIRS * 4);
  int*   prow   = (int*)  alloc(PAIRS * 4);
  int*   pexp   = (int*)  alloc(PAIRS * 4);
  int*   ppos   = (int*)  alloc(PAIRS * 4);
  float* X      = (float*)alloc((size_t)MPMAX * 128 * 4);
  short* ANP    = (short*)alloc((size_t)MPMAX * 128 * 2);
  float* SB     = (float*)alloc((size_t)MPMAX * 384 * 4);  // QKV f32 / Qc / HP(bf16)
  float* Rbuf   = (float*)alloc((size_t)PAIRS * 140 * 4);
  const size_t NEEDED2 = (size_t)(cur - (char*)d_ws);

  const bool t1 = (ws_size >= NEEDED1);
  const bool t2 = (ws_size >= NEEDED2);
  if (!t1) return;  // environment guarantees ws >= NEEDED1 (observed rounds 2-3)

  qpe_kernel<<<dim3(10), dim3(256), 0, stream>>>(qpe);

  // ---- weight packing
  {
    const int tq = 36 * 6144;
    pack_kernel<<<dim3((tq + 255) / 256), dim3(256), 0, stream>>>(
        (const float*)d_in[34], pQ, 128, 384, tq);
    const int to = 36 * 2048;
    pack_kernel<<<dim3((to + 255) / 256), dim3(256), 0, stream>>>(
        (const float*)d_in[36], pO, 128, 128, to);
    const int t1c = 18 * 8192;
    pack_kernel<<<dim3((t1c + 255) / 256), dim3(256), 0, stream>>>(
        (const float*)d_in[40], pF1, 128, 512, t1c);
    const int t2c = 18 * 8192;
    pack_kernel<<<dim3((t2c + 255) / 256), dim3(256), 0, stream>>>(
        (const float*)d_in[42], pF2, 512, 128, t2c);
    const int bq = 4 * 6144;
    pack2_kernel<<<dim3((bq + 255) / 256), dim3(256), 0, stream>>>(
        (const float*)d_in[4], pbQ, 128, 384, bq);
    const int bo = 4 * 2048;
    pack2_kernel<<<dim3((bo + 255) / 256), dim3(256), 0, stream>>>(
        (const float*)d_in[6], pbO, 128, 128, bo);
    const int bw1 = 4 * 8192;
    pack2_kernel<<<dim3((bw1 + 255) / 256), dim3(256), 0, stream>>>(
        (const float*)d_in[8], pbW1, 128, 512, bw1);
    const int bw2 = 4 * 8192;
    pack2_kernel<<<dim3((bw2 + 255) / 256), dim3(256), 0, stream>>>(
        (const float*)d_in[10], pbW2, 512, 128, bw2);
  }

  // ---- BERT (split-bf16 MFMA)
  {
    BertMP bp;
    bp.ids  = ids; bp.tok = tok_emb; bp.pos = pos_emb;
    bp.bqkv = (const float*)d_in[5];  bp.bo = (const float*)d_in[7];
    bp.b1   = (const float*)d_in[9];  bp.b2 = (const float*)d_in[11];
    bp.ln_s = (const float*)d_in[12]; bp.ln_b = (const float*)d_in[13];
    bp.lnf_s= (const float*)d_in[14]; bp.lnf_b= (const float*)d_in[15];
    bp.pQ = pbQ; bp.pO = pbO; bp.pW1 = pbW1; bp.pW2 = pbW2;
    bp.intent = intent;
    bert_mfma_kernel<<<dim3(Bn), dim3(256), 0, stream>>>(bp);
  }

  // ---- router
  {
    RouterP rp;
    rp.state = state; rp.intent = intent;
    rp.se_W1 = (const float*)d_in[16]; rp.se_b1 = (const float*)d_in[17];
    rp.se_W2 = (const float*)d_in[18]; rp.se_b2 = (const float*)d_in[19];
    rp.se_ln_s = (const float*)d_in[20]; rp.se_ln_b = (const float*)d_in[21];
    rp.r_W1 = (const float*)d_in[22]; rp.r_b1 = (const float*)d_in[23];
    rp.r_W2 = (const float*)d_in[24]; rp.r_b2 = (const float*)d_in[25];
    rp.r_ln_s = (const float*)d_in[26]; rp.r_ln_b = (const float*)d_in[27];
    rp.gate_W = (const float*)d_in[28]; rp.gate_b = (const float*)d_in[29];
    rp.ridx = ridx; rp.rwgt = rwgt;
    router_kernel<<<dim3(Bn), dim3(128), 0, stream>>>(rp);
  }

  const float* sp_W = (const float*)d_in[30];
  const float* sp_b = (const float*)d_in[31];
  const float* zp_b = (const float*)d_in[33];
  const float* aW   = (const float*)d_in[34];
  const float* ab   = (const float*)d_in[35];
  const float* abo  = (const float*)d_in[37];
  const float* lnsA = (const float*)d_in[38];
  const float* lnbA = (const float*)d_in[39];
  const float* fb1A = (const float*)d_in[41];
  const float* fb2A = (const float*)d_in[43];
  const float* hW   = (const float*)d_in[44];
  const float* hB   = (const float*)d_in[45];

  if (t2) {
    // ---- tier-2 phase pipeline
    sched_kernel<<<dim3(1), dim3(256), 0, stream>>>(ridx, sch, plist, prow, pexp, ppos);
    xinit_kernel<<<dim3(MPMAX * 32 / 256), dim3(256), 0, stream>>>(qpe, sch, X);
    short* HP = (short*)SB;
    for (int l = 0; l < NLDn; ++l) {
      // self-attention block
      ln_pack_kernel<<<dim3(MPMAX / 16), dim3(256), 0, stream>>>(
          X, ANP, lnsA, lnbA, (l * 3 + 0) * 128, sch);
      gemm_k128<6, 0, true><<<dim3(NBGMAX), dim3(256), 0, stream>>>(
          ANP, pQ + (l * 2 + 0) * 49152, 294912,
          ab + (l * 2 + 0) * 384, 2304, 0, SB, nullptr, sch);
      sattn_kernel<<<dim3(PAIRS), dim3(256), 0, stream>>>(SB, prow, ANP);
      gemm_k128<2, 1, true><<<dim3(NBGMAX), dim3(256), 0, stream>>>(
          ANP, pO + (l * 2 + 0) * 16384, 98304,
          abo + (l * 2 + 0) * 128, 768, 0, X, nullptr, sch);
      // cross-attention block
      ln_pack_kernel<<<dim3(MPMAX / 16), dim3(256), 0, stream>>>(
          X, ANP, lnsA, lnbA, (l * 3 + 1) * 128, sch);
      gemm_k128<2, 2, true><<<dim3(NBGMAX), dim3(256), 0, stream>>>(
          ANP, pQ + (l * 2 + 1) * 49152, 294912,
          ab + (l * 2 + 1) * 384, 2304, 0, SB, nullptr, sch);
      cattn_kernel<<<dim3(PAIRS), dim3(256), 0, stream>>>(
          SB, state, sp_W, sp_b, zp_b, aW, ab, l, plist, prow, pexp, ANP);
      gemm_k128<2, 1, true><<<dim3(NBGMAX), dim3(256), 0, stream>>>(
          ANP, pO + (l * 2 + 1) * 16384, 98304,
          abo + (l * 2 + 1) * 128, 768, 0, X, nullptr, sch);
      // FFN block (two 256-col halves)
      ln_pack_kernel<<<dim3(MPMAX / 16), dim3(256), 0, stream>>>(
          X, ANP, lnsA, lnbA, (l * 3 + 2) * 128, sch);
      gemm_k128<4, 3, true><<<dim3(NBGMAX), dim3(256), 0, stream>>>(
          ANP, pF1 + l * 65536, 196608,
          fb1A + l * 512 + 0 * 256, 1536, 0, nullptr, HP, sch);
      gemm_k256<true><<<dim3(NBGMAX), dim3(256), 0, stream>>>(
          HP, pF2 + l * 65536, 196608, fb2A + l * 128, 384, 0, X, sch);
      gemm_k128<4, 3, true><<<dim3(NBGMAX), dim3(256), 0, stream>>>(
          ANP, pF1 + l * 65536, 196608,
          fb1A + l * 512 + 1 * 256, 1536, 16, nullptr, HP, sch);
      gemm_k256<false><<<dim3(NBGMAX), dim3(256), 0, stream>>>(
          HP, pF2 + l * 65536, 196608, fb2A + l * 128, 384, 8, X, sch);
    }
    head_kernel<<<dim3(PAIRS), dim3(256), 0, stream>>>(
        X, plist, prow, pexp, rwgt, hW, hB, Rbuf);
    combine_kernel<<<dim3((Bn * 140 + 255) / 256), dim3(256), 0, stream>>>(
        Rbuf, ppos, (float*)d_out);
  } else {
    // ---- tier-1 monolithic fallback
    ExpertMP ep;
    ep.state = state; ep.qpe = qpe; ep.ridx = ridx; ep.rwgt = rwgt;
    ep.sp_W = sp_W; ep.sp_b = sp_b; ep.zp_b = zp_b;
    ep.aW = aW; ep.ab = ab; ep.abo = abo;
    ep.ln_s = lnsA; ep.ln_b = lnbA;
    ep.fb1 = fb1A; ep.fb2 = fb2A;
    ep.headW = hW; ep.headB = hB;
    ep.pQ = pQ; ep.pO = pO; ep.pF1 = pF1; ep.pF2 = pF2;
    ep.out = (float*)d_out;
    expert_mfma_kernel<<<dim3(Bn), dim3(256), 0, stream>>>(ep);
  }
}

// Round 5
// 1919.397 us; speedup vs baseline: 3.6392x; 1.0866x over previous
//
#include <hip/hip_runtime.h>
#include <math.h>

#define DEVI __device__ __forceinline__

namespace {

constexpr int Bn   = 2048;
constexpr int En   = 6;
constexpr int Hn   = 4;
constexpr int Dn   = 128;
constexpr int DHn  = 32;
constexpr int LTn  = 24;   // text length
constexpr int CSn  = 20;   // chunk (decoder query) length
constexpr int JDn  = 7;
constexpr int SDn  = 16;
constexpr int NLBn = 4;
constexpr int NLDn = 3;
constexpr int DFFn = 512;
constexpr int QSTR = 388;  // qkv LDS row stride (388 mod 32 = 4 -> no 32-way bank conflicts)
constexpr float INV_SQRT_DH = 0.17677669529663687f;  // 1/sqrt(32)

// expert phase-pipeline geometry
constexpr int PAIRS  = 4096;                  // 2048 items x top-2
constexpr int MPMAX  = PAIRS * 20 + En * 128; // padded rows (per-expert 128-aligned)
constexpr int NBGMAX = PAIRS * 20 / 128 + En; // 646 grouped-GEMM blocks max
constexpr int GEXP_OFF = 64;
constexpr int GMT_OFF  = 64 + NBGMAX;

// BERT pipeline geometry
constexpr int ROWSB = Bn * LTn;               // 49152 rows, 3072 M-tiles, no padding

typedef float f32x4v __attribute__((ext_vector_type(4)));
typedef short short8 __attribute__((ext_vector_type(8)));

DEVI float geluf(float x) { return 0.5f * x * (1.0f + erff(x * 0.70710678118654752f)); }

DEVI short f2bf(float f) {  // fp32 -> bf16 bits, round-to-nearest-even
  unsigned u = __float_as_uint(f);
  return (short)((u + 0x7FFFu + ((u >> 16) & 1u)) >> 16);
}
DEVI float bf2f(short s) { return __uint_as_float(((unsigned)(unsigned short)s) << 16); }
DEVI void split2(float v, short& h, short& l) {  // v ~= hi + lo to ~2^-16 rel
  h = f2bf(v);
  l = f2bf(v - bf2f(h));
}

// packed-A position for (row, col), K-tile count KT: ((row/16*KT + col/32)*64 + lane)*8 + j
DEVI size_t apos(int row, int col, int KT) {
  return (((size_t)(row >> 4) * KT + (col >> 5)) * 64 + ((col >> 3) & 3) * 16 + (row & 15)) * 8
         + (col & 7);
}

// scores: att[h*L*L + i*L + j] = (q_i . k_j) / sqrt(32), optional key-pad mask.
template<int L, int STR, bool MASK>
DEVI void attn_scores(const float* qkv, float* att, const int* pad)
{
  for (int e = (int)threadIdx.x; e < Hn * L * L; e += 256) {
    const int h = e / (L * L);
    const int rem = e % (L * L);
    const int i = rem / L, j = rem % L;
    const float* qp = qkv + i * STR + h * DHn;
    const float* kp = qkv + j * STR + 128 + h * DHn;
    float acc = 0.f;
#pragma unroll
    for (int d = 0; d < DHn; d += 4) {
      const float4 qa = *reinterpret_cast<const float4*>(qp + d);
      const float4 kb = *reinterpret_cast<const float4*>(kp + d);
      acc += qa.x * kb.x + qa.y * kb.y + qa.z * kb.z + qa.w * kb.w;
    }
    acc *= INV_SQRT_DH;
    if (MASK && pad[j]) acc = -1e9f;
    att[e] = acc;
  }
}

template<int L>
DEVI void softmax_rows(float* att)
{
  for (int r = (int)threadIdx.x; r < Hn * L; r += 256) {
    float* row = att + r * L;
    float m = row[0];
#pragma unroll 4
    for (int j = 1; j < L; ++j) m = fmaxf(m, row[j]);
    float s = 0.f;
#pragma unroll 4
    for (int j = 0; j < L; ++j) { const float ex = expf(row[j] - m); row[j] = ex; s += ex; }
    const float inv = 1.f / s;
#pragma unroll 4
    for (int j = 0; j < L; ++j) row[j] *= inv;
  }
}

// ---------------------------------------------------------------------------
// pack fp32 [K][N] into single-bf16 B tiles (512 shorts/tile)
__global__ void pack_kernel(const float* __restrict__ W, short* __restrict__ out,
                            const int K, const int N, const int total)
{
  const int p = (int)blockIdx.x * 256 + (int)threadIdx.x;
  if (p >= total) return;
  const int perMat = (K * N) >> 3;
  const int m = p / perMat, r = p - m * perMat;
  const int t = r >> 6, lane = r & 63;
  const int KT = K >> 5;
  const int nt = t / KT, kt = t - nt * KT;
  const int row0 = kt * 32 + (lane >> 4) * 8;
  const int col  = nt * 16 + (lane & 15);
  const float* src = W + (size_t)m * K * N;
  short8 v;
#pragma unroll
  for (int j = 0; j < 8; ++j) v[j] = f2bf(src[(size_t)(row0 + j) * N + col]);
  *reinterpret_cast<short8*>(out + (size_t)p * 8) = v;
}

// pack fp32 [K][N] into split hi/lo B tiles (1024 shorts/tile)
__global__ void pack2_kernel(const float* __restrict__ W, short* __restrict__ out,
                             const int K, const int N, const int total)
{
  const int p = (int)blockIdx.x * 256 + (int)threadIdx.x;
  if (p >= total) return;
  const int perMat = (K * N) >> 3;
  const int m = p / perMat, r = p - m * perMat;
  const int t = r >> 6, lane = r & 63;
  const int KT = K >> 5;
  const int nt = t / KT, kt = t - nt * KT;
  const int row0 = kt * 32 + (lane >> 4) * 8;
  const int col  = nt * 16 + (lane & 15);
  const float* src = W + (size_t)m * K * N;
  short8 vh, vl;
#pragma unroll
  for (int j = 0; j < 8; ++j) {
    short hh, ll;
    split2(src[(size_t)(row0 + j) * N + col], hh, ll);
    vh[j] = hh; vl[j] = ll;
  }
  const size_t T  = (size_t)(perMat >> 6);
  const size_t tg = (size_t)m * T + t;
  *reinterpret_cast<short8*>(out + tg * 1024 + lane * 8)       = vh;
  *reinterpret_cast<short8*>(out + tg * 1024 + 512 + lane * 8) = vl;
}

// ===========================================================================
// BERT phase pipeline (split-bf16, M = 49152 rows)
// ===========================================================================

// embedding: X = tok[id] + pos; write fp32 X and split-packed A (KT=4)
__global__ __launch_bounds__(256) void bembed_kernel(
    const int* __restrict__ ids, const float* __restrict__ tok,
    const float* __restrict__ pos, float* __restrict__ X,
    short* __restrict__ Ah, short* __restrict__ Al)
{
  const int mt = (int)blockIdx.x;          // 0..3071
  const int t = (int)threadIdx.x;
  const int rl = t >> 4, j = t & 15;
  const int row = mt * 16 + rl;
  const int b = row / 24, i = row - b * 24;
  const int id = ids[b * 24 + i];
  const float* tp = tok + (size_t)id * 128 + j * 8;
  const float* pp = pos + i * 128 + j * 8;
  float x[8];
  short8 vh, vl;
#pragma unroll
  for (int u = 0; u < 8; ++u) {
    x[u] = tp[u] + pp[u];
    short hh, ll; split2(x[u], hh, ll);
    vh[u] = hh; vl[u] = ll;
  }
  float4 f0 = {x[0], x[1], x[2], x[3]}, f1 = {x[4], x[5], x[6], x[7]};
  *reinterpret_cast<float4*>(X + (size_t)row * 128 + j * 8) = f0;
  *reinterpret_cast<float4*>(X + (size_t)row * 128 + j * 8 + 4) = f1;
  const size_t pk = (((size_t)mt * 4 + (j >> 2)) * 64 + (j & 3) * 16 + rl) * 8;
  *reinterpret_cast<short8*>(Ah + pk) = vh;
  *reinterpret_cast<short8*>(Al + pk) = vl;
}

// QKV gemm: A split-packed, B split tiles; out fp32 [49152][384]. grid (768, 3)
__global__ __launch_bounds__(256) void bqkv_kernel(
    const short* __restrict__ Ah, const short* __restrict__ Al,
    const short* __restrict__ Bp, const float* __restrict__ bias,
    float* __restrict__ Out)
{
  const int mt0 = (int)blockIdx.x * 4;
  const int nc  = (int)blockIdx.y;
  const int lane = (int)threadIdx.x & 63, wv = (int)threadIdx.x >> 6;
  const int r0 = lane & 15, g = lane >> 4;
  short8 bh[2][4], bl[2][4];
#pragma unroll
  for (int i = 0; i < 2; ++i)
#pragma unroll
    for (int kt = 0; kt < 4; ++kt) {
      const short* tb = Bp + (((size_t)(nc * 8 + wv * 2 + i) * 4 + kt) << 10);
      bh[i][kt] = *reinterpret_cast<const short8*>(tb + lane * 8);
      bl[i][kt] = *reinterpret_cast<const short8*>(tb + 512 + lane * 8);
    }
#pragma unroll 2
  for (int mt = 0; mt < 4; ++mt) {
    const int mtg = mt0 + mt;
    short8 ah[4], al[4];
#pragma unroll
    for (int kt = 0; kt < 4; ++kt) {
      ah[kt] = *reinterpret_cast<const short8*>(Ah + (((size_t)mtg * 4 + kt) * 64 + lane) * 8);
      al[kt] = *reinterpret_cast<const short8*>(Al + (((size_t)mtg * 4 + kt) * 64 + lane) * 8);
    }
#pragma unroll
    for (int i = 0; i < 2; ++i) {
      f32x4v c = {0.f, 0.f, 0.f, 0.f};
#pragma unroll
      for (int kt = 0; kt < 4; ++kt) {
        c = __builtin_amdgcn_mfma_f32_16x16x32_bf16(ah[kt], bh[i][kt], c, 0, 0, 0);
        c = __builtin_amdgcn_mfma_f32_16x16x32_bf16(al[kt], bh[i][kt], c, 0, 0, 0);
        c = __builtin_amdgcn_mfma_f32_16x16x32_bf16(ah[kt], bl[i][kt], c, 0, 0, 0);
      }
      const int col = nc * 128 + (wv * 2 + i) * 16 + r0;
      const float bb = bias[col];
#pragma unroll
      for (int q = 0; q < 4; ++q)
        Out[(size_t)(mtg * 16 + g * 4 + q) * 384 + col] = c[q] + bb;
    }
  }
}

// per-item BERT attention: QKV fp32 -> attn out split-packed A. grid 2048
__global__ __launch_bounds__(256) void battn_kernel(
    const float* __restrict__ QKV, const int* __restrict__ ids,
    short* __restrict__ Ah, short* __restrict__ Al)
{
  __shared__ float qkv[LTn * QSTR];
  __shared__ float att[Hn * LTn * LTn];
  __shared__ int pad_s[LTn];
  const int b = (int)blockIdx.x;
  const int tid = (int)threadIdx.x;
  const int row0 = b * LTn;
  for (int e4 = tid; e4 < LTn * 96; e4 += 256) {
    const int il = e4 / 96, c4 = e4 - il * 96;
    *reinterpret_cast<float4*>(qkv + il * QSTR + c4 * 4) =
        *reinterpret_cast<const float4*>(QKV + (size_t)(row0 + il) * 384 + c4 * 4);
  }
  for (int i2 = tid; i2 < LTn; i2 += 256) pad_s[i2] = (ids[row0 + i2] == 0) ? 1 : 0;
  __syncthreads();
  attn_scores<LTn, QSTR, true>(qkv, att, pad_s);
  __syncthreads();
  softmax_rows<LTn>(att);
  __syncthreads();
  for (int e = tid; e < LTn * Dn; e += 256) {
    const int il = e >> 7, c = e & 127, h = c >> 5;
    const float* arow = att + (h * LTn + il) * LTn;
    const float* vp = qkv + 256 + c;
    float acc = 0.f;
#pragma unroll 4
    for (int j = 0; j < LTn; ++j) acc = fmaf(arow[j], vp[j * QSTR], acc);
    short hh, ll; split2(acc, hh, ll);
    const size_t pk = apos(row0 + il, c, 4);
    Ah[pk] = hh; Al[pk] = ll;
  }
}

// O-proj gemm with fused residual + LayerNorm epilogue:
// X = LN(X + A@Wo + bo); also writes split-packed A (FFN input). grid 768
__global__ __launch_bounds__(256) void bo_ln_kernel(
    const short* __restrict__ Ah, const short* __restrict__ Al,
    const short* __restrict__ Bp, const float* __restrict__ bo,
    const float* __restrict__ gs, const float* __restrict__ gb,
    float* __restrict__ X, short* __restrict__ OAh, short* __restrict__ OAl)
{
  __shared__ float red[16][4][2];
  const int mt0 = (int)blockIdx.x * 4;
  const int lane = (int)threadIdx.x & 63, wv = (int)threadIdx.x >> 6;
  const int r0 = lane & 15, g = lane >> 4;
  short8 bh[2][4], bl[2][4];
#pragma unroll
  for (int i = 0; i < 2; ++i)
#pragma unroll
    for (int kt = 0; kt < 4; ++kt) {
      const short* tb = Bp + (((size_t)(wv * 2 + i) * 4 + kt) << 10);
      bh[i][kt] = *reinterpret_cast<const short8*>(tb + lane * 8);
      bl[i][kt] = *reinterpret_cast<const short8*>(tb + 512 + lane * 8);
    }
  for (int mt = 0; mt < 4; ++mt) {
    const int mtg = mt0 + mt;
    short8 ah[4], al[4];
#pragma unroll
    for (int kt = 0; kt < 4; ++kt) {
      ah[kt] = *reinterpret_cast<const short8*>(Ah + (((size_t)mtg * 4 + kt) * 64 + lane) * 8);
      al[kt] = *reinterpret_cast<const short8*>(Al + (((size_t)mtg * 4 + kt) * 64 + lane) * 8);
    }
    float v[2][4];
#pragma unroll
    for (int i = 0; i < 2; ++i) {
      f32x4v c = {0.f, 0.f, 0.f, 0.f};
#pragma unroll
      for (int kt = 0; kt < 4; ++kt) {
        c = __builtin_amdgcn_mfma_f32_16x16x32_bf16(ah[kt], bh[i][kt], c, 0, 0, 0);
        c = __builtin_amdgcn_mfma_f32_16x16x32_bf16(al[kt], bh[i][kt], c, 0, 0, 0);
        c = __builtin_amdgcn_mfma_f32_16x16x32_bf16(ah[kt], bl[i][kt], c, 0, 0, 0);
      }
      const int col = (wv * 2 + i) * 16 + r0;
      const float bb = bo[col];
#pragma unroll
      for (int q = 0; q < 4; ++q) {
        const int row = mtg * 16 + g * 4 + q;
        v[i][q] = c[q] + bb + X[(size_t)row * 128 + col];
      }
    }
    float s1[4], s2[4];
#pragma unroll
    for (int q = 0; q < 4; ++q) {
      s1[q] = v[0][q] + v[1][q];
      s2[q] = v[0][q] * v[0][q] + v[1][q] * v[1][q];
    }
#pragma unroll
    for (int o = 1; o < 16; o <<= 1)
#pragma unroll
      for (int q = 0; q < 4; ++q) { s1[q] += __shfl_xor(s1[q], o); s2[q] += __shfl_xor(s2[q], o); }
    if (r0 == 0)
#pragma unroll
      for (int q = 0; q < 4; ++q) { red[g * 4 + q][wv][0] = s1[q]; red[g * 4 + q][wv][1] = s2[q]; }
    __syncthreads();
#pragma unroll
    for (int q = 0; q < 4; ++q) {
      const int r = g * 4 + q;
      const float t1 = red[r][0][0] + red[r][1][0] + red[r][2][0] + red[r][3][0];
      const float t2 = red[r][0][1] + red[r][1][1] + red[r][2][1] + red[r][3][1];
      const float m  = t1 * (1.f / 128.f);
      const float rs = rsqrtf(t2 * (1.f / 128.f) - m * m + 1e-5f);
      const int row = mtg * 16 + r;
#pragma unroll
      for (int i = 0; i < 2; ++i) {
        const int col = (wv * 2 + i) * 16 + r0;
        const float o = (v[i][q] - m) * rs * gs[col] + gb[col];
        X[(size_t)row * 128 + col] = o;
        short hh, ll; split2(o, hh, ll);
        const size_t pk = apos(row, col, 4);
        OAh[pk] = hh; OAl[pk] = ll;
      }
    }
    __syncthreads();
  }
}

// FFN W1: A@W1+b1, gelu -> split-packed H (KT=16). grid (768, 4)
__global__ __launch_bounds__(256) void bw1_kernel(
    const short* __restrict__ Ah, const short* __restrict__ Al,
    const short* __restrict__ Bp, const float* __restrict__ bias,
    short* __restrict__ Hh, short* __restrict__ Hl)
{
  const int mt0 = (int)blockIdx.x * 4;
  const int nc  = (int)blockIdx.y;
  const int lane = (int)threadIdx.x & 63, wv = (int)threadIdx.x >> 6;
  const int r0 = lane & 15, g = lane >> 4;
  short8 bh[2][4], bl[2][4];
#pragma unroll
  for (int i = 0; i < 2; ++i)
#pragma unroll
    for (int kt = 0; kt < 4; ++kt) {
      const short* tb = Bp + (((size_t)(nc * 8 + wv * 2 + i) * 4 + kt) << 10);
      bh[i][kt] = *reinterpret_cast<const short8*>(tb + lane * 8);
      bl[i][kt] = *reinterpret_cast<const short8*>(tb + 512 + lane * 8);
    }
#pragma unroll 2
  for (int mt = 0; mt < 4; ++mt) {
    const int mtg = mt0 + mt;
    short8 ah[4], al[4];
#pragma unroll
    for (int kt = 0; kt < 4; ++kt) {
      ah[kt] = *reinterpret_cast<const short8*>(Ah + (((size_t)mtg * 4 + kt) * 64 + lane) * 8);
      al[kt] = *reinterpret_cast<const short8*>(Al + (((size_t)mtg * 4 + kt) * 64 + lane) * 8);
    }
#pragma unroll
    for (int i = 0; i < 2; ++i) {
      f32x4v c = {0.f, 0.f, 0.f, 0.f};
#pragma unroll
      for (int kt = 0; kt < 4; ++kt) {
        c = __builtin_amdgcn_mfma_f32_16x16x32_bf16(ah[kt], bh[i][kt], c, 0, 0, 0);
        c = __builtin_amdgcn_mfma_f32_16x16x32_bf16(al[kt], bh[i][kt], c, 0, 0, 0);
        c = __builtin_amdgcn_mfma_f32_16x16x32_bf16(ah[kt], bl[i][kt], c, 0, 0, 0);
      }
      const int col = nc * 128 + (wv * 2 + i) * 16 + r0;
      const float bb = bias[col];
#pragma unroll
      for (int q = 0; q < 4; ++q) {
        const int row = mtg * 16 + g * 4 + q;
        short hh, ll; split2(geluf(c[q] + bb), hh, ll);
        const size_t pk = apos(row, col, 16);
        Hh[pk] = hh; Hl[pk] = ll;
      }
    }
  }
}

// FFN W2 first K-half: X += H@W2[0:256] + b2. 512 threads, grid 768
__global__ __launch_bounds__(512) void bw2a_kernel(
    const short* __restrict__ Hh, const short* __restrict__ Hl,
    const short* __restrict__ Bp, const float* __restrict__ bias,
    float* __restrict__ X)
{
  const int mt0 = (int)blockIdx.x * 4;
  const int lane = (int)threadIdx.x & 63, wv = (int)threadIdx.x >> 6;  // 8 waves
  const int r0 = lane & 15, g = lane >> 4;
  short8 bh[8], bl[8];
#pragma unroll
  for (int kk = 0; kk < 8; ++kk) {
    const short* tb = Bp + (((size_t)wv * 16 + kk) << 10);
    bh[kk] = *reinterpret_cast<const short8*>(tb + lane * 8);
    bl[kk] = *reinterpret_cast<const short8*>(tb + 512 + lane * 8);
  }
#pragma unroll 2
  for (int mt = 0; mt < 4; ++mt) {
    const int mtg = mt0 + mt;
    f32x4v c = {0.f, 0.f, 0.f, 0.f};
#pragma unroll
    for (int kk = 0; kk < 8; ++kk) {
      const short8 ah = *reinterpret_cast<const short8*>(Hh + (((size_t)mtg * 16 + kk) * 64 + lane) * 8);
      const short8 al = *reinterpret_cast<const short8*>(Hl + (((size_t)mtg * 16 + kk) * 64 + lane) * 8);
      c = __builtin_amdgcn_mfma_f32_16x16x32_bf16(ah, bh[kk], c, 0, 0, 0);
      c = __builtin_amdgcn_mfma_f32_16x16x32_bf16(al, bh[kk], c, 0, 0, 0);
      c = __builtin_amdgcn_mfma_f32_16x16x32_bf16(ah, bl[kk], c, 0, 0, 0);
    }
    const int col = wv * 16 + r0;
    const float bb = bias[col];
#pragma unroll
    for (int q = 0; q < 4; ++q)
      X[(size_t)(mtg * 16 + g * 4 + q) * 128 + col] += c[q] + bb;
  }
}

// FFN W2 second K-half + fused LN: X = LN(X + H@W2[256:512]); packed next-A.
__global__ __launch_bounds__(512) void bw2b_kernel(
    const short* __restrict__ Hh, const short* __restrict__ Hl,
    const short* __restrict__ Bp, const float* __restrict__ gs,
    const float* __restrict__ gb, float* __restrict__ X,
    short* __restrict__ OAh, short* __restrict__ OAl)
{
  __shared__ float red[16][8][2];
  const int mt0 = (int)blockIdx.x * 4;
  const int lane = (int)threadIdx.x & 63, wv = (int)threadIdx.x >> 6;
  const int r0 = lane & 15, g = lane >> 4;
  short8 bh[8], bl[8];
#pragma unroll
  for (int kk = 0; kk < 8; ++kk) {
    const short* tb = Bp + (((size_t)wv * 16 + 8 + kk) << 10);
    bh[kk] = *reinterpret_cast<const short8*>(tb + lane * 8);
    bl[kk] = *reinterpret_cast<const short8*>(tb + 512 + lane * 8);
  }
  for (int mt = 0; mt < 4; ++mt) {
    const int mtg = mt0 + mt;
    f32x4v c = {0.f, 0.f, 0.f, 0.f};
#pragma unroll
    for (int kk = 0; kk < 8; ++kk) {
      const short8 ah = *reinterpret_cast<const short8*>(Hh + (((size_t)mtg * 16 + 8 + kk) * 64 + lane) * 8);
      const short8 al = *reinterpret_cast<const short8*>(Hl + (((size_t)mtg * 16 + 8 + kk) * 64 + lane) * 8);
      c = __builtin_amdgcn_mfma_f32_16x16x32_bf16(ah, bh[kk], c, 0, 0, 0);
      c = __builtin_amdgcn_mfma_f32_16x16x32_bf16(al, bh[kk], c, 0, 0, 0);
      c = __builtin_amdgcn_mfma_f32_16x16x32_bf16(ah, bl[kk], c, 0, 0, 0);
    }
    const int col = wv * 16 + r0;
    float v[4], s1[4], s2[4];
#pragma unroll
    for (int q = 0; q < 4; ++q) {
      const int row = mtg * 16 + g * 4 + q;
      v[q] = c[q] + X[(size_t)row * 128 + col];
      s1[q] = v[q]; s2[q] = v[q] * v[q];
    }
#pragma unroll
    for (int o = 1; o < 16; o <<= 1)
#pragma unroll
      for (int q = 0; q < 4; ++q) { s1[q] += __shfl_xor(s1[q], o); s2[q] += __shfl_xor(s2[q], o); }
    if (r0 == 0)
#pragma unroll
      for (int q = 0; q < 4; ++q) { red[g * 4 + q][wv][0] = s1[q]; red[g * 4 + q][wv][1] = s2[q]; }
    __syncthreads();
#pragma unroll
    for (int q = 0; q < 4; ++q) {
      const int r = g * 4 + q;
      float t1 = 0.f, t2 = 0.f;
#pragma unroll
      for (int w = 0; w < 8; ++w) { t1 += red[r][w][0]; t2 += red[r][w][1]; }
      const float m  = t1 * (1.f / 128.f);
      const float rs = rsqrtf(t2 * (1.f / 128.f) - m * m + 1e-5f);
      const int row = mtg * 16 + r;
      const float o = (v[q] - m) * rs * gs[col] + gb[col];
      X[(size_t)row * 128 + col] = o;
      short hh, ll; split2(o, hh, ll);
      const size_t pk = apos(row, col, 4);
      OAh[pk] = hh; OAl[pk] = ll;
    }
    __syncthreads();
  }
}

// intent = LN(X[CLS row], lnf). grid 512 x 256 (4 items/block)
__global__ __launch_bounds__(256) void bintent_kernel(
    const float* __restrict__ X, const float* __restrict__ lnf_s,
    const float* __restrict__ lnf_b, float* __restrict__ intent)
{
  const int w = (int)threadIdx.x >> 6, lane = (int)threadIdx.x & 63;
  const int b = (int)blockIdx.x * 4 + w;
  const float* xr = X + (size_t)b * LTn * 128;
  const float a0 = xr[lane], a1 = xr[lane + 64];
  float s1 = a0 + a1, s2 = a0 * a0 + a1 * a1;
#pragma unroll
  for (int o = 32; o > 0; o >>= 1) { s1 += __shfl_xor(s1, o); s2 += __shfl_xor(s2, o); }
  const float m  = s1 * (1.f / 128.f);
  const float rs = rsqrtf(s2 * (1.f / 128.f) - m * m + 1e-5f);
  intent[b * 128 + lane]      = (a0 - m) * rs * lnf_s[lane]      + lnf_b[lane];
  intent[b * 128 + lane + 64] = (a1 - m) * rs * lnf_s[lane + 64] + lnf_b[lane + 64];
}

// ---------------------------------------------------------------------------
struct RouterP {
  const float* state; const float* intent;
  const float* se_W1; const float* se_b1; const float* se_W2; const float* se_b2;
  const float* se_ln_s; const float* se_ln_b;
  const float* r_W1; const float* r_b1; const float* r_W2; const float* r_b2;
  const float* r_ln_s; const float* r_ln_b;
  const float* gate_W; const float* gate_b;
  int* ridx; float* rwgt;
};

DEVI void ln128(float* x, const float* gs, const float* gb, float* red)
{
  const int c = (int)threadIdx.x;      // blockDim == 128
  const float a = x[c];
  float s1 = a, s2 = a * a;
#pragma unroll
  for (int o = 32; o > 0; o >>= 1) { s1 += __shfl_xor(s1, o); s2 += __shfl_xor(s2, o); }
  const int wid = c >> 6;
  if ((c & 63) == 0) { red[wid * 2] = s1; red[wid * 2 + 1] = s2; }
  __syncthreads();
  s1 = red[0] + red[2]; s2 = red[1] + red[3];
  const float m  = s1 * (1.f / 128.f);
  const float rs = rsqrtf(s2 * (1.f / 128.f) - m * m + 1e-5f);
  __syncthreads();
  x[c] = (a - m) * rs * gs[c] + gb[c];
}

__global__ __launch_bounds__(128) void router_kernel(RouterP p)
{
  __shared__ float sstate[SDn];
  __shared__ float h1[Dn];
  __shared__ float vv[Dn];
  __shared__ float red[4];
  __shared__ float slog[En];
  const int b = blockIdx.x;
  const int c = (int)threadIdx.x;

  if (c < SDn) sstate[c] = p.state[b * SDn + c];
  __syncthreads();
  {
    float acc = p.se_b1[c];
#pragma unroll
    for (int k = 0; k < SDn; ++k) acc = fmaf(sstate[k], p.se_W1[k * Dn + c], acc);
    h1[c] = geluf(acc);
  }
  __syncthreads();
  {
    float acc = p.se_b2[c];
#pragma unroll 4
    for (int k = 0; k < Dn; ++k) acc = fmaf(h1[k], p.se_W2[k * Dn + c], acc);
    vv[c] = acc;
  }
  __syncthreads();
  ln128(vv, p.se_ln_s, p.se_ln_b, red);
  __syncthreads();
  {
    float acc = p.r_b1[c];
    const float* ib = p.intent + b * Dn;
#pragma unroll 4
    for (int k = 0; k < Dn; ++k) acc = fmaf(ib[k], p.r_W1[k * Dn + c], acc);
#pragma unroll 4
    for (int k = 0; k < Dn; ++k) acc = fmaf(vv[k], p.r_W1[(Dn + k) * Dn + c], acc);
    h1[c] = geluf(acc);
  }
  __syncthreads();
  {
    float acc = p.r_b2[c];
#pragma unroll 4
    for (int k = 0; k < Dn; ++k) acc = fmaf(h1[k], p.r_W2[k * Dn + c], acc);
    vv[c] = acc;
  }
  __syncthreads();
  ln128(vv, p.r_ln_s, p.r_ln_b, red);
  __syncthreads();
  if (c < En) {
    float acc = p.gate_b[c];
#pragma unroll 4
    for (int k = 0; k < Dn; ++k) acc = fmaf(vv[k], p.gate_W[k * En + c], acc);
    slog[c] = acc;
  }
  __syncthreads();
  if (c == 0) {
    int i0 = 0; float v0 = slog[0];
#pragma unroll
    for (int e2 = 1; e2 < En; ++e2) if (slog[e2] > v0) { v0 = slog[e2]; i0 = e2; }
    int i1 = -1; float v1 = -3.4e38f;
#pragma unroll
    for (int e2 = 0; e2 < En; ++e2) if (e2 != i0 && slog[e2] > v1) { v1 = slog[e2]; i1 = e2; }
    const float e1  = expf(v1 - v0);
    const float inv = 1.f / (1.f + e1);
    p.ridx[b * 2 + 0] = i0; p.ridx[b * 2 + 1] = i1;
    p.rwgt[b * 2 + 0] = inv; p.rwgt[b * 2 + 1] = e1 * inv;
  }
}

// ===========================================================================
// EXPERT PHASE PIPELINE (unchanged from round 4)
// ===========================================================================

__global__ void sched_kernel(const int* __restrict__ ridx, int* __restrict__ sch,
                             int* plist, int* prow, int* pexp, int* ppos)
{
  __shared__ int scnt[En], scur[En], soff[En], srb[En + 1];
  const int t = (int)threadIdx.x;
  if (t < En) { scnt[t] = 0; scur[t] = 0; }
  __syncthreads();
  for (int p = t; p < PAIRS; p += 256) atomicAdd(&scnt[ridx[p]], 1);
  __syncthreads();
  if (t == 0) {
    int off = 0, rb = 0, k = 0;
    for (int e = 0; e < En; ++e) {
      soff[e] = off; srb[e] = rb;
      const int rows = scnt[e] * 20;
      const int nb = (rows + 127) >> 7;
      for (int q = 0; q < nb; ++q) {
        sch[GEXP_OFF + k] = e;
        sch[GMT_OFF + k]  = (rb >> 4) + q * 8;
        ++k;
      }
      off += scnt[e];
      rb += nb * 128;
    }
    srb[En] = rb;
    sch[0] = k;
    for (int e = 0; e < En; ++e) { sch[1 + e] = scnt[e]; sch[7 + e] = soff[e]; }
    for (int e = 0; e <= En; ++e) sch[13 + e] = srb[e];
  }
  __syncthreads();
  for (int p = t; p < PAIRS; p += 256) {
    const int e = ridx[p];
    const int pos = atomicAdd(&scur[e], 1);
    const int i = soff[e] + pos;
    plist[i] = p; ppos[p] = i; pexp[i] = e; prow[i] = srb[e] + pos * 20;
  }
}

__global__ void xinit_kernel(const float* __restrict__ qpe, const int* __restrict__ sch,
                             float* __restrict__ X)
{
  const int idx = (int)blockIdx.x * 256 + (int)threadIdx.x;  // quad index
  const int row = idx >> 5;
  if (row >= MPMAX) return;
  const int c4 = (idx & 31) * 4;
  const int* RB = sch + 13;
  float4 v = {0.f, 0.f, 0.f, 0.f};
  int e = 0;
  while (e < En && row >= RB[e + 1]) ++e;
  if (e < En) {
    const int local = row - RB[e];
    if (local < sch[1 + e] * 20) {
      const int r = local - (local / 20) * 20;
      v = *reinterpret_cast<const float4*>(qpe + r * 128 + c4);
    }
  }
  *reinterpret_cast<float4*>(X + (size_t)row * 128 + c4) = v;
}

__global__ __launch_bounds__(256) void ln_pack_kernel(
    const float* __restrict__ X, short* __restrict__ XnP,
    const float* __restrict__ lns_all, const float* __restrict__ lnb_all,
    const int subOff, const int* __restrict__ sch)
{
  const int* RB = sch + 13;
  const int mt = (int)blockIdx.x;
  const int row0 = mt << 4;
  if (row0 >= RB[En]) return;
  int e = 0;
  while (e < En - 1 && row0 >= RB[e + 1]) ++e;
  const float* gs = lns_all + e * (NLDn * 3 * 128) + subOff;
  const float* gb = lnb_all + e * (NLDn * 3 * 128) + subOff;
  const int t = (int)threadIdx.x;
  const int rl = t >> 4, j = t & 15;
  const int row = row0 + rl;
  float x[8];
  {
    const float4 a = *reinterpret_cast<const float4*>(X + (size_t)row * 128 + j * 8);
    const float4 bq = *reinterpret_cast<const float4*>(X + (size_t)row * 128 + j * 8 + 4);
    x[0] = a.x; x[1] = a.y; x[2] = a.z; x[3] = a.w;
    x[4] = bq.x; x[5] = bq.y; x[6] = bq.z; x[7] = bq.w;
  }
  float s1 = 0.f, s2 = 0.f;
#pragma unroll
  for (int u = 0; u < 8; ++u) { s1 += x[u]; s2 += x[u] * x[u]; }
#pragma unroll
  for (int o = 1; o < 16; o <<= 1) { s1 += __shfl_xor(s1, o); s2 += __shfl_xor(s2, o); }
  const float m  = s1 * (1.f / 128.f);
  const float rs = rsqrtf(s2 * (1.f / 128.f) - m * m + 1e-5f);
  short8 pk;
#pragma unroll
  for (int u = 0; u < 8; ++u)
    pk[u] = f2bf((x[u] - m) * rs * gs[j * 8 + u] + gb[j * 8 + u]);
  const int kt = j >> 2, g = j & 3, lp = g * 16 + rl;
  *reinterpret_cast<short8*>(XnP + (((size_t)mt * 4 + kt) * 64 + lp) * 8) = pk;
}

template<int NTW, int EPI, bool HASB>
__global__ __launch_bounds__(256) void gemm_k128(
    const short* __restrict__ A, const short* __restrict__ Bb, const int strideB,
    const float* __restrict__ biasb, const int strideBias, const int ntOff,
    float* __restrict__ OutF, short* __restrict__ OutP, const int* __restrict__ sch)
{
  const int k = (int)blockIdx.x;
  if (k >= sch[0]) return;
  const int ex  = sch[GEXP_OFF + k];
  const int mt0 = sch[GMT_OFF + k];
  const short* Bp = Bb + (size_t)ex * strideB;
  const float* bias = biasb + (size_t)ex * strideBias;
  const int lane = (int)threadIdx.x & 63, wv = (int)threadIdx.x >> 6;
  const int r0 = lane & 15, g = lane >> 4;
  short8 bf[NTW][4];
#pragma unroll
  for (int i = 0; i < NTW; ++i)
#pragma unroll
    for (int kt = 0; kt < 4; ++kt)
      bf[i][kt] = *reinterpret_cast<const short8*>(
          Bp + (((size_t)(ntOff + wv * NTW + i) * 4 + kt) * 64 + lane) * 8);
#pragma unroll 2
  for (int mt = 0; mt < 8; ++mt) {
    short8 a[4];
#pragma unroll
    for (int kt = 0; kt < 4; ++kt)
      a[kt] = *reinterpret_cast<const short8*>(
          A + (((size_t)(mt0 + mt) * 4 + kt) * 64 + lane) * 8);
#pragma unroll
    for (int i = 0; i < NTW; ++i) {
      f32x4v c = {0.f, 0.f, 0.f, 0.f};
#pragma unroll
      for (int kt = 0; kt < 4; ++kt)
        c = __builtin_amdgcn_mfma_f32_16x16x32_bf16(a[kt], bf[i][kt], c, 0, 0, 0);
      const int colL = (wv * NTW + i) * 16 + r0;
      const float bb = HASB ? bias[colL] : 0.f;
      const int rowB = (mt0 + mt) * 16 + g * 4;
#pragma unroll
      for (int q = 0; q < 4; ++q) {
        const int row = rowB + q;
        const float v = c[q] + bb;
        if (EPI == 0)      OutF[(size_t)row * 384 + colL] = v;
        else if (EPI == 1) OutF[(size_t)row * 128 + colL] += v;
        else if (EPI == 2) OutF[(size_t)row * 128 + colL] = v;
        else {
          const float rv = fmaxf(v, 0.f);
          const int j = colL >> 3, kt2 = j >> 2, g2 = j & 3;
          const int lp = g2 * 16 + (row & 15);
          OutP[(((size_t)(row >> 4) * 8 + kt2) * 64 + lp) * 8 + (colL & 7)] = f2bf(rv);
        }
      }
    }
  }
}

template<bool HASB>
__global__ __launch_bounds__(256) void gemm_k256(
    const short* __restrict__ A, const short* __restrict__ Bb, const int strideB,
    const float* __restrict__ biasb, const int strideBias, const int ktOff,
    float* __restrict__ X, const int* __restrict__ sch)
{
  const int k = (int)blockIdx.x;
  if (k >= sch[0]) return;
  const int ex  = sch[GEXP_OFF + k];
  const int mt0 = sch[GMT_OFF + k];
  const short* Bp = Bb + (size_t)ex * strideB;
  const float* bias = biasb + (size_t)ex * strideBias;
  const int lane = (int)threadIdx.x & 63, wv = (int)threadIdx.x >> 6;
  const int r0 = lane & 15, g = lane >> 4;
  short8 bf[2][8];
#pragma unroll
  for (int i = 0; i < 2; ++i)
#pragma unroll
    for (int kk = 0; kk < 8; ++kk)
      bf[i][kk] = *reinterpret_cast<const short8*>(
          Bp + (((size_t)(wv * 2 + i) * 16 + ktOff + kk) * 64 + lane) * 8);
#pragma unroll 2
  for (int mt = 0; mt < 8; ++mt) {
    short8 a[8];
#pragma unroll
    for (int kk = 0; kk < 8; ++kk)
      a[kk] = *reinterpret_cast<const short8*>(
          A + (((size_t)(mt0 + mt) * 8 + kk) * 64 + lane) * 8);
#pragma unroll
    for (int i = 0; i < 2; ++i) {
      f32x4v c = {0.f, 0.f, 0.f, 0.f};
#pragma unroll
      for (int kk = 0; kk < 8; ++kk)
        c = __builtin_amdgcn_mfma_f32_16x16x32_bf16(a[kk], bf[i][kk], c, 0, 0, 0);
      const int colL = (wv * 2 + i) * 16 + r0;
      const float bb = HASB ? bias[colL] : 0.f;
      const int rowB = (mt0 + mt) * 16 + g * 4;
#pragma unroll
      for (int q = 0; q < 4; ++q)
        X[(size_t)(rowB + q) * 128 + colL] += c[q] + bb;
    }
  }
}

__global__ __launch_bounds__(256) void sattn_kernel(
    const float* __restrict__ QKV, const int* __restrict__ prow,
    short* __restrict__ ANP)
{
  __shared__ float qkv[CSn * QSTR];
  __shared__ float att[Hn * CSn * CSn];
  const int i = (int)blockIdx.x;
  const int row0 = prow[i];
  for (int e4 = (int)threadIdx.x; e4 < CSn * 96; e4 += 256) {
    const int il = e4 / 96, c4 = e4 - il * 96;
    *reinterpret_cast<float4*>(qkv + il * QSTR + c4 * 4) =
        *reinterpret_cast<const float4*>(QKV + (size_t)(row0 + il) * 384 + c4 * 4);
  }
  __syncthreads();
  attn_scores<CSn, QSTR, false>(qkv, att, nullptr);
  __syncthreads();
  softmax_rows<CSn>(att);
  __syncthreads();
  for (int e = (int)threadIdx.x; e < CSn * Dn; e += 256) {
    const int il = e >> 7, c = e & 127, h = c >> 5;
    const float* arow = att + (h * CSn + il) * CSn;
    const float* vp = qkv + 256 + c;
    float acc = 0.f;
#pragma unroll 4
    for (int j = 0; j < CSn; ++j) acc = fmaf(arow[j], vp[j * QSTR], acc);
    const int row = row0 + il;
    const int j2 = c >> 3, kt = j2 >> 2, g2 = j2 & 3;
    const int lp = g2 * 16 + (row & 15);
    ANP[(((size_t)(row >> 4) * 4 + kt) * 64 + lp) * 8 + (c & 7)] = f2bf(acc);
  }
}

__global__ __launch_bounds__(256) void cattn_kernel(
    const float* __restrict__ Qc, const float* __restrict__ state,
    const float* __restrict__ sp_W, const float* __restrict__ sp_b,
    const float* __restrict__ zp_b, const float* __restrict__ aW,
    const float* __restrict__ ab, const int layer,
    const int* __restrict__ plist, const int* __restrict__ prow,
    const int* __restrict__ pexp, short* __restrict__ ANP)
{
  __shared__ float q[CSn * Dn];
  __shared__ float mem[2 * Dn];
  __shared__ float memkv[2 * 256];
  __shared__ float catt[2 * Hn * CSn];
  const int i = (int)blockIdx.x;
  const int ex = pexp[i];
  const int orig = plist[i];
  const int b = orig >> 1;
  const int row0 = prow[i];
  const int li = ex * NLDn + layer;
  const float* aW1f = aW + (size_t)(li * 2 + 1) * Dn * 384;
  const float* ab1  = ab + (size_t)(li * 2 + 1) * 384;
  const int tid = (int)threadIdx.x;

  if (tid < Dn) {
    float acc = sp_b[ex * Dn + tid];
    const float* spw = sp_W + ex * SDn * Dn;
#pragma unroll
    for (int kk = 0; kk < SDn; ++kk) acc = fmaf(state[b * SDn + kk], spw[kk * Dn + tid], acc);
    mem[tid] = acc;
  } else {
    mem[Dn + (tid - Dn)] = zp_b[ex * Dn + (tid - Dn)];
  }
  for (int e4 = tid; e4 < CSn * 32; e4 += 256) {
    const int il = e4 >> 5, c4 = (e4 & 31) * 4;
    *reinterpret_cast<float4*>(q + il * Dn + c4) =
        *reinterpret_cast<const float4*>(Qc + (size_t)(row0 + il) * 128 + c4);
  }
  __syncthreads();
  for (int e = tid; e < 2 * 256; e += 256) {
    const int j = e >> 8, c2 = e & 255;
    float acc = ab1[Dn + c2];
    const float* wp = aW1f + Dn + c2;
#pragma unroll 4
    for (int kk = 0; kk < Dn; ++kk) acc = fmaf(mem[j * Dn + kk], wp[kk * 384], acc);
    memkv[j * 256 + c2] = acc;
  }
  __syncthreads();
  for (int e = tid; e < Hn * CSn; e += 256) {
    const int h = e / CSn, il = e % CSn;
    const float* qp = q + il * Dn + h * DHn;
    float s0 = 0.f, s1 = 0.f;
#pragma unroll
    for (int d = 0; d < DHn; d += 4) {
      const float4 q4 = *reinterpret_cast<const float4*>(qp + d);
      const float4 k0 = *reinterpret_cast<const float4*>(memkv + 0 * 256 + h * DHn + d);
      const float4 k1 = *reinterpret_cast<const float4*>(memkv + 1 * 256 + h * DHn + d);
      s0 += q4.x * k0.x + q4.y * k0.y + q4.z * k0.z + q4.w * k0.w;
      s1 += q4.x * k1.x + q4.y * k1.y + q4.z * k1.z + q4.w * k1.w;
    }
    s0 *= INV_SQRT_DH; s1 *= INV_SQRT_DH;
    const float m = fmaxf(s0, s1);
    const float e0 = expf(s0 - m), e1 = expf(s1 - m);
    const float inv = 1.f / (e0 + e1);
    catt[e * 2] = e0 * inv; catt[e * 2 + 1] = e1 * inv;
  }
  __syncthreads();
  for (int e = tid; e < CSn * Dn; e += 256) {
    const int il = e >> 7, c = e & 127, h = c >> 5;
    const int a = (h * CSn + il) * 2;
    const float v = catt[a]     * memkv[0 * 256 + Dn + c]
                  + catt[a + 1] * memkv[1 * 256 + Dn + c];
    const int row = row0 + il;
    const int j2 = c >> 3, kt = j2 >> 2, g2 = j2 & 3;
    const int lp = g2 * 16 + (row & 15);
    ANP[(((size_t)(row >> 4) * 4 + kt) * 64 + lp) * 8 + (c & 7)] = f2bf(v);
  }
}

__global__ __launch_bounds__(256) void head_kernel(
    const float* __restrict__ X, const int* __restrict__ plist,
    const int* __restrict__ prow, const int* __restrict__ pexp,
    const float* __restrict__ rwgt, const float* __restrict__ hW,
    const float* __restrict__ hb, float* __restrict__ Rbuf)
{
  __shared__ float xr[CSn * Dn];
  const int i = (int)blockIdx.x;
  const int ex = pexp[i];
  const int orig = plist[i];
  const int row0 = prow[i];
  const float wgt = rwgt[orig];
  for (int e4 = (int)threadIdx.x; e4 < CSn * 32; e4 += 256) {
    const int il = e4 >> 5, c4 = (e4 & 31) * 4;
    *reinterpret_cast<float4*>(xr + il * Dn + c4) =
        *reinterpret_cast<const float4*>(X + (size_t)(row0 + il) * 128 + c4);
  }
  __syncthreads();
  const int e = (int)threadIdx.x;
  if (e < CSn * JDn) {
    const int t = e / JDn, j = e - t * JDn;
    const float* w = hW + ex * Dn * JDn + j;
    float acc = hb[ex * JDn + j];
#pragma unroll 4
    for (int kk = 0; kk < Dn; ++kk) acc = fmaf(xr[t * Dn + kk], w[kk * JDn], acc);
    Rbuf[(size_t)i * 140 + e] = wgt * acc;
  }
}

__global__ void combine_kernel(const float* __restrict__ Rbuf,
                               const int* __restrict__ ppos, float* __restrict__ out)
{
  const int idx = (int)blockIdx.x * 256 + (int)threadIdx.x;
  if (idx >= Bn * 140) return;
  const int b = idx / 140, e = idx - b * 140;
  out[idx] = Rbuf[(size_t)ppos[2 * b] * 140 + e] + Rbuf[(size_t)ppos[2 * b + 1] * 140 + e];
}

// ---------------------------------------------------------------------------
__global__ void qpe_kernel(float* qpe)
{
  const int e = (int)blockIdx.x * 256 + (int)threadIdx.x;
  if (e < CSn * Dn) {
    const int t = e >> 7, d = e & 127;
    const float j  = (float)(d & ~1);
    const float dv = expf(j * (-logf(10000.f) / 128.f));
    const float a  = (float)t * dv;
    qpe[e] = (d & 1) ? cosf(a) : sinf(a);
  }
}

} // namespace

// ---------------------------------------------------------------------------
extern "C" void kernel_launch(void* const* d_in, const int* in_sizes, int n_in,
                              void* d_out, int out_size, void* d_ws, size_t ws_size,
                              hipStream_t stream)
{
  (void)in_sizes; (void)n_in; (void)out_size;

  const int*   ids     = (const int*)  d_in[0];
  const float* state   = (const float*)d_in[1];
  const float* tok_emb = (const float*)d_in[2];
  const float* pos_emb = (const float*)d_in[3];

  // persistent workspace (256B-aligned cursor)
  char* cur = (char*)d_ws;
  auto alloc = [&cur](size_t bytes) -> char* {
    char* p = cur; cur += (bytes + 255) & ~(size_t)255; return p;
  };
  float* qpe    = (float*)alloc(4096 * 4);
  float* intent = (float*)alloc((size_t)Bn * Dn * 4);
  int*   ridx   = (int*)  alloc(PAIRS * 4);
  float* rwgt   = (float*)alloc(PAIRS * 4);
  short* pQ     = (short*)alloc((size_t)36 * 49152 * 2);   // expert packs (single bf16)
  short* pO     = (short*)alloc((size_t)36 * 16384 * 2);
  short* pF1    = (short*)alloc((size_t)18 * 65536 * 2);
  short* pF2    = (short*)alloc((size_t)18 * 65536 * 2);
  short* pbQ    = (short*)alloc((size_t)4 * 98304 * 2);    // BERT packs (split hi/lo)
  short* pbO    = (short*)alloc((size_t)4 * 32768 * 2);
  short* pbW1   = (short*)alloc((size_t)4 * 131072 * 2);
  short* pbW2   = (short*)alloc((size_t)4 * 131072 * 2);
  int*   sch    = (int*)  alloc(2048 * 4);
  int*   plist  = (int*)  alloc(PAIRS * 4);
  int*   prow   = (int*)  alloc(PAIRS * 4);
  int*   pexp   = (int*)  alloc(PAIRS * 4);
  int*   ppos   = (int*)  alloc(PAIRS * 4);
  // shared arena: BERT pipeline (phase 1) then expert pipeline (phase 2)
  constexpr size_t ARENA_BYTES = 192806912;  // max(BERT 151.0 MB, expert 192.8 MB)
  char* arena = alloc(ARENA_BYTES);
  if ((size_t)(cur - (char*)d_ws) > ws_size) return;  // ws confirmed >= this in R4

  // BERT views
  float* Xb  = (float*)(arena);                          // 49152*128 f  (25.2 MB)
  short* Ah  = (short*)(arena + 25165824);               // 12.6 MB
  short* Al  = (short*)(arena + 37748736);               // 12.6 MB
  float* SBb = (float*)(arena + 50331648);               // QKV fp32 75.5 MB
  short* Hh  = (short*)(arena + 50331648);               // aliases SBb (sequential use)
  short* Hl  = (short*)(arena + 100663296);              // 50.3 MB
  // expert views
  float* X2   = (float*)(arena);                         // 42.3 MB
  short* ANP  = (short*)(arena + 42336256);              // 21.2 MB
  float* SB2  = (float*)(arena + 63504384);              // 127.0 MB
  float* Rbuf = (float*)(arena + 190513152);             // 2.3 MB

  qpe_kernel<<<dim3(10), dim3(256), 0, stream>>>(qpe);

  // ---- weight packing
  {
    const int tq = 36 * 6144;
    pack_kernel<<<dim3((tq + 255) / 256), dim3(256), 0, stream>>>(
        (const float*)d_in[34], pQ, 128, 384, tq);
    const int to = 36 * 2048;
    pack_kernel<<<dim3((to + 255) / 256), dim3(256), 0, stream>>>(
        (const float*)d_in[36], pO, 128, 128, to);
    const int t1c = 18 * 8192;
    pack_kernel<<<dim3((t1c + 255) / 256), dim3(256), 0, stream>>>(
        (const float*)d_in[40], pF1, 128, 512, t1c);
    const int t2c = 18 * 8192;
    pack_kernel<<<dim3((t2c + 255) / 256), dim3(256), 0, stream>>>(
        (const float*)d_in[42], pF2, 512, 128, t2c);
    const int bq = 4 * 6144;
    pack2_kernel<<<dim3((bq + 255) / 256), dim3(256), 0, stream>>>(
        (const float*)d_in[4], pbQ, 128, 384, bq);
    const int bo = 4 * 2048;
    pack2_kernel<<<dim3((bo + 255) / 256), dim3(256), 0, stream>>>(
        (const float*)d_in[6], pbO, 128, 128, bo);
    const int bw1 = 4 * 8192;
    pack2_kernel<<<dim3((bw1 + 255) / 256), dim3(256), 0, stream>>>(
        (const float*)d_in[8], pbW1, 128, 512, bw1);
    const int bw2 = 4 * 8192;
    pack2_kernel<<<dim3((bw2 + 255) / 256), dim3(256), 0, stream>>>(
        (const float*)d_in[10], pbW2, 512, 128, bw2);
  }

  // ---- BERT phase pipeline
  {
    const float* bq  = (const float*)d_in[5];
    const float* bo  = (const float*)d_in[7];
    const float* b1  = (const float*)d_in[9];
    const float* b2  = (const float*)d_in[11];
    const float* lns = (const float*)d_in[12];
    const float* lnb = (const float*)d_in[13];

    bembed_kernel<<<dim3(ROWSB / 16), dim3(256), 0, stream>>>(
        ids, tok_emb, pos_emb, Xb, Ah, Al);
    for (int l = 0; l < NLBn; ++l) {
      bqkv_kernel<<<dim3(ROWSB / 64, 3), dim3(256), 0, stream>>>(
          Ah, Al, pbQ + (size_t)l * 98304, bq + l * 384, SBb);
      battn_kernel<<<dim3(Bn), dim3(256), 0, stream>>>(SBb, ids, Ah, Al);
      bo_ln_kernel<<<dim3(ROWSB / 64), dim3(256), 0, stream>>>(
          Ah, Al, pbO + (size_t)l * 32768, bo + l * 128,
          lns + l * 256, lnb + l * 256, Xb, Ah, Al);
      bw1_kernel<<<dim3(ROWSB / 64, 4), dim3(256), 0, stream>>>(
          Ah, Al, pbW1 + (size_t)l * 131072, b1 + l * 512, Hh, Hl);
      bw2a_kernel<<<dim3(ROWSB / 64), dim3(512), 0, stream>>>(
          Hh, Hl, pbW2 + (size_t)l * 131072, b2 + l * 128, Xb);
      bw2b_kernel<<<dim3(ROWSB / 64), dim3(512), 0, stream>>>(
          Hh, Hl, pbW2 + (size_t)l * 131072,
          lns + l * 256 + 128, lnb + l * 256 + 128, Xb, Ah, Al);
    }
    bintent_kernel<<<dim3(Bn / 4), dim3(256), 0, stream>>>(
        Xb, (const float*)d_in[14], (const float*)d_in[15], intent);
  }

  // ---- router
  {
    RouterP rp;
    rp.state = state; rp.intent = intent;
    rp.se_W1 = (const float*)d_in[16]; rp.se_b1 = (const float*)d_in[17];
    rp.se_W2 = (const float*)d_in[18]; rp.se_b2 = (const float*)d_in[19];
    rp.se_ln_s = (const float*)d_in[20]; rp.se_ln_b = (const float*)d_in[21];
    rp.r_W1 = (const float*)d_in[22]; rp.r_b1 = (const float*)d_in[23];
    rp.r_W2 = (const float*)d_in[24]; rp.r_b2 = (const float*)d_in[25];
    rp.r_ln_s = (const float*)d_in[26]; rp.r_ln_b = (const float*)d_in[27];
    rp.gate_W = (const float*)d_in[28]; rp.gate_b = (const float*)d_in[29];
    rp.ridx = ridx; rp.rwgt = rwgt;
    router_kernel<<<dim3(Bn), dim3(128), 0, stream>>>(rp);
  }

  const float* sp_W = (const float*)d_in[30];
  const float* sp_b = (const float*)d_in[31];
  const float* zp_b = (const float*)d_in[33];
  const float* aW   = (const float*)d_in[34];
  const float* ab   = (const float*)d_in[35];
  const float* abo  = (const float*)d_in[37];
  const float* lnsA = (const float*)d_in[38];
  const float* lnbA = (const float*)d_in[39];
  const float* fb1A = (const float*)d_in[41];
  const float* fb2A = (const float*)d_in[43];
  const float* hW   = (const float*)d_in[44];
  const float* hB   = (const float*)d_in[45];

  // ---- expert phase pipeline
  {
    sched_kernel<<<dim3(1), dim3(256), 0, stream>>>(ridx, sch, plist, prow, pexp, ppos);
    xinit_kernel<<<dim3(MPMAX * 32 / 256), dim3(256), 0, stream>>>(qpe, sch, X2);
    short* HP = (short*)SB2;
    for (int l = 0; l < NLDn; ++l) {
      // self-attention block
      ln_pack_kernel<<<dim3(MPMAX / 16), dim3(256), 0, stream>>>(
          X2, ANP, lnsA, lnbA, (l * 3 + 0) * 128, sch);
      gemm_k128<6, 0, true><<<dim3(NBGMAX), dim3(256), 0, stream>>>(
          ANP, pQ + (l * 2 + 0) * 49152, 294912,
          ab + (l * 2 + 0) * 384, 2304, 0, SB2, nullptr, sch);
      sattn_kernel<<<dim3(PAIRS), dim3(256), 0, stream>>>(SB2, prow, ANP);
      gemm_k128<2, 1, true><<<dim3(NBGMAX), dim3(256), 0, stream>>>(
          ANP, pO + (l * 2 + 0) * 16384, 98304,
          abo + (l * 2 + 0) * 128, 768, 0, X2, nullptr, sch);
      // cross-attention block
      ln_pack_kernel<<<dim3(MPMAX / 16), dim3(256), 0, stream>>>(
          X2, ANP, lnsA, lnbA, (l * 3 + 1) * 128, sch);
      gemm_k128<2, 2, true><<<dim3(NBGMAX), dim3(256), 0, stream>>>(
          ANP, pQ + (l * 2 + 1) * 49152, 294912,
          ab + (l * 2 + 1) * 384, 2304, 0, SB2, nullptr, sch);
      cattn_kernel<<<dim3(PAIRS), dim3(256), 0, stream>>>(
          SB2, state, sp_W, sp_b, zp_b, aW, ab, l, plist, prow, pexp, ANP);
      gemm_k128<2, 1, true><<<dim3(NBGMAX), dim3(256), 0, stream>>>(
          ANP, pO + (l * 2 + 1) * 16384, 98304,
          abo + (l * 2 + 1) * 128, 768, 0, X2, nullptr, sch);
      // FFN block (two 256-col halves)
      ln_pack_kernel<<<dim3(MPMAX / 16), dim3(256), 0, stream>>>(
          X2, ANP, lnsA, lnbA, (l * 3 + 2) * 128, sch);
      gemm_k128<4, 3, true><<<dim3(NBGMAX), dim3(256), 0, stream>>>(
          ANP, pF1 + l * 65536, 196608,
          fb1A + l * 512 + 0 * 256, 1536, 0, nullptr, HP, sch);
      gemm_k256<true><<<dim3(NBGMAX), dim3(256), 0, stream>>>(
          HP, pF2 + l * 65536, 196608, fb2A + l * 128, 384, 0, X2, sch);
      gemm_k128<4, 3, true><<<dim3(NBGMAX), dim3(256), 0, stream>>>(
          ANP, pF1 + l * 65536, 196608,
          fb1A + l * 512 + 1 * 256, 1536, 16, nullptr, HP, sch);
      gemm_k256<false><<<dim3(NBGMAX), dim3(256), 0, stream>>>(
          HP, pF2 + l * 65536, 196608, fb2A + l * 128, 384, 8, X2, sch);
    }
    head_kernel<<<dim3(PAIRS), dim3(256), 0, stream>>>(
        X2, plist, prow, pexp, rwgt, hW, hB, Rbuf);
    combine_kernel<<<dim3((Bn * 140 + 255) / 256), dim3(256), 0, stream>>>(
        Rbuf, ppos, (float*)d_out);
  }
}

// Round 7
// 1797.882 us; speedup vs baseline: 3.8851x; 1.0676x over previous
//
#include <hip/hip_runtime.h>
#include <math.h>

#define DEVI __device__ __forceinline__

namespace {

constexpr int Bn   = 2048;
constexpr int En   = 6;
constexpr int Hn   = 4;
constexpr int Dn   = 128;
constexpr int DHn  = 32;
constexpr int LTn  = 24;   // text length
constexpr int CSn  = 20;   // chunk (decoder query) length
constexpr int JDn  = 7;
constexpr int SDn  = 16;
constexpr int NLBn = 4;
constexpr int NLDn = 3;
constexpr int DFFn = 512;
constexpr int QSTR = 388;  // qkv LDS row stride (388 mod 32 = 4 -> no 32-way bank conflicts)
constexpr float INV_SQRT_DH = 0.17677669529663687f;  // 1/sqrt(32)

// expert phase-pipeline geometry
constexpr int PAIRS  = 4096;                  // 2048 items x top-2
constexpr int MPMAX  = PAIRS * 20 + En * 128; // padded rows (per-expert 128-aligned)
constexpr int NBGMAX = PAIRS * 20 / 128 + En; // 646 grouped-GEMM blocks max
constexpr int GEXP_OFF = 64;
constexpr int GMT_OFF  = 64 + NBGMAX;

// BERT pipeline geometry
constexpr int ROWSB = Bn * LTn;               // 49152 rows, 3072 M-tiles, no padding

typedef float f32x4v __attribute__((ext_vector_type(4)));
typedef short short8 __attribute__((ext_vector_type(8)));

DEVI float geluf(float x) { return 0.5f * x * (1.0f + erff(x * 0.70710678118654752f)); }

DEVI short f2bf(float f) {  // fp32 -> bf16 bits, round-to-nearest-even
  unsigned u = __float_as_uint(f);
  return (short)((u + 0x7FFFu + ((u >> 16) & 1u)) >> 16);
}
DEVI float bf2f(short s) { return __uint_as_float(((unsigned)(unsigned short)s) << 16); }
DEVI void split2(float v, short& h, short& l) {  // v ~= hi + lo to ~2^-16 rel
  h = f2bf(v);
  l = f2bf(v - bf2f(h));
}

// packed-A position for (row, col), K-tile count KT
DEVI size_t apos(int row, int col, int KT) {
  return (((size_t)(row >> 4) * KT + (col >> 5)) * 64 + ((col >> 3) & 3) * 16 + (row & 15)) * 8
         + (col & 7);
}

// scores: att[h*L*L + i*L + j] = (q_i . k_j) / sqrt(32), optional key-pad mask.
template<int L, int STR, bool MASK>
DEVI void attn_scores(const float* qkv, float* att, const int* pad)
{
  for (int e = (int)threadIdx.x; e < Hn * L * L; e += 256) {
    const int h = e / (L * L);
    const int rem = e % (L * L);
    const int i = rem / L, j = rem % L;
    const float* qp = qkv + i * STR + h * DHn;
    const float* kp = qkv + j * STR + 128 + h * DHn;
    float acc = 0.f;
#pragma unroll
    for (int d = 0; d < DHn; d += 4) {
      const float4 qa = *reinterpret_cast<const float4*>(qp + d);
      const float4 kb = *reinterpret_cast<const float4*>(kp + d);
      acc += qa.x * kb.x + qa.y * kb.y + qa.z * kb.z + qa.w * kb.w;
    }
    acc *= INV_SQRT_DH;
    if (MASK && pad[j]) acc = -1e9f;
    att[e] = acc;
  }
}

template<int L>
DEVI void softmax_rows(float* att)
{
  for (int r = (int)threadIdx.x; r < Hn * L; r += 256) {
    float* row = att + r * L;
    float m = row[0];
#pragma unroll 4
    for (int j = 1; j < L; ++j) m = fmaxf(m, row[j]);
    float s = 0.f;
#pragma unroll 4
    for (int j = 0; j < L; ++j) { const float ex = expf(row[j] - m); row[j] = ex; s += ex; }
    const float inv = 1.f / s;
#pragma unroll 4
    for (int j = 0; j < L; ++j) row[j] *= inv;
  }
}

// ---------------------------------------------------------------------------
// pack fp32 [K][N] into single-bf16 B tiles (512 shorts/tile)
__global__ void pack_kernel(const float* __restrict__ W, short* __restrict__ out,
                            const int K, const int N, const int total)
{
  const int p = (int)blockIdx.x * 256 + (int)threadIdx.x;
  if (p >= total) return;
  const int perMat = (K * N) >> 3;
  const int m = p / perMat, r = p - m * perMat;
  const int t = r >> 6, lane = r & 63;
  const int KT = K >> 5;
  const int nt = t / KT, kt = t - nt * KT;
  const int row0 = kt * 32 + (lane >> 4) * 8;
  const int col  = nt * 16 + (lane & 15);
  const float* src = W + (size_t)m * K * N;
  short8 v;
#pragma unroll
  for (int j = 0; j < 8; ++j) v[j] = f2bf(src[(size_t)(row0 + j) * N + col]);
  *reinterpret_cast<short8*>(out + (size_t)p * 8) = v;
}

// pack fp32 [K][N] into split hi/lo B tiles (1024 shorts/tile)
__global__ void pack2_kernel(const float* __restrict__ W, short* __restrict__ out,
                             const int K, const int N, const int total)
{
  const int p = (int)blockIdx.x * 256 + (int)threadIdx.x;
  if (p >= total) return;
  const int perMat = (K * N) >> 3;
  const int m = p / perMat, r = p - m * perMat;
  const int t = r >> 6, lane = r & 63;
  const int KT = K >> 5;
  const int nt = t / KT, kt = t - nt * KT;
  const int row0 = kt * 32 + (lane >> 4) * 8;
  const int col  = nt * 16 + (lane & 15);
  const float* src = W + (size_t)m * K * N;
  short8 vh, vl;
#pragma unroll
  for (int j = 0; j < 8; ++j) {
    short hh, ll;
    split2(src[(size_t)(row0 + j) * N + col], hh, ll);
    vh[j] = hh; vl[j] = ll;
  }
  const size_t T  = (size_t)(perMat >> 6);
  const size_t tg = (size_t)m * T + t;
  *reinterpret_cast<short8*>(out + tg * 1024 + lane * 8)       = vh;
  *reinterpret_cast<short8*>(out + tg * 1024 + 512 + lane * 8) = vl;
}

// ===========================================================================
// BERT phase pipeline (split-bf16, M = 49152 rows) — unchanged (post-LN: X=LN ok)
// ===========================================================================

__global__ __launch_bounds__(256) void bembed_kernel(
    const int* __restrict__ ids, const float* __restrict__ tok,
    const float* __restrict__ pos, float* __restrict__ X,
    short* __restrict__ Ah, short* __restrict__ Al)
{
  const int mt = (int)blockIdx.x;          // 0..3071
  const int t = (int)threadIdx.x;
  const int rl = t >> 4, j = t & 15;
  const int row = mt * 16 + rl;
  const int b = row / 24, i = row - b * 24;
  const int id = ids[b * 24 + i];
  const float* tp = tok + (size_t)id * 128 + j * 8;
  const float* pp = pos + i * 128 + j * 8;
  float x[8];
  short8 vh, vl;
#pragma unroll
  for (int u = 0; u < 8; ++u) {
    x[u] = tp[u] + pp[u];
    short hh, ll; split2(x[u], hh, ll);
    vh[u] = hh; vl[u] = ll;
  }
  float4 f0 = {x[0], x[1], x[2], x[3]}, f1 = {x[4], x[5], x[6], x[7]};
  *reinterpret_cast<float4*>(X + (size_t)row * 128 + j * 8) = f0;
  *reinterpret_cast<float4*>(X + (size_t)row * 128 + j * 8 + 4) = f1;
  const size_t pk = (((size_t)mt * 4 + (j >> 2)) * 64 + (j & 3) * 16 + rl) * 8;
  *reinterpret_cast<short8*>(Ah + pk) = vh;
  *reinterpret_cast<short8*>(Al + pk) = vl;
}

__global__ __launch_bounds__(256) void bqkv_kernel(
    const short* __restrict__ Ah, const short* __restrict__ Al,
    const short* __restrict__ Bp, const float* __restrict__ bias,
    float* __restrict__ Out)
{
  const int mt0 = (int)blockIdx.x * 4;
  const int nc  = (int)blockIdx.y;
  const int lane = (int)threadIdx.x & 63, wv = (int)threadIdx.x >> 6;
  const int r0 = lane & 15, g = lane >> 4;
  short8 bh[2][4], bl[2][4];
#pragma unroll
  for (int i = 0; i < 2; ++i)
#pragma unroll
    for (int kt = 0; kt < 4; ++kt) {
      const short* tb = Bp + (((size_t)(nc * 8 + wv * 2 + i) * 4 + kt) << 10);
      bh[i][kt] = *reinterpret_cast<const short8*>(tb + lane * 8);
      bl[i][kt] = *reinterpret_cast<const short8*>(tb + 512 + lane * 8);
    }
#pragma unroll 2
  for (int mt = 0; mt < 4; ++mt) {
    const int mtg = mt0 + mt;
    short8 ah[4], al[4];
#pragma unroll
    for (int kt = 0; kt < 4; ++kt) {
      ah[kt] = *reinterpret_cast<const short8*>(Ah + (((size_t)mtg * 4 + kt) * 64 + lane) * 8);
      al[kt] = *reinterpret_cast<const short8*>(Al + (((size_t)mtg * 4 + kt) * 64 + lane) * 8);
    }
#pragma unroll
    for (int i = 0; i < 2; ++i) {
      f32x4v c = {0.f, 0.f, 0.f, 0.f};
#pragma unroll
      for (int kt = 0; kt < 4; ++kt) {
        c = __builtin_amdgcn_mfma_f32_16x16x32_bf16(ah[kt], bh[i][kt], c, 0, 0, 0);
        c = __builtin_amdgcn_mfma_f32_16x16x32_bf16(al[kt], bh[i][kt], c, 0, 0, 0);
        c = __builtin_amdgcn_mfma_f32_16x16x32_bf16(ah[kt], bl[i][kt], c, 0, 0, 0);
      }
      const int col = nc * 128 + (wv * 2 + i) * 16 + r0;
      const float bb = bias[col];
#pragma unroll
      for (int q = 0; q < 4; ++q)
        Out[(size_t)(mtg * 16 + g * 4 + q) * 384 + col] = c[q] + bb;
    }
  }
}

__global__ __launch_bounds__(256) void battn_kernel(
    const float* __restrict__ QKV, const int* __restrict__ ids,
    short* __restrict__ Ah, short* __restrict__ Al)
{
  __shared__ float qkv[LTn * QSTR];
  __shared__ float att[Hn * LTn * LTn];
  __shared__ int pad_s[LTn];
  const int b = (int)blockIdx.x;
  const int tid = (int)threadIdx.x;
  const int row0 = b * LTn;
  for (int e4 = tid; e4 < LTn * 96; e4 += 256) {
    const int il = e4 / 96, c4 = e4 - il * 96;
    *reinterpret_cast<float4*>(qkv + il * QSTR + c4 * 4) =
        *reinterpret_cast<const float4*>(QKV + (size_t)(row0 + il) * 384 + c4 * 4);
  }
  for (int i2 = tid; i2 < LTn; i2 += 256) pad_s[i2] = (ids[row0 + i2] == 0) ? 1 : 0;
  __syncthreads();
  attn_scores<LTn, QSTR, true>(qkv, att, pad_s);
  __syncthreads();
  softmax_rows<LTn>(att);
  __syncthreads();
  for (int e = tid; e < LTn * Dn; e += 256) {
    const int il = e >> 7, c = e & 127, h = c >> 5;
    const float* arow = att + (h * LTn + il) * LTn;
    const float* vp = qkv + 256 + c;
    float acc = 0.f;
#pragma unroll 4
    for (int j = 0; j < LTn; ++j) acc = fmaf(arow[j], vp[j * QSTR], acc);
    short hh, ll; split2(acc, hh, ll);
    const size_t pk = apos(row0 + il, c, 4);
    Ah[pk] = hh; Al[pk] = ll;
  }
}

__global__ __launch_bounds__(256) void bo_ln_kernel(
    const short* __restrict__ Ah, const short* __restrict__ Al,
    const short* __restrict__ Bp, const float* __restrict__ bo,
    const float* __restrict__ gs, const float* __restrict__ gb,
    float* __restrict__ X, short* __restrict__ OAh, short* __restrict__ OAl)
{
  __shared__ float red[16][4][2];
  const int mt0 = (int)blockIdx.x * 4;
  const int lane = (int)threadIdx.x & 63, wv = (int)threadIdx.x >> 6;
  const int r0 = lane & 15, g = lane >> 4;
  short8 bh[2][4], bl[2][4];
#pragma unroll
  for (int i = 0; i < 2; ++i)
#pragma unroll
    for (int kt = 0; kt < 4; ++kt) {
      const short* tb = Bp + (((size_t)(wv * 2 + i) * 4 + kt) << 10);
      bh[i][kt] = *reinterpret_cast<const short8*>(tb + lane * 8);
      bl[i][kt] = *reinterpret_cast<const short8*>(tb + 512 + lane * 8);
    }
  for (int mt = 0; mt < 4; ++mt) {
    const int mtg = mt0 + mt;
    short8 ah[4], al[4];
#pragma unroll
    for (int kt = 0; kt < 4; ++kt) {
      ah[kt] = *reinterpret_cast<const short8*>(Ah + (((size_t)mtg * 4 + kt) * 64 + lane) * 8);
      al[kt] = *reinterpret_cast<const short8*>(Al + (((size_t)mtg * 4 + kt) * 64 + lane) * 8);
    }
    float v[2][4];
#pragma unroll
    for (int i = 0; i < 2; ++i) {
      f32x4v c = {0.f, 0.f, 0.f, 0.f};
#pragma unroll
      for (int kt = 0; kt < 4; ++kt) {
        c = __builtin_amdgcn_mfma_f32_16x16x32_bf16(ah[kt], bh[i][kt], c, 0, 0, 0);
        c = __builtin_amdgcn_mfma_f32_16x16x32_bf16(al[kt], bh[i][kt], c, 0, 0, 0);
        c = __builtin_amdgcn_mfma_f32_16x16x32_bf16(ah[kt], bl[i][kt], c, 0, 0, 0);
      }
      const int col = (wv * 2 + i) * 16 + r0;
      const float bb = bo[col];
#pragma unroll
      for (int q = 0; q < 4; ++q) {
        const int row = mtg * 16 + g * 4 + q;
        v[i][q] = c[q] + bb + X[(size_t)row * 128 + col];
      }
    }
    float s1[4], s2[4];
#pragma unroll
    for (int q = 0; q < 4; ++q) {
      s1[q] = v[0][q] + v[1][q];
      s2[q] = v[0][q] * v[0][q] + v[1][q] * v[1][q];
    }
#pragma unroll
    for (int o = 1; o < 16; o <<= 1)
#pragma unroll
      for (int q = 0; q < 4; ++q) { s1[q] += __shfl_xor(s1[q], o); s2[q] += __shfl_xor(s2[q], o); }
    if (r0 == 0)
#pragma unroll
      for (int q = 0; q < 4; ++q) { red[g * 4 + q][wv][0] = s1[q]; red[g * 4 + q][wv][1] = s2[q]; }
    __syncthreads();
#pragma unroll
    for (int q = 0; q < 4; ++q) {
      const int r = g * 4 + q;
      const float t1 = red[r][0][0] + red[r][1][0] + red[r][2][0] + red[r][3][0];
      const float t2 = red[r][0][1] + red[r][1][1] + red[r][2][1] + red[r][3][1];
      const float m  = t1 * (1.f / 128.f);
      const float rs = rsqrtf(t2 * (1.f / 128.f) - m * m + 1e-5f);
      const int row = mtg * 16 + r;
#pragma unroll
      for (int i = 0; i < 2; ++i) {
        const int col = (wv * 2 + i) * 16 + r0;
        const float o = (v[i][q] - m) * rs * gs[col] + gb[col];
        X[(size_t)row * 128 + col] = o;   // post-LN: LN'd value IS the residual
        short hh, ll; split2(o, hh, ll);
        const size_t pk = apos(row, col, 4);
        OAh[pk] = hh; OAl[pk] = ll;
      }
    }
    __syncthreads();
  }
}

__global__ __launch_bounds__(256) void bw1_kernel(
    const short* __restrict__ Ah, const short* __restrict__ Al,
    const short* __restrict__ Bp, const float* __restrict__ bias,
    short* __restrict__ Hh, short* __restrict__ Hl)
{
  const int mt0 = (int)blockIdx.x * 4;
  const int nc  = (int)blockIdx.y;
  const int lane = (int)threadIdx.x & 63, wv = (int)threadIdx.x >> 6;
  const int r0 = lane & 15, g = lane >> 4;
  short8 bh[2][4], bl[2][4];
#pragma unroll
  for (int i = 0; i < 2; ++i)
#pragma unroll
    for (int kt = 0; kt < 4; ++kt) {
      const short* tb = Bp + (((size_t)(nc * 8 + wv * 2 + i) * 4 + kt) << 10);
      bh[i][kt] = *reinterpret_cast<const short8*>(tb + lane * 8);
      bl[i][kt] = *reinterpret_cast<const short8*>(tb + 512 + lane * 8);
    }
#pragma unroll 2
  for (int mt = 0; mt < 4; ++mt) {
    const int mtg = mt0 + mt;
    short8 ah[4], al[4];
#pragma unroll
    for (int kt = 0; kt < 4; ++kt) {
      ah[kt] = *reinterpret_cast<const short8*>(Ah + (((size_t)mtg * 4 + kt) * 64 + lane) * 8);
      al[kt] = *reinterpret_cast<const short8*>(Al + (((size_t)mtg * 4 + kt) * 64 + lane) * 8);
    }
#pragma unroll
    for (int i = 0; i < 2; ++i) {
      f32x4v c = {0.f, 0.f, 0.f, 0.f};
#pragma unroll
      for (int kt = 0; kt < 4; ++kt) {
        c = __builtin_amdgcn_mfma_f32_16x16x32_bf16(ah[kt], bh[i][kt], c, 0, 0, 0);
        c = __builtin_amdgcn_mfma_f32_16x16x32_bf16(al[kt], bh[i][kt], c, 0, 0, 0);
        c = __builtin_amdgcn_mfma_f32_16x16x32_bf16(ah[kt], bl[i][kt], c, 0, 0, 0);
      }
      const int col = nc * 128 + (wv * 2 + i) * 16 + r0;
      const float bb = bias[col];
#pragma unroll
      for (int q = 0; q < 4; ++q) {
        const int row = mtg * 16 + g * 4 + q;
        short hh, ll; split2(geluf(c[q] + bb), hh, ll);
        const size_t pk = apos(row, col, 16);
        Hh[pk] = hh; Hl[pk] = ll;
      }
    }
  }
}

__global__ __launch_bounds__(512) void bw2a_kernel(
    const short* __restrict__ Hh, const short* __restrict__ Hl,
    const short* __restrict__ Bp, const float* __restrict__ bias,
    float* __restrict__ X)
{
  const int mt0 = (int)blockIdx.x * 4;
  const int lane = (int)threadIdx.x & 63, wv = (int)threadIdx.x >> 6;  // 8 waves
  const int r0 = lane & 15, g = lane >> 4;
  short8 bh[8], bl[8];
#pragma unroll
  for (int kk = 0; kk < 8; ++kk) {
    const short* tb = Bp + (((size_t)wv * 16 + kk) << 10);
    bh[kk] = *reinterpret_cast<const short8*>(tb + lane * 8);
    bl[kk] = *reinterpret_cast<const short8*>(tb + 512 + lane * 8);
  }
#pragma unroll 2
  for (int mt = 0; mt < 4; ++mt) {
    const int mtg = mt0 + mt;
    f32x4v c = {0.f, 0.f, 0.f, 0.f};
#pragma unroll
    for (int kk = 0; kk < 8; ++kk) {
      const short8 ah = *reinterpret_cast<const short8*>(Hh + (((size_t)mtg * 16 + kk) * 64 + lane) * 8);
      const short8 al = *reinterpret_cast<const short8*>(Hl + (((size_t)mtg * 16 + kk) * 64 + lane) * 8);
      c = __builtin_amdgcn_mfma_f32_16x16x32_bf16(ah, bh[kk], c, 0, 0, 0);
      c = __builtin_amdgcn_mfma_f32_16x16x32_bf16(al, bh[kk], c, 0, 0, 0);
      c = __builtin_amdgcn_mfma_f32_16x16x32_bf16(ah, bl[kk], c, 0, 0, 0);
    }
    const int col = wv * 16 + r0;
    const float bb = bias[col];
#pragma unroll
    for (int q = 0; q < 4; ++q)
      X[(size_t)(mtg * 16 + g * 4 + q) * 128 + col] += c[q] + bb;
  }
}

__global__ __launch_bounds__(512) void bw2b_kernel(
    const short* __restrict__ Hh, const short* __restrict__ Hl,
    const short* __restrict__ Bp, const float* __restrict__ gs,
    const float* __restrict__ gb, float* __restrict__ X,
    short* __restrict__ OAh, short* __restrict__ OAl)
{
  __shared__ float red[16][8][2];
  const int mt0 = (int)blockIdx.x * 4;
  const int lane = (int)threadIdx.x & 63, wv = (int)threadIdx.x >> 6;
  const int r0 = lane & 15, g = lane >> 4;
  short8 bh[8], bl[8];
#pragma unroll
  for (int kk = 0; kk < 8; ++kk) {
    const short* tb = Bp + (((size_t)wv * 16 + 8 + kk) << 10);
    bh[kk] = *reinterpret_cast<const short8*>(tb + lane * 8);
    bl[kk] = *reinterpret_cast<const short8*>(tb + 512 + lane * 8);
  }
  for (int mt = 0; mt < 4; ++mt) {
    const int mtg = mt0 + mt;
    f32x4v c = {0.f, 0.f, 0.f, 0.f};
#pragma unroll
    for (int kk = 0; kk < 8; ++kk) {
      const short8 ah = *reinterpret_cast<const short8*>(Hh + (((size_t)mtg * 16 + 8 + kk) * 64 + lane) * 8);
      const short8 al = *reinterpret_cast<const short8*>(Hl + (((size_t)mtg * 16 + 8 + kk) * 64 + lane) * 8);
      c = __builtin_amdgcn_mfma_f32_16x16x32_bf16(ah, bh[kk], c, 0, 0, 0);
      c = __builtin_amdgcn_mfma_f32_16x16x32_bf16(al, bh[kk], c, 0, 0, 0);
      c = __builtin_amdgcn_mfma_f32_16x16x32_bf16(ah, bl[kk], c, 0, 0, 0);
    }
    const int col = wv * 16 + r0;
    float v[4], s1[4], s2[4];
#pragma unroll
    for (int q = 0; q < 4; ++q) {
      const int row = mtg * 16 + g * 4 + q;
      v[q] = c[q] + X[(size_t)row * 128 + col];
      s1[q] = v[q]; s2[q] = v[q] * v[q];
    }
#pragma unroll
    for (int o = 1; o < 16; o <<= 1)
#pragma unroll
      for (int q = 0; q < 4; ++q) { s1[q] += __shfl_xor(s1[q], o); s2[q] += __shfl_xor(s2[q], o); }
    if (r0 == 0)
#pragma unroll
      for (int q = 0; q < 4; ++q) { red[g * 4 + q][wv][0] = s1[q]; red[g * 4 + q][wv][1] = s2[q]; }
    __syncthreads();
#pragma unroll
    for (int q = 0; q < 4; ++q) {
      const int r = g * 4 + q;
      float t1 = 0.f, t2 = 0.f;
#pragma unroll
      for (int w = 0; w < 8; ++w) { t1 += red[r][w][0]; t2 += red[r][w][1]; }
      const float m  = t1 * (1.f / 128.f);
      const float rs = rsqrtf(t2 * (1.f / 128.f) - m * m + 1e-5f);
      const int row = mtg * 16 + r;
      const float o = (v[q] - m) * rs * gs[col] + gb[col];
      X[(size_t)row * 128 + col] = o;     // post-LN
      short hh, ll; split2(o, hh, ll);
      const size_t pk = apos(row, col, 4);
      OAh[pk] = hh; OAl[pk] = ll;
    }
    __syncthreads();
  }
}

__global__ __launch_bounds__(256) void bintent_kernel(
    const float* __restrict__ X, const float* __restrict__ lnf_s,
    const float* __restrict__ lnf_b, float* __restrict__ intent)
{
  const int w = (int)threadIdx.x >> 6, lane = (int)threadIdx.x & 63;
  const int b = (int)blockIdx.x * 4 + w;
  const float* xr = X + (size_t)b * LTn * 128;
  const float a0 = xr[lane], a1 = xr[lane + 64];
  float s1 = a0 + a1, s2 = a0 * a0 + a1 * a1;
#pragma unroll
  for (int o = 32; o > 0; o >>= 1) { s1 += __shfl_xor(s1, o); s2 += __shfl_xor(s2, o); }
  const float m  = s1 * (1.f / 128.f);
  const float rs = rsqrtf(s2 * (1.f / 128.f) - m * m + 1e-5f);
  intent[b * 128 + lane]      = (a0 - m) * rs * lnf_s[lane]      + lnf_b[lane];
  intent[b * 128 + lane + 64] = (a1 - m) * rs * lnf_s[lane + 64] + lnf_b[lane + 64];
}

// ---------------------------------------------------------------------------
struct RouterP {
  const float* state; const float* intent;
  const float* se_W1; const float* se_b1; const float* se_W2; const float* se_b2;
  const float* se_ln_s; const float* se_ln_b;
  const float* r_W1; const float* r_b1; const float* r_W2; const float* r_b2;
  const float* r_ln_s; const float* r_ln_b;
  const float* gate_W; const float* gate_b;
  int* ridx; float* rwgt;
};

DEVI void ln128(float* x, const float* gs, const float* gb, float* red)
{
  const int c = (int)threadIdx.x;      // blockDim == 128
  const float a = x[c];
  float s1 = a, s2 = a * a;
#pragma unroll
  for (int o = 32; o > 0; o >>= 1) { s1 += __shfl_xor(s1, o); s2 += __shfl_xor(s2, o); }
  const int wid = c >> 6;
  if ((c & 63) == 0) { red[wid * 2] = s1; red[wid * 2 + 1] = s2; }
  __syncthreads();
  s1 = red[0] + red[2]; s2 = red[1] + red[3];
  const float m  = s1 * (1.f / 128.f);
  const float rs = rsqrtf(s2 * (1.f / 128.f) - m * m + 1e-5f);
  __syncthreads();
  x[c] = (a - m) * rs * gs[c] + gb[c];
}

// 128-deep dot with 4 independent accumulator chains (latency fix)
DEVI float dot128i(const float* __restrict__ h, const float* __restrict__ W,
                   const int c, const int wstr)
{
  float a0 = 0.f, a1 = 0.f, a2 = 0.f, a3 = 0.f;
#pragma unroll 8
  for (int k = 0; k < 128; k += 4) {
    a0 = fmaf(h[k + 0], W[(k + 0) * wstr + c], a0);
    a1 = fmaf(h[k + 1], W[(k + 1) * wstr + c], a1);
    a2 = fmaf(h[k + 2], W[(k + 2) * wstr + c], a2);
    a3 = fmaf(h[k + 3], W[(k + 3) * wstr + c], a3);
  }
  return (a0 + a1) + (a2 + a3);
}

__global__ __launch_bounds__(128) void router_kernel(RouterP p)
{
  __shared__ float sstate[SDn];
  __shared__ float h1[Dn];
  __shared__ float vv[Dn];
  __shared__ float red[4];
  __shared__ float slog[En];
  const int b = blockIdx.x;
  const int c = (int)threadIdx.x;

  if (c < SDn) sstate[c] = p.state[b * SDn + c];
  __syncthreads();
  {
    float acc = p.se_b1[c];
#pragma unroll
    for (int k = 0; k < SDn; ++k) acc = fmaf(sstate[k], p.se_W1[k * Dn + c], acc);
    h1[c] = geluf(acc);
  }
  __syncthreads();
  vv[c] = p.se_b2[c] + dot128i(h1, p.se_W2, c, Dn);
  __syncthreads();
  ln128(vv, p.se_ln_s, p.se_ln_b, red);
  __syncthreads();
  {
    const float* ib = p.intent + b * Dn;
    float acc = p.r_b1[c] + dot128i(ib, p.r_W1, c, Dn)
                          + dot128i(vv, p.r_W1 + Dn * Dn, c, Dn);
    h1[c] = geluf(acc);
  }
  __syncthreads();
  vv[c] = p.r_b2[c] + dot128i(h1, p.r_W2, c, Dn);
  __syncthreads();
  ln128(vv, p.r_ln_s, p.r_ln_b, red);
  __syncthreads();
  if (c < En) slog[c] = p.gate_b[c] + dot128i(vv, p.gate_W, c, En);
  __syncthreads();
  if (c == 0) {
    int i0 = 0; float v0 = slog[0];
#pragma unroll
    for (int e2 = 1; e2 < En; ++e2) if (slog[e2] > v0) { v0 = slog[e2]; i0 = e2; }
    int i1 = -1; float v1 = -3.4e38f;
#pragma unroll
    for (int e2 = 0; e2 < En; ++e2) if (e2 != i0 && slog[e2] > v1) { v1 = slog[e2]; i1 = e2; }
    const float e1  = expf(v1 - v0);
    const float inv = 1.f / (1.f + e1);
    p.ridx[b * 2 + 0] = i0; p.ridx[b * 2 + 1] = i1;
    p.rwgt[b * 2 + 0] = inv; p.rwgt[b * 2 + 1] = e1 * inv;
  }
}

// ===========================================================================
// EXPERT PHASE PIPELINE — norm_first: X keeps RAW residual, packed A gets LN
// ===========================================================================

__global__ void sched_kernel(const int* __restrict__ ridx, int* __restrict__ sch,
                             int* plist, int* prow, int* pexp, int* ppos)
{
  __shared__ int scnt[En], scur[En], soff[En], srb[En + 1];
  const int t = (int)threadIdx.x;
  if (t < En) { scnt[t] = 0; scur[t] = 0; }
  __syncthreads();
  for (int p = t; p < PAIRS; p += 256) atomicAdd(&scnt[ridx[p]], 1);
  __syncthreads();
  if (t == 0) {
    int off = 0, rb = 0, k = 0;
    for (int e = 0; e < En; ++e) {
      soff[e] = off; srb[e] = rb;
      const int rows = scnt[e] * 20;
      const int nb = (rows + 127) >> 7;
      for (int q = 0; q < nb; ++q) {
        sch[GEXP_OFF + k] = e;
        sch[GMT_OFF + k]  = (rb >> 4) + q * 8;
        ++k;
      }
      off += scnt[e];
      rb += nb * 128;
    }
    srb[En] = rb;
    sch[0] = k;
    for (int e = 0; e < En; ++e) { sch[1 + e] = scnt[e]; sch[7 + e] = soff[e]; }
    for (int e = 0; e <= En; ++e) sch[13 + e] = srb[e];
  }
  __syncthreads();
  for (int p = t; p < PAIRS; p += 256) {
    const int e = ridx[p];
    const int pos = atomicAdd(&scur[e], 1);
    const int i = soff[e] + pos;
    plist[i] = p; ppos[p] = i; pexp[i] = e; prow[i] = srb[e] + pos * 20;
  }
}

__global__ void xinit_kernel(const float* __restrict__ qpe, const int* __restrict__ sch,
                             float* __restrict__ X)
{
  const int idx = (int)blockIdx.x * 256 + (int)threadIdx.x;  // quad index
  const int row = idx >> 5;
  if (row >= MPMAX) return;
  const int c4 = (idx & 31) * 4;
  const int* RB = sch + 13;
  float4 v = {0.f, 0.f, 0.f, 0.f};
  int e = 0;
  while (e < En && row >= RB[e + 1]) ++e;
  if (e < En) {
    const int local = row - RB[e];
    if (local < sch[1 + e] * 20) {
      const int r = local - (local / 20) * 20;
      v = *reinterpret_cast<const float4*>(qpe + r * 128 + c4);
    }
  }
  *reinterpret_cast<float4*>(X + (size_t)row * 128 + c4) = v;
}

// LN over X rows -> packed bf16 A-fragments (used once, layer-0 sub-0)
__global__ __launch_bounds__(256) void ln_pack_kernel(
    const float* __restrict__ X, short* __restrict__ XnP,
    const float* __restrict__ lns_all, const float* __restrict__ lnb_all,
    const int subOff, const int* __restrict__ sch)
{
  const int* RB = sch + 13;
  const int mt = (int)blockIdx.x;
  const int row0 = mt << 4;
  if (row0 >= RB[En]) return;
  int e = 0;
  while (e < En - 1 && row0 >= RB[e + 1]) ++e;
  const float* gs = lns_all + e * (NLDn * 3 * 128) + subOff;
  const float* gb = lnb_all + e * (NLDn * 3 * 128) + subOff;
  const int t = (int)threadIdx.x;
  const int rl = t >> 4, j = t & 15;
  const int row = row0 + rl;
  float x[8];
  {
    const float4 a = *reinterpret_cast<const float4*>(X + (size_t)row * 128 + j * 8);
    const float4 bq = *reinterpret_cast<const float4*>(X + (size_t)row * 128 + j * 8 + 4);
    x[0] = a.x; x[1] = a.y; x[2] = a.z; x[3] = a.w;
    x[4] = bq.x; x[5] = bq.y; x[6] = bq.z; x[7] = bq.w;
  }
  float s1 = 0.f, s2 = 0.f;
#pragma unroll
  for (int u = 0; u < 8; ++u) { s1 += x[u]; s2 += x[u] * x[u]; }
#pragma unroll
  for (int o = 1; o < 16; o <<= 1) { s1 += __shfl_xor(s1, o); s2 += __shfl_xor(s2, o); }
  const float m  = s1 * (1.f / 128.f);
  const float rs = rsqrtf(s2 * (1.f / 128.f) - m * m + 1e-5f);
  short8 pk;
#pragma unroll
  for (int u = 0; u < 8; ++u)
    pk[u] = f2bf((x[u] - m) * rs * gs[j * 8 + u] + gb[j * 8 + u]);
  const int kt = j >> 2, g = j & 3, lp = g * 16 + rl;
  *reinterpret_cast<short8*>(XnP + (((size_t)mt * 4 + kt) * 64 + lp) * 8) = pk;
}

// grouped GEMM, K=128 (packed A, 4 k-tiles).
// EPI 0: store bf16 row-major (stride obstr)   [QKV / cross-Q]
// EPI 3: relu -> packed bf16 KT=8              [FFN W1 halves]
// EPI 4: fused norm_first epilogue: v = c + bias + X; X = v (RAW);
//        packed A = LN(v) with (lnsA,lnbA,subOff)           [O-proj]
template<int NTW, int EPI, bool HASB>
__global__ __launch_bounds__(256) void gemm_k128(
    const short* __restrict__ A, const short* __restrict__ Bb, const int strideB,
    const float* __restrict__ biasb, const int strideBias, const int ntOff,
    short* __restrict__ OutBf, const int obstr, short* __restrict__ OutP,
    const float* __restrict__ lnsA, const float* __restrict__ lnbA, const int subOff,
    float* __restrict__ X, const int* __restrict__ sch)
{
  __shared__ float red[16][4][2];
  const int k = (int)blockIdx.x;
  if (k >= sch[0]) return;
  const int ex  = sch[GEXP_OFF + k];
  const int mt0 = sch[GMT_OFF + k];
  const short* Bp = Bb + (size_t)ex * strideB;
  const float* bias = biasb + (size_t)ex * strideBias;
  const float* gs = (EPI == 4) ? lnsA + ex * (NLDn * 3 * 128) + subOff : nullptr;
  const float* gb = (EPI == 4) ? lnbA + ex * (NLDn * 3 * 128) + subOff : nullptr;
  const int lane = (int)threadIdx.x & 63, wv = (int)threadIdx.x >> 6;
  const int r0 = lane & 15, g = lane >> 4;
  short8 bf[NTW][4];
#pragma unroll
  for (int i = 0; i < NTW; ++i)
#pragma unroll
    for (int kt = 0; kt < 4; ++kt)
      bf[i][kt] = *reinterpret_cast<const short8*>(
          Bp + (((size_t)(ntOff + wv * NTW + i) * 4 + kt) * 64 + lane) * 8);
  for (int mt = 0; mt < 8; ++mt) {
    short8 a[4];
#pragma unroll
    for (int kt = 0; kt < 4; ++kt)
      a[kt] = *reinterpret_cast<const short8*>(
          A + (((size_t)(mt0 + mt) * 4 + kt) * 64 + lane) * 8);
    float v[NTW][4];
#pragma unroll
    for (int i = 0; i < NTW; ++i) {
      f32x4v c = {0.f, 0.f, 0.f, 0.f};
#pragma unroll
      for (int kt = 0; kt < 4; ++kt)
        c = __builtin_amdgcn_mfma_f32_16x16x32_bf16(a[kt], bf[i][kt], c, 0, 0, 0);
      const int colL = (wv * NTW + i) * 16 + r0;
      const float bb = HASB ? bias[colL] : 0.f;
      const int rowB = (mt0 + mt) * 16 + g * 4;
#pragma unroll
      for (int q = 0; q < 4; ++q) {
        const int row = rowB + q;
        const float val = c[q] + bb;
        if (EPI == 0) {
          OutBf[(size_t)row * obstr + colL] = f2bf(val);
        } else if (EPI == 3) {
          const float rv = fmaxf(val, 0.f);
          const int j = colL >> 3, kt2 = j >> 2, g2 = j & 3;
          const int lp = g2 * 16 + (row & 15);
          OutP[(((size_t)(row >> 4) * 8 + kt2) * 64 + lp) * 8 + (colL & 7)] = f2bf(rv);
        } else {
          v[i][q] = val + X[(size_t)row * 128 + colL];
        }
      }
    }
    if (EPI == 4) {
      static_assert(EPI != 4 || NTW == 2, "fused LN requires NTW==2");
      float s1[4], s2[4];
#pragma unroll
      for (int q = 0; q < 4; ++q) {
        s1[q] = v[0][q] + v[1][q];
        s2[q] = v[0][q] * v[0][q] + v[1][q] * v[1][q];
      }
#pragma unroll
      for (int o = 1; o < 16; o <<= 1)
#pragma unroll
        for (int q = 0; q < 4; ++q) { s1[q] += __shfl_xor(s1[q], o); s2[q] += __shfl_xor(s2[q], o); }
      if (r0 == 0)
#pragma unroll
        for (int q = 0; q < 4; ++q) { red[g * 4 + q][wv][0] = s1[q]; red[g * 4 + q][wv][1] = s2[q]; }
      __syncthreads();
#pragma unroll
      for (int q = 0; q < 4; ++q) {
        const int r = g * 4 + q;
        const float t1 = red[r][0][0] + red[r][1][0] + red[r][2][0] + red[r][3][0];
        const float t2 = red[r][0][1] + red[r][1][1] + red[r][2][1] + red[r][3][1];
        const float m  = t1 * (1.f / 128.f);
        const float rs = rsqrtf(t2 * (1.f / 128.f) - m * m + 1e-5f);
        const int row = (mt0 + mt) * 16 + r;
#pragma unroll
        for (int i = 0; i < 2; ++i) {
          const int col = (wv * 2 + i) * 16 + r0;
          const float o = (v[i][q] - m) * rs * gs[col] + gb[col];
          X[(size_t)row * 128 + col] = v[i][q];   // norm_first: RAW residual
          OutP[apos(row, col, 4)] = f2bf(o);      // LN'd input for next phase
        }
      }
      __syncthreads();
    }
  }
}

// grouped GEMM, K=256 half of 512 (packed A: 8 k-tiles).
// DOLN=false: X += c (+bias).
// DOLN=true : v = X + c; X = v (RAW); packed A = LN(v) with subOff.
template<bool HASB, bool DOLN>
__global__ __launch_bounds__(256) void gemm_k256(
    const short* __restrict__ A, const short* __restrict__ Bb, const int strideB,
    const float* __restrict__ biasb, const int strideBias, const int ktOff,
    float* __restrict__ X, short* __restrict__ OutP,
    const float* __restrict__ lnsA, const float* __restrict__ lnbA, const int subOff,
    const int* __restrict__ sch)
{
  __shared__ float red[16][4][2];
  const int k = (int)blockIdx.x;
  if (k >= sch[0]) return;
  const int ex  = sch[GEXP_OFF + k];
  const int mt0 = sch[GMT_OFF + k];
  const short* Bp = Bb + (size_t)ex * strideB;
  const float* bias = biasb + (size_t)ex * strideBias;
  const float* gs = DOLN ? lnsA + ex * (NLDn * 3 * 128) + subOff : nullptr;
  const float* gb = DOLN ? lnbA + ex * (NLDn * 3 * 128) + subOff : nullptr;
  const int lane = (int)threadIdx.x & 63, wv = (int)threadIdx.x >> 6;
  const int r0 = lane & 15, g = lane >> 4;
  short8 bf[2][8];
#pragma unroll
  for (int i = 0; i < 2; ++i)
#pragma unroll
    for (int kk = 0; kk < 8; ++kk)
      bf[i][kk] = *reinterpret_cast<const short8*>(
          Bp + (((size_t)(wv * 2 + i) * 16 + ktOff + kk) * 64 + lane) * 8);
  for (int mt = 0; mt < 8; ++mt) {
    short8 a[8];
#pragma unroll
    for (int kk = 0; kk < 8; ++kk)
      a[kk] = *reinterpret_cast<const short8*>(
          A + (((size_t)(mt0 + mt) * 8 + kk) * 64 + lane) * 8);
    float v[2][4];
#pragma unroll
    for (int i = 0; i < 2; ++i) {
      f32x4v c = {0.f, 0.f, 0.f, 0.f};
#pragma unroll
      for (int kk = 0; kk < 8; ++kk)
        c = __builtin_amdgcn_mfma_f32_16x16x32_bf16(a[kk], bf[i][kk], c, 0, 0, 0);
      const int colL = (wv * 2 + i) * 16 + r0;
      const float bb = HASB ? bias[colL] : 0.f;
      const int rowB = (mt0 + mt) * 16 + g * 4;
#pragma unroll
      for (int q = 0; q < 4; ++q) {
        const int row = rowB + q;
        if (DOLN) v[i][q] = c[q] + bb + X[(size_t)row * 128 + colL];
        else      X[(size_t)row * 128 + colL] += c[q] + bb;
      }
    }
    if (DOLN) {
      float s1[4], s2[4];
#pragma unroll
      for (int q = 0; q < 4; ++q) {
        s1[q] = v[0][q] + v[1][q];
        s2[q] = v[0][q] * v[0][q] + v[1][q] * v[1][q];
      }
#pragma unroll
      for (int o = 1; o < 16; o <<= 1)
#pragma unroll
        for (int q = 0; q < 4; ++q) { s1[q] += __shfl_xor(s1[q], o); s2[q] += __shfl_xor(s2[q], o); }
      if (r0 == 0)
#pragma unroll
        for (int q = 0; q < 4; ++q) { red[g * 4 + q][wv][0] = s1[q]; red[g * 4 + q][wv][1] = s2[q]; }
      __syncthreads();
#pragma unroll
      for (int q = 0; q < 4; ++q) {
        const int r = g * 4 + q;
        const float t1 = red[r][0][0] + red[r][1][0] + red[r][2][0] + red[r][3][0];
        const float t2 = red[r][0][1] + red[r][1][1] + red[r][2][1] + red[r][3][1];
        const float m  = t1 * (1.f / 128.f);
        const float rs = rsqrtf(t2 * (1.f / 128.f) - m * m + 1e-5f);
        const int row = (mt0 + mt) * 16 + r;
#pragma unroll
        for (int i = 0; i < 2; ++i) {
          const int col = (wv * 2 + i) * 16 + r0;
          const float o = (v[i][q] - m) * rs * gs[col] + gb[col];
          X[(size_t)row * 128 + col] = v[i][q];   // norm_first: RAW residual
          OutP[apos(row, col, 4)] = f2bf(o);      // LN'd input for next layer
        }
      }
      __syncthreads();
    }
  }
}

// per-pair self-attention: QKV bf16 (stride 384) -> O packed bf16
__global__ __launch_bounds__(256) void sattn_kernel(
    const short* __restrict__ QKVb, const int* __restrict__ prow,
    short* __restrict__ ANP)
{
  __shared__ float qkv[CSn * QSTR];
  __shared__ float att[Hn * CSn * CSn];
  const int i = (int)blockIdx.x;
  const int row0 = prow[i];
  for (int e8 = (int)threadIdx.x; e8 < CSn * 48; e8 += 256) {
    const int il = e8 / 48, c8 = e8 - il * 48;
    const short8 s = *reinterpret_cast<const short8*>(
        QKVb + (size_t)(row0 + il) * 384 + c8 * 8);
    float* dst = qkv + il * QSTR + c8 * 8;
#pragma unroll
    for (int u = 0; u < 8; ++u) dst[u] = bf2f(s[u]);
  }
  __syncthreads();
  attn_scores<CSn, QSTR, false>(qkv, att, nullptr);
  __syncthreads();
  softmax_rows<CSn>(att);
  __syncthreads();
  for (int e = (int)threadIdx.x; e < CSn * Dn; e += 256) {
    const int il = e >> 7, c = e & 127, h = c >> 5;
    const float* arow = att + (h * CSn + il) * CSn;
    const float* vp = qkv + 256 + c;
    float acc = 0.f;
#pragma unroll 4
    for (int j = 0; j < CSn; ++j) acc = fmaf(arow[j], vp[j * QSTR], acc);
    ANP[apos(row0 + il, c, 4)] = f2bf(acc);
  }
}

// per-pair cross-attention (2 keys): Qc bf16 (stride 128) -> co packed bf16
__global__ __launch_bounds__(256) void cattn_kernel(
    const short* __restrict__ Qb, const float* __restrict__ state,
    const float* __restrict__ sp_W, const float* __restrict__ sp_b,
    const float* __restrict__ zp_b, const float* __restrict__ aW,
    const float* __restrict__ ab, const int layer,
    const int* __restrict__ plist, const int* __restrict__ prow,
    const int* __restrict__ pexp, short* __restrict__ ANP)
{
  __shared__ float q[CSn * Dn];
  __shared__ float mem[2 * Dn];
  __shared__ float memkv[2 * 256];
  __shared__ float catt[2 * Hn * CSn];
  const int i = (int)blockIdx.x;
  const int ex = pexp[i];
  const int orig = plist[i];
  const int b = orig >> 1;
  const int row0 = prow[i];
  const int li = ex * NLDn + layer;
  const float* aW1f = aW + (size_t)(li * 2 + 1) * Dn * 384;
  const float* ab1  = ab + (size_t)(li * 2 + 1) * 384;
  const int tid = (int)threadIdx.x;

  if (tid < Dn) {
    float acc = sp_b[ex * Dn + tid];
    const float* spw = sp_W + ex * SDn * Dn;
#pragma unroll
    for (int kk = 0; kk < SDn; ++kk) acc = fmaf(state[b * SDn + kk], spw[kk * Dn + tid], acc);
    mem[tid] = acc;
  } else {
    mem[Dn + (tid - Dn)] = zp_b[ex * Dn + (tid - Dn)];
  }
  for (int e8 = tid; e8 < CSn * 16; e8 += 256) {
    const int il = e8 >> 4, c8 = e8 & 15;
    const short8 s = *reinterpret_cast<const short8*>(
        Qb + (size_t)(row0 + il) * 128 + c8 * 8);
    float* dst = q + il * Dn + c8 * 8;
#pragma unroll
    for (int u = 0; u < 8; ++u) dst[u] = bf2f(s[u]);
  }
  __syncthreads();
  for (int e = tid; e < 2 * 256; e += 256) {
    const int j = e >> 8, c2 = e & 255;
    float acc = ab1[Dn + c2];
    const float* wp = aW1f + Dn + c2;
#pragma unroll 4
    for (int kk = 0; kk < Dn; ++kk) acc = fmaf(mem[j * Dn + kk], wp[kk * 384], acc);
    memkv[j * 256 + c2] = acc;
  }
  __syncthreads();
  for (int e = tid; e < Hn * CSn; e += 256) {
    const int h = e / CSn, il = e % CSn;
    const float* qp = q + il * Dn + h * DHn;
    float s0 = 0.f, s1 = 0.f;
#pragma unroll
    for (int d = 0; d < DHn; d += 4) {
      const float4 q4 = *reinterpret_cast<const float4*>(qp + d);
      const float4 k0 = *reinterpret_cast<const float4*>(memkv + 0 * 256 + h * DHn + d);
      const float4 k1 = *reinterpret_cast<const float4*>(memkv + 1 * 256 + h * DHn + d);
      s0 += q4.x * k0.x + q4.y * k0.y + q4.z * k0.z + q4.w * k0.w;
      s1 += q4.x * k1.x + q4.y * k1.y + q4.z * k1.z + q4.w * k1.w;
    }
    s0 *= INV_SQRT_DH; s1 *= INV_SQRT_DH;
    const float m = fmaxf(s0, s1);
    const float e0 = expf(s0 - m), e1 = expf(s1 - m);
    const float inv = 1.f / (e0 + e1);
    catt[e * 2] = e0 * inv; catt[e * 2 + 1] = e1 * inv;
  }
  __syncthreads();
  for (int e = tid; e < CSn * Dn; e += 256) {
    const int il = e >> 7, c = e & 127, h = c >> 5;
    const int a = (h * CSn + il) * 2;
    const float v = catt[a]     * memkv[0 * 256 + Dn + c]
                  + catt[a + 1] * memkv[1 * 256 + Dn + c];
    ANP[apos(row0 + il, c, 4)] = f2bf(v);
  }
}

__global__ __launch_bounds__(256) void head_kernel(
    const float* __restrict__ X, const int* __restrict__ plist,
    const int* __restrict__ prow, const int* __restrict__ pexp,
    const float* __restrict__ rwgt, const float* __restrict__ hW,
    const float* __restrict__ hb, float* __restrict__ Rbuf)
{
  __shared__ float xr[CSn * Dn];
  const int i = (int)blockIdx.x;
  const int ex = pexp[i];
  const int orig = plist[i];
  const int row0 = prow[i];
  const float wgt = rwgt[orig];
  for (int e4 = (int)threadIdx.x; e4 < CSn * 32; e4 += 256) {
    const int il = e4 >> 5, c4 = (e4 & 31) * 4;
    *reinterpret_cast<float4*>(xr + il * Dn + c4) =
        *reinterpret_cast<const float4*>(X + (size_t)(row0 + il) * 128 + c4);
  }
  __syncthreads();
  const int e = (int)threadIdx.x;
  if (e < CSn * JDn) {
    const int t = e / JDn, j = e - t * JDn;
    const float* w = hW + ex * Dn * JDn + j;
    float acc = hb[ex * JDn + j];
#pragma unroll 4
    for (int kk = 0; kk < Dn; ++kk) acc = fmaf(xr[t * Dn + kk], w[kk * JDn], acc);
    Rbuf[(size_t)i * 140 + e] = wgt * acc;
  }
}

__global__ void combine_kernel(const float* __restrict__ Rbuf,
                               const int* __restrict__ ppos, float* __restrict__ out)
{
  const int idx = (int)blockIdx.x * 256 + (int)threadIdx.x;
  if (idx >= Bn * 140) return;
  const int b = idx / 140, e = idx - b * 140;
  out[idx] = Rbuf[(size_t)ppos[2 * b] * 140 + e] + Rbuf[(size_t)ppos[2 * b + 1] * 140 + e];
}

// ---------------------------------------------------------------------------
__global__ void qpe_kernel(float* qpe)
{
  const int e = (int)blockIdx.x * 256 + (int)threadIdx.x;
  if (e < CSn * Dn) {
    const int t = e >> 7, d = e & 127;
    const float j  = (float)(d & ~1);
    const float dv = expf(j * (-logf(10000.f) / 128.f));
    const float a  = (float)t * dv;
    qpe[e] = (d & 1) ? cosf(a) : sinf(a);
  }
}

} // namespace

// ---------------------------------------------------------------------------
extern "C" void kernel_launch(void* const* d_in, const int* in_sizes, int n_in,
                              void* d_out, int out_size, void* d_ws, size_t ws_size,
                              hipStream_t stream)
{
  (void)in_sizes; (void)n_in; (void)out_size;

  const int*   ids     = (const int*)  d_in[0];
  const float* state   = (const float*)d_in[1];
  const float* tok_emb = (const float*)d_in[2];
  const float* pos_emb = (const float*)d_in[3];

  // persistent workspace (256B-aligned cursor)
  char* cur = (char*)d_ws;
  auto alloc = [&cur](size_t bytes) -> char* {
    char* p = cur; cur += (bytes + 255) & ~(size_t)255; return p;
  };
  float* qpe    = (float*)alloc(4096 * 4);
  float* intent = (float*)alloc((size_t)Bn * Dn * 4);
  int*   ridx   = (int*)  alloc(PAIRS * 4);
  float* rwgt   = (float*)alloc(PAIRS * 4);
  short* pQ     = (short*)alloc((size_t)36 * 49152 * 2);   // expert packs (single bf16)
  short* pO     = (short*)alloc((size_t)36 * 16384 * 2);
  short* pF1    = (short*)alloc((size_t)18 * 65536 * 2);
  short* pF2    = (short*)alloc((size_t)18 * 65536 * 2);
  short* pbQ    = (short*)alloc((size_t)4 * 98304 * 2);    // BERT packs (split hi/lo)
  short* pbO    = (short*)alloc((size_t)4 * 32768 * 2);
  short* pbW1   = (short*)alloc((size_t)4 * 131072 * 2);
  short* pbW2   = (short*)alloc((size_t)4 * 131072 * 2);
  int*   sch    = (int*)  alloc(2048 * 4);
  int*   plist  = (int*)  alloc(PAIRS * 4);
  int*   prow   = (int*)  alloc(PAIRS * 4);
  int*   pexp   = (int*)  alloc(PAIRS * 4);
  int*   ppos   = (int*)  alloc(PAIRS * 4);
  constexpr size_t ARENA_BYTES = 192806912;
  char* arena = alloc(ARENA_BYTES);
  if ((size_t)(cur - (char*)d_ws) > ws_size) return;  // ws confirmed sufficient in R4/R5

  // BERT views
  float* Xb  = (float*)(arena);                          // 25.2 MB
  short* Ah  = (short*)(arena + 25165824);               // 12.6 MB
  short* Al  = (short*)(arena + 37748736);               // 12.6 MB
  float* SBb = (float*)(arena + 50331648);               // QKV fp32 75.5 MB
  short* Hh  = (short*)(arena + 50331648);               // aliases SBb (sequential use)
  short* Hl  = (short*)(arena + 100663296);              // 50.3 MB
  // expert views
  float* X2   = (float*)(arena);                         // 42.3 MB
  short* ANP  = (short*)(arena + 42336256);              // 21.2 MB
  short* SBh  = (short*)(arena + 63504384);              // bf16 QKV/Qc/HP (63.5 MB max)
  float* Rbuf = (float*)(arena + 190513152);             // 2.3 MB

  qpe_kernel<<<dim3(10), dim3(256), 0, stream>>>(qpe);

  // ---- weight packing
  {
    const int tq = 36 * 6144;
    pack_kernel<<<dim3((tq + 255) / 256), dim3(256), 0, stream>>>(
        (const float*)d_in[34], pQ, 128, 384, tq);
    const int to = 36 * 2048;
    pack_kernel<<<dim3((to + 255) / 256), dim3(256), 0, stream>>>(
        (const float*)d_in[36], pO, 128, 128, to);
    const int t1c = 18 * 8192;
    pack_kernel<<<dim3((t1c + 255) / 256), dim3(256), 0, stream>>>(
        (const float*)d_in[40], pF1, 128, 512, t1c);
    const int t2c = 18 * 8192;
    pack_kernel<<<dim3((t2c + 255) / 256), dim3(256), 0, stream>>>(
        (const float*)d_in[42], pF2, 512, 128, t2c);
    const int bq = 4 * 6144;
    pack2_kernel<<<dim3((bq + 255) / 256), dim3(256), 0, stream>>>(
        (const float*)d_in[4], pbQ, 128, 384, bq);
    const int bo = 4 * 2048;
    pack2_kernel<<<dim3((bo + 255) / 256), dim3(256), 0, stream>>>(
        (const float*)d_in[6], pbO, 128, 128, bo);
    const int bw1 = 4 * 8192;
    pack2_kernel<<<dim3((bw1 + 255) / 256), dim3(256), 0, stream>>>(
        (const float*)d_in[8], pbW1, 128, 512, bw1);
    const int bw2 = 4 * 8192;
    pack2_kernel<<<dim3((bw2 + 255) / 256), dim3(256), 0, stream>>>(
        (const float*)d_in[10], pbW2, 512, 128, bw2);
  }

  // ---- BERT phase pipeline
  {
    const float* bq  = (const float*)d_in[5];
    const float* bo  = (const float*)d_in[7];
    const float* b1  = (const float*)d_in[9];
    const float* b2  = (const float*)d_in[11];
    const float* lns = (const float*)d_in[12];
    const float* lnb = (const float*)d_in[13];

    bembed_kernel<<<dim3(ROWSB / 16), dim3(256), 0, stream>>>(
        ids, tok_emb, pos_emb, Xb, Ah, Al);
    for (int l = 0; l < NLBn; ++l) {
      bqkv_kernel<<<dim3(ROWSB / 64, 3), dim3(256), 0, stream>>>(
          Ah, Al, pbQ + (size_t)l * 98304, bq + l * 384, SBb);
      battn_kernel<<<dim3(Bn), dim3(256), 0, stream>>>(SBb, ids, Ah, Al);
      bo_ln_kernel<<<dim3(ROWSB / 64), dim3(256), 0, stream>>>(
          Ah, Al, pbO + (size_t)l * 32768, bo + l * 128,
          lns + l * 256, lnb + l * 256, Xb, Ah, Al);
      bw1_kernel<<<dim3(ROWSB / 64, 4), dim3(256), 0, stream>>>(
          Ah, Al, pbW1 + (size_t)l * 131072, b1 + l * 512, Hh, Hl);
      bw2a_kernel<<<dim3(ROWSB / 64), dim3(512), 0, stream>>>(
          Hh, Hl, pbW2 + (size_t)l * 131072, b2 + l * 128, Xb);
      bw2b_kernel<<<dim3(ROWSB / 64), dim3(512), 0, stream>>>(
          Hh, Hl, pbW2 + (size_t)l * 131072,
          lns + l * 256 + 128, lnb + l * 256 + 128, Xb, Ah, Al);
    }
    bintent_kernel<<<dim3(Bn / 4), dim3(256), 0, stream>>>(
        Xb, (const float*)d_in[14], (const float*)d_in[15], intent);
  }

  // ---- router
  {
    RouterP rp;
    rp.state = state; rp.intent = intent;
    rp.se_W1 = (const float*)d_in[16]; rp.se_b1 = (const float*)d_in[17];
    rp.se_W2 = (const float*)d_in[18]; rp.se_b2 = (const float*)d_in[19];
    rp.se_ln_s = (const float*)d_in[20]; rp.se_ln_b = (const float*)d_in[21];
    rp.r_W1 = (const float*)d_in[22]; rp.r_b1 = (const float*)d_in[23];
    rp.r_W2 = (const float*)d_in[24]; rp.r_b2 = (const float*)d_in[25];
    rp.r_ln_s = (const float*)d_in[26]; rp.r_ln_b = (const float*)d_in[27];
    rp.gate_W = (const float*)d_in[28]; rp.gate_b = (const float*)d_in[29];
    rp.ridx = ridx; rp.rwgt = rwgt;
    router_kernel<<<dim3(Bn), dim3(128), 0, stream>>>(rp);
  }

  const float* sp_W = (const float*)d_in[30];
  const float* sp_b = (const float*)d_in[31];
  const float* zp_b = (const float*)d_in[33];
  const float* aW   = (const float*)d_in[34];
  const float* ab   = (const float*)d_in[35];
  const float* abo  = (const float*)d_in[37];
  const float* lnsA = (const float*)d_in[38];
  const float* lnbA = (const float*)d_in[39];
  const float* fb1A = (const float*)d_in[41];
  const float* fb2A = (const float*)d_in[43];
  const float* hW   = (const float*)d_in[44];
  const float* hB   = (const float*)d_in[45];

  // ---- expert phase pipeline (fused-LN epilogues keep raw residual in X)
  {
    sched_kernel<<<dim3(1), dim3(256), 0, stream>>>(ridx, sch, plist, prow, pexp, ppos);
    xinit_kernel<<<dim3(MPMAX * 32 / 256), dim3(256), 0, stream>>>(qpe, sch, X2);
    ln_pack_kernel<<<dim3(MPMAX / 16), dim3(256), 0, stream>>>(
        X2, ANP, lnsA, lnbA, 0, sch);
    short* HP = SBh;
    for (int l = 0; l < NLDn; ++l) {
      // self-attention block
      gemm_k128<6, 0, true><<<dim3(NBGMAX), dim3(256), 0, stream>>>(
          ANP, pQ + (l * 2 + 0) * 49152, 294912,
          ab + (l * 2 + 0) * 384, 2304, 0,
          SBh, 384, nullptr, nullptr, nullptr, 0, nullptr, sch);
      sattn_kernel<<<dim3(PAIRS), dim3(256), 0, stream>>>(SBh, prow, ANP);
      gemm_k128<2, 4, true><<<dim3(NBGMAX), dim3(256), 0, stream>>>(
          ANP, pO + (l * 2 + 0) * 16384, 98304,
          abo + (l * 2 + 0) * 128, 768, 0,
          nullptr, 0, ANP, lnsA, lnbA, (l * 3 + 1) * 128, X2, sch);
      // cross-attention block
      gemm_k128<2, 0, true><<<dim3(NBGMAX), dim3(256), 0, stream>>>(
          ANP, pQ + (l * 2 + 1) * 49152, 294912,
          ab + (l * 2 + 1) * 384, 2304, 0,
          SBh, 128, nullptr, nullptr, nullptr, 0, nullptr, sch);
      cattn_kernel<<<dim3(PAIRS), dim3(256), 0, stream>>>(
          SBh, state, sp_W, sp_b, zp_b, aW, ab, l, plist, prow, pexp, ANP);
      gemm_k128<2, 4, true><<<dim3(NBGMAX), dim3(256), 0, stream>>>(
          ANP, pO + (l * 2 + 1) * 16384, 98304,
          abo + (l * 2 + 1) * 128, 768, 0,
          nullptr, 0, ANP, lnsA, lnbA, (l * 3 + 2) * 128, X2, sch);
      // FFN block (two 256-col halves)
      gemm_k128<4, 3, true><<<dim3(NBGMAX), dim3(256), 0, stream>>>(
          ANP, pF1 + l * 65536, 196608,
          fb1A + l * 512 + 0 * 256, 1536, 0,
          nullptr, 0, HP, nullptr, nullptr, 0, nullptr, sch);
      gemm_k256<true, false><<<dim3(NBGMAX), dim3(256), 0, stream>>>(
          HP, pF2 + l * 65536, 196608, fb2A + l * 128, 384, 0,
          X2, nullptr, nullptr, nullptr, 0, sch);
      gemm_k128<4, 3, true><<<dim3(NBGMAX), dim3(256), 0, stream>>>(
          ANP, pF1 + l * 65536, 196608,
          fb1A + l * 512 + 1 * 256, 1536, 16,
          nullptr, 0, HP, nullptr, nullptr, 0, nullptr, sch);
      if (l < NLDn - 1) {
        gemm_k256<false, true><<<dim3(NBGMAX), dim3(256), 0, stream>>>(
            HP, pF2 + l * 65536, 196608, fb2A + l * 128, 384, 8,
            X2, ANP, lnsA, lnbA, ((l + 1) * 3 + 0) * 128, sch);
      } else {
        gemm_k256<false, false><<<dim3(NBGMAX), dim3(256), 0, stream>>>(
            HP, pF2 + l * 65536, 196608, fb2A + l * 128, 384, 8,
            X2, nullptr, nullptr, nullptr, 0, sch);
      }
    }
    head_kernel<<<dim3(PAIRS), dim3(256), 0, stream>>>(
        X2, plist, prow, pexp, rwgt, hW, hB, Rbuf);
    combine_kernel<<<dim3((Bn * 140 + 255) / 256), dim3(256), 0, stream>>>(
        Rbuf, ppos, (float*)d_out);
  }
}

// Round 8
// 1796.425 us; speedup vs baseline: 3.8883x; 1.0008x over previous
//
#include <hip/hip_runtime.h>
#include <math.h>

#define DEVI __device__ __forceinline__

namespace {

constexpr int Bn   = 2048;
constexpr int En   = 6;
constexpr int Hn   = 4;
constexpr int Dn   = 128;
constexpr int DHn  = 32;
constexpr int LTn  = 24;   // text length
constexpr int CSn  = 20;   // chunk (decoder query) length
constexpr int JDn  = 7;
constexpr int SDn  = 16;
constexpr int NLBn = 4;
constexpr int NLDn = 3;
constexpr int DFFn = 512;
constexpr float INV_SQRT_DH = 0.17677669529663687f;  // 1/sqrt(32)

// expert phase-pipeline geometry
constexpr int PAIRS  = 4096;                  // 2048 items x top-2
constexpr int MPMAX  = PAIRS * 20 + En * 128; // padded rows (per-expert 128-aligned)
constexpr int NBGMAX = PAIRS * 20 / 128 + En; // 646 grouped-GEMM blocks max
constexpr int GEXP_OFF = 64;
constexpr int GMT_OFF  = 64 + NBGMAX;

// BERT pipeline geometry
constexpr int ROWSB = Bn * LTn;               // 49152 rows, 3072 M-tiles, no padding

// per-head attention LDS stride (36 mod 32 = 4 -> conflict-light, 16B-aligned)
constexpr int HSTR = 36;

typedef float f32x4v __attribute__((ext_vector_type(4)));
typedef short short8 __attribute__((ext_vector_type(8)));

DEVI float geluf(float x) { return 0.5f * x * (1.0f + erff(x * 0.70710678118654752f)); }

DEVI short f2bf(float f) {  // fp32 -> bf16 bits, round-to-nearest-even
  unsigned u = __float_as_uint(f);
  return (short)((u + 0x7FFFu + ((u >> 16) & 1u)) >> 16);
}
DEVI float bf2f(short s) { return __uint_as_float(((unsigned)(unsigned short)s) << 16); }
DEVI void split2(float v, short& h, short& l) {  // v ~= hi + lo to ~2^-16 rel
  h = f2bf(v);
  l = f2bf(v - bf2f(h));
}

// packed-A position for (row, col), K-tile count KT
DEVI size_t apos(int row, int col, int KT) {
  return (((size_t)(row >> 4) * KT + (col >> 5)) * 64 + ((col >> 3) & 3) * 16 + (row & 15)) * 8
         + (col & 7);
}

// ---------------------------------------------------------------------------
// pack fp32 [K][N] into single-bf16 B tiles (512 shorts/tile)
__global__ void pack_kernel(const float* __restrict__ W, short* __restrict__ out,
                            const int K, const int N, const int total)
{
  const int p = (int)blockIdx.x * 256 + (int)threadIdx.x;
  if (p >= total) return;
  const int perMat = (K * N) >> 3;
  const int m = p / perMat, r = p - m * perMat;
  const int t = r >> 6, lane = r & 63;
  const int KT = K >> 5;
  const int nt = t / KT, kt = t - nt * KT;
  const int row0 = kt * 32 + (lane >> 4) * 8;
  const int col  = nt * 16 + (lane & 15);
  const float* src = W + (size_t)m * K * N;
  short8 v;
#pragma unroll
  for (int j = 0; j < 8; ++j) v[j] = f2bf(src[(size_t)(row0 + j) * N + col]);
  *reinterpret_cast<short8*>(out + (size_t)p * 8) = v;
}

// pack fp32 [K][N] into split hi/lo B tiles (1024 shorts/tile)
__global__ void pack2_kernel(const float* __restrict__ W, short* __restrict__ out,
                             const int K, const int N, const int total)
{
  const int p = (int)blockIdx.x * 256 + (int)threadIdx.x;
  if (p >= total) return;
  const int perMat = (K * N) >> 3;
  const int m = p / perMat, r = p - m * perMat;
  const int t = r >> 6, lane = r & 63;
  const int KT = K >> 5;
  const int nt = t / KT, kt = t - nt * KT;
  const int row0 = kt * 32 + (lane >> 4) * 8;
  const int col  = nt * 16 + (lane & 15);
  const float* src = W + (size_t)m * K * N;
  short8 vh, vl;
#pragma unroll
  for (int j = 0; j < 8; ++j) {
    short hh, ll;
    split2(src[(size_t)(row0 + j) * N + col], hh, ll);
    vh[j] = hh; vl[j] = ll;
  }
  const size_t T  = (size_t)(perMat >> 6);
  const size_t tg = (size_t)m * T + t;
  *reinterpret_cast<short8*>(out + tg * 1024 + lane * 8)       = vh;
  *reinterpret_cast<short8*>(out + tg * 1024 + 512 + lane * 8) = vl;
}

// ===========================================================================
// BERT phase pipeline (split-bf16, M = 49152 rows)
// ===========================================================================

__global__ __launch_bounds__(256) void bembed_kernel(
    const int* __restrict__ ids, const float* __restrict__ tok,
    const float* __restrict__ pos, float* __restrict__ X,
    short* __restrict__ Ah, short* __restrict__ Al)
{
  const int mt = (int)blockIdx.x;          // 0..3071
  const int t = (int)threadIdx.x;
  const int rl = t >> 4, j = t & 15;
  const int row = mt * 16 + rl;
  const int b = row / 24, i = row - b * 24;
  const int id = ids[b * 24 + i];
  const float* tp = tok + (size_t)id * 128 + j * 8;
  const float* pp = pos + i * 128 + j * 8;
  float x[8];
  short8 vh, vl;
#pragma unroll
  for (int u = 0; u < 8; ++u) {
    x[u] = tp[u] + pp[u];
    short hh, ll; split2(x[u], hh, ll);
    vh[u] = hh; vl[u] = ll;
  }
  float4 f0 = {x[0], x[1], x[2], x[3]}, f1 = {x[4], x[5], x[6], x[7]};
  *reinterpret_cast<float4*>(X + (size_t)row * 128 + j * 8) = f0;
  *reinterpret_cast<float4*>(X + (size_t)row * 128 + j * 8 + 4) = f1;
  const size_t pk = (((size_t)mt * 4 + (j >> 2)) * 64 + (j & 3) * 16 + rl) * 8;
  *reinterpret_cast<short8*>(Ah + pk) = vh;
  *reinterpret_cast<short8*>(Al + pk) = vl;
}

__global__ __launch_bounds__(256) void bqkv_kernel(
    const short* __restrict__ Ah, const short* __restrict__ Al,
    const short* __restrict__ Bp, const float* __restrict__ bias,
    float* __restrict__ Out)
{
  const int mt0 = (int)blockIdx.x * 4;
  const int nc  = (int)blockIdx.y;
  const int lane = (int)threadIdx.x & 63, wv = (int)threadIdx.x >> 6;
  const int r0 = lane & 15, g = lane >> 4;
  short8 bh[2][4], bl[2][4];
#pragma unroll
  for (int i = 0; i < 2; ++i)
#pragma unroll
    for (int kt = 0; kt < 4; ++kt) {
      const short* tb = Bp + (((size_t)(nc * 8 + wv * 2 + i) * 4 + kt) << 10);
      bh[i][kt] = *reinterpret_cast<const short8*>(tb + lane * 8);
      bl[i][kt] = *reinterpret_cast<const short8*>(tb + 512 + lane * 8);
    }
#pragma unroll 2
  for (int mt = 0; mt < 4; ++mt) {
    const int mtg = mt0 + mt;
    short8 ah[4], al[4];
#pragma unroll
    for (int kt = 0; kt < 4; ++kt) {
      ah[kt] = *reinterpret_cast<const short8*>(Ah + (((size_t)mtg * 4 + kt) * 64 + lane) * 8);
      al[kt] = *reinterpret_cast<const short8*>(Al + (((size_t)mtg * 4 + kt) * 64 + lane) * 8);
    }
#pragma unroll
    for (int i = 0; i < 2; ++i) {
      f32x4v c = {0.f, 0.f, 0.f, 0.f};
#pragma unroll
      for (int kt = 0; kt < 4; ++kt) {
        c = __builtin_amdgcn_mfma_f32_16x16x32_bf16(ah[kt], bh[i][kt], c, 0, 0, 0);
        c = __builtin_amdgcn_mfma_f32_16x16x32_bf16(al[kt], bh[i][kt], c, 0, 0, 0);
        c = __builtin_amdgcn_mfma_f32_16x16x32_bf16(ah[kt], bl[i][kt], c, 0, 0, 0);
      }
      const int col = nc * 128 + (wv * 2 + i) * 16 + r0;
      const float bb = bias[col];
#pragma unroll
      for (int q = 0; q < 4; ++q)
        Out[(size_t)(mtg * 16 + g * 4 + q) * 384 + col] = c[q] + bb;
    }
  }
}

// per (item, head) BERT attention: QKV fp32 -> attn out split-packed A.
// grid (2048, 4), 64 threads (1 wave).
__global__ __launch_bounds__(64) void battn_kernel(
    const float* __restrict__ QKV, const int* __restrict__ ids,
    short* __restrict__ Ah, short* __restrict__ Al)
{
  __shared__ float qs[LTn * HSTR], ks[LTn * HSTR], vs[LTn * HSTR];
  __shared__ float att[LTn * LTn];
  __shared__ int pad_s[LTn];
  const int b = (int)blockIdx.x, h = (int)blockIdx.y;
  const int tid = (int)threadIdx.x;
  const int row0 = b * LTn;
  for (int u = tid; u < LTn * 24; u += 64) {
    const int il = u / 24, r = u % 24, which = r >> 3, d4 = r & 7;
    const float4 v = *reinterpret_cast<const float4*>(
        QKV + (size_t)(row0 + il) * 384 + which * 128 + h * 32 + d4 * 4);
    float* dst = (which == 0 ? qs : which == 1 ? ks : vs) + il * HSTR + d4 * 4;
    *reinterpret_cast<float4*>(dst) = v;
  }
  if (tid < LTn) pad_s[tid] = (ids[row0 + tid] == 0) ? 1 : 0;
  __syncthreads();
  for (int e = tid; e < LTn * LTn; e += 64) {
    const int i = e / LTn, j = e % LTn;
    const float* qp = qs + i * HSTR;
    const float* kp = ks + j * HSTR;
    float acc = 0.f;
#pragma unroll
    for (int d = 0; d < DHn; d += 4) {
      const float4 qa = *reinterpret_cast<const float4*>(qp + d);
      const float4 kb = *reinterpret_cast<const float4*>(kp + d);
      acc += qa.x * kb.x + qa.y * kb.y + qa.z * kb.z + qa.w * kb.w;
    }
    acc *= INV_SQRT_DH;
    if (pad_s[j]) acc = -1e9f;
    att[e] = acc;
  }
  __syncthreads();
  if (tid < LTn) {
    float* row = att + tid * LTn;
    float m = row[0];
#pragma unroll 4
    for (int j = 1; j < LTn; ++j) m = fmaxf(m, row[j]);
    float s = 0.f;
#pragma unroll 4
    for (int j = 0; j < LTn; ++j) { const float ex = expf(row[j] - m); row[j] = ex; s += ex; }
    const float inv = 1.f / s;
#pragma unroll 4
    for (int j = 0; j < LTn; ++j) row[j] *= inv;
  }
  __syncthreads();
  for (int e = tid; e < LTn * 32; e += 64) {
    const int i = e >> 5, c = e & 31;
    const float* arow = att + i * LTn;
    float acc = 0.f;
#pragma unroll 4
    for (int j = 0; j < LTn; ++j) acc = fmaf(arow[j], vs[j * HSTR + c], acc);
    short hh, ll; split2(acc, hh, ll);
    const size_t pk = apos(row0 + i, h * 32 + c, 4);
    Ah[pk] = hh; Al[pk] = ll;
  }
}

__global__ __launch_bounds__(256) void bo_ln_kernel(
    const short* __restrict__ Ah, const short* __restrict__ Al,
    const short* __restrict__ Bp, const float* __restrict__ bo,
    const float* __restrict__ gs, const float* __restrict__ gb,
    float* __restrict__ X, short* __restrict__ OAh, short* __restrict__ OAl)
{
  __shared__ float red[16][4][2];
  const int mt0 = (int)blockIdx.x * 4;
  const int lane = (int)threadIdx.x & 63, wv = (int)threadIdx.x >> 6;
  const int r0 = lane & 15, g = lane >> 4;
  short8 bh[2][4], bl[2][4];
#pragma unroll
  for (int i = 0; i < 2; ++i)
#pragma unroll
    for (int kt = 0; kt < 4; ++kt) {
      const short* tb = Bp + (((size_t)(wv * 2 + i) * 4 + kt) << 10);
      bh[i][kt] = *reinterpret_cast<const short8*>(tb + lane * 8);
      bl[i][kt] = *reinterpret_cast<const short8*>(tb + 512 + lane * 8);
    }
  for (int mt = 0; mt < 4; ++mt) {
    const int mtg = mt0 + mt;
    short8 ah[4], al[4];
#pragma unroll
    for (int kt = 0; kt < 4; ++kt) {
      ah[kt] = *reinterpret_cast<const short8*>(Ah + (((size_t)mtg * 4 + kt) * 64 + lane) * 8);
      al[kt] = *reinterpret_cast<const short8*>(Al + (((size_t)mtg * 4 + kt) * 64 + lane) * 8);
    }
    float v[2][4];
#pragma unroll
    for (int i = 0; i < 2; ++i) {
      f32x4v c = {0.f, 0.f, 0.f, 0.f};
#pragma unroll
      for (int kt = 0; kt < 4; ++kt) {
        c = __builtin_amdgcn_mfma_f32_16x16x32_bf16(ah[kt], bh[i][kt], c, 0, 0, 0);
        c = __builtin_amdgcn_mfma_f32_16x16x32_bf16(al[kt], bh[i][kt], c, 0, 0, 0);
        c = __builtin_amdgcn_mfma_f32_16x16x32_bf16(ah[kt], bl[i][kt], c, 0, 0, 0);
      }
      const int col = (wv * 2 + i) * 16 + r0;
      const float bb = bo[col];
#pragma unroll
      for (int q = 0; q < 4; ++q) {
        const int row = mtg * 16 + g * 4 + q;
        v[i][q] = c[q] + bb + X[(size_t)row * 128 + col];
      }
    }
    float s1[4], s2[4];
#pragma unroll
    for (int q = 0; q < 4; ++q) {
      s1[q] = v[0][q] + v[1][q];
      s2[q] = v[0][q] * v[0][q] + v[1][q] * v[1][q];
    }
#pragma unroll
    for (int o = 1; o < 16; o <<= 1)
#pragma unroll
      for (int q = 0; q < 4; ++q) { s1[q] += __shfl_xor(s1[q], o); s2[q] += __shfl_xor(s2[q], o); }
    if (r0 == 0)
#pragma unroll
      for (int q = 0; q < 4; ++q) { red[g * 4 + q][wv][0] = s1[q]; red[g * 4 + q][wv][1] = s2[q]; }
    __syncthreads();
#pragma unroll
    for (int q = 0; q < 4; ++q) {
      const int r = g * 4 + q;
      const float t1 = red[r][0][0] + red[r][1][0] + red[r][2][0] + red[r][3][0];
      const float t2 = red[r][0][1] + red[r][1][1] + red[r][2][1] + red[r][3][1];
      const float m  = t1 * (1.f / 128.f);
      const float rs = rsqrtf(t2 * (1.f / 128.f) - m * m + 1e-5f);
      const int row = mtg * 16 + r;
#pragma unroll
      for (int i = 0; i < 2; ++i) {
        const int col = (wv * 2 + i) * 16 + r0;
        const float o = (v[i][q] - m) * rs * gs[col] + gb[col];
        X[(size_t)row * 128 + col] = o;   // post-LN: LN'd value IS the residual
        short hh, ll; split2(o, hh, ll);
        const size_t pk = apos(row, col, 4);
        OAh[pk] = hh; OAl[pk] = ll;
      }
    }
    __syncthreads();
  }
}

__global__ __launch_bounds__(256) void bw1_kernel(
    const short* __restrict__ Ah, const short* __restrict__ Al,
    const short* __restrict__ Bp, const float* __restrict__ bias,
    short* __restrict__ Hh, short* __restrict__ Hl)
{
  const int mt0 = (int)blockIdx.x * 4;
  const int nc  = (int)blockIdx.y;
  const int lane = (int)threadIdx.x & 63, wv = (int)threadIdx.x >> 6;
  const int r0 = lane & 15, g = lane >> 4;
  short8 bh[2][4], bl[2][4];
#pragma unroll
  for (int i = 0; i < 2; ++i)
#pragma unroll
    for (int kt = 0; kt < 4; ++kt) {
      const short* tb = Bp + (((size_t)(nc * 8 + wv * 2 + i) * 4 + kt) << 10);
      bh[i][kt] = *reinterpret_cast<const short8*>(tb + lane * 8);
      bl[i][kt] = *reinterpret_cast<const short8*>(tb + 512 + lane * 8);
    }
#pragma unroll 2
  for (int mt = 0; mt < 4; ++mt) {
    const int mtg = mt0 + mt;
    short8 ah[4], al[4];
#pragma unroll
    for (int kt = 0; kt < 4; ++kt) {
      ah[kt] = *reinterpret_cast<const short8*>(Ah + (((size_t)mtg * 4 + kt) * 64 + lane) * 8);
      al[kt] = *reinterpret_cast<const short8*>(Al + (((size_t)mtg * 4 + kt) * 64 + lane) * 8);
    }
#pragma unroll
    for (int i = 0; i < 2; ++i) {
      f32x4v c = {0.f, 0.f, 0.f, 0.f};
#pragma unroll
      for (int kt = 0; kt < 4; ++kt) {
        c = __builtin_amdgcn_mfma_f32_16x16x32_bf16(ah[kt], bh[i][kt], c, 0, 0, 0);
        c = __builtin_amdgcn_mfma_f32_16x16x32_bf16(al[kt], bh[i][kt], c, 0, 0, 0);
        c = __builtin_amdgcn_mfma_f32_16x16x32_bf16(ah[kt], bl[i][kt], c, 0, 0, 0);
      }
      const int col = nc * 128 + (wv * 2 + i) * 16 + r0;
      const float bb = bias[col];
#pragma unroll
      for (int q = 0; q < 4; ++q) {
        const int row = mtg * 16 + g * 4 + q;
        short hh, ll; split2(geluf(c[q] + bb), hh, ll);
        const size_t pk = apos(row, col, 16);
        Hh[pk] = hh; Hl[pk] = ll;
      }
    }
  }
}

__global__ __launch_bounds__(512) void bw2a_kernel(
    const short* __restrict__ Hh, const short* __restrict__ Hl,
    const short* __restrict__ Bp, const float* __restrict__ bias,
    float* __restrict__ X)
{
  const int mt0 = (int)blockIdx.x * 4;
  const int lane = (int)threadIdx.x & 63, wv = (int)threadIdx.x >> 6;  // 8 waves
  const int r0 = lane & 15, g = lane >> 4;
  short8 bh[8], bl[8];
#pragma unroll
  for (int kk = 0; kk < 8; ++kk) {
    const short* tb = Bp + (((size_t)wv * 16 + kk) << 10);
    bh[kk] = *reinterpret_cast<const short8*>(tb + lane * 8);
    bl[kk] = *reinterpret_cast<const short8*>(tb + 512 + lane * 8);
  }
#pragma unroll 2
  for (int mt = 0; mt < 4; ++mt) {
    const int mtg = mt0 + mt;
    f32x4v c = {0.f, 0.f, 0.f, 0.f};
#pragma unroll
    for (int kk = 0; kk < 8; ++kk) {
      const short8 ah = *reinterpret_cast<const short8*>(Hh + (((size_t)mtg * 16 + kk) * 64 + lane) * 8);
      const short8 al = *reinterpret_cast<const short8*>(Hl + (((size_t)mtg * 16 + kk) * 64 + lane) * 8);
      c = __builtin_amdgcn_mfma_f32_16x16x32_bf16(ah, bh[kk], c, 0, 0, 0);
      c = __builtin_amdgcn_mfma_f32_16x16x32_bf16(al, bh[kk], c, 0, 0, 0);
      c = __builtin_amdgcn_mfma_f32_16x16x32_bf16(ah, bl[kk], c, 0, 0, 0);
    }
    const int col = wv * 16 + r0;
    const float bb = bias[col];
#pragma unroll
    for (int q = 0; q < 4; ++q)
      X[(size_t)(mtg * 16 + g * 4 + q) * 128 + col] += c[q] + bb;
  }
}

__global__ __launch_bounds__(512) void bw2b_kernel(
    const short* __restrict__ Hh, const short* __restrict__ Hl,
    const short* __restrict__ Bp, const float* __restrict__ gs,
    const float* __restrict__ gb, float* __restrict__ X,
    short* __restrict__ OAh, short* __restrict__ OAl)
{
  __shared__ float red[16][8][2];
  const int mt0 = (int)blockIdx.x * 4;
  const int lane = (int)threadIdx.x & 63, wv = (int)threadIdx.x >> 6;
  const int r0 = lane & 15, g = lane >> 4;
  short8 bh[8], bl[8];
#pragma unroll
  for (int kk = 0; kk < 8; ++kk) {
    const short* tb = Bp + (((size_t)wv * 16 + 8 + kk) << 10);
    bh[kk] = *reinterpret_cast<const short8*>(tb + lane * 8);
    bl[kk] = *reinterpret_cast<const short8*>(tb + 512 + lane * 8);
  }
  for (int mt = 0; mt < 4; ++mt) {
    const int mtg = mt0 + mt;
    f32x4v c = {0.f, 0.f, 0.f, 0.f};
#pragma unroll
    for (int kk = 0; kk < 8; ++kk) {
      const short8 ah = *reinterpret_cast<const short8*>(Hh + (((size_t)mtg * 16 + 8 + kk) * 64 + lane) * 8);
      const short8 al = *reinterpret_cast<const short8*>(Hl + (((size_t)mtg * 16 + 8 + kk) * 64 + lane) * 8);
      c = __builtin_amdgcn_mfma_f32_16x16x32_bf16(ah, bh[kk], c, 0, 0, 0);
      c = __builtin_amdgcn_mfma_f32_16x16x32_bf16(al, bh[kk], c, 0, 0, 0);
      c = __builtin_amdgcn_mfma_f32_16x16x32_bf16(ah, bl[kk], c, 0, 0, 0);
    }
    const int col = wv * 16 + r0;
    float v[4], s1[4], s2[4];
#pragma unroll
    for (int q = 0; q < 4; ++q) {
      const int row = mtg * 16 + g * 4 + q;
      v[q] = c[q] + X[(size_t)row * 128 + col];
      s1[q] = v[q]; s2[q] = v[q] * v[q];
    }
#pragma unroll
    for (int o = 1; o < 16; o <<= 1)
#pragma unroll
      for (int q = 0; q < 4; ++q) { s1[q] += __shfl_xor(s1[q], o); s2[q] += __shfl_xor(s2[q], o); }
    if (r0 == 0)
#pragma unroll
      for (int q = 0; q < 4; ++q) { red[g * 4 + q][wv][0] = s1[q]; red[g * 4 + q][wv][1] = s2[q]; }
    __syncthreads();
#pragma unroll
    for (int q = 0; q < 4; ++q) {
      const int r = g * 4 + q;
      float t1 = 0.f, t2 = 0.f;
#pragma unroll
      for (int w = 0; w < 8; ++w) { t1 += red[r][w][0]; t2 += red[r][w][1]; }
      const float m  = t1 * (1.f / 128.f);
      const float rs = rsqrtf(t2 * (1.f / 128.f) - m * m + 1e-5f);
      const int row = mtg * 16 + r;
      const float o = (v[q] - m) * rs * gs[col] + gb[col];
      X[(size_t)row * 128 + col] = o;     // post-LN
      short hh, ll; split2(o, hh, ll);
      const size_t pk = apos(row, col, 4);
      OAh[pk] = hh; OAl[pk] = ll;
    }
    __syncthreads();
  }
}

__global__ __launch_bounds__(256) void bintent_kernel(
    const float* __restrict__ X, const float* __restrict__ lnf_s,
    const float* __restrict__ lnf_b, float* __restrict__ intent)
{
  const int w = (int)threadIdx.x >> 6, lane = (int)threadIdx.x & 63;
  const int b = (int)blockIdx.x * 4 + w;
  const float* xr = X + (size_t)b * LTn * 128;
  const float a0 = xr[lane], a1 = xr[lane + 64];
  float s1 = a0 + a1, s2 = a0 * a0 + a1 * a1;
#pragma unroll
  for (int o = 32; o > 0; o >>= 1) { s1 += __shfl_xor(s1, o); s2 += __shfl_xor(s2, o); }
  const float m  = s1 * (1.f / 128.f);
  const float rs = rsqrtf(s2 * (1.f / 128.f) - m * m + 1e-5f);
  intent[b * 128 + lane]      = (a0 - m) * rs * lnf_s[lane]      + lnf_b[lane];
  intent[b * 128 + lane + 64] = (a1 - m) * rs * lnf_s[lane + 64] + lnf_b[lane + 64];
}

// ---------------------------------------------------------------------------
struct RouterP {
  const float* state; const float* intent;
  const float* se_W1; const float* se_b1; const float* se_W2; const float* se_b2;
  const float* se_ln_s; const float* se_ln_b;
  const float* r_W1; const float* r_b1; const float* r_W2; const float* r_b2;
  const float* r_ln_s; const float* r_ln_b;
  const float* gate_W; const float* gate_b;
  int* ridx; float* rwgt;
};

DEVI void ln128(float* x, const float* gs, const float* gb, float* red)
{
  const int c = (int)threadIdx.x;      // blockDim == 128
  const float a = x[c];
  float s1 = a, s2 = a * a;
#pragma unroll
  for (int o = 32; o > 0; o >>= 1) { s1 += __shfl_xor(s1, o); s2 += __shfl_xor(s2, o); }
  const int wid = c >> 6;
  if ((c & 63) == 0) { red[wid * 2] = s1; red[wid * 2 + 1] = s2; }
  __syncthreads();
  s1 = red[0] + red[2]; s2 = red[1] + red[3];
  const float m  = s1 * (1.f / 128.f);
  const float rs = rsqrtf(s2 * (1.f / 128.f) - m * m + 1e-5f);
  __syncthreads();
  x[c] = (a - m) * rs * gs[c] + gb[c];
}

// 128-deep dot with 4 independent accumulator chains (latency fix)
DEVI float dot128i(const float* __restrict__ h, const float* __restrict__ W,
                   const int c, const int wstr)
{
  float a0 = 0.f, a1 = 0.f, a2 = 0.f, a3 = 0.f;
#pragma unroll 8
  for (int k = 0; k < 128; k += 4) {
    a0 = fmaf(h[k + 0], W[(k + 0) * wstr + c], a0);
    a1 = fmaf(h[k + 1], W[(k + 1) * wstr + c], a1);
    a2 = fmaf(h[k + 2], W[(k + 2) * wstr + c], a2);
    a3 = fmaf(h[k + 3], W[(k + 3) * wstr + c], a3);
  }
  return (a0 + a1) + (a2 + a3);
}

__global__ __launch_bounds__(128) void router_kernel(RouterP p)
{
  __shared__ float sstate[SDn];
  __shared__ float h1[Dn];
  __shared__ float vv[Dn];
  __shared__ float red[4];
  __shared__ float slog[En];
  const int b = blockIdx.x;
  const int c = (int)threadIdx.x;

  if (c < SDn) sstate[c] = p.state[b * SDn + c];
  __syncthreads();
  {
    float acc = p.se_b1[c];
#pragma unroll
    for (int k = 0; k < SDn; ++k) acc = fmaf(sstate[k], p.se_W1[k * Dn + c], acc);
    h1[c] = geluf(acc);
  }
  __syncthreads();
  vv[c] = p.se_b2[c] + dot128i(h1, p.se_W2, c, Dn);
  __syncthreads();
  ln128(vv, p.se_ln_s, p.se_ln_b, red);
  __syncthreads();
  {
    const float* ib = p.intent + b * Dn;
    float acc = p.r_b1[c] + dot128i(ib, p.r_W1, c, Dn)
                          + dot128i(vv, p.r_W1 + Dn * Dn, c, Dn);
    h1[c] = geluf(acc);
  }
  __syncthreads();
  vv[c] = p.r_b2[c] + dot128i(h1, p.r_W2, c, Dn);
  __syncthreads();
  ln128(vv, p.r_ln_s, p.r_ln_b, red);
  __syncthreads();
  if (c < En) slog[c] = p.gate_b[c] + dot128i(vv, p.gate_W, c, En);
  __syncthreads();
  if (c == 0) {
    int i0 = 0; float v0 = slog[0];
#pragma unroll
    for (int e2 = 1; e2 < En; ++e2) if (slog[e2] > v0) { v0 = slog[e2]; i0 = e2; }
    int i1 = -1; float v1 = -3.4e38f;
#pragma unroll
    for (int e2 = 0; e2 < En; ++e2) if (e2 != i0 && slog[e2] > v1) { v1 = slog[e2]; i1 = e2; }
    const float e1  = expf(v1 - v0);
    const float inv = 1.f / (1.f + e1);
    p.ridx[b * 2 + 0] = i0; p.ridx[b * 2 + 1] = i1;
    p.rwgt[b * 2 + 0] = inv; p.rwgt[b * 2 + 1] = e1 * inv;
  }
}

// ===========================================================================
// EXPERT PHASE PIPELINE — norm_first: X keeps RAW residual, packed A gets LN
// ===========================================================================

__global__ void sched_kernel(const int* __restrict__ ridx, int* __restrict__ sch,
                             int* plist, int* prow, int* pexp, int* ppos)
{
  __shared__ int scnt[En], scur[En], soff[En], srb[En + 1];
  const int t = (int)threadIdx.x;
  if (t < En) { scnt[t] = 0; scur[t] = 0; }
  __syncthreads();
  for (int p = t; p < PAIRS; p += 256) atomicAdd(&scnt[ridx[p]], 1);
  __syncthreads();
  if (t == 0) {
    int off = 0, rb = 0, k = 0;
    for (int e = 0; e < En; ++e) {
      soff[e] = off; srb[e] = rb;
      const int rows = scnt[e] * 20;
      const int nb = (rows + 127) >> 7;
      for (int q = 0; q < nb; ++q) {
        sch[GEXP_OFF + k] = e;
        sch[GMT_OFF + k]  = (rb >> 4) + q * 8;
        ++k;
      }
      off += scnt[e];
      rb += nb * 128;
    }
    srb[En] = rb;
    sch[0] = k;
    for (int e = 0; e < En; ++e) { sch[1 + e] = scnt[e]; sch[7 + e] = soff[e]; }
    for (int e = 0; e <= En; ++e) sch[13 + e] = srb[e];
  }
  __syncthreads();
  for (int p = t; p < PAIRS; p += 256) {
    const int e = ridx[p];
    const int pos = atomicAdd(&scur[e], 1);
    const int i = soff[e] + pos;
    plist[i] = p; ppos[p] = i; pexp[i] = e; prow[i] = srb[e] + pos * 20;
  }
}

__global__ void xinit_kernel(const float* __restrict__ qpe, const int* __restrict__ sch,
                             float* __restrict__ X)
{
  const int idx = (int)blockIdx.x * 256 + (int)threadIdx.x;  // quad index
  const int row = idx >> 5;
  if (row >= MPMAX) return;
  const int c4 = (idx & 31) * 4;
  const int* RB = sch + 13;
  float4 v = {0.f, 0.f, 0.f, 0.f};
  int e = 0;
  while (e < En && row >= RB[e + 1]) ++e;
  if (e < En) {
    const int local = row - RB[e];
    if (local < sch[1 + e] * 20) {
      const int r = local - (local / 20) * 20;
      v = *reinterpret_cast<const float4*>(qpe + r * 128 + c4);
    }
  }
  *reinterpret_cast<float4*>(X + (size_t)row * 128 + c4) = v;
}

// LN over X rows -> packed bf16 A-fragments (used once, layer-0 sub-0)
__global__ __launch_bounds__(256) void ln_pack_kernel(
    const float* __restrict__ X, short* __restrict__ XnP,
    const float* __restrict__ lns_all, const float* __restrict__ lnb_all,
    const int subOff, const int* __restrict__ sch)
{
  const int* RB = sch + 13;
  const int mt = (int)blockIdx.x;
  const int row0 = mt << 4;
  if (row0 >= RB[En]) return;
  int e = 0;
  while (e < En - 1 && row0 >= RB[e + 1]) ++e;
  const float* gs = lns_all + e * (NLDn * 3 * 128) + subOff;
  const float* gb = lnb_all + e * (NLDn * 3 * 128) + subOff;
  const int t = (int)threadIdx.x;
  const int rl = t >> 4, j = t & 15;
  const int row = row0 + rl;
  float x[8];
  {
    const float4 a = *reinterpret_cast<const float4*>(X + (size_t)row * 128 + j * 8);
    const float4 bq = *reinterpret_cast<const float4*>(X + (size_t)row * 128 + j * 8 + 4);
    x[0] = a.x; x[1] = a.y; x[2] = a.z; x[3] = a.w;
    x[4] = bq.x; x[5] = bq.y; x[6] = bq.z; x[7] = bq.w;
  }
  float s1 = 0.f, s2 = 0.f;
#pragma unroll
  for (int u = 0; u < 8; ++u) { s1 += x[u]; s2 += x[u] * x[u]; }
#pragma unroll
  for (int o = 1; o < 16; o <<= 1) { s1 += __shfl_xor(s1, o); s2 += __shfl_xor(s2, o); }
  const float m  = s1 * (1.f / 128.f);
  const float rs = rsqrtf(s2 * (1.f / 128.f) - m * m + 1e-5f);
  short8 pk;
#pragma unroll
  for (int u = 0; u < 8; ++u)
    pk[u] = f2bf((x[u] - m) * rs * gs[j * 8 + u] + gb[j * 8 + u]);
  const int kt = j >> 2, g = j & 3, lp = g * 16 + rl;
  *reinterpret_cast<short8*>(XnP + (((size_t)mt * 4 + kt) * 64 + lp) * 8) = pk;
}

// precompute cross-attention K/V for all (pair, layer):
// MEMKV[i][l][j][c2] = mem_j . Wkv + bias, mem0 = state@sp_W+sp_b, mem1 = zp_b
__global__ __launch_bounds__(256) void memkv_kernel(
    const float* __restrict__ state, const float* __restrict__ sp_W,
    const float* __restrict__ sp_b, const float* __restrict__ zp_b,
    const float* __restrict__ aW, const float* __restrict__ ab,
    const int* __restrict__ plist, const int* __restrict__ pexp,
    float* __restrict__ MEMKV)
{
  __shared__ float m0[Dn], m1[Dn];
  const int i = (int)blockIdx.x;
  const int ex = pexp[i];
  const int b = plist[i] >> 1;
  const int tid = (int)threadIdx.x;
  if (tid < Dn) {
    float acc = sp_b[ex * Dn + tid];
    const float* spw = sp_W + ex * SDn * Dn;
#pragma unroll
    for (int k = 0; k < SDn; ++k) acc = fmaf(state[b * SDn + k], spw[k * Dn + tid], acc);
    m0[tid] = acc;
  } else {
    m1[tid - Dn] = zp_b[ex * Dn + (tid - Dn)];
  }
  __syncthreads();
  for (int l = 0; l < NLDn; ++l) {
    const int li = ex * NLDn + l;
    const float* W  = aW + (size_t)(li * 2 + 1) * Dn * 384 + Dn;  // k,v cols
    const float* bb = ab + (size_t)(li * 2 + 1) * 384 + Dn;
    for (int e = tid; e < 512; e += 256) {
      const int j = e >> 8, c2 = e & 255;
      const float* mj = j ? m1 : m0;
      const float* wp = W + c2;
      float a0 = 0.f, a1 = 0.f, a2 = 0.f, a3 = 0.f;
#pragma unroll 8
      for (int kk = 0; kk < 128; kk += 4) {
        a0 = fmaf(mj[kk + 0], wp[(kk + 0) * 384], a0);
        a1 = fmaf(mj[kk + 1], wp[(kk + 1) * 384], a1);
        a2 = fmaf(mj[kk + 2], wp[(kk + 2) * 384], a2);
        a3 = fmaf(mj[kk + 3], wp[(kk + 3) * 384], a3);
      }
      MEMKV[((size_t)i * 3 + l) * 512 + e] = bb[c2] + (a0 + a1) + (a2 + a3);
    }
  }
}

// grouped GEMM, K=128 (packed A, 4 k-tiles).
// EPI 0: store bf16 row-major (stride obstr)   [QKV / cross-Q]
// EPI 3: relu -> packed bf16 KT=8              [FFN W1 halves]
// EPI 4: fused norm_first epilogue: v = c + bias + X; X = v (RAW);
//        packed A = LN(v) with (lnsA,lnbA,subOff)           [O-proj]
template<int NTW, int EPI, bool HASB>
__global__ __launch_bounds__(256) void gemm_k128(
    const short* __restrict__ A, const short* __restrict__ Bb, const int strideB,
    const float* __restrict__ biasb, const int strideBias, const int ntOff,
    short* __restrict__ OutBf, const int obstr, short* __restrict__ OutP,
    const float* __restrict__ lnsA, const float* __restrict__ lnbA, const int subOff,
    float* __restrict__ X, const int* __restrict__ sch)
{
  __shared__ float red[16][4][2];
  const int k = (int)blockIdx.x;
  if (k >= sch[0]) return;
  const int ex  = sch[GEXP_OFF + k];
  const int mt0 = sch[GMT_OFF + k];
  const short* Bp = Bb + (size_t)ex * strideB;
  const float* bias = biasb + (size_t)ex * strideBias;
  const float* gs = (EPI == 4) ? lnsA + ex * (NLDn * 3 * 128) + subOff : nullptr;
  const float* gb = (EPI == 4) ? lnbA + ex * (NLDn * 3 * 128) + subOff : nullptr;
  const int lane = (int)threadIdx.x & 63, wv = (int)threadIdx.x >> 6;
  const int r0 = lane & 15, g = lane >> 4;
  short8 bf[NTW][4];
#pragma unroll
  for (int i = 0; i < NTW; ++i)
#pragma unroll
    for (int kt = 0; kt < 4; ++kt)
      bf[i][kt] = *reinterpret_cast<const short8*>(
          Bp + (((size_t)(ntOff + wv * NTW + i) * 4 + kt) * 64 + lane) * 8);
  for (int mt = 0; mt < 8; ++mt) {
    short8 a[4];
#pragma unroll
    for (int kt = 0; kt < 4; ++kt)
      a[kt] = *reinterpret_cast<const short8*>(
          A + (((size_t)(mt0 + mt) * 4 + kt) * 64 + lane) * 8);
    float v[NTW][4];
#pragma unroll
    for (int i = 0; i < NTW; ++i) {
      f32x4v c = {0.f, 0.f, 0.f, 0.f};
#pragma unroll
      for (int kt = 0; kt < 4; ++kt)
        c = __builtin_amdgcn_mfma_f32_16x16x32_bf16(a[kt], bf[i][kt], c, 0, 0, 0);
      const int colL = (wv * NTW + i) * 16 + r0;
      const float bb = HASB ? bias[colL] : 0.f;
      const int rowB = (mt0 + mt) * 16 + g * 4;
#pragma unroll
      for (int q = 0; q < 4; ++q) {
        const int row = rowB + q;
        const float val = c[q] + bb;
        if (EPI == 0) {
          OutBf[(size_t)row * obstr + colL] = f2bf(val);
        } else if (EPI == 3) {
          const float rv = fmaxf(val, 0.f);
          const int j = colL >> 3, kt2 = j >> 2, g2 = j & 3;
          const int lp = g2 * 16 + (row & 15);
          OutP[(((size_t)(row >> 4) * 8 + kt2) * 64 + lp) * 8 + (colL & 7)] = f2bf(rv);
        } else {
          v[i][q] = val + X[(size_t)row * 128 + colL];
        }
      }
    }
    if (EPI == 4) {
      static_assert(EPI != 4 || NTW == 2, "fused LN requires NTW==2");
      float s1[4], s2[4];
#pragma unroll
      for (int q = 0; q < 4; ++q) {
        s1[q] = v[0][q] + v[1][q];
        s2[q] = v[0][q] * v[0][q] + v[1][q] * v[1][q];
      }
#pragma unroll
      for (int o = 1; o < 16; o <<= 1)
#pragma unroll
        for (int q = 0; q < 4; ++q) { s1[q] += __shfl_xor(s1[q], o); s2[q] += __shfl_xor(s2[q], o); }
      if (r0 == 0)
#pragma unroll
        for (int q = 0; q < 4; ++q) { red[g * 4 + q][wv][0] = s1[q]; red[g * 4 + q][wv][1] = s2[q]; }
      __syncthreads();
#pragma unroll
      for (int q = 0; q < 4; ++q) {
        const int r = g * 4 + q;
        const float t1 = red[r][0][0] + red[r][1][0] + red[r][2][0] + red[r][3][0];
        const float t2 = red[r][0][1] + red[r][1][1] + red[r][2][1] + red[r][3][1];
        const float m  = t1 * (1.f / 128.f);
        const float rs = rsqrtf(t2 * (1.f / 128.f) - m * m + 1e-5f);
        const int row = (mt0 + mt) * 16 + r;
#pragma unroll
        for (int i = 0; i < 2; ++i) {
          const int col = (wv * 2 + i) * 16 + r0;
          const float o = (v[i][q] - m) * rs * gs[col] + gb[col];
          X[(size_t)row * 128 + col] = v[i][q];   // norm_first: RAW residual
          OutP[apos(row, col, 4)] = f2bf(o);      // LN'd input for next phase
        }
      }
      __syncthreads();
    }
  }
}

// grouped GEMM, K=256 half of 512 (packed A: 8 k-tiles).
// DOLN=false: X += c (+bias).
// DOLN=true : v = X + c; X = v (RAW); packed A = LN(v) with subOff.
template<bool HASB, bool DOLN>
__global__ __launch_bounds__(256) void gemm_k256(
    const short* __restrict__ A, const short* __restrict__ Bb, const int strideB,
    const float* __restrict__ biasb, const int strideBias, const int ktOff,
    float* __restrict__ X, short* __restrict__ OutP,
    const float* __restrict__ lnsA, const float* __restrict__ lnbA, const int subOff,
    const int* __restrict__ sch)
{
  __shared__ float red[16][4][2];
  const int k = (int)blockIdx.x;
  if (k >= sch[0]) return;
  const int ex  = sch[GEXP_OFF + k];
  const int mt0 = sch[GMT_OFF + k];
  const short* Bp = Bb + (size_t)ex * strideB;
  const float* bias = biasb + (size_t)ex * strideBias;
  const float* gs = DOLN ? lnsA + ex * (NLDn * 3 * 128) + subOff : nullptr;
  const float* gb = DOLN ? lnbA + ex * (NLDn * 3 * 128) + subOff : nullptr;
  const int lane = (int)threadIdx.x & 63, wv = (int)threadIdx.x >> 6;
  const int r0 = lane & 15, g = lane >> 4;
  short8 bf[2][8];
#pragma unroll
  for (int i = 0; i < 2; ++i)
#pragma unroll
    for (int kk = 0; kk < 8; ++kk)
      bf[i][kk] = *reinterpret_cast<const short8*>(
          Bp + (((size_t)(wv * 2 + i) * 16 + ktOff + kk) * 64 + lane) * 8);
  for (int mt = 0; mt < 8; ++mt) {
    short8 a[8];
#pragma unroll
    for (int kk = 0; kk < 8; ++kk)
      a[kk] = *reinterpret_cast<const short8*>(
          A + (((size_t)(mt0 + mt) * 8 + kk) * 64 + lane) * 8);
    float v[2][4];
#pragma unroll
    for (int i = 0; i < 2; ++i) {
      f32x4v c = {0.f, 0.f, 0.f, 0.f};
#pragma unroll
      for (int kk = 0; kk < 8; ++kk)
        c = __builtin_amdgcn_mfma_f32_16x16x32_bf16(a[kk], bf[i][kk], c, 0, 0, 0);
      const int colL = (wv * 2 + i) * 16 + r0;
      const float bb = HASB ? bias[colL] : 0.f;
      const int rowB = (mt0 + mt) * 16 + g * 4;
#pragma unroll
      for (int q = 0; q < 4; ++q) {
        const int row = rowB + q;
        if (DOLN) v[i][q] = c[q] + bb + X[(size_t)row * 128 + colL];
        else      X[(size_t)row * 128 + colL] += c[q] + bb;
      }
    }
    if (DOLN) {
      float s1[4], s2[4];
#pragma unroll
      for (int q = 0; q < 4; ++q) {
        s1[q] = v[0][q] + v[1][q];
        s2[q] = v[0][q] * v[0][q] + v[1][q] * v[1][q];
      }
#pragma unroll
      for (int o = 1; o < 16; o <<= 1)
#pragma unroll
        for (int q = 0; q < 4; ++q) { s1[q] += __shfl_xor(s1[q], o); s2[q] += __shfl_xor(s2[q], o); }
      if (r0 == 0)
#pragma unroll
        for (int q = 0; q < 4; ++q) { red[g * 4 + q][wv][0] = s1[q]; red[g * 4 + q][wv][1] = s2[q]; }
      __syncthreads();
#pragma unroll
      for (int q = 0; q < 4; ++q) {
        const int r = g * 4 + q;
        const float t1 = red[r][0][0] + red[r][1][0] + red[r][2][0] + red[r][3][0];
        const float t2 = red[r][0][1] + red[r][1][1] + red[r][2][1] + red[r][3][1];
        const float m  = t1 * (1.f / 128.f);
        const float rs = rsqrtf(t2 * (1.f / 128.f) - m * m + 1e-5f);
        const int row = (mt0 + mt) * 16 + r;
#pragma unroll
        for (int i = 0; i < 2; ++i) {
          const int col = (wv * 2 + i) * 16 + r0;
          const float o = (v[i][q] - m) * rs * gs[col] + gb[col];
          X[(size_t)row * 128 + col] = v[i][q];   // norm_first: RAW residual
          OutP[apos(row, col, 4)] = f2bf(o);      // LN'd input for next layer
        }
      }
      __syncthreads();
    }
  }
}

// per (pair, head) self-attention: QKV bf16 (stride 384) -> O packed bf16.
// grid (4096, 4), 64 threads (1 wave).
__global__ __launch_bounds__(64) void sattn_kernel(
    const short* __restrict__ QKVb, const int* __restrict__ prow,
    short* __restrict__ ANP)
{
  __shared__ float qs[CSn * HSTR], ks[CSn * HSTR], vs[CSn * HSTR];
  __shared__ float att[CSn * CSn];
  const int i = (int)blockIdx.x, h = (int)blockIdx.y;
  const int tid = (int)threadIdx.x;
  const int row0 = prow[i];
  for (int u = tid; u < CSn * 12; u += 64) {
    const int il = u / 12, r = u % 12, which = r >> 2, d8 = r & 3;
    const short8 s = *reinterpret_cast<const short8*>(
        QKVb + (size_t)(row0 + il) * 384 + which * 128 + h * 32 + d8 * 8);
    float* dst = (which == 0 ? qs : which == 1 ? ks : vs) + il * HSTR + d8 * 8;
#pragma unroll
    for (int u8 = 0; u8 < 8; ++u8) dst[u8] = bf2f(s[u8]);
  }
  __syncthreads();
  for (int e = tid; e < CSn * CSn; e += 64) {
    const int ii = e / CSn, j = e % CSn;
    const float* qp = qs + ii * HSTR;
    const float* kp = ks + j * HSTR;
    float acc = 0.f;
#pragma unroll
    for (int d = 0; d < DHn; d += 4) {
      const float4 qa = *reinterpret_cast<const float4*>(qp + d);
      const float4 kb = *reinterpret_cast<const float4*>(kp + d);
      acc += qa.x * kb.x + qa.y * kb.y + qa.z * kb.z + qa.w * kb.w;
    }
    att[e] = acc * INV_SQRT_DH;
  }
  __syncthreads();
  if (tid < CSn) {
    float* row = att + tid * CSn;
    float m = row[0];
#pragma unroll 4
    for (int j = 1; j < CSn; ++j) m = fmaxf(m, row[j]);
    float s = 0.f;
#pragma unroll 4
    for (int j = 0; j < CSn; ++j) { const float ex = expf(row[j] - m); row[j] = ex; s += ex; }
    const float inv = 1.f / s;
#pragma unroll 4
    for (int j = 0; j < CSn; ++j) row[j] *= inv;
  }
  __syncthreads();
  for (int e = tid; e < CSn * 32; e += 64) {
    const int ii = e >> 5, c = e & 31;
    const float* arow = att + ii * CSn;
    float acc = 0.f;
#pragma unroll 4
    for (int j = 0; j < CSn; ++j) acc = fmaf(arow[j], vs[j * HSTR + c], acc);
    ANP[apos(row0 + ii, h * 32 + c, 4)] = f2bf(acc);
  }
}

// per-pair cross-attention (2 keys): Qc bf16 (stride 128) + precomputed MEMKV
__global__ __launch_bounds__(256) void cattn_kernel(
    const short* __restrict__ Qb, const float* __restrict__ MEMKV, const int layer,
    const int* __restrict__ prow, short* __restrict__ ANP)
{
  __shared__ float q[CSn * Dn];
  __shared__ float memkv[2 * 256];
  __shared__ float catt[2 * Hn * CSn];
  const int i = (int)blockIdx.x;
  const int row0 = prow[i];
  const int tid = (int)threadIdx.x;

  for (int e = tid; e < 512; e += 256)
    memkv[e] = MEMKV[((size_t)i * 3 + layer) * 512 + e];
  for (int e8 = tid; e8 < CSn * 16; e8 += 256) {
    const int il = e8 >> 4, c8 = e8 & 15;
    const short8 s = *reinterpret_cast<const short8*>(
        Qb + (size_t)(row0 + il) * 128 + c8 * 8);
    float* dst = q + il * Dn + c8 * 8;
#pragma unroll
    for (int u = 0; u < 8; ++u) dst[u] = bf2f(s[u]);
  }
  __syncthreads();
  for (int e = tid; e < Hn * CSn; e += 256) {
    const int h = e / CSn, il = e % CSn;
    const float* qp = q + il * Dn + h * DHn;
    float s0 = 0.f, s1 = 0.f;
#pragma unroll
    for (int d = 0; d < DHn; d += 4) {
      const float4 q4 = *reinterpret_cast<const float4*>(qp + d);
      const float4 k0 = *reinterpret_cast<const float4*>(memkv + 0 * 256 + h * DHn + d);
      const float4 k1 = *reinterpret_cast<const float4*>(memkv + 1 * 256 + h * DHn + d);
      s0 += q4.x * k0.x + q4.y * k0.y + q4.z * k0.z + q4.w * k0.w;
      s1 += q4.x * k1.x + q4.y * k1.y + q4.z * k1.z + q4.w * k1.w;
    }
    s0 *= INV_SQRT_DH; s1 *= INV_SQRT_DH;
    const float m = fmaxf(s0, s1);
    const float e0 = expf(s0 - m), e1 = expf(s1 - m);
    const float inv = 1.f / (e0 + e1);
    catt[e * 2] = e0 * inv; catt[e * 2 + 1] = e1 * inv;
  }
  __syncthreads();
  for (int e = tid; e < CSn * Dn; e += 256) {
    const int il = e >> 7, c = e & 127, h = c >> 5;
    const int a = (h * CSn + il) * 2;
    const float v = catt[a]     * memkv[0 * 256 + Dn + c]
                  + catt[a + 1] * memkv[1 * 256 + Dn + c];
    ANP[apos(row0 + il, c, 4)] = f2bf(v);
  }
}

__global__ __launch_bounds__(256) void head_kernel(
    const float* __restrict__ X, const int* __restrict__ plist,
    const int* __restrict__ prow, const int* __restrict__ pexp,
    const float* __restrict__ rwgt, const float* __restrict__ hW,
    const float* __restrict__ hb, float* __restrict__ Rbuf)
{
  __shared__ float xr[CSn * Dn];
  const int i = (int)blockIdx.x;
  const int ex = pexp[i];
  const int orig = plist[i];
  const int row0 = prow[i];
  const float wgt = rwgt[orig];
  for (int e4 = (int)threadIdx.x; e4 < CSn * 32; e4 += 256) {
    const int il = e4 >> 5, c4 = (e4 & 31) * 4;
    *reinterpret_cast<float4*>(xr + il * Dn + c4) =
        *reinterpret_cast<const float4*>(X + (size_t)(row0 + il) * 128 + c4);
  }
  __syncthreads();
  const int e = (int)threadIdx.x;
  if (e < CSn * JDn) {
    const int t = e / JDn, j = e - t * JDn;
    const float* w = hW + ex * Dn * JDn + j;
    float acc = hb[ex * JDn + j];
#pragma unroll 4
    for (int kk = 0; kk < Dn; ++kk) acc = fmaf(xr[t * Dn + kk], w[kk * JDn], acc);
    Rbuf[(size_t)i * 140 + e] = wgt * acc;
  }
}

__global__ void combine_kernel(const float* __restrict__ Rbuf,
                               const int* __restrict__ ppos, float* __restrict__ out)
{
  const int idx = (int)blockIdx.x * 256 + (int)threadIdx.x;
  if (idx >= Bn * 140) return;
  const int b = idx / 140, e = idx - b * 140;
  out[idx] = Rbuf[(size_t)ppos[2 * b] * 140 + e] + Rbuf[(size_t)ppos[2 * b + 1] * 140 + e];
}

// ---------------------------------------------------------------------------
__global__ void qpe_kernel(float* qpe)
{
  const int e = (int)blockIdx.x * 256 + (int)threadIdx.x;
  if (e < CSn * Dn) {
    const int t = e >> 7, d = e & 127;
    const float j  = (float)(d & ~1);
    const float dv = expf(j * (-logf(10000.f) / 128.f));
    const float a  = (float)t * dv;
    qpe[e] = (d & 1) ? cosf(a) : sinf(a);
  }
}

} // namespace

// ---------------------------------------------------------------------------
extern "C" void kernel_launch(void* const* d_in, const int* in_sizes, int n_in,
                              void* d_out, int out_size, void* d_ws, size_t ws_size,
                              hipStream_t stream)
{
  (void)in_sizes; (void)n_in; (void)out_size;

  const int*   ids     = (const int*)  d_in[0];
  const float* state   = (const float*)d_in[1];
  const float* tok_emb = (const float*)d_in[2];
  const float* pos_emb = (const float*)d_in[3];

  // persistent workspace (256B-aligned cursor)
  char* cur = (char*)d_ws;
  auto alloc = [&cur](size_t bytes) -> char* {
    char* p = cur; cur += (bytes + 255) & ~(size_t)255; return p;
  };
  float* qpe    = (float*)alloc(4096 * 4);
  float* intent = (float*)alloc((size_t)Bn * Dn * 4);
  int*   ridx   = (int*)  alloc(PAIRS * 4);
  float* rwgt   = (float*)alloc(PAIRS * 4);
  short* pQ     = (short*)alloc((size_t)36 * 49152 * 2);   // expert packs (single bf16)
  short* pO     = (short*)alloc((size_t)36 * 16384 * 2);
  short* pF1    = (short*)alloc((size_t)18 * 65536 * 2);
  short* pF2    = (short*)alloc((size_t)18 * 65536 * 2);
  short* pbQ    = (short*)alloc((size_t)4 * 98304 * 2);    // BERT packs (split hi/lo)
  short* pbO    = (short*)alloc((size_t)4 * 32768 * 2);
  short* pbW1   = (short*)alloc((size_t)4 * 131072 * 2);
  short* pbW2   = (short*)alloc((size_t)4 * 131072 * 2);
  int*   sch    = (int*)  alloc(2048 * 4);
  int*   plist  = (int*)  alloc(PAIRS * 4);
  int*   prow   = (int*)  alloc(PAIRS * 4);
  int*   pexp   = (int*)  alloc(PAIRS * 4);
  int*   ppos   = (int*)  alloc(PAIRS * 4);
  constexpr size_t ARENA_BYTES = 192806912;
  char* arena = alloc(ARENA_BYTES);
  if ((size_t)(cur - (char*)d_ws) > ws_size) return;  // ws confirmed sufficient R4-R7

  // BERT views
  float* Xb  = (float*)(arena);                          // 25.2 MB
  short* Ah  = (short*)(arena + 25165824);               // 12.6 MB
  short* Al  = (short*)(arena + 37748736);               // 12.6 MB
  float* SBb = (float*)(arena + 50331648);               // QKV fp32 75.5 MB
  short* Hh  = (short*)(arena + 50331648);               // aliases SBb (sequential use)
  short* Hl  = (short*)(arena + 100663296);              // 50.3 MB
  // expert views
  float* X2    = (float*)(arena);                        // 42.3 MB
  short* ANP   = (short*)(arena + 42336256);             // 21.2 MB
  short* SBh   = (short*)(arena + 63504384);             // bf16 QKV/Qc/HP (<=63.5 MB)
  float* MEMKV = (float*)(arena + 63504384 + 63504384);  // 25.2 MB (after QKV region)
  float* Rbuf  = (float*)(arena + 190513152);            // 2.3 MB

  qpe_kernel<<<dim3(10), dim3(256), 0, stream>>>(qpe);

  // ---- weight packing
  {
    const int tq = 36 * 6144;
    pack_kernel<<<dim3((tq + 255) / 256), dim3(256), 0, stream>>>(
        (const float*)d_in[34], pQ, 128, 384, tq);
    const int to = 36 * 2048;
    pack_kernel<<<dim3((to + 255) / 256), dim3(256), 0, stream>>>(
        (const float*)d_in[36], pO, 128, 128, to);
    const int t1c = 18 * 8192;
    pack_kernel<<<dim3((t1c + 255) / 256), dim3(256), 0, stream>>>(
        (const float*)d_in[40], pF1, 128, 512, t1c);
    const int t2c = 18 * 8192;
    pack_kernel<<<dim3((t2c + 255) / 256), dim3(256), 0, stream>>>(
        (const float*)d_in[42], pF2, 512, 128, t2c);
    const int bq = 4 * 6144;
    pack2_kernel<<<dim3((bq + 255) / 256), dim3(256), 0, stream>>>(
        (const float*)d_in[4], pbQ, 128, 384, bq);
    const int bo = 4 * 2048;
    pack2_kernel<<<dim3((bo + 255) / 256), dim3(256), 0, stream>>>(
        (const float*)d_in[6], pbO, 128, 128, bo);
    const int bw1 = 4 * 8192;
    pack2_kernel<<<dim3((bw1 + 255) / 256), dim3(256), 0, stream>>>(
        (const float*)d_in[8], pbW1, 128, 512, bw1);
    const int bw2 = 4 * 8192;
    pack2_kernel<<<dim3((bw2 + 255) / 256), dim3(256), 0, stream>>>(
        (const float*)d_in[10], pbW2, 512, 128, bw2);
  }

  // ---- BERT phase pipeline
  {
    const float* bq  = (const float*)d_in[5];
    const float* bo  = (const float*)d_in[7];
    const float* b1  = (const float*)d_in[9];
    const float* b2  = (const float*)d_in[11];
    const float* lns = (const float*)d_in[12];
    const float* lnb = (const float*)d_in[13];

    bembed_kernel<<<dim3(ROWSB / 16), dim3(256), 0, stream>>>(
        ids, tok_emb, pos_emb, Xb, Ah, Al);
    for (int l = 0; l < NLBn; ++l) {
      bqkv_kernel<<<dim3(ROWSB / 64, 3), dim3(256), 0, stream>>>(
          Ah, Al, pbQ + (size_t)l * 98304, bq + l * 384, SBb);
      battn_kernel<<<dim3(Bn, Hn), dim3(64), 0, stream>>>(SBb, ids, Ah, Al);
      bo_ln_kernel<<<dim3(ROWSB / 64), dim3(256), 0, stream>>>(
          Ah, Al, pbO + (size_t)l * 32768, bo + l * 128,
          lns + l * 256, lnb + l * 256, Xb, Ah, Al);
      bw1_kernel<<<dim3(ROWSB / 64, 4), dim3(256), 0, stream>>>(
          Ah, Al, pbW1 + (size_t)l * 131072, b1 + l * 512, Hh, Hl);
      bw2a_kernel<<<dim3(ROWSB / 64), dim3(512), 0, stream>>>(
          Hh, Hl, pbW2 + (size_t)l * 131072, b2 + l * 128, Xb);
      bw2b_kernel<<<dim3(ROWSB / 64), dim3(512), 0, stream>>>(
          Hh, Hl, pbW2 + (size_t)l * 131072,
          lns + l * 256 + 128, lnb + l * 256 + 128, Xb, Ah, Al);
    }
    bintent_kernel<<<dim3(Bn / 4), dim3(256), 0, stream>>>(
        Xb, (const float*)d_in[14], (const float*)d_in[15], intent);
  }

  // ---- router
  {
    RouterP rp;
    rp.state = state; rp.intent = intent;
    rp.se_W1 = (const float*)d_in[16]; rp.se_b1 = (const float*)d_in[17];
    rp.se_W2 = (const float*)d_in[18]; rp.se_b2 = (const float*)d_in[19];
    rp.se_ln_s = (const float*)d_in[20]; rp.se_ln_b = (const float*)d_in[21];
    rp.r_W1 = (const float*)d_in[22]; rp.r_b1 = (const float*)d_in[23];
    rp.r_W2 = (const float*)d_in[24]; rp.r_b2 = (const float*)d_in[25];
    rp.r_ln_s = (const float*)d_in[26]; rp.r_ln_b = (const float*)d_in[27];
    rp.gate_W = (const float*)d_in[28]; rp.gate_b = (const float*)d_in[29];
    rp.ridx = ridx; rp.rwgt = rwgt;
    router_kernel<<<dim3(Bn), dim3(128), 0, stream>>>(rp);
  }

  const float* sp_W = (const float*)d_in[30];
  const float* sp_b = (const float*)d_in[31];
  const float* zp_b = (const float*)d_in[33];
  const float* aW   = (const float*)d_in[34];
  const float* ab   = (const float*)d_in[35];
  const float* abo  = (const float*)d_in[37];
  const float* lnsA = (const float*)d_in[38];
  const float* lnbA = (const float*)d_in[39];
  const float* fb1A = (const float*)d_in[41];
  const float* fb2A = (const float*)d_in[43];
  const float* hW   = (const float*)d_in[44];
  const float* hB   = (const float*)d_in[45];

  // ---- expert phase pipeline
  {
    sched_kernel<<<dim3(1), dim3(256), 0, stream>>>(ridx, sch, plist, prow, pexp, ppos);
    memkv_kernel<<<dim3(PAIRS), dim3(256), 0, stream>>>(
        state, sp_W, sp_b, zp_b, aW, ab, plist, pexp, MEMKV);
    xinit_kernel<<<dim3(MPMAX * 32 / 256), dim3(256), 0, stream>>>(qpe, sch, X2);
    ln_pack_kernel<<<dim3(MPMAX / 16), dim3(256), 0, stream>>>(
        X2, ANP, lnsA, lnbA, 0, sch);
    short* HP = SBh;
    for (int l = 0; l < NLDn; ++l) {
      // self-attention block
      gemm_k128<6, 0, true><<<dim3(NBGMAX), dim3(256), 0, stream>>>(
          ANP, pQ + (l * 2 + 0) * 49152, 294912,
          ab + (l * 2 + 0) * 384, 2304, 0,
          SBh, 384, nullptr, nullptr, nullptr, 0, nullptr, sch);
      sattn_kernel<<<dim3(PAIRS, Hn), dim3(64), 0, stream>>>(SBh, prow, ANP);
      gemm_k128<2, 4, true><<<dim3(NBGMAX), dim3(256), 0, stream>>>(
          ANP, pO + (l * 2 + 0) * 16384, 98304,
          abo + (l * 2 + 0) * 128, 768, 0,
          nullptr, 0, ANP, lnsA, lnbA, (l * 3 + 1) * 128, X2, sch);
      // cross-attention block
      gemm_k128<2, 0, true><<<dim3(NBGMAX), dim3(256), 0, stream>>>(
          ANP, pQ + (l * 2 + 1) * 49152, 294912,
          ab + (l * 2 + 1) * 384, 2304, 0,
          SBh, 128, nullptr, nullptr, nullptr, 0, nullptr, sch);
      cattn_kernel<<<dim3(PAIRS), dim3(256), 0, stream>>>(
          SBh, MEMKV, l, prow, ANP);
      gemm_k128<2, 4, true><<<dim3(NBGMAX), dim3(256), 0, stream>>>(
          ANP, pO + (l * 2 + 1) * 16384, 98304,
          abo + (l * 2 + 1) * 128, 768, 0,
          nullptr, 0, ANP, lnsA, lnbA, (l * 3 + 2) * 128, X2, sch);
      // FFN block (two 256-col halves)
      gemm_k128<4, 3, true><<<dim3(NBGMAX), dim3(256), 0, stream>>>(
          ANP, pF1 + l * 65536, 196608,
          fb1A + l * 512 + 0 * 256, 1536, 0,
          nullptr, 0, HP, nullptr, nullptr, 0, nullptr, sch);
      gemm_k256<true, false><<<dim3(NBGMAX), dim3(256), 0, stream>>>(
          HP, pF2 + l * 65536, 196608, fb2A + l * 128, 384, 0,
          X2, nullptr, nullptr, nullptr, 0, sch);
      gemm_k128<4, 3, true><<<dim3(NBGMAX), dim3(256), 0, stream>>>(
          ANP, pF1 + l * 65536, 196608,
          fb1A + l * 512 + 1 * 256, 1536, 16,
          nullptr, 0, HP, nullptr, nullptr, 0, nullptr, sch);
      if (l < NLDn - 1) {
        gemm_k256<false, true><<<dim3(NBGMAX), dim3(256), 0, stream>>>(
            HP, pF2 + l * 65536, 196608, fb2A + l * 128, 384, 8,
            X2, ANP, lnsA, lnbA, ((l + 1) * 3 + 0) * 128, sch);
      } else {
        gemm_k256<false, false><<<dim3(NBGMAX), dim3(256), 0, stream>>>(
            HP, pF2 + l * 65536, 196608, fb2A + l * 128, 384, 8,
            X2, nullptr, nullptr, nullptr, 0, sch);
      }
    }
    head_kernel<<<dim3(PAIRS), dim3(256), 0, stream>>>(
        X2, plist, prow, pexp, rwgt, hW, hB, Rbuf);
    combine_kernel<<<dim3((Bn * 140 + 255) / 256), dim3(256), 0, stream>>>(
        Rbuf, ppos, (float*)d_out);
  }
}

// Round 9
// 1713.793 us; speedup vs baseline: 4.0758x; 1.0482x over previous
//
#include <hip/hip_runtime.h>
#include <math.h>

#define DEVI __device__ __forceinline__

namespace {

constexpr int Bn   = 2048;
constexpr int En   = 6;
constexpr int Hn   = 4;
constexpr int Dn   = 128;
constexpr int DHn  = 32;
constexpr int LTn  = 24;   // text length
constexpr int CSn  = 20;   // chunk (decoder query) length
constexpr int JDn  = 7;
constexpr int SDn  = 16;
constexpr int NLBn = 4;
constexpr int NLDn = 3;
constexpr int DFFn = 512;
constexpr float INV_SQRT_DH = 0.17677669529663687f;  // 1/sqrt(32)

// expert phase-pipeline geometry
constexpr int PAIRS  = 4096;                  // 2048 items x top-2
constexpr int MPMAX  = PAIRS * 20 + En * 128; // padded rows (per-expert 128-aligned)
constexpr int NBGMAX = PAIRS * 20 / 128 + En; // 646 grouped-GEMM blocks max
constexpr int GEXP_OFF = 64;
constexpr int GMT_OFF  = 64 + NBGMAX;

// BERT pipeline geometry
constexpr int ROWSB = Bn * LTn;               // 49152 rows, 3072 M-tiles, no padding

// per-head attention LDS stride (36 mod 32 = 4 -> conflict-light, 16B-aligned)
constexpr int HSTR = 36;

typedef float f32x4v __attribute__((ext_vector_type(4)));
typedef short short8 __attribute__((ext_vector_type(8)));

DEVI float geluf(float x) { return 0.5f * x * (1.0f + erff(x * 0.70710678118654752f)); }

DEVI short f2bf(float f) {  // fp32 -> bf16 bits, round-to-nearest-even
  unsigned u = __float_as_uint(f);
  return (short)((u + 0x7FFFu + ((u >> 16) & 1u)) >> 16);
}
DEVI float bf2f(short s) { return __uint_as_float(((unsigned)(unsigned short)s) << 16); }
DEVI void split2(float v, short& h, short& l) {  // v ~= hi + lo to ~2^-16 rel
  h = f2bf(v);
  l = f2bf(v - bf2f(h));
}

// packed-A position for (row, col), K-tile count KT
DEVI size_t apos(int row, int col, int KT) {
  return (((size_t)(row >> 4) * KT + (col >> 5)) * 64 + ((col >> 3) & 3) * 16 + (row & 15)) * 8
         + (col & 7);
}

// ---------------------------------------------------------------------------
// pack fp32 [K][N] into single-bf16 B tiles (512 shorts/tile)
__global__ void pack_kernel(const float* __restrict__ W, short* __restrict__ out,
                            const int K, const int N, const int total)
{
  const int p = (int)blockIdx.x * 256 + (int)threadIdx.x;
  if (p >= total) return;
  const int perMat = (K * N) >> 3;
  const int m = p / perMat, r = p - m * perMat;
  const int t = r >> 6, lane = r & 63;
  const int KT = K >> 5;
  const int nt = t / KT, kt = t - nt * KT;
  const int row0 = kt * 32 + (lane >> 4) * 8;
  const int col  = nt * 16 + (lane & 15);
  const float* src = W + (size_t)m * K * N;
  short8 v;
#pragma unroll
  for (int j = 0; j < 8; ++j) v[j] = f2bf(src[(size_t)(row0 + j) * N + col]);
  *reinterpret_cast<short8*>(out + (size_t)p * 8) = v;
}

// pack fp32 [K][N] into split hi/lo B tiles (1024 shorts/tile)
__global__ void pack2_kernel(const float* __restrict__ W, short* __restrict__ out,
                             const int K, const int N, const int total)
{
  const int p = (int)blockIdx.x * 256 + (int)threadIdx.x;
  if (p >= total) return;
  const int perMat = (K * N) >> 3;
  const int m = p / perMat, r = p - m * perMat;
  const int t = r >> 6, lane = r & 63;
  const int KT = K >> 5;
  const int nt = t / KT, kt = t - nt * KT;
  const int row0 = kt * 32 + (lane >> 4) * 8;
  const int col  = nt * 16 + (lane & 15);
  const float* src = W + (size_t)m * K * N;
  short8 vh, vl;
#pragma unroll
  for (int j = 0; j < 8; ++j) {
    short hh, ll;
    split2(src[(size_t)(row0 + j) * N + col], hh, ll);
    vh[j] = hh; vl[j] = ll;
  }
  const size_t T  = (size_t)(perMat >> 6);
  const size_t tg = (size_t)m * T + t;
  *reinterpret_cast<short8*>(out + tg * 1024 + lane * 8)       = vh;
  *reinterpret_cast<short8*>(out + tg * 1024 + 512 + lane * 8) = vl;
}

// ===========================================================================
// BERT phase pipeline (split-bf16, M = 49152 rows)
// ===========================================================================

__global__ __launch_bounds__(256) void bembed_kernel(
    const int* __restrict__ ids, const float* __restrict__ tok,
    const float* __restrict__ pos, float* __restrict__ X,
    short* __restrict__ Ah, short* __restrict__ Al)
{
  const int mt = (int)blockIdx.x;          // 0..3071
  const int t = (int)threadIdx.x;
  const int rl = t >> 4, j = t & 15;
  const int row = mt * 16 + rl;
  const int b = row / 24, i = row - b * 24;
  const int id = ids[b * 24 + i];
  const float* tp = tok + (size_t)id * 128 + j * 8;
  const float* pp = pos + i * 128 + j * 8;
  float x[8];
  short8 vh, vl;
#pragma unroll
  for (int u = 0; u < 8; ++u) {
    x[u] = tp[u] + pp[u];
    short hh, ll; split2(x[u], hh, ll);
    vh[u] = hh; vl[u] = ll;
  }
  float4 f0 = {x[0], x[1], x[2], x[3]}, f1 = {x[4], x[5], x[6], x[7]};
  *reinterpret_cast<float4*>(X + (size_t)row * 128 + j * 8) = f0;
  *reinterpret_cast<float4*>(X + (size_t)row * 128 + j * 8 + 4) = f1;
  const size_t pk = (((size_t)mt * 4 + (j >> 2)) * 64 + (j & 3) * 16 + rl) * 8;
  *reinterpret_cast<short8*>(Ah + pk) = vh;
  *reinterpret_cast<short8*>(Al + pk) = vl;
}

__global__ __launch_bounds__(256) void bqkv_kernel(
    const short* __restrict__ Ah, const short* __restrict__ Al,
    const short* __restrict__ Bp, const float* __restrict__ bias,
    float* __restrict__ Out)
{
  const int mt0 = (int)blockIdx.x * 4;
  const int nc  = (int)blockIdx.y;
  const int lane = (int)threadIdx.x & 63, wv = (int)threadIdx.x >> 6;
  const int r0 = lane & 15, g = lane >> 4;
  short8 bh[2][4], bl[2][4];
#pragma unroll
  for (int i = 0; i < 2; ++i)
#pragma unroll
    for (int kt = 0; kt < 4; ++kt) {
      const short* tb = Bp + (((size_t)(nc * 8 + wv * 2 + i) * 4 + kt) << 10);
      bh[i][kt] = *reinterpret_cast<const short8*>(tb + lane * 8);
      bl[i][kt] = *reinterpret_cast<const short8*>(tb + 512 + lane * 8);
    }
#pragma unroll 2
  for (int mt = 0; mt < 4; ++mt) {
    const int mtg = mt0 + mt;
    short8 ah[4], al[4];
#pragma unroll
    for (int kt = 0; kt < 4; ++kt) {
      ah[kt] = *reinterpret_cast<const short8*>(Ah + (((size_t)mtg * 4 + kt) * 64 + lane) * 8);
      al[kt] = *reinterpret_cast<const short8*>(Al + (((size_t)mtg * 4 + kt) * 64 + lane) * 8);
    }
#pragma unroll
    for (int i = 0; i < 2; ++i) {
      f32x4v c = {0.f, 0.f, 0.f, 0.f};
#pragma unroll
      for (int kt = 0; kt < 4; ++kt) {
        c = __builtin_amdgcn_mfma_f32_16x16x32_bf16(ah[kt], bh[i][kt], c, 0, 0, 0);
        c = __builtin_amdgcn_mfma_f32_16x16x32_bf16(al[kt], bh[i][kt], c, 0, 0, 0);
        c = __builtin_amdgcn_mfma_f32_16x16x32_bf16(ah[kt], bl[i][kt], c, 0, 0, 0);
      }
      const int col = nc * 128 + (wv * 2 + i) * 16 + r0;
      const float bb = bias[col];
#pragma unroll
      for (int q = 0; q < 4; ++q)
        Out[(size_t)(mtg * 16 + g * 4 + q) * 384 + col] = c[q] + bb;
    }
  }
}

// per (item, head) BERT attention: QKV fp32 -> attn out split-packed A.
// grid (2048, 4), 64 threads (1 wave).
__global__ __launch_bounds__(64) void battn_kernel(
    const float* __restrict__ QKV, const int* __restrict__ ids,
    short* __restrict__ Ah, short* __restrict__ Al)
{
  __shared__ float qs[LTn * HSTR], ks[LTn * HSTR], vs[LTn * HSTR];
  __shared__ float att[LTn * LTn];
  __shared__ int pad_s[LTn];
  const int b = (int)blockIdx.x, h = (int)blockIdx.y;
  const int tid = (int)threadIdx.x;
  const int row0 = b * LTn;
  for (int u = tid; u < LTn * 24; u += 64) {
    const int il = u / 24, r = u % 24, which = r >> 3, d4 = r & 7;
    const float4 v = *reinterpret_cast<const float4*>(
        QKV + (size_t)(row0 + il) * 384 + which * 128 + h * 32 + d4 * 4);
    float* dst = (which == 0 ? qs : which == 1 ? ks : vs) + il * HSTR + d4 * 4;
    *reinterpret_cast<float4*>(dst) = v;
  }
  if (tid < LTn) pad_s[tid] = (ids[row0 + tid] == 0) ? 1 : 0;
  __syncthreads();
  for (int e = tid; e < LTn * LTn; e += 64) {
    const int i = e / LTn, j = e % LTn;
    const float* qp = qs + i * HSTR;
    const float* kp = ks + j * HSTR;
    float acc = 0.f;
#pragma unroll
    for (int d = 0; d < DHn; d += 4) {
      const float4 qa = *reinterpret_cast<const float4*>(qp + d);
      const float4 kb = *reinterpret_cast<const float4*>(kp + d);
      acc += qa.x * kb.x + qa.y * kb.y + qa.z * kb.z + qa.w * kb.w;
    }
    acc *= INV_SQRT_DH;
    if (pad_s[j]) acc = -1e9f;
    att[e] = acc;
  }
  __syncthreads();
  if (tid < LTn) {
    float* row = att + tid * LTn;
    float m = row[0];
#pragma unroll 4
    for (int j = 1; j < LTn; ++j) m = fmaxf(m, row[j]);
    float s = 0.f;
#pragma unroll 4
    for (int j = 0; j < LTn; ++j) { const float ex = expf(row[j] - m); row[j] = ex; s += ex; }
    const float inv = 1.f / s;
#pragma unroll 4
    for (int j = 0; j < LTn; ++j) row[j] *= inv;
  }
  __syncthreads();
  for (int e = tid; e < LTn * 32; e += 64) {
    const int i = e >> 5, c = e & 31;
    const float* arow = att + i * LTn;
    float acc = 0.f;
#pragma unroll 4
    for (int j = 0; j < LTn; ++j) acc = fmaf(arow[j], vs[j * HSTR + c], acc);
    short hh, ll; split2(acc, hh, ll);
    const size_t pk = apos(row0 + i, h * 32 + c, 4);
    Ah[pk] = hh; Al[pk] = ll;
  }
}

__global__ __launch_bounds__(256) void bo_ln_kernel(
    const short* __restrict__ Ah, const short* __restrict__ Al,
    const short* __restrict__ Bp, const float* __restrict__ bo,
    const float* __restrict__ gs, const float* __restrict__ gb,
    float* __restrict__ X, short* __restrict__ OAh, short* __restrict__ OAl)
{
  __shared__ float red[16][4][2];
  const int mt0 = (int)blockIdx.x * 4;
  const int lane = (int)threadIdx.x & 63, wv = (int)threadIdx.x >> 6;
  const int r0 = lane & 15, g = lane >> 4;
  short8 bh[2][4], bl[2][4];
#pragma unroll
  for (int i = 0; i < 2; ++i)
#pragma unroll
    for (int kt = 0; kt < 4; ++kt) {
      const short* tb = Bp + (((size_t)(wv * 2 + i) * 4 + kt) << 10);
      bh[i][kt] = *reinterpret_cast<const short8*>(tb + lane * 8);
      bl[i][kt] = *reinterpret_cast<const short8*>(tb + 512 + lane * 8);
    }
  for (int mt = 0; mt < 4; ++mt) {
    const int mtg = mt0 + mt;
    short8 ah[4], al[4];
#pragma unroll
    for (int kt = 0; kt < 4; ++kt) {
      ah[kt] = *reinterpret_cast<const short8*>(Ah + (((size_t)mtg * 4 + kt) * 64 + lane) * 8);
      al[kt] = *reinterpret_cast<const short8*>(Al + (((size_t)mtg * 4 + kt) * 64 + lane) * 8);
    }
    float v[2][4];
#pragma unroll
    for (int i = 0; i < 2; ++i) {
      f32x4v c = {0.f, 0.f, 0.f, 0.f};
#pragma unroll
      for (int kt = 0; kt < 4; ++kt) {
        c = __builtin_amdgcn_mfma_f32_16x16x32_bf16(ah[kt], bh[i][kt], c, 0, 0, 0);
        c = __builtin_amdgcn_mfma_f32_16x16x32_bf16(al[kt], bh[i][kt], c, 0, 0, 0);
        c = __builtin_amdgcn_mfma_f32_16x16x32_bf16(ah[kt], bl[i][kt], c, 0, 0, 0);
      }
      const int col = (wv * 2 + i) * 16 + r0;
      const float bb = bo[col];
#pragma unroll
      for (int q = 0; q < 4; ++q) {
        const int row = mtg * 16 + g * 4 + q;
        v[i][q] = c[q] + bb + X[(size_t)row * 128 + col];
      }
    }
    float s1[4], s2[4];
#pragma unroll
    for (int q = 0; q < 4; ++q) {
      s1[q] = v[0][q] + v[1][q];
      s2[q] = v[0][q] * v[0][q] + v[1][q] * v[1][q];
    }
#pragma unroll
    for (int o = 1; o < 16; o <<= 1)
#pragma unroll
      for (int q = 0; q < 4; ++q) { s1[q] += __shfl_xor(s1[q], o); s2[q] += __shfl_xor(s2[q], o); }
    if (r0 == 0)
#pragma unroll
      for (int q = 0; q < 4; ++q) { red[g * 4 + q][wv][0] = s1[q]; red[g * 4 + q][wv][1] = s2[q]; }
    __syncthreads();
#pragma unroll
    for (int q = 0; q < 4; ++q) {
      const int r = g * 4 + q;
      const float t1 = red[r][0][0] + red[r][1][0] + red[r][2][0] + red[r][3][0];
      const float t2 = red[r][0][1] + red[r][1][1] + red[r][2][1] + red[r][3][1];
      const float m  = t1 * (1.f / 128.f);
      const float rs = rsqrtf(t2 * (1.f / 128.f) - m * m + 1e-5f);
      const int row = mtg * 16 + r;
#pragma unroll
      for (int i = 0; i < 2; ++i) {
        const int col = (wv * 2 + i) * 16 + r0;
        const float o = (v[i][q] - m) * rs * gs[col] + gb[col];
        X[(size_t)row * 128 + col] = o;   // post-LN: LN'd value IS the residual
        short hh, ll; split2(o, hh, ll);
        const size_t pk = apos(row, col, 4);
        OAh[pk] = hh; OAl[pk] = ll;
      }
    }
    __syncthreads();
  }
}

__global__ __launch_bounds__(256) void bw1_kernel(
    const short* __restrict__ Ah, const short* __restrict__ Al,
    const short* __restrict__ Bp, const float* __restrict__ bias,
    short* __restrict__ Hh, short* __restrict__ Hl)
{
  const int mt0 = (int)blockIdx.x * 4;
  const int nc  = (int)blockIdx.y;
  const int lane = (int)threadIdx.x & 63, wv = (int)threadIdx.x >> 6;
  const int r0 = lane & 15, g = lane >> 4;
  short8 bh[2][4], bl[2][4];
#pragma unroll
  for (int i = 0; i < 2; ++i)
#pragma unroll
    for (int kt = 0; kt < 4; ++kt) {
      const short* tb = Bp + (((size_t)(nc * 8 + wv * 2 + i) * 4 + kt) << 10);
      bh[i][kt] = *reinterpret_cast<const short8*>(tb + lane * 8);
      bl[i][kt] = *reinterpret_cast<const short8*>(tb + 512 + lane * 8);
    }
#pragma unroll 2
  for (int mt = 0; mt < 4; ++mt) {
    const int mtg = mt0 + mt;
    short8 ah[4], al[4];
#pragma unroll
    for (int kt = 0; kt < 4; ++kt) {
      ah[kt] = *reinterpret_cast<const short8*>(Ah + (((size_t)mtg * 4 + kt) * 64 + lane) * 8);
      al[kt] = *reinterpret_cast<const short8*>(Al + (((size_t)mtg * 4 + kt) * 64 + lane) * 8);
    }
#pragma unroll
    for (int i = 0; i < 2; ++i) {
      f32x4v c = {0.f, 0.f, 0.f, 0.f};
#pragma unroll
      for (int kt = 0; kt < 4; ++kt) {
        c = __builtin_amdgcn_mfma_f32_16x16x32_bf16(ah[kt], bh[i][kt], c, 0, 0, 0);
        c = __builtin_amdgcn_mfma_f32_16x16x32_bf16(al[kt], bh[i][kt], c, 0, 0, 0);
        c = __builtin_amdgcn_mfma_f32_16x16x32_bf16(ah[kt], bl[i][kt], c, 0, 0, 0);
      }
      const int col = nc * 128 + (wv * 2 + i) * 16 + r0;
      const float bb = bias[col];
#pragma unroll
      for (int q = 0; q < 4; ++q) {
        const int row = mtg * 16 + g * 4 + q;
        short hh, ll; split2(geluf(c[q] + bb), hh, ll);
        const size_t pk = apos(row, col, 16);
        Hh[pk] = hh; Hl[pk] = ll;
      }
    }
  }
}

__global__ __launch_bounds__(512) void bw2a_kernel(
    const short* __restrict__ Hh, const short* __restrict__ Hl,
    const short* __restrict__ Bp, const float* __restrict__ bias,
    float* __restrict__ X)
{
  const int mt0 = (int)blockIdx.x * 4;
  const int lane = (int)threadIdx.x & 63, wv = (int)threadIdx.x >> 6;  // 8 waves
  const int r0 = lane & 15, g = lane >> 4;
  short8 bh[8], bl[8];
#pragma unroll
  for (int kk = 0; kk < 8; ++kk) {
    const short* tb = Bp + (((size_t)wv * 16 + kk) << 10);
    bh[kk] = *reinterpret_cast<const short8*>(tb + lane * 8);
    bl[kk] = *reinterpret_cast<const short8*>(tb + 512 + lane * 8);
  }
#pragma unroll 2
  for (int mt = 0; mt < 4; ++mt) {
    const int mtg = mt0 + mt;
    f32x4v c = {0.f, 0.f, 0.f, 0.f};
#pragma unroll
    for (int kk = 0; kk < 8; ++kk) {
      const short8 ah = *reinterpret_cast<const short8*>(Hh + (((size_t)mtg * 16 + kk) * 64 + lane) * 8);
      const short8 al = *reinterpret_cast<const short8*>(Hl + (((size_t)mtg * 16 + kk) * 64 + lane) * 8);
      c = __builtin_amdgcn_mfma_f32_16x16x32_bf16(ah, bh[kk], c, 0, 0, 0);
      c = __builtin_amdgcn_mfma_f32_16x16x32_bf16(al, bh[kk], c, 0, 0, 0);
      c = __builtin_amdgcn_mfma_f32_16x16x32_bf16(ah, bl[kk], c, 0, 0, 0);
    }
    const int col = wv * 16 + r0;
    const float bb = bias[col];
#pragma unroll
    for (int q = 0; q < 4; ++q)
      X[(size_t)(mtg * 16 + g * 4 + q) * 128 + col] += c[q] + bb;
  }
}

__global__ __launch_bounds__(512) void bw2b_kernel(
    const short* __restrict__ Hh, const short* __restrict__ Hl,
    const short* __restrict__ Bp, const float* __restrict__ gs,
    const float* __restrict__ gb, float* __restrict__ X,
    short* __restrict__ OAh, short* __restrict__ OAl)
{
  __shared__ float red[16][8][2];
  const int mt0 = (int)blockIdx.x * 4;
  const int lane = (int)threadIdx.x & 63, wv = (int)threadIdx.x >> 6;
  const int r0 = lane & 15, g = lane >> 4;
  short8 bh[8], bl[8];
#pragma unroll
  for (int kk = 0; kk < 8; ++kk) {
    const short* tb = Bp + (((size_t)wv * 16 + 8 + kk) << 10);
    bh[kk] = *reinterpret_cast<const short8*>(tb + lane * 8);
    bl[kk] = *reinterpret_cast<const short8*>(tb + 512 + lane * 8);
  }
  for (int mt = 0; mt < 4; ++mt) {
    const int mtg = mt0 + mt;
    f32x4v c = {0.f, 0.f, 0.f, 0.f};
#pragma unroll
    for (int kk = 0; kk < 8; ++kk) {
      const short8 ah = *reinterpret_cast<const short8*>(Hh + (((size_t)mtg * 16 + 8 + kk) * 64 + lane) * 8);
      const short8 al = *reinterpret_cast<const short8*>(Hl + (((size_t)mtg * 16 + 8 + kk) * 64 + lane) * 8);
      c = __builtin_amdgcn_mfma_f32_16x16x32_bf16(ah, bh[kk], c, 0, 0, 0);
      c = __builtin_amdgcn_mfma_f32_16x16x32_bf16(al, bh[kk], c, 0, 0, 0);
      c = __builtin_amdgcn_mfma_f32_16x16x32_bf16(ah, bl[kk], c, 0, 0, 0);
    }
    const int col = wv * 16 + r0;
    float v[4], s1[4], s2[4];
#pragma unroll
    for (int q = 0; q < 4; ++q) {
      const int row = mtg * 16 + g * 4 + q;
      v[q] = c[q] + X[(size_t)row * 128 + col];
      s1[q] = v[q]; s2[q] = v[q] * v[q];
    }
#pragma unroll
    for (int o = 1; o < 16; o <<= 1)
#pragma unroll
      for (int q = 0; q < 4; ++q) { s1[q] += __shfl_xor(s1[q], o); s2[q] += __shfl_xor(s2[q], o); }
    if (r0 == 0)
#pragma unroll
      for (int q = 0; q < 4; ++q) { red[g * 4 + q][wv][0] = s1[q]; red[g * 4 + q][wv][1] = s2[q]; }
    __syncthreads();
#pragma unroll
    for (int q = 0; q < 4; ++q) {
      const int r = g * 4 + q;
      float t1 = 0.f, t2 = 0.f;
#pragma unroll
      for (int w = 0; w < 8; ++w) { t1 += red[r][w][0]; t2 += red[r][w][1]; }
      const float m  = t1 * (1.f / 128.f);
      const float rs = rsqrtf(t2 * (1.f / 128.f) - m * m + 1e-5f);
      const int row = mtg * 16 + r;
      const float o = (v[q] - m) * rs * gs[col] + gb[col];
      X[(size_t)row * 128 + col] = o;     // post-LN
      short hh, ll; split2(o, hh, ll);
      const size_t pk = apos(row, col, 4);
      OAh[pk] = hh; OAl[pk] = ll;
    }
    __syncthreads();
  }
}

__global__ __launch_bounds__(256) void bintent_kernel(
    const float* __restrict__ X, const float* __restrict__ lnf_s,
    const float* __restrict__ lnf_b, float* __restrict__ intent)
{
  const int w = (int)threadIdx.x >> 6, lane = (int)threadIdx.x & 63;
  const int b = (int)blockIdx.x * 4 + w;
  const float* xr = X + (size_t)b * LTn * 128;
  const float a0 = xr[lane], a1 = xr[lane + 64];
  float s1 = a0 + a1, s2 = a0 * a0 + a1 * a1;
#pragma unroll
  for (int o = 32; o > 0; o >>= 1) { s1 += __shfl_xor(s1, o); s2 += __shfl_xor(s2, o); }
  const float m  = s1 * (1.f / 128.f);
  const float rs = rsqrtf(s2 * (1.f / 128.f) - m * m + 1e-5f);
  intent[b * 128 + lane]      = (a0 - m) * rs * lnf_s[lane]      + lnf_b[lane];
  intent[b * 128 + lane + 64] = (a1 - m) * rs * lnf_s[lane + 64] + lnf_b[lane + 64];
}

// ---------------------------------------------------------------------------
struct RouterP {
  const float* state; const float* intent;
  const float* se_W1; const float* se_b1; const float* se_W2; const float* se_b2;
  const float* se_ln_s; const float* se_ln_b;
  const float* r_W1; const float* r_b1; const float* r_W2; const float* r_b2;
  const float* r_ln_s; const float* r_ln_b;
  const float* gate_W; const float* gate_b;
  int* ridx; float* rwgt;
};

DEVI void ln128(float* x, const float* gs, const float* gb, float* red)
{
  const int c = (int)threadIdx.x;      // blockDim == 128
  const float a = x[c];
  float s1 = a, s2 = a * a;
#pragma unroll
  for (int o = 32; o > 0; o >>= 1) { s1 += __shfl_xor(s1, o); s2 += __shfl_xor(s2, o); }
  const int wid = c >> 6;
  if ((c & 63) == 0) { red[wid * 2] = s1; red[wid * 2 + 1] = s2; }
  __syncthreads();
  s1 = red[0] + red[2]; s2 = red[1] + red[3];
  const float m  = s1 * (1.f / 128.f);
  const float rs = rsqrtf(s2 * (1.f / 128.f) - m * m + 1e-5f);
  __syncthreads();
  x[c] = (a - m) * rs * gs[c] + gb[c];
}

// 128-deep dot with 4 independent accumulator chains (latency fix)
DEVI float dot128i(const float* __restrict__ h, const float* __restrict__ W,
                   const int c, const int wstr)
{
  float a0 = 0.f, a1 = 0.f, a2 = 0.f, a3 = 0.f;
#pragma unroll 8
  for (int k = 0; k < 128; k += 4) {
    a0 = fmaf(h[k + 0], W[(k + 0) * wstr + c], a0);
    a1 = fmaf(h[k + 1], W[(k + 1) * wstr + c], a1);
    a2 = fmaf(h[k + 2], W[(k + 2) * wstr + c], a2);
    a3 = fmaf(h[k + 3], W[(k + 3) * wstr + c], a3);
  }
  return (a0 + a1) + (a2 + a3);
}

__global__ __launch_bounds__(128) void router_kernel(RouterP p)
{
  __shared__ float sstate[SDn];
  __shared__ float h1[Dn];
  __shared__ float vv[Dn];
  __shared__ float red[4];
  __shared__ float slog[En];
  const int b = blockIdx.x;
  const int c = (int)threadIdx.x;

  if (c < SDn) sstate[c] = p.state[b * SDn + c];
  __syncthreads();
  {
    float acc = p.se_b1[c];
#pragma unroll
    for (int k = 0; k < SDn; ++k) acc = fmaf(sstate[k], p.se_W1[k * Dn + c], acc);
    h1[c] = geluf(acc);
  }
  __syncthreads();
  vv[c] = p.se_b2[c] + dot128i(h1, p.se_W2, c, Dn);
  __syncthreads();
  ln128(vv, p.se_ln_s, p.se_ln_b, red);
  __syncthreads();
  {
    const float* ib = p.intent + b * Dn;
    float acc = p.r_b1[c] + dot128i(ib, p.r_W1, c, Dn)
                          + dot128i(vv, p.r_W1 + Dn * Dn, c, Dn);
    h1[c] = geluf(acc);
  }
  __syncthreads();
  vv[c] = p.r_b2[c] + dot128i(h1, p.r_W2, c, Dn);
  __syncthreads();
  ln128(vv, p.r_ln_s, p.r_ln_b, red);
  __syncthreads();
  if (c < En) slog[c] = p.gate_b[c] + dot128i(vv, p.gate_W, c, En);
  __syncthreads();
  if (c == 0) {
    int i0 = 0; float v0 = slog[0];
#pragma unroll
    for (int e2 = 1; e2 < En; ++e2) if (slog[e2] > v0) { v0 = slog[e2]; i0 = e2; }
    int i1 = -1; float v1 = -3.4e38f;
#pragma unroll
    for (int e2 = 0; e2 < En; ++e2) if (e2 != i0 && slog[e2] > v1) { v1 = slog[e2]; i1 = e2; }
    const float e1  = expf(v1 - v0);
    const float inv = 1.f / (1.f + e1);
    p.ridx[b * 2 + 0] = i0; p.ridx[b * 2 + 1] = i1;
    p.rwgt[b * 2 + 0] = inv; p.rwgt[b * 2 + 1] = e1 * inv;
  }
}

// ===========================================================================
// EXPERT PHASE PIPELINE — norm_first: X keeps RAW residual, packed A gets LN
// ===========================================================================

__global__ void sched_kernel(const int* __restrict__ ridx, int* __restrict__ sch,
                             int* plist, int* prow, int* pexp, int* ppos)
{
  __shared__ int scnt[En], scur[En], soff[En], srb[En + 1];
  const int t = (int)threadIdx.x;
  if (t < En) { scnt[t] = 0; scur[t] = 0; }
  __syncthreads();
  for (int p = t; p < PAIRS; p += 256) atomicAdd(&scnt[ridx[p]], 1);
  __syncthreads();
  if (t == 0) {
    int off = 0, rb = 0, k = 0;
    for (int e = 0; e < En; ++e) {
      soff[e] = off; srb[e] = rb;
      const int rows = scnt[e] * 20;
      const int nb = (rows + 127) >> 7;
      for (int q = 0; q < nb; ++q) {
        sch[GEXP_OFF + k] = e;
        sch[GMT_OFF + k]  = (rb >> 4) + q * 8;
        ++k;
      }
      off += scnt[e];
      rb += nb * 128;
    }
    srb[En] = rb;
    sch[0] = k;
    for (int e = 0; e < En; ++e) { sch[1 + e] = scnt[e]; sch[7 + e] = soff[e]; }
    for (int e = 0; e <= En; ++e) sch[13 + e] = srb[e];
  }
  __syncthreads();
  for (int p = t; p < PAIRS; p += 256) {
    const int e = ridx[p];
    const int pos = atomicAdd(&scur[e], 1);
    const int i = soff[e] + pos;
    plist[i] = p; ppos[p] = i; pexp[i] = e; prow[i] = srb[e] + pos * 20;
  }
}

__global__ void xinit_kernel(const float* __restrict__ qpe, const int* __restrict__ sch,
                             float* __restrict__ X)
{
  const int idx = (int)blockIdx.x * 256 + (int)threadIdx.x;  // quad index
  const int row = idx >> 5;
  if (row >= MPMAX) return;
  const int c4 = (idx & 31) * 4;
  const int* RB = sch + 13;
  float4 v = {0.f, 0.f, 0.f, 0.f};
  int e = 0;
  while (e < En && row >= RB[e + 1]) ++e;
  if (e < En) {
    const int local = row - RB[e];
    if (local < sch[1 + e] * 20) {
      const int r = local - (local / 20) * 20;
      v = *reinterpret_cast<const float4*>(qpe + r * 128 + c4);
    }
  }
  *reinterpret_cast<float4*>(X + (size_t)row * 128 + c4) = v;
}

// LN over X rows -> packed bf16 A-fragments (used once, layer-0 sub-0)
__global__ __launch_bounds__(256) void ln_pack_kernel(
    const float* __restrict__ X, short* __restrict__ XnP,
    const float* __restrict__ lns_all, const float* __restrict__ lnb_all,
    const int subOff, const int* __restrict__ sch)
{
  const int* RB = sch + 13;
  const int mt = (int)blockIdx.x;
  const int row0 = mt << 4;
  if (row0 >= RB[En]) return;
  int e = 0;
  while (e < En - 1 && row0 >= RB[e + 1]) ++e;
  const float* gs = lns_all + e * (NLDn * 3 * 128) + subOff;
  const float* gb = lnb_all + e * (NLDn * 3 * 128) + subOff;
  const int t = (int)threadIdx.x;
  const int rl = t >> 4, j = t & 15;
  const int row = row0 + rl;
  float x[8];
  {
    const float4 a = *reinterpret_cast<const float4*>(X + (size_t)row * 128 + j * 8);
    const float4 bq = *reinterpret_cast<const float4*>(X + (size_t)row * 128 + j * 8 + 4);
    x[0] = a.x; x[1] = a.y; x[2] = a.z; x[3] = a.w;
    x[4] = bq.x; x[5] = bq.y; x[6] = bq.z; x[7] = bq.w;
  }
  float s1 = 0.f, s2 = 0.f;
#pragma unroll
  for (int u = 0; u < 8; ++u) { s1 += x[u]; s2 += x[u] * x[u]; }
#pragma unroll
  for (int o = 1; o < 16; o <<= 1) { s1 += __shfl_xor(s1, o); s2 += __shfl_xor(s2, o); }
  const float m  = s1 * (1.f / 128.f);
  const float rs = rsqrtf(s2 * (1.f / 128.f) - m * m + 1e-5f);
  short8 pk;
#pragma unroll
  for (int u = 0; u < 8; ++u)
    pk[u] = f2bf((x[u] - m) * rs * gs[j * 8 + u] + gb[j * 8 + u]);
  const int kt = j >> 2, g = j & 3, lp = g * 16 + rl;
  *reinterpret_cast<short8*>(XnP + (((size_t)mt * 4 + kt) * 64 + lp) * 8) = pk;
}

// composite cross-attn K/V factors: C[li][k][c2] = sum_d sp_W[ex][k][d]*Wkv[d][c2],
// k0c[li][c2] = sp_b@Wkv + bias, k1c[li][c2] = zp_b@Wkv + bias.  grid (18), 256 thr.
__global__ __launch_bounds__(256) void compose_kernel(
    const float* __restrict__ sp_W, const float* __restrict__ sp_b,
    const float* __restrict__ zp_b, const float* __restrict__ aW,
    const float* __restrict__ ab,
    float* __restrict__ C, float* __restrict__ k0c, float* __restrict__ k1c)
{
  const int li = (int)blockIdx.x;          // ex*NLDn + l
  const int ex = li / NLDn;
  const int c2 = (int)threadIdx.x;         // 0..255
  const float* W   = aW + (size_t)(li * 2 + 1) * Dn * 384 + Dn;  // k,v columns
  const float* bb  = ab + (size_t)(li * 2 + 1) * 384 + Dn;
  const float* spw = sp_W + ex * SDn * Dn;
  const float* spb = sp_b + ex * Dn;
  const float* zpb = zp_b + ex * Dn;
  float acc[SDn];
#pragma unroll
  for (int k = 0; k < SDn; ++k) acc[k] = 0.f;
  float a0 = 0.f, a1 = 0.f;
  for (int d = 0; d < Dn; ++d) {
    const float w = W[(size_t)d * 384 + c2];
#pragma unroll
    for (int k = 0; k < SDn; ++k) acc[k] = fmaf(spw[k * Dn + d], w, acc[k]);
    a0 = fmaf(spb[d], w, a0);
    a1 = fmaf(zpb[d], w, a1);
  }
#pragma unroll
  for (int k = 0; k < SDn; ++k) C[((size_t)li * SDn + k) * 256 + c2] = acc[k];
  k0c[li * 256 + c2] = bb[c2] + a0;
  k1c[li * 256 + c2] = bb[c2] + a1;
}

// grouped GEMM, K=128 (packed A, 4 k-tiles).
// EPI 0: store bf16 row-major (stride obstr)   [QKV / cross-Q]
// EPI 3: relu -> packed bf16 KT=8              [FFN W1 halves]
// EPI 4: fused norm_first epilogue: v = c + bias + X; X = v (RAW);
//        packed A = LN(v) with (lnsA,lnbA,subOff)           [O-proj]
template<int NTW, int EPI, bool HASB>
__global__ __launch_bounds__(256) void gemm_k128(
    const short* __restrict__ A, const short* __restrict__ Bb, const int strideB,
    const float* __restrict__ biasb, const int strideBias, const int ntOff,
    short* __restrict__ OutBf, const int obstr, short* __restrict__ OutP,
    const float* __restrict__ lnsA, const float* __restrict__ lnbA, const int subOff,
    float* __restrict__ X, const int* __restrict__ sch)
{
  __shared__ float red[16][4][2];
  const int k = (int)blockIdx.x;
  if (k >= sch[0]) return;
  const int ex  = sch[GEXP_OFF + k];
  const int mt0 = sch[GMT_OFF + k];
  const short* Bp = Bb + (size_t)ex * strideB;
  const float* bias = biasb + (size_t)ex * strideBias;
  const float* gs = (EPI == 4) ? lnsA + ex * (NLDn * 3 * 128) + subOff : nullptr;
  const float* gb = (EPI == 4) ? lnbA + ex * (NLDn * 3 * 128) + subOff : nullptr;
  const int lane = (int)threadIdx.x & 63, wv = (int)threadIdx.x >> 6;
  const int r0 = lane & 15, g = lane >> 4;
  short8 bf[NTW][4];
#pragma unroll
  for (int i = 0; i < NTW; ++i)
#pragma unroll
    for (int kt = 0; kt < 4; ++kt)
      bf[i][kt] = *reinterpret_cast<const short8*>(
          Bp + (((size_t)(ntOff + wv * NTW + i) * 4 + kt) * 64 + lane) * 8);
  for (int mt = 0; mt < 8; ++mt) {
    short8 a[4];
#pragma unroll
    for (int kt = 0; kt < 4; ++kt)
      a[kt] = *reinterpret_cast<const short8*>(
          A + (((size_t)(mt0 + mt) * 4 + kt) * 64 + lane) * 8);
    float v[NTW][4];
#pragma unroll
    for (int i = 0; i < NTW; ++i) {
      f32x4v c = {0.f, 0.f, 0.f, 0.f};
#pragma unroll
      for (int kt = 0; kt < 4; ++kt)
        c = __builtin_amdgcn_mfma_f32_16x16x32_bf16(a[kt], bf[i][kt], c, 0, 0, 0);
      const int colL = (wv * NTW + i) * 16 + r0;
      const float bb = HASB ? bias[colL] : 0.f;
      const int rowB = (mt0 + mt) * 16 + g * 4;
#pragma unroll
      for (int q = 0; q < 4; ++q) {
        const int row = rowB + q;
        const float val = c[q] + bb;
        if (EPI == 0) {
          OutBf[(size_t)row * obstr + colL] = f2bf(val);
        } else if (EPI == 3) {
          const float rv = fmaxf(val, 0.f);
          const int j = colL >> 3, kt2 = j >> 2, g2 = j & 3;
          const int lp = g2 * 16 + (row & 15);
          OutP[(((size_t)(row >> 4) * 8 + kt2) * 64 + lp) * 8 + (colL & 7)] = f2bf(rv);
        } else {
          v[i][q] = val + X[(size_t)row * 128 + colL];
        }
      }
    }
    if (EPI == 4) {
      static_assert(EPI != 4 || NTW == 2, "fused LN requires NTW==2");
      float s1[4], s2[4];
#pragma unroll
      for (int q = 0; q < 4; ++q) {
        s1[q] = v[0][q] + v[1][q];
        s2[q] = v[0][q] * v[0][q] + v[1][q] * v[1][q];
      }
#pragma unroll
      for (int o = 1; o < 16; o <<= 1)
#pragma unroll
        for (int q = 0; q < 4; ++q) { s1[q] += __shfl_xor(s1[q], o); s2[q] += __shfl_xor(s2[q], o); }
      if (r0 == 0)
#pragma unroll
        for (int q = 0; q < 4; ++q) { red[g * 4 + q][wv][0] = s1[q]; red[g * 4 + q][wv][1] = s2[q]; }
      __syncthreads();
#pragma unroll
      for (int q = 0; q < 4; ++q) {
        const int r = g * 4 + q;
        const float t1 = red[r][0][0] + red[r][1][0] + red[r][2][0] + red[r][3][0];
        const float t2 = red[r][0][1] + red[r][1][1] + red[r][2][1] + red[r][3][1];
        const float m  = t1 * (1.f / 128.f);
        const float rs = rsqrtf(t2 * (1.f / 128.f) - m * m + 1e-5f);
        const int row = (mt0 + mt) * 16 + r;
#pragma unroll
        for (int i = 0; i < 2; ++i) {
          const int col = (wv * 2 + i) * 16 + r0;
          const float o = (v[i][q] - m) * rs * gs[col] + gb[col];
          X[(size_t)row * 128 + col] = v[i][q];   // norm_first: RAW residual
          OutP[apos(row, col, 4)] = f2bf(o);      // LN'd input for next phase
        }
      }
      __syncthreads();
    }
  }
}

// grouped GEMM, K=256 half of 512 (packed A: 8 k-tiles).
// DOLN=false: X += c (+bias).
// DOLN=true : v = X + c; X = v (RAW); packed A = LN(v) with subOff.
template<bool HASB, bool DOLN>
__global__ __launch_bounds__(256) void gemm_k256(
    const short* __restrict__ A, const short* __restrict__ Bb, const int strideB,
    const float* __restrict__ biasb, const int strideBias, const int ktOff,
    float* __restrict__ X, short* __restrict__ OutP,
    const float* __restrict__ lnsA, const float* __restrict__ lnbA, const int subOff,
    const int* __restrict__ sch)
{
  __shared__ float red[16][4][2];
  const int k = (int)blockIdx.x;
  if (k >= sch[0]) return;
  const int ex  = sch[GEXP_OFF + k];
  const int mt0 = sch[GMT_OFF + k];
  const short* Bp = Bb + (size_t)ex * strideB;
  const float* bias = biasb + (size_t)ex * strideBias;
  const float* gs = DOLN ? lnsA + ex * (NLDn * 3 * 128) + subOff : nullptr;
  const float* gb = DOLN ? lnbA + ex * (NLDn * 3 * 128) + subOff : nullptr;
  const int lane = (int)threadIdx.x & 63, wv = (int)threadIdx.x >> 6;
  const int r0 = lane & 15, g = lane >> 4;
  short8 bf[2][8];
#pragma unroll
  for (int i = 0; i < 2; ++i)
#pragma unroll
    for (int kk = 0; kk < 8; ++kk)
      bf[i][kk] = *reinterpret_cast<const short8*>(
          Bp + (((size_t)(wv * 2 + i) * 16 + ktOff + kk) * 64 + lane) * 8);
  for (int mt = 0; mt < 8; ++mt) {
    short8 a[8];
#pragma unroll
    for (int kk = 0; kk < 8; ++kk)
      a[kk] = *reinterpret_cast<const short8*>(
          A + (((size_t)(mt0 + mt) * 8 + kk) * 64 + lane) * 8);
    float v[2][4];
#pragma unroll
    for (int i = 0; i < 2; ++i) {
      f32x4v c = {0.f, 0.f, 0.f, 0.f};
#pragma unroll
      for (int kk = 0; kk < 8; ++kk)
        c = __builtin_amdgcn_mfma_f32_16x16x32_bf16(a[kk], bf[i][kk], c, 0, 0, 0);
      const int colL = (wv * 2 + i) * 16 + r0;
      const float bb = HASB ? bias[colL] : 0.f;
      const int rowB = (mt0 + mt) * 16 + g * 4;
#pragma unroll
      for (int q = 0; q < 4; ++q) {
        const int row = rowB + q;
        if (DOLN) v[i][q] = c[q] + bb + X[(size_t)row * 128 + colL];
        else      X[(size_t)row * 128 + colL] += c[q] + bb;
      }
    }
    if (DOLN) {
      float s1[4], s2[4];
#pragma unroll
      for (int q = 0; q < 4; ++q) {
        s1[q] = v[0][q] + v[1][q];
        s2[q] = v[0][q] * v[0][q] + v[1][q] * v[1][q];
      }
#pragma unroll
      for (int o = 1; o < 16; o <<= 1)
#pragma unroll
        for (int q = 0; q < 4; ++q) { s1[q] += __shfl_xor(s1[q], o); s2[q] += __shfl_xor(s2[q], o); }
      if (r0 == 0)
#pragma unroll
        for (int q = 0; q < 4; ++q) { red[g * 4 + q][wv][0] = s1[q]; red[g * 4 + q][wv][1] = s2[q]; }
      __syncthreads();
#pragma unroll
      for (int q = 0; q < 4; ++q) {
        const int r = g * 4 + q;
        const float t1 = red[r][0][0] + red[r][1][0] + red[r][2][0] + red[r][3][0];
        const float t2 = red[r][0][1] + red[r][1][1] + red[r][2][1] + red[r][3][1];
        const float m  = t1 * (1.f / 128.f);
        const float rs = rsqrtf(t2 * (1.f / 128.f) - m * m + 1e-5f);
        const int row = (mt0 + mt) * 16 + r;
#pragma unroll
        for (int i = 0; i < 2; ++i) {
          const int col = (wv * 2 + i) * 16 + r0;
          const float o = (v[i][q] - m) * rs * gs[col] + gb[col];
          X[(size_t)row * 128 + col] = v[i][q];   // norm_first: RAW residual
          OutP[apos(row, col, 4)] = f2bf(o);      // LN'd input for next layer
        }
      }
      __syncthreads();
    }
  }
}

// per (pair, head) self-attention: QKV bf16 (stride 384) -> O packed bf16.
// grid (4096, 4), 64 threads (1 wave).
__global__ __launch_bounds__(64) void sattn_kernel(
    const short* __restrict__ QKVb, const int* __restrict__ prow,
    short* __restrict__ ANP)
{
  __shared__ float qs[CSn * HSTR], ks[CSn * HSTR], vs[CSn * HSTR];
  __shared__ float att[CSn * CSn];
  const int i = (int)blockIdx.x, h = (int)blockIdx.y;
  const int tid = (int)threadIdx.x;
  const int row0 = prow[i];
  for (int u = tid; u < CSn * 12; u += 64) {
    const int il = u / 12, r = u % 12, which = r >> 2, d8 = r & 3;
    const short8 s = *reinterpret_cast<const short8*>(
        QKVb + (size_t)(row0 + il) * 384 + which * 128 + h * 32 + d8 * 8);
    float* dst = (which == 0 ? qs : which == 1 ? ks : vs) + il * HSTR + d8 * 8;
#pragma unroll
    for (int u8 = 0; u8 < 8; ++u8) dst[u8] = bf2f(s[u8]);
  }
  __syncthreads();
  for (int e = tid; e < CSn * CSn; e += 64) {
    const int ii = e / CSn, j = e % CSn;
    const float* qp = qs + ii * HSTR;
    const float* kp = ks + j * HSTR;
    float acc = 0.f;
#pragma unroll
    for (int d = 0; d < DHn; d += 4) {
      const float4 qa = *reinterpret_cast<const float4*>(qp + d);
      const float4 kb = *reinterpret_cast<const float4*>(kp + d);
      acc += qa.x * kb.x + qa.y * kb.y + qa.z * kb.z + qa.w * kb.w;
    }
    att[e] = acc * INV_SQRT_DH;
  }
  __syncthreads();
  if (tid < CSn) {
    float* row = att + tid * CSn;
    float m = row[0];
#pragma unroll 4
    for (int j = 1; j < CSn; ++j) m = fmaxf(m, row[j]);
    float s = 0.f;
#pragma unroll 4
    for (int j = 0; j < CSn; ++j) { const float ex = expf(row[j] - m); row[j] = ex; s += ex; }
    const float inv = 1.f / s;
#pragma unroll 4
    for (int j = 0; j < CSn; ++j) row[j] *= inv;
  }
  __syncthreads();
  for (int e = tid; e < CSn * 32; e += 64) {
    const int ii = e >> 5, c = e & 31;
    const float* arow = att + ii * CSn;
    float acc = 0.f;
#pragma unroll 4
    for (int j = 0; j < CSn; ++j) acc = fmaf(arow[j], vs[j * HSTR + c], acc);
    ANP[apos(row0 + ii, h * 32 + c, 4)] = f2bf(acc);
  }
}

// per-pair cross-attention (2 keys): Qc bf16 (stride 128) + composite memkv
__global__ __launch_bounds__(256) void cattn_kernel(
    const short* __restrict__ Qb, const float* __restrict__ state,
    const float* __restrict__ C, const float* __restrict__ k0c,
    const float* __restrict__ k1c, const int layer,
    const int* __restrict__ plist, const int* __restrict__ prow,
    const int* __restrict__ pexp, short* __restrict__ ANP)
{
  __shared__ float q[CSn * Dn];
  __shared__ float memkv[2 * 256];
  __shared__ float catt[2 * Hn * CSn];
  __shared__ float st[SDn];
  const int i = (int)blockIdx.x;
  const int ex = pexp[i];
  const int b = plist[i] >> 1;
  const int li = ex * NLDn + layer;
  const int row0 = prow[i];
  const int tid = (int)threadIdx.x;

  if (tid < SDn) st[tid] = state[b * SDn + tid];
  for (int e8 = tid; e8 < CSn * 16; e8 += 256) {
    const int il = e8 >> 4, c8 = e8 & 15;
    const short8 s = *reinterpret_cast<const short8*>(
        Qb + (size_t)(row0 + il) * 128 + c8 * 8);
    float* dst = q + il * Dn + c8 * 8;
#pragma unroll
    for (int u = 0; u < 8; ++u) dst[u] = bf2f(s[u]);
  }
  __syncthreads();
  {
    const int c2 = tid;                       // 256 threads, one column each
    float acc = k0c[li * 256 + c2];
#pragma unroll
    for (int k = 0; k < SDn; ++k)
      acc = fmaf(st[k], C[((size_t)li * SDn + k) * 256 + c2], acc);
    memkv[c2] = acc;
    memkv[256 + c2] = k1c[li * 256 + c2];
  }
  __syncthreads();
  for (int e = tid; e < Hn * CSn; e += 256) {
    const int h = e / CSn, il = e % CSn;
    const float* qp = q + il * Dn + h * DHn;
    float s0 = 0.f, s1 = 0.f;
#pragma unroll
    for (int d = 0; d < DHn; d += 4) {
      const float4 q4 = *reinterpret_cast<const float4*>(qp + d);
      const float4 k0 = *reinterpret_cast<const float4*>(memkv + 0 * 256 + h * DHn + d);
      const float4 k1 = *reinterpret_cast<const float4*>(memkv + 1 * 256 + h * DHn + d);
      s0 += q4.x * k0.x + q4.y * k0.y + q4.z * k0.z + q4.w * k0.w;
      s1 += q4.x * k1.x + q4.y * k1.y + q4.z * k1.z + q4.w * k1.w;
    }
    s0 *= INV_SQRT_DH; s1 *= INV_SQRT_DH;
    const float m = fmaxf(s0, s1);
    const float e0 = expf(s0 - m), e1 = expf(s1 - m);
    const float inv = 1.f / (e0 + e1);
    catt[e * 2] = e0 * inv; catt[e * 2 + 1] = e1 * inv;
  }
  __syncthreads();
  for (int e = tid; e < CSn * Dn; e += 256) {
    const int il = e >> 7, c = e & 127, h = c >> 5;
    const int a = (h * CSn + il) * 2;
    const float v = catt[a]     * memkv[0 * 256 + Dn + c]
                  + catt[a + 1] * memkv[1 * 256 + Dn + c];
    ANP[apos(row0 + il, c, 4)] = f2bf(v);
  }
}

__global__ __launch_bounds__(256) void head_kernel(
    const float* __restrict__ X, const int* __restrict__ plist,
    const int* __restrict__ prow, const int* __restrict__ pexp,
    const float* __restrict__ rwgt, const float* __restrict__ hW,
    const float* __restrict__ hb, float* __restrict__ Rbuf)
{
  __shared__ float xr[CSn * Dn];
  const int i = (int)blockIdx.x;
  const int ex = pexp[i];
  const int orig = plist[i];
  const int row0 = prow[i];
  const float wgt = rwgt[orig];
  for (int e4 = (int)threadIdx.x; e4 < CSn * 32; e4 += 256) {
    const int il = e4 >> 5, c4 = (e4 & 31) * 4;
    *reinterpret_cast<float4*>(xr + il * Dn + c4) =
        *reinterpret_cast<const float4*>(X + (size_t)(row0 + il) * 128 + c4);
  }
  __syncthreads();
  const int e = (int)threadIdx.x;
  if (e < CSn * JDn) {
    const int t = e / JDn, j = e - t * JDn;
    const float* w = hW + ex * Dn * JDn + j;
    float acc = hb[ex * JDn + j];
#pragma unroll 4
    for (int kk = 0; kk < Dn; ++kk) acc = fmaf(xr[t * Dn + kk], w[kk * JDn], acc);
    Rbuf[(size_t)i * 140 + e] = wgt * acc;
  }
}

__global__ void combine_kernel(const float* __restrict__ Rbuf,
                               const int* __restrict__ ppos, float* __restrict__ out)
{
  const int idx = (int)blockIdx.x * 256 + (int)threadIdx.x;
  if (idx >= Bn * 140) return;
  const int b = idx / 140, e = idx - b * 140;
  out[idx] = Rbuf[(size_t)ppos[2 * b] * 140 + e] + Rbuf[(size_t)ppos[2 * b + 1] * 140 + e];
}

// ---------------------------------------------------------------------------
__global__ void qpe_kernel(float* qpe)
{
  const int e = (int)blockIdx.x * 256 + (int)threadIdx.x;
  if (e < CSn * Dn) {
    const int t = e >> 7, d = e & 127;
    const float j  = (float)(d & ~1);
    const float dv = expf(j * (-logf(10000.f) / 128.f));
    const float a  = (float)t * dv;
    qpe[e] = (d & 1) ? cosf(a) : sinf(a);
  }
}

} // namespace

// ---------------------------------------------------------------------------
extern "C" void kernel_launch(void* const* d_in, const int* in_sizes, int n_in,
                              void* d_out, int out_size, void* d_ws, size_t ws_size,
                              hipStream_t stream)
{
  (void)in_sizes; (void)n_in; (void)out_size;

  const int*   ids     = (const int*)  d_in[0];
  const float* state   = (const float*)d_in[1];
  const float* tok_emb = (const float*)d_in[2];
  const float* pos_emb = (const float*)d_in[3];

  // persistent workspace (256B-aligned cursor)
  char* cur = (char*)d_ws;
  auto alloc = [&cur](size_t bytes) -> char* {
    char* p = cur; cur += (bytes + 255) & ~(size_t)255; return p;
  };
  float* qpe    = (float*)alloc(4096 * 4);
  float* intent = (float*)alloc((size_t)Bn * Dn * 4);
  int*   ridx   = (int*)  alloc(PAIRS * 4);
  float* rwgt   = (float*)alloc(PAIRS * 4);
  short* pQ     = (short*)alloc((size_t)36 * 49152 * 2);   // expert packs (single bf16)
  short* pO     = (short*)alloc((size_t)36 * 16384 * 2);
  short* pF1    = (short*)alloc((size_t)18 * 65536 * 2);
  short* pF2    = (short*)alloc((size_t)18 * 65536 * 2);
  short* pbQ    = (short*)alloc((size_t)4 * 98304 * 2);    // BERT packs (split hi/lo)
  short* pbO    = (short*)alloc((size_t)4 * 32768 * 2);
  short* pbW1   = (short*)alloc((size_t)4 * 131072 * 2);
  short* pbW2   = (short*)alloc((size_t)4 * 131072 * 2);
  int*   sch    = (int*)  alloc(2048 * 4);
  int*   plist  = (int*)  alloc(PAIRS * 4);
  int*   prow   = (int*)  alloc(PAIRS * 4);
  int*   pexp   = (int*)  alloc(PAIRS * 4);
  int*   ppos   = (int*)  alloc(PAIRS * 4);
  float* Cmat   = (float*)alloc((size_t)18 * SDn * 256 * 4);  // 294912 B
  float* k0c    = (float*)alloc((size_t)18 * 256 * 4);
  float* k1c    = (float*)alloc((size_t)18 * 256 * 4);
  constexpr size_t ARENA_BYTES = 192806912;
  char* arena = alloc(ARENA_BYTES);
  if ((size_t)(cur - (char*)d_ws) > ws_size) return;  // ws confirmed sufficient R4-R8

  // BERT views
  float* Xb  = (float*)(arena);                          // 25.2 MB
  short* Ah  = (short*)(arena + 25165824);               // 12.6 MB
  short* Al  = (short*)(arena + 37748736);               // 12.6 MB
  float* SBb = (float*)(arena + 50331648);               // QKV fp32 75.5 MB
  short* Hh  = (short*)(arena + 50331648);               // aliases SBb (sequential use)
  short* Hl  = (short*)(arena + 100663296);              // 50.3 MB
  // expert views
  float* X2   = (float*)(arena);                         // 42.3 MB
  short* ANP  = (short*)(arena + 42336256);              // 21.2 MB
  short* SBh  = (short*)(arena + 63504384);              // bf16 QKV/Qc/HP (<=63.5 MB)
  float* Rbuf = (float*)(arena + 190513152);             // 2.3 MB

  qpe_kernel<<<dim3(10), dim3(256), 0, stream>>>(qpe);

  // ---- weight packing + composite cross-attn factors
  {
    const int tq = 36 * 6144;
    pack_kernel<<<dim3((tq + 255) / 256), dim3(256), 0, stream>>>(
        (const float*)d_in[34], pQ, 128, 384, tq);
    const int to = 36 * 2048;
    pack_kernel<<<dim3((to + 255) / 256), dim3(256), 0, stream>>>(
        (const float*)d_in[36], pO, 128, 128, to);
    const int t1c = 18 * 8192;
    pack_kernel<<<dim3((t1c + 255) / 256), dim3(256), 0, stream>>>(
        (const float*)d_in[40], pF1, 128, 512, t1c);
    const int t2c = 18 * 8192;
    pack_kernel<<<dim3((t2c + 255) / 256), dim3(256), 0, stream>>>(
        (const float*)d_in[42], pF2, 512, 128, t2c);
    const int bq = 4 * 6144;
    pack2_kernel<<<dim3((bq + 255) / 256), dim3(256), 0, stream>>>(
        (const float*)d_in[4], pbQ, 128, 384, bq);
    const int bo = 4 * 2048;
    pack2_kernel<<<dim3((bo + 255) / 256), dim3(256), 0, stream>>>(
        (const float*)d_in[6], pbO, 128, 128, bo);
    const int bw1 = 4 * 8192;
    pack2_kernel<<<dim3((bw1 + 255) / 256), dim3(256), 0, stream>>>(
        (const float*)d_in[8], pbW1, 128, 512, bw1);
    const int bw2 = 4 * 8192;
    pack2_kernel<<<dim3((bw2 + 255) / 256), dim3(256), 0, stream>>>(
        (const float*)d_in[10], pbW2, 512, 128, bw2);
    compose_kernel<<<dim3(En * NLDn), dim3(256), 0, stream>>>(
        (const float*)d_in[30], (const float*)d_in[31], (const float*)d_in[33],
        (const float*)d_in[34], (const float*)d_in[35], Cmat, k0c, k1c);
  }

  // ---- BERT phase pipeline
  {
    const float* bq  = (const float*)d_in[5];
    const float* bo  = (const float*)d_in[7];
    const float* b1  = (const float*)d_in[9];
    const float* b2  = (const float*)d_in[11];
    const float* lns = (const float*)d_in[12];
    const float* lnb = (const float*)d_in[13];

    bembed_kernel<<<dim3(ROWSB / 16), dim3(256), 0, stream>>>(
        ids, tok_emb, pos_emb, Xb, Ah, Al);
    for (int l = 0; l < NLBn; ++l) {
      bqkv_kernel<<<dim3(ROWSB / 64, 3), dim3(256), 0, stream>>>(
          Ah, Al, pbQ + (size_t)l * 98304, bq + l * 384, SBb);
      battn_kernel<<<dim3(Bn, Hn), dim3(64), 0, stream>>>(SBb, ids, Ah, Al);
      bo_ln_kernel<<<dim3(ROWSB / 64), dim3(256), 0, stream>>>(
          Ah, Al, pbO + (size_t)l * 32768, bo + l * 128,
          lns + l * 256, lnb + l * 256, Xb, Ah, Al);
      bw1_kernel<<<dim3(ROWSB / 64, 4), dim3(256), 0, stream>>>(
          Ah, Al, pbW1 + (size_t)l * 131072, b1 + l * 512, Hh, Hl);
      bw2a_kernel<<<dim3(ROWSB / 64), dim3(512), 0, stream>>>(
          Hh, Hl, pbW2 + (size_t)l * 131072, b2 + l * 128, Xb);
      bw2b_kernel<<<dim3(ROWSB / 64), dim3(512), 0, stream>>>(
          Hh, Hl, pbW2 + (size_t)l * 131072,
          lns + l * 256 + 128, lnb + l * 256 + 128, Xb, Ah, Al);
    }
    bintent_kernel<<<dim3(Bn / 4), dim3(256), 0, stream>>>(
        Xb, (const float*)d_in[14], (const float*)d_in[15], intent);
  }

  // ---- router
  {
    RouterP rp;
    rp.state = state; rp.intent = intent;
    rp.se_W1 = (const float*)d_in[16]; rp.se_b1 = (const float*)d_in[17];
    rp.se_W2 = (const float*)d_in[18]; rp.se_b2 = (const float*)d_in[19];
    rp.se_ln_s = (const float*)d_in[20]; rp.se_ln_b = (const float*)d_in[21];
    rp.r_W1 = (const float*)d_in[22]; rp.r_b1 = (const float*)d_in[23];
    rp.r_W2 = (const float*)d_in[24]; rp.r_b2 = (const float*)d_in[25];
    rp.r_ln_s = (const float*)d_in[26]; rp.r_ln_b = (const float*)d_in[27];
    rp.gate_W = (const float*)d_in[28]; rp.gate_b = (const float*)d_in[29];
    rp.ridx = ridx; rp.rwgt = rwgt;
    router_kernel<<<dim3(Bn), dim3(128), 0, stream>>>(rp);
  }

  const float* ab   = (const float*)d_in[35];
  const float* abo  = (const float*)d_in[37];
  const float* lnsA = (const float*)d_in[38];
  const float* lnbA = (const float*)d_in[39];
  const float* fb1A = (const float*)d_in[41];
  const float* fb2A = (const float*)d_in[43];
  const float* hW   = (const float*)d_in[44];
  const float* hB   = (const float*)d_in[45];

  // ---- expert phase pipeline
  {
    sched_kernel<<<dim3(1), dim3(256), 0, stream>>>(ridx, sch, plist, prow, pexp, ppos);
    xinit_kernel<<<dim3(MPMAX * 32 / 256), dim3(256), 0, stream>>>(qpe, sch, X2);
    ln_pack_kernel<<<dim3(MPMAX / 16), dim3(256), 0, stream>>>(
        X2, ANP, lnsA, lnbA, 0, sch);
    short* HP = SBh;
    for (int l = 0; l < NLDn; ++l) {
      // self-attention block
      gemm_k128<6, 0, true><<<dim3(NBGMAX), dim3(256), 0, stream>>>(
          ANP, pQ + (l * 2 + 0) * 49152, 294912,
          ab + (l * 2 + 0) * 384, 2304, 0,
          SBh, 384, nullptr, nullptr, nullptr, 0, nullptr, sch);
      sattn_kernel<<<dim3(PAIRS, Hn), dim3(64), 0, stream>>>(SBh, prow, ANP);
      gemm_k128<2, 4, true><<<dim3(NBGMAX), dim3(256), 0, stream>>>(
          ANP, pO + (l * 2 + 0) * 16384, 98304,
          abo + (l * 2 + 0) * 128, 768, 0,
          nullptr, 0, ANP, lnsA, lnbA, (l * 3 + 1) * 128, X2, sch);
      // cross-attention block
      gemm_k128<2, 0, true><<<dim3(NBGMAX), dim3(256), 0, stream>>>(
          ANP, pQ + (l * 2 + 1) * 49152, 294912,
          ab + (l * 2 + 1) * 384, 2304, 0,
          SBh, 128, nullptr, nullptr, nullptr, 0, nullptr, sch);
      cattn_kernel<<<dim3(PAIRS), dim3(256), 0, stream>>>(
          SBh, state, Cmat, k0c, k1c, l, plist, prow, pexp, ANP);
      gemm_k128<2, 4, true><<<dim3(NBGMAX), dim3(256), 0, stream>>>(
          ANP, pO + (l * 2 + 1) * 16384, 98304,
          abo + (l * 2 + 1) * 128, 768, 0,
          nullptr, 0, ANP, lnsA, lnbA, (l * 3 + 2) * 128, X2, sch);
      // FFN block (two 256-col halves)
      gemm_k128<4, 3, true><<<dim3(NBGMAX), dim3(256), 0, stream>>>(
          ANP, pF1 + l * 65536, 196608,
          fb1A + l * 512 + 0 * 256, 1536, 0,
          nullptr, 0, HP, nullptr, nullptr, 0, nullptr, sch);
      gemm_k256<true, false><<<dim3(NBGMAX), dim3(256), 0, stream>>>(
          HP, pF2 + l * 65536, 196608, fb2A + l * 128, 384, 0,
          X2, nullptr, nullptr, nullptr, 0, sch);
      gemm_k128<4, 3, true><<<dim3(NBGMAX), dim3(256), 0, stream>>>(
          ANP, pF1 + l * 65536, 196608,
          fb1A + l * 512 + 1 * 256, 1536, 16,
          nullptr, 0, HP, nullptr, nullptr, 0, nullptr, sch);
      if (l < NLDn - 1) {
        gemm_k256<false, true><<<dim3(NBGMAX), dim3(256), 0, stream>>>(
            HP, pF2 + l * 65536, 196608, fb2A + l * 128, 384, 8,
            X2, ANP, lnsA, lnbA, ((l + 1) * 3 + 0) * 128, sch);
      } else {
        gemm_k256<false, false><<<dim3(NBGMAX), dim3(256), 0, stream>>>(
            HP, pF2 + l * 65536, 196608, fb2A + l * 128, 384, 8,
            X2, nullptr, nullptr, nullptr, 0, sch);
      }
    }
    head_kernel<<<dim3(PAIRS), dim3(256), 0, stream>>>(
        X2, plist, prow, pexp, rwgt, hW, hB, Rbuf);
    combine_kernel<<<dim3((Bn * 140 + 255) / 256), dim3(256), 0, stream>>>(
        Rbuf, ppos, (float*)d_out);
  }
}

// Round 10
// 1687.569 us; speedup vs baseline: 4.1391x; 1.0155x over previous
//
#include <hip/hip_runtime.h>
#include <math.h>

#define DEVI __device__ __forceinline__

namespace {

constexpr int Bn   = 2048;
constexpr int En   = 6;
constexpr int Hn   = 4;
constexpr int Dn   = 128;
constexpr int DHn  = 32;
constexpr int LTn  = 24;   // text length
constexpr int CSn  = 20;   // chunk (decoder query) length
constexpr int JDn  = 7;
constexpr int SDn  = 16;
constexpr int NLBn = 4;
constexpr int NLDn = 3;
constexpr int DFFn = 512;
constexpr float INV_SQRT_DH = 0.17677669529663687f;  // 1/sqrt(32)

// expert phase-pipeline geometry
constexpr int PAIRS  = 4096;                  // 2048 items x top-2
constexpr int MPMAX  = PAIRS * 20 + En * 128; // padded rows (per-expert 128-aligned)
constexpr int NBGMAX = PAIRS * 20 / 128 + En; // 646 grouped-GEMM blocks max
constexpr int GEXP_OFF = 64;
constexpr int GMT_OFF  = 64 + NBGMAX;

// BERT pipeline geometry
constexpr int ROWSB = Bn * LTn;               // 49152 rows, 3072 M-tiles, no padding

// per-head attention LDS stride (36 mod 32 = 4 -> conflict-light, 16B-aligned)
constexpr int HSTR = 36;

typedef float f32x4v __attribute__((ext_vector_type(4)));
typedef short short8 __attribute__((ext_vector_type(8)));

DEVI float geluf(float x) { return 0.5f * x * (1.0f + erff(x * 0.70710678118654752f)); }

DEVI short f2bf(float f) {  // fp32 -> bf16 bits, round-to-nearest-even
  unsigned u = __float_as_uint(f);
  return (short)((u + 0x7FFFu + ((u >> 16) & 1u)) >> 16);
}
DEVI float bf2f(short s) { return __uint_as_float(((unsigned)(unsigned short)s) << 16); }
DEVI void split2(float v, short& h, short& l) {  // v ~= hi + lo to ~2^-16 rel
  h = f2bf(v);
  l = f2bf(v - bf2f(h));
}

// packed-A position for (row, col), K-tile count KT
DEVI size_t apos(int row, int col, int KT) {
  return (((size_t)(row >> 4) * KT + (col >> 5)) * 64 + ((col >> 3) & 3) * 16 + (row & 15)) * 8
         + (col & 7);
}

// ---------------------------------------------------------------------------
// pack fp32 [K][N] into single-bf16 B tiles (512 shorts/tile)
__global__ void pack_kernel(const float* __restrict__ W, short* __restrict__ out,
                            const int K, const int N, const int total)
{
  const int p = (int)blockIdx.x * 256 + (int)threadIdx.x;
  if (p >= total) return;
  const int perMat = (K * N) >> 3;
  const int m = p / perMat, r = p - m * perMat;
  const int t = r >> 6, lane = r & 63;
  const int KT = K >> 5;
  const int nt = t / KT, kt = t - nt * KT;
  const int row0 = kt * 32 + (lane >> 4) * 8;
  const int col  = nt * 16 + (lane & 15);
  const float* src = W + (size_t)m * K * N;
  short8 v;
#pragma unroll
  for (int j = 0; j < 8; ++j) v[j] = f2bf(src[(size_t)(row0 + j) * N + col]);
  *reinterpret_cast<short8*>(out + (size_t)p * 8) = v;
}

// pack fp32 [K][N] into split hi/lo B tiles (1024 shorts/tile)
__global__ void pack2_kernel(const float* __restrict__ W, short* __restrict__ out,
                             const int K, const int N, const int total)
{
  const int p = (int)blockIdx.x * 256 + (int)threadIdx.x;
  if (p >= total) return;
  const int perMat = (K * N) >> 3;
  const int m = p / perMat, r = p - m * perMat;
  const int t = r >> 6, lane = r & 63;
  const int KT = K >> 5;
  const int nt = t / KT, kt = t - nt * KT;
  const int row0 = kt * 32 + (lane >> 4) * 8;
  const int col  = nt * 16 + (lane & 15);
  const float* src = W + (size_t)m * K * N;
  short8 vh, vl;
#pragma unroll
  for (int j = 0; j < 8; ++j) {
    short hh, ll;
    split2(src[(size_t)(row0 + j) * N + col], hh, ll);
    vh[j] = hh; vl[j] = ll;
  }
  const size_t T  = (size_t)(perMat >> 6);
  const size_t tg = (size_t)m * T + t;
  *reinterpret_cast<short8*>(out + tg * 1024 + lane * 8)       = vh;
  *reinterpret_cast<short8*>(out + tg * 1024 + 512 + lane * 8) = vl;
}

// ===========================================================================
// BERT phase pipeline (split-bf16, M = 49152 rows)
// ===========================================================================

__global__ __launch_bounds__(256) void bembed_kernel(
    const int* __restrict__ ids, const float* __restrict__ tok,
    const float* __restrict__ pos, float* __restrict__ X,
    short* __restrict__ Ah, short* __restrict__ Al)
{
  const int mt = (int)blockIdx.x;          // 0..3071
  const int t = (int)threadIdx.x;
  const int rl = t >> 4, j = t & 15;
  const int row = mt * 16 + rl;
  const int b = row / 24, i = row - b * 24;
  const int id = ids[b * 24 + i];
  const float* tp = tok + (size_t)id * 128 + j * 8;
  const float* pp = pos + i * 128 + j * 8;
  float x[8];
  short8 vh, vl;
#pragma unroll
  for (int u = 0; u < 8; ++u) {
    x[u] = tp[u] + pp[u];
    short hh, ll; split2(x[u], hh, ll);
    vh[u] = hh; vl[u] = ll;
  }
  float4 f0 = {x[0], x[1], x[2], x[3]}, f1 = {x[4], x[5], x[6], x[7]};
  *reinterpret_cast<float4*>(X + (size_t)row * 128 + j * 8) = f0;
  *reinterpret_cast<float4*>(X + (size_t)row * 128 + j * 8 + 4) = f1;
  const size_t pk = (((size_t)mt * 4 + (j >> 2)) * 64 + (j & 3) * 16 + rl) * 8;
  *reinterpret_cast<short8*>(Ah + pk) = vh;
  *reinterpret_cast<short8*>(Al + pk) = vl;
}

__global__ __launch_bounds__(256) void bqkv_kernel(
    const short* __restrict__ Ah, const short* __restrict__ Al,
    const short* __restrict__ Bp, const float* __restrict__ bias,
    float* __restrict__ Out)
{
  const int mt0 = (int)blockIdx.x * 4;
  const int nc  = (int)blockIdx.y;
  const int lane = (int)threadIdx.x & 63, wv = (int)threadIdx.x >> 6;
  const int r0 = lane & 15, g = lane >> 4;
  short8 bh[2][4], bl[2][4];
#pragma unroll
  for (int i = 0; i < 2; ++i)
#pragma unroll
    for (int kt = 0; kt < 4; ++kt) {
      const short* tb = Bp + (((size_t)(nc * 8 + wv * 2 + i) * 4 + kt) << 10);
      bh[i][kt] = *reinterpret_cast<const short8*>(tb + lane * 8);
      bl[i][kt] = *reinterpret_cast<const short8*>(tb + 512 + lane * 8);
    }
#pragma unroll 2
  for (int mt = 0; mt < 4; ++mt) {
    const int mtg = mt0 + mt;
    short8 ah[4], al[4];
#pragma unroll
    for (int kt = 0; kt < 4; ++kt) {
      ah[kt] = *reinterpret_cast<const short8*>(Ah + (((size_t)mtg * 4 + kt) * 64 + lane) * 8);
      al[kt] = *reinterpret_cast<const short8*>(Al + (((size_t)mtg * 4 + kt) * 64 + lane) * 8);
    }
#pragma unroll
    for (int i = 0; i < 2; ++i) {
      f32x4v c = {0.f, 0.f, 0.f, 0.f};
#pragma unroll
      for (int kt = 0; kt < 4; ++kt) {
        c = __builtin_amdgcn_mfma_f32_16x16x32_bf16(ah[kt], bh[i][kt], c, 0, 0, 0);
        c = __builtin_amdgcn_mfma_f32_16x16x32_bf16(al[kt], bh[i][kt], c, 0, 0, 0);
        c = __builtin_amdgcn_mfma_f32_16x16x32_bf16(ah[kt], bl[i][kt], c, 0, 0, 0);
      }
      const int col = nc * 128 + (wv * 2 + i) * 16 + r0;
      const float bb = bias[col];
#pragma unroll
      for (int q = 0; q < 4; ++q)
        Out[(size_t)(mtg * 16 + g * 4 + q) * 384 + col] = c[q] + bb;
    }
  }
}

// per (item, head) BERT attention: QKV fp32 -> attn out split-packed A.
// grid (2048, 4), 64 threads (1 wave).
__global__ __launch_bounds__(64) void battn_kernel(
    const float* __restrict__ QKV, const int* __restrict__ ids,
    short* __restrict__ Ah, short* __restrict__ Al)
{
  __shared__ float qs[LTn * HSTR], ks[LTn * HSTR], vs[LTn * HSTR];
  __shared__ float att[LTn * LTn];
  __shared__ int pad_s[LTn];
  const int b = (int)blockIdx.x, h = (int)blockIdx.y;
  const int tid = (int)threadIdx.x;
  const int row0 = b * LTn;
  for (int u = tid; u < LTn * 24; u += 64) {
    const int il = u / 24, r = u % 24, which = r >> 3, d4 = r & 7;
    const float4 v = *reinterpret_cast<const float4*>(
        QKV + (size_t)(row0 + il) * 384 + which * 128 + h * 32 + d4 * 4);
    float* dst = (which == 0 ? qs : which == 1 ? ks : vs) + il * HSTR + d4 * 4;
    *reinterpret_cast<float4*>(dst) = v;
  }
  if (tid < LTn) pad_s[tid] = (ids[row0 + tid] == 0) ? 1 : 0;
  __syncthreads();
  for (int e = tid; e < LTn * LTn; e += 64) {
    const int i = e / LTn, j = e % LTn;
    const float* qp = qs + i * HSTR;
    const float* kp = ks + j * HSTR;
    float acc = 0.f;
#pragma unroll
    for (int d = 0; d < DHn; d += 4) {
      const float4 qa = *reinterpret_cast<const float4*>(qp + d);
      const float4 kb = *reinterpret_cast<const float4*>(kp + d);
      acc += qa.x * kb.x + qa.y * kb.y + qa.z * kb.z + qa.w * kb.w;
    }
    acc *= INV_SQRT_DH;
    if (pad_s[j]) acc = -1e9f;
    att[e] = acc;
  }
  __syncthreads();
  if (tid < LTn) {
    float* row = att + tid * LTn;
    float m = row[0];
#pragma unroll 4
    for (int j = 1; j < LTn; ++j) m = fmaxf(m, row[j]);
    float s = 0.f;
#pragma unroll 4
    for (int j = 0; j < LTn; ++j) { const float ex = expf(row[j] - m); row[j] = ex; s += ex; }
    const float inv = 1.f / s;
#pragma unroll 4
    for (int j = 0; j < LTn; ++j) row[j] *= inv;
  }
  __syncthreads();
  for (int e = tid; e < LTn * 32; e += 64) {
    const int i = e >> 5, c = e & 31;
    const float* arow = att + i * LTn;
    float acc = 0.f;
#pragma unroll 4
    for (int j = 0; j < LTn; ++j) acc = fmaf(arow[j], vs[j * HSTR + c], acc);
    short hh, ll; split2(acc, hh, ll);
    const size_t pk = apos(row0 + i, h * 32 + c, 4);
    Ah[pk] = hh; Al[pk] = ll;
  }
}

__global__ __launch_bounds__(256) void bo_ln_kernel(
    const short* __restrict__ Ah, const short* __restrict__ Al,
    const short* __restrict__ Bp, const float* __restrict__ bo,
    const float* __restrict__ gs, const float* __restrict__ gb,
    float* __restrict__ X, short* __restrict__ OAh, short* __restrict__ OAl)
{
  __shared__ float red[16][4][2];
  const int mt0 = (int)blockIdx.x * 4;
  const int lane = (int)threadIdx.x & 63, wv = (int)threadIdx.x >> 6;
  const int r0 = lane & 15, g = lane >> 4;
  short8 bh[2][4], bl[2][4];
#pragma unroll
  for (int i = 0; i < 2; ++i)
#pragma unroll
    for (int kt = 0; kt < 4; ++kt) {
      const short* tb = Bp + (((size_t)(wv * 2 + i) * 4 + kt) << 10);
      bh[i][kt] = *reinterpret_cast<const short8*>(tb + lane * 8);
      bl[i][kt] = *reinterpret_cast<const short8*>(tb + 512 + lane * 8);
    }
  for (int mt = 0; mt < 4; ++mt) {
    const int mtg = mt0 + mt;
    short8 ah[4], al[4];
#pragma unroll
    for (int kt = 0; kt < 4; ++kt) {
      ah[kt] = *reinterpret_cast<const short8*>(Ah + (((size_t)mtg * 4 + kt) * 64 + lane) * 8);
      al[kt] = *reinterpret_cast<const short8*>(Al + (((size_t)mtg * 4 + kt) * 64 + lane) * 8);
    }
    float v[2][4];
#pragma unroll
    for (int i = 0; i < 2; ++i) {
      f32x4v c = {0.f, 0.f, 0.f, 0.f};
#pragma unroll
      for (int kt = 0; kt < 4; ++kt) {
        c = __builtin_amdgcn_mfma_f32_16x16x32_bf16(ah[kt], bh[i][kt], c, 0, 0, 0);
        c = __builtin_amdgcn_mfma_f32_16x16x32_bf16(al[kt], bh[i][kt], c, 0, 0, 0);
        c = __builtin_amdgcn_mfma_f32_16x16x32_bf16(ah[kt], bl[i][kt], c, 0, 0, 0);
      }
      const int col = (wv * 2 + i) * 16 + r0;
      const float bb = bo[col];
#pragma unroll
      for (int q = 0; q < 4; ++q) {
        const int row = mtg * 16 + g * 4 + q;
        v[i][q] = c[q] + bb + X[(size_t)row * 128 + col];
      }
    }
    float s1[4], s2[4];
#pragma unroll
    for (int q = 0; q < 4; ++q) {
      s1[q] = v[0][q] + v[1][q];
      s2[q] = v[0][q] * v[0][q] + v[1][q] * v[1][q];
    }
#pragma unroll
    for (int o = 1; o < 16; o <<= 1)
#pragma unroll
      for (int q = 0; q < 4; ++q) { s1[q] += __shfl_xor(s1[q], o); s2[q] += __shfl_xor(s2[q], o); }
    if (r0 == 0)
#pragma unroll
      for (int q = 0; q < 4; ++q) { red[g * 4 + q][wv][0] = s1[q]; red[g * 4 + q][wv][1] = s2[q]; }
    __syncthreads();
#pragma unroll
    for (int q = 0; q < 4; ++q) {
      const int r = g * 4 + q;
      const float t1 = red[r][0][0] + red[r][1][0] + red[r][2][0] + red[r][3][0];
      const float t2 = red[r][0][1] + red[r][1][1] + red[r][2][1] + red[r][3][1];
      const float m  = t1 * (1.f / 128.f);
      const float rs = rsqrtf(t2 * (1.f / 128.f) - m * m + 1e-5f);
      const int row = mtg * 16 + r;
#pragma unroll
      for (int i = 0; i < 2; ++i) {
        const int col = (wv * 2 + i) * 16 + r0;
        const float o = (v[i][q] - m) * rs * gs[col] + gb[col];
        X[(size_t)row * 128 + col] = o;   // post-LN: LN'd value IS the residual
        short hh, ll; split2(o, hh, ll);
        const size_t pk = apos(row, col, 4);
        OAh[pk] = hh; OAl[pk] = ll;
      }
    }
    __syncthreads();
  }
}

__global__ __launch_bounds__(256) void bw1_kernel(
    const short* __restrict__ Ah, const short* __restrict__ Al,
    const short* __restrict__ Bp, const float* __restrict__ bias,
    short* __restrict__ Hh, short* __restrict__ Hl)
{
  const int mt0 = (int)blockIdx.x * 4;
  const int nc  = (int)blockIdx.y;
  const int lane = (int)threadIdx.x & 63, wv = (int)threadIdx.x >> 6;
  const int r0 = lane & 15, g = lane >> 4;
  short8 bh[2][4], bl[2][4];
#pragma unroll
  for (int i = 0; i < 2; ++i)
#pragma unroll
    for (int kt = 0; kt < 4; ++kt) {
      const short* tb = Bp + (((size_t)(nc * 8 + wv * 2 + i) * 4 + kt) << 10);
      bh[i][kt] = *reinterpret_cast<const short8*>(tb + lane * 8);
      bl[i][kt] = *reinterpret_cast<const short8*>(tb + 512 + lane * 8);
    }
#pragma unroll 2
  for (int mt = 0; mt < 4; ++mt) {
    const int mtg = mt0 + mt;
    short8 ah[4], al[4];
#pragma unroll
    for (int kt = 0; kt < 4; ++kt) {
      ah[kt] = *reinterpret_cast<const short8*>(Ah + (((size_t)mtg * 4 + kt) * 64 + lane) * 8);
      al[kt] = *reinterpret_cast<const short8*>(Al + (((size_t)mtg * 4 + kt) * 64 + lane) * 8);
    }
#pragma unroll
    for (int i = 0; i < 2; ++i) {
      f32x4v c = {0.f, 0.f, 0.f, 0.f};
#pragma unroll
      for (int kt = 0; kt < 4; ++kt) {
        c = __builtin_amdgcn_mfma_f32_16x16x32_bf16(ah[kt], bh[i][kt], c, 0, 0, 0);
        c = __builtin_amdgcn_mfma_f32_16x16x32_bf16(al[kt], bh[i][kt], c, 0, 0, 0);
        c = __builtin_amdgcn_mfma_f32_16x16x32_bf16(ah[kt], bl[i][kt], c, 0, 0, 0);
      }
      const int col = nc * 128 + (wv * 2 + i) * 16 + r0;
      const float bb = bias[col];
#pragma unroll
      for (int q = 0; q < 4; ++q) {
        const int row = mtg * 16 + g * 4 + q;
        short hh, ll; split2(geluf(c[q] + bb), hh, ll);
        const size_t pk = apos(row, col, 16);
        Hh[pk] = hh; Hl[pk] = ll;
      }
    }
  }
}

// merged FFN W2 (both K halves) + fused residual + LN + pack. 512 thr, grid 768.
__global__ __launch_bounds__(512) void bw2_kernel(
    const short* __restrict__ Hh, const short* __restrict__ Hl,
    const short* __restrict__ Bp, const float* __restrict__ bias,
    const float* __restrict__ gs, const float* __restrict__ gb,
    float* __restrict__ X, short* __restrict__ OAh, short* __restrict__ OAl)
{
  __shared__ float red[16][8][2];
  const int mt0 = (int)blockIdx.x * 4;
  const int lane = (int)threadIdx.x & 63, wv = (int)threadIdx.x >> 6;  // 8 waves
  const int r0 = lane & 15, g = lane >> 4;
  f32x4v c[4];
#pragma unroll
  for (int mt = 0; mt < 4; ++mt) c[mt] = (f32x4v){0.f, 0.f, 0.f, 0.f};
#pragma unroll
  for (int half = 0; half < 2; ++half) {
    short8 bh[8], bl[8];
#pragma unroll
    for (int kk = 0; kk < 8; ++kk) {
      const short* tb = Bp + (((size_t)(wv * 16 + half * 8 + kk)) << 10);
      bh[kk] = *reinterpret_cast<const short8*>(tb + lane * 8);
      bl[kk] = *reinterpret_cast<const short8*>(tb + 512 + lane * 8);
    }
#pragma unroll
    for (int mt = 0; mt < 4; ++mt) {
      const int mtg = mt0 + mt;
#pragma unroll
      for (int kk = 0; kk < 8; ++kk) {
        const short8 ah = *reinterpret_cast<const short8*>(
            Hh + (((size_t)mtg * 16 + half * 8 + kk) * 64 + lane) * 8);
        const short8 al = *reinterpret_cast<const short8*>(
            Hl + (((size_t)mtg * 16 + half * 8 + kk) * 64 + lane) * 8);
        c[mt] = __builtin_amdgcn_mfma_f32_16x16x32_bf16(ah, bh[kk], c[mt], 0, 0, 0);
        c[mt] = __builtin_amdgcn_mfma_f32_16x16x32_bf16(al, bh[kk], c[mt], 0, 0, 0);
        c[mt] = __builtin_amdgcn_mfma_f32_16x16x32_bf16(ah, bl[kk], c[mt], 0, 0, 0);
      }
    }
  }
  const int col = wv * 16 + r0;
  const float bb = bias[col];
  for (int mt = 0; mt < 4; ++mt) {
    const int mtg = mt0 + mt;
    float v[4], s1[4], s2[4];
#pragma unroll
    for (int q = 0; q < 4; ++q) {
      const int row = mtg * 16 + g * 4 + q;
      v[q] = c[mt][q] + bb + X[(size_t)row * 128 + col];
      s1[q] = v[q]; s2[q] = v[q] * v[q];
    }
#pragma unroll
    for (int o = 1; o < 16; o <<= 1)
#pragma unroll
      for (int q = 0; q < 4; ++q) { s1[q] += __shfl_xor(s1[q], o); s2[q] += __shfl_xor(s2[q], o); }
    if (r0 == 0)
#pragma unroll
      for (int q = 0; q < 4; ++q) { red[g * 4 + q][wv][0] = s1[q]; red[g * 4 + q][wv][1] = s2[q]; }
    __syncthreads();
#pragma unroll
    for (int q = 0; q < 4; ++q) {
      const int r = g * 4 + q;
      float t1 = 0.f, t2 = 0.f;
#pragma unroll
      for (int w = 0; w < 8; ++w) { t1 += red[r][w][0]; t2 += red[r][w][1]; }
      const float m  = t1 * (1.f / 128.f);
      const float rs = rsqrtf(t2 * (1.f / 128.f) - m * m + 1e-5f);
      const int row = mtg * 16 + r;
      const float o = (v[q] - m) * rs * gs[col] + gb[col];
      X[(size_t)row * 128 + col] = o;     // post-LN
      short hh, ll; split2(o, hh, ll);
      const size_t pk = apos(row, col, 4);
      OAh[pk] = hh; OAl[pk] = ll;
    }
    __syncthreads();
  }
}

__global__ __launch_bounds__(256) void bintent_kernel(
    const float* __restrict__ X, const float* __restrict__ lnf_s,
    const float* __restrict__ lnf_b, float* __restrict__ intent)
{
  const int w = (int)threadIdx.x >> 6, lane = (int)threadIdx.x & 63;
  const int b = (int)blockIdx.x * 4 + w;
  const float* xr = X + (size_t)b * LTn * 128;
  const float a0 = xr[lane], a1 = xr[lane + 64];
  float s1 = a0 + a1, s2 = a0 * a0 + a1 * a1;
#pragma unroll
  for (int o = 32; o > 0; o >>= 1) { s1 += __shfl_xor(s1, o); s2 += __shfl_xor(s2, o); }
  const float m  = s1 * (1.f / 128.f);
  const float rs = rsqrtf(s2 * (1.f / 128.f) - m * m + 1e-5f);
  intent[b * 128 + lane]      = (a0 - m) * rs * lnf_s[lane]      + lnf_b[lane];
  intent[b * 128 + lane + 64] = (a1 - m) * rs * lnf_s[lane + 64] + lnf_b[lane + 64];
}

// ---------------------------------------------------------------------------
struct RouterP {
  const float* state; const float* intent;
  const float* se_W1; const float* se_b1; const float* se_W2; const float* se_b2;
  const float* se_ln_s; const float* se_ln_b;
  const float* r_W1; const float* r_b1; const float* r_W2; const float* r_b2;
  const float* r_ln_s; const float* r_ln_b;
  const float* gate_W; const float* gate_b;
  int* ridx; float* rwgt;
};

DEVI void ln128(float* x, const float* gs, const float* gb, float* red)
{
  const int c = (int)threadIdx.x;      // blockDim == 128
  const float a = x[c];
  float s1 = a, s2 = a * a;
#pragma unroll
  for (int o = 32; o > 0; o >>= 1) { s1 += __shfl_xor(s1, o); s2 += __shfl_xor(s2, o); }
  const int wid = c >> 6;
  if ((c & 63) == 0) { red[wid * 2] = s1; red[wid * 2 + 1] = s2; }
  __syncthreads();
  s1 = red[0] + red[2]; s2 = red[1] + red[3];
  const float m  = s1 * (1.f / 128.f);
  const float rs = rsqrtf(s2 * (1.f / 128.f) - m * m + 1e-5f);
  __syncthreads();
  x[c] = (a - m) * rs * gs[c] + gb[c];
}

// 128-deep dot with 4 independent accumulator chains (latency fix)
DEVI float dot128i(const float* __restrict__ h, const float* __restrict__ W,
                   const int c, const int wstr)
{
  float a0 = 0.f, a1 = 0.f, a2 = 0.f, a3 = 0.f;
#pragma unroll 8
  for (int k = 0; k < 128; k += 4) {
    a0 = fmaf(h[k + 0], W[(k + 0) * wstr + c], a0);
    a1 = fmaf(h[k + 1], W[(k + 1) * wstr + c], a1);
    a2 = fmaf(h[k + 2], W[(k + 2) * wstr + c], a2);
    a3 = fmaf(h[k + 3], W[(k + 3) * wstr + c], a3);
  }
  return (a0 + a1) + (a2 + a3);
}

__global__ __launch_bounds__(128) void router_kernel(RouterP p)
{
  __shared__ float sstate[SDn];
  __shared__ float h1[Dn];
  __shared__ float vv[Dn];
  __shared__ float red[4];
  __shared__ float slog[En];
  const int b = blockIdx.x;
  const int c = (int)threadIdx.x;

  if (c < SDn) sstate[c] = p.state[b * SDn + c];
  __syncthreads();
  {
    float acc = p.se_b1[c];
#pragma unroll
    for (int k = 0; k < SDn; ++k) acc = fmaf(sstate[k], p.se_W1[k * Dn + c], acc);
    h1[c] = geluf(acc);
  }
  __syncthreads();
  vv[c] = p.se_b2[c] + dot128i(h1, p.se_W2, c, Dn);
  __syncthreads();
  ln128(vv, p.se_ln_s, p.se_ln_b, red);
  __syncthreads();
  {
    const float* ib = p.intent + b * Dn;
    float acc = p.r_b1[c] + dot128i(ib, p.r_W1, c, Dn)
                          + dot128i(vv, p.r_W1 + Dn * Dn, c, Dn);
    h1[c] = geluf(acc);
  }
  __syncthreads();
  vv[c] = p.r_b2[c] + dot128i(h1, p.r_W2, c, Dn);
  __syncthreads();
  ln128(vv, p.r_ln_s, p.r_ln_b, red);
  __syncthreads();
  if (c < En) slog[c] = p.gate_b[c] + dot128i(vv, p.gate_W, c, En);
  __syncthreads();
  if (c == 0) {
    int i0 = 0; float v0 = slog[0];
#pragma unroll
    for (int e2 = 1; e2 < En; ++e2) if (slog[e2] > v0) { v0 = slog[e2]; i0 = e2; }
    int i1 = -1; float v1 = -3.4e38f;
#pragma unroll
    for (int e2 = 0; e2 < En; ++e2) if (e2 != i0 && slog[e2] > v1) { v1 = slog[e2]; i1 = e2; }
    const float e1  = expf(v1 - v0);
    const float inv = 1.f / (1.f + e1);
    p.ridx[b * 2 + 0] = i0; p.ridx[b * 2 + 1] = i1;
    p.rwgt[b * 2 + 0] = inv; p.rwgt[b * 2 + 1] = e1 * inv;
  }
}

// ===========================================================================
// EXPERT PHASE PIPELINE — norm_first: X keeps RAW residual, packed A gets LN
// ===========================================================================

__global__ void sched_kernel(const int* __restrict__ ridx, int* __restrict__ sch,
                             int* plist, int* prow, int* pexp, int* ppos)
{
  __shared__ int scnt[En], scur[En], soff[En], srb[En + 1];
  const int t = (int)threadIdx.x;
  if (t < En) { scnt[t] = 0; scur[t] = 0; }
  __syncthreads();
  for (int p = t; p < PAIRS; p += 256) atomicAdd(&scnt[ridx[p]], 1);
  __syncthreads();
  if (t == 0) {
    int off = 0, rb = 0, k = 0;
    for (int e = 0; e < En; ++e) {
      soff[e] = off; srb[e] = rb;
      const int rows = scnt[e] * 20;
      const int nb = (rows + 127) >> 7;
      for (int q = 0; q < nb; ++q) {
        sch[GEXP_OFF + k] = e;
        sch[GMT_OFF + k]  = (rb >> 4) + q * 8;
        ++k;
      }
      off += scnt[e];
      rb += nb * 128;
    }
    srb[En] = rb;
    sch[0] = k;
    for (int e = 0; e < En; ++e) { sch[1 + e] = scnt[e]; sch[7 + e] = soff[e]; }
    for (int e = 0; e <= En; ++e) sch[13 + e] = srb[e];
  }
  __syncthreads();
  for (int p = t; p < PAIRS; p += 256) {
    const int e = ridx[p];
    const int pos = atomicAdd(&scur[e], 1);
    const int i = soff[e] + pos;
    plist[i] = p; ppos[p] = i; pexp[i] = e; prow[i] = srb[e] + pos * 20;
  }
}

__global__ void xinit_kernel(const float* __restrict__ qpe, const int* __restrict__ sch,
                             float* __restrict__ X)
{
  const int idx = (int)blockIdx.x * 256 + (int)threadIdx.x;  // quad index
  const int row = idx >> 5;
  if (row >= MPMAX) return;
  const int c4 = (idx & 31) * 4;
  const int* RB = sch + 13;
  float4 v = {0.f, 0.f, 0.f, 0.f};
  int e = 0;
  while (e < En && row >= RB[e + 1]) ++e;
  if (e < En) {
    const int local = row - RB[e];
    if (local < sch[1 + e] * 20) {
      const int r = local - (local / 20) * 20;
      v = *reinterpret_cast<const float4*>(qpe + r * 128 + c4);
    }
  }
  *reinterpret_cast<float4*>(X + (size_t)row * 128 + c4) = v;
}

// LN over X rows -> packed bf16 A-fragments (used once, layer-0 sub-0)
__global__ __launch_bounds__(256) void ln_pack_kernel(
    const float* __restrict__ X, short* __restrict__ XnP,
    const float* __restrict__ lns_all, const float* __restrict__ lnb_all,
    const int subOff, const int* __restrict__ sch)
{
  const int* RB = sch + 13;
  const int mt = (int)blockIdx.x;
  const int row0 = mt << 4;
  if (row0 >= RB[En]) return;
  int e = 0;
  while (e < En - 1 && row0 >= RB[e + 1]) ++e;
  const float* gs = lns_all + e * (NLDn * 3 * 128) + subOff;
  const float* gb = lnb_all + e * (NLDn * 3 * 128) + subOff;
  const int t = (int)threadIdx.x;
  const int rl = t >> 4, j = t & 15;
  const int row = row0 + rl;
  float x[8];
  {
    const float4 a = *reinterpret_cast<const float4*>(X + (size_t)row * 128 + j * 8);
    const float4 bq = *reinterpret_cast<const float4*>(X + (size_t)row * 128 + j * 8 + 4);
    x[0] = a.x; x[1] = a.y; x[2] = a.z; x[3] = a.w;
    x[4] = bq.x; x[5] = bq.y; x[6] = bq.z; x[7] = bq.w;
  }
  float s1 = 0.f, s2 = 0.f;
#pragma unroll
  for (int u = 0; u < 8; ++u) { s1 += x[u]; s2 += x[u] * x[u]; }
#pragma unroll
  for (int o = 1; o < 16; o <<= 1) { s1 += __shfl_xor(s1, o); s2 += __shfl_xor(s2, o); }
  const float m  = s1 * (1.f / 128.f);
  const float rs = rsqrtf(s2 * (1.f / 128.f) - m * m + 1e-5f);
  short8 pk;
#pragma unroll
  for (int u = 0; u < 8; ++u)
    pk[u] = f2bf((x[u] - m) * rs * gs[j * 8 + u] + gb[j * 8 + u]);
  const int kt = j >> 2, g = j & 3, lp = g * 16 + rl;
  *reinterpret_cast<short8*>(XnP + (((size_t)mt * 4 + kt) * 64 + lp) * 8) = pk;
}

// composite cross-attn K/V factors: C[li][k][c2] = sum_d sp_W[ex][k][d]*Wkv[d][c2],
// k0c[li][c2] = sp_b@Wkv + bias, k1c[li][c2] = zp_b@Wkv + bias.  grid (18), 256 thr.
__global__ __launch_bounds__(256) void compose_kernel(
    const float* __restrict__ sp_W, const float* __restrict__ sp_b,
    const float* __restrict__ zp_b, const float* __restrict__ aW,
    const float* __restrict__ ab,
    float* __restrict__ C, float* __restrict__ k0c, float* __restrict__ k1c)
{
  const int li = (int)blockIdx.x;          // ex*NLDn + l
  const int ex = li / NLDn;
  const int c2 = (int)threadIdx.x;         // 0..255
  const float* W   = aW + (size_t)(li * 2 + 1) * Dn * 384 + Dn;  // k,v columns
  const float* bb  = ab + (size_t)(li * 2 + 1) * 384 + Dn;
  const float* spw = sp_W + ex * SDn * Dn;
  const float* spb = sp_b + ex * Dn;
  const float* zpb = zp_b + ex * Dn;
  float acc[SDn];
#pragma unroll
  for (int k = 0; k < SDn; ++k) acc[k] = 0.f;
  float a0 = 0.f, a1 = 0.f;
  for (int d = 0; d < Dn; ++d) {
    const float w = W[(size_t)d * 384 + c2];
#pragma unroll
    for (int k = 0; k < SDn; ++k) acc[k] = fmaf(spw[k * Dn + d], w, acc[k]);
    a0 = fmaf(spb[d], w, a0);
    a1 = fmaf(zpb[d], w, a1);
  }
#pragma unroll
  for (int k = 0; k < SDn; ++k) C[((size_t)li * SDn + k) * 256 + c2] = acc[k];
  k0c[li * 256 + c2] = bb[c2] + a0;
  k1c[li * 256 + c2] = bb[c2] + a1;
}

// grouped GEMM, K=128 (packed A, 4 k-tiles).
// EPI 0: store bf16 row-major (stride obstr)   [QKV / cross-Q]
// EPI 3: relu -> packed bf16 KT=16, k-tile base ntOff>>1   [FFN W1 halves]
// EPI 4: fused norm_first epilogue: v = c + bias + X; X = v (RAW);
//        packed A = LN(v) with (lnsA,lnbA,subOff)           [O-proj]
template<int NTW, int EPI, bool HASB>
__global__ __launch_bounds__(256) void gemm_k128(
    const short* __restrict__ A, const short* __restrict__ Bb, const int strideB,
    const float* __restrict__ biasb, const int strideBias, const int ntOff,
    short* __restrict__ OutBf, const int obstr, short* __restrict__ OutP,
    const float* __restrict__ lnsA, const float* __restrict__ lnbA, const int subOff,
    float* __restrict__ X, const int* __restrict__ sch)
{
  __shared__ float red[16][4][2];
  const int k = (int)blockIdx.x;
  if (k >= sch[0]) return;
  const int ex  = sch[GEXP_OFF + k];
  const int mt0 = sch[GMT_OFF + k];
  const short* Bp = Bb + (size_t)ex * strideB;
  const float* bias = biasb + (size_t)ex * strideBias;
  const float* gs = (EPI == 4) ? lnsA + ex * (NLDn * 3 * 128) + subOff : nullptr;
  const float* gb = (EPI == 4) ? lnbA + ex * (NLDn * 3 * 128) + subOff : nullptr;
  const int lane = (int)threadIdx.x & 63, wv = (int)threadIdx.x >> 6;
  const int r0 = lane & 15, g = lane >> 4;
  short8 bf[NTW][4];
#pragma unroll
  for (int i = 0; i < NTW; ++i)
#pragma unroll
    for (int kt = 0; kt < 4; ++kt)
      bf[i][kt] = *reinterpret_cast<const short8*>(
          Bp + (((size_t)(ntOff + wv * NTW + i) * 4 + kt) * 64 + lane) * 8);
  for (int mt = 0; mt < 8; ++mt) {
    short8 a[4];
#pragma unroll
    for (int kt = 0; kt < 4; ++kt)
      a[kt] = *reinterpret_cast<const short8*>(
          A + (((size_t)(mt0 + mt) * 4 + kt) * 64 + lane) * 8);
    float v[NTW][4];
#pragma unroll
    for (int i = 0; i < NTW; ++i) {
      f32x4v c = {0.f, 0.f, 0.f, 0.f};
#pragma unroll
      for (int kt = 0; kt < 4; ++kt)
        c = __builtin_amdgcn_mfma_f32_16x16x32_bf16(a[kt], bf[i][kt], c, 0, 0, 0);
      const int colL = (wv * NTW + i) * 16 + r0;
      const float bb = HASB ? bias[colL] : 0.f;
      const int rowB = (mt0 + mt) * 16 + g * 4;
#pragma unroll
      for (int q = 0; q < 4; ++q) {
        const int row = rowB + q;
        const float val = c[q] + bb;
        if (EPI == 0) {
          OutBf[(size_t)row * obstr + colL] = f2bf(val);
        } else if (EPI == 3) {
          const float rv = fmaxf(val, 0.f);
          const int j = colL >> 3, kt2 = j >> 2, g2 = j & 3;
          const int lp = g2 * 16 + (row & 15);
          OutP[(((size_t)(row >> 4) * 16 + (ntOff >> 1) + kt2) * 64 + lp) * 8 + (colL & 7)]
              = f2bf(rv);
        } else {
          v[i][q] = val + X[(size_t)row * 128 + colL];
        }
      }
    }
    if (EPI == 4) {
      float s1[4], s2[4];
#pragma unroll
      for (int q = 0; q < 4; ++q) {
        s1[q] = v[0][q] + v[1][q];
        s2[q] = v[0][q] * v[0][q] + v[1][q] * v[1][q];
      }
#pragma unroll
      for (int o = 1; o < 16; o <<= 1)
#pragma unroll
        for (int q = 0; q < 4; ++q) { s1[q] += __shfl_xor(s1[q], o); s2[q] += __shfl_xor(s2[q], o); }
      if (r0 == 0)
#pragma unroll
        for (int q = 0; q < 4; ++q) { red[g * 4 + q][wv][0] = s1[q]; red[g * 4 + q][wv][1] = s2[q]; }
      __syncthreads();
#pragma unroll
      for (int q = 0; q < 4; ++q) {
        const int r = g * 4 + q;
        const float t1 = red[r][0][0] + red[r][1][0] + red[r][2][0] + red[r][3][0];
        const float t2 = red[r][0][1] + red[r][1][1] + red[r][2][1] + red[r][3][1];
        const float m  = t1 * (1.f / 128.f);
        const float rs = rsqrtf(t2 * (1.f / 128.f) - m * m + 1e-5f);
        const int row = (mt0 + mt) * 16 + r;
#pragma unroll
        for (int i = 0; i < 2; ++i) {
          const int col = (wv * 2 + i) * 16 + r0;
          const float o = (v[i][q] - m) * rs * gs[col] + gb[col];
          X[(size_t)row * 128 + col] = v[i][q];   // norm_first: RAW residual
          OutP[apos(row, col, 4)] = f2bf(o);      // LN'd input for next phase
        }
      }
      __syncthreads();
    }
  }
}

// merged grouped GEMM over full K=512 (packed A KT=16).
// v = c + bias + X; DOLN: X = v (RAW), packed A = LN(v); else X = v.
template<bool DOLN>
__global__ __launch_bounds__(256) void gemm_k256f(
    const short* __restrict__ A, const short* __restrict__ Bb, const int strideB,
    const float* __restrict__ biasb, const int strideBias,
    float* __restrict__ X, short* __restrict__ OutP,
    const float* __restrict__ lnsA, const float* __restrict__ lnbA, const int subOff,
    const int* __restrict__ sch)
{
  __shared__ float red[16][4][2];
  const int k = (int)blockIdx.x;
  if (k >= sch[0]) return;
  const int ex  = sch[GEXP_OFF + k];
  const int mt0 = sch[GMT_OFF + k];
  const short* Bp = Bb + (size_t)ex * strideB;
  const float* bias = biasb + (size_t)ex * strideBias;
  const float* gs = DOLN ? lnsA + ex * (NLDn * 3 * 128) + subOff : nullptr;
  const float* gb = DOLN ? lnbA + ex * (NLDn * 3 * 128) + subOff : nullptr;
  const int lane = (int)threadIdx.x & 63, wv = (int)threadIdx.x >> 6;
  const int r0 = lane & 15, g = lane >> 4;
#pragma unroll
  for (int mc = 0; mc < 2; ++mc) {
    f32x4v c[4][2];
#pragma unroll
    for (int mtl = 0; mtl < 4; ++mtl)
#pragma unroll
      for (int i = 0; i < 2; ++i) c[mtl][i] = (f32x4v){0.f, 0.f, 0.f, 0.f};
#pragma unroll
    for (int half = 0; half < 2; ++half) {
      short8 bf[2][8];
#pragma unroll
      for (int i = 0; i < 2; ++i)
#pragma unroll
        for (int kk = 0; kk < 8; ++kk)
          bf[i][kk] = *reinterpret_cast<const short8*>(
              Bp + (((size_t)(wv * 2 + i) * 16 + half * 8 + kk) * 64 + lane) * 8);
#pragma unroll
      for (int mtl = 0; mtl < 4; ++mtl) {
        const int mtg = mt0 + mc * 4 + mtl;
        short8 a[8];
#pragma unroll
        for (int kk = 0; kk < 8; ++kk)
          a[kk] = *reinterpret_cast<const short8*>(
              A + (((size_t)mtg * 16 + half * 8 + kk) * 64 + lane) * 8);
#pragma unroll
        for (int i = 0; i < 2; ++i)
#pragma unroll
          for (int kk = 0; kk < 8; ++kk)
            c[mtl][i] = __builtin_amdgcn_mfma_f32_16x16x32_bf16(a[kk], bf[i][kk], c[mtl][i], 0, 0, 0);
      }
    }
#pragma unroll
    for (int mtl = 0; mtl < 4; ++mtl) {
      const int mtg = mt0 + mc * 4 + mtl;
      float v[2][4];
#pragma unroll
      for (int i = 0; i < 2; ++i) {
        const int colL = (wv * 2 + i) * 16 + r0;
        const float bb = bias[colL];
#pragma unroll
        for (int q = 0; q < 4; ++q) {
          const int row = mtg * 16 + g * 4 + q;
          v[i][q] = c[mtl][i][q] + bb + X[(size_t)row * 128 + colL];
        }
      }
      if (DOLN) {
        float s1[4], s2[4];
#pragma unroll
        for (int q = 0; q < 4; ++q) {
          s1[q] = v[0][q] + v[1][q];
          s2[q] = v[0][q] * v[0][q] + v[1][q] * v[1][q];
        }
#pragma unroll
        for (int o = 1; o < 16; o <<= 1)
#pragma unroll
          for (int q = 0; q < 4; ++q) { s1[q] += __shfl_xor(s1[q], o); s2[q] += __shfl_xor(s2[q], o); }
        if (r0 == 0)
#pragma unroll
          for (int q = 0; q < 4; ++q) { red[g * 4 + q][wv][0] = s1[q]; red[g * 4 + q][wv][1] = s2[q]; }
        __syncthreads();
#pragma unroll
        for (int q = 0; q < 4; ++q) {
          const int r = g * 4 + q;
          const float t1 = red[r][0][0] + red[r][1][0] + red[r][2][0] + red[r][3][0];
          const float t2 = red[r][0][1] + red[r][1][1] + red[r][2][1] + red[r][3][1];
          const float m  = t1 * (1.f / 128.f);
          const float rs = rsqrtf(t2 * (1.f / 128.f) - m * m + 1e-5f);
          const int row = mtg * 16 + r;
#pragma unroll
          for (int i = 0; i < 2; ++i) {
            const int col = (wv * 2 + i) * 16 + r0;
            const float o = (v[i][q] - m) * rs * gs[col] + gb[col];
            X[(size_t)row * 128 + col] = v[i][q];   // norm_first: RAW residual
            OutP[apos(row, col, 4)] = f2bf(o);      // LN'd input for next layer
          }
        }
        __syncthreads();
      } else {
#pragma unroll
        for (int i = 0; i < 2; ++i) {
          const int colL = (wv * 2 + i) * 16 + r0;
#pragma unroll
          for (int q = 0; q < 4; ++q) {
            const int row = mtg * 16 + g * 4 + q;
            X[(size_t)row * 128 + colL] = v[i][q];
          }
        }
      }
    }
  }
}

// per (pair, head) self-attention: QKV bf16 (stride 384) -> O packed bf16.
// grid (4096, 4), 64 threads (1 wave).
__global__ __launch_bounds__(64) void sattn_kernel(
    const short* __restrict__ QKVb, const int* __restrict__ prow,
    short* __restrict__ ANP)
{
  __shared__ float qs[CSn * HSTR], ks[CSn * HSTR], vs[CSn * HSTR];
  __shared__ float att[CSn * CSn];
  const int i = (int)blockIdx.x, h = (int)blockIdx.y;
  const int tid = (int)threadIdx.x;
  const int row0 = prow[i];
  for (int u = tid; u < CSn * 12; u += 64) {
    const int il = u / 12, r = u % 12, which = r >> 2, d8 = r & 3;
    const short8 s = *reinterpret_cast<const short8*>(
        QKVb + (size_t)(row0 + il) * 384 + which * 128 + h * 32 + d8 * 8);
    float* dst = (which == 0 ? qs : which == 1 ? ks : vs) + il * HSTR + d8 * 8;
#pragma unroll
    for (int u8 = 0; u8 < 8; ++u8) dst[u8] = bf2f(s[u8]);
  }
  __syncthreads();
  for (int e = tid; e < CSn * CSn; e += 64) {
    const int ii = e / CSn, j = e % CSn;
    const float* qp = qs + ii * HSTR;
    const float* kp = ks + j * HSTR;
    float acc = 0.f;
#pragma unroll
    for (int d = 0; d < DHn; d += 4) {
      const float4 qa = *reinterpret_cast<const float4*>(qp + d);
      const float4 kb = *reinterpret_cast<const float4*>(kp + d);
      acc += qa.x * kb.x + qa.y * kb.y + qa.z * kb.z + qa.w * kb.w;
    }
    att[e] = acc * INV_SQRT_DH;
  }
  __syncthreads();
  if (tid < CSn) {
    float* row = att + tid * CSn;
    float m = row[0];
#pragma unroll 4
    for (int j = 1; j < CSn; ++j) m = fmaxf(m, row[j]);
    float s = 0.f;
#pragma unroll 4
    for (int j = 0; j < CSn; ++j) { const float ex = expf(row[j] - m); row[j] = ex; s += ex; }
    const float inv = 1.f / s;
#pragma unroll 4
    for (int j = 0; j < CSn; ++j) row[j] *= inv;
  }
  __syncthreads();
  for (int e = tid; e < CSn * 32; e += 64) {
    const int ii = e >> 5, c = e & 31;
    const float* arow = att + ii * CSn;
    float acc = 0.f;
#pragma unroll 4
    for (int j = 0; j < CSn; ++j) acc = fmaf(arow[j], vs[j * HSTR + c], acc);
    ANP[apos(row0 + ii, h * 32 + c, 4)] = f2bf(acc);
  }
}

// per-pair cross-attention (2 keys): Qc bf16 (stride 128) + composite memkv
__global__ __launch_bounds__(256) void cattn_kernel(
    const short* __restrict__ Qb, const float* __restrict__ state,
    const float* __restrict__ C, const float* __restrict__ k0c,
    const float* __restrict__ k1c, const int layer,
    const int* __restrict__ plist, const int* __restrict__ prow,
    const int* __restrict__ pexp, short* __restrict__ ANP)
{
  __shared__ float q[CSn * Dn];
  __shared__ float memkv[2 * 256];
  __shared__ float catt[2 * Hn * CSn];
  __shared__ float st[SDn];
  const int i = (int)blockIdx.x;
  const int ex = pexp[i];
  const int b = plist[i] >> 1;
  const int li = ex * NLDn + layer;
  const int row0 = prow[i];
  const int tid = (int)threadIdx.x;

  if (tid < SDn) st[tid] = state[b * SDn + tid];
  for (int e8 = tid; e8 < CSn * 16; e8 += 256) {
    const int il = e8 >> 4, c8 = e8 & 15;
    const short8 s = *reinterpret_cast<const short8*>(
        Qb + (size_t)(row0 + il) * 128 + c8 * 8);
    float* dst = q + il * Dn + c8 * 8;
#pragma unroll
    for (int u = 0; u < 8; ++u) dst[u] = bf2f(s[u]);
  }
  __syncthreads();
  {
    const int c2 = tid;                       // 256 threads, one column each
    float acc = k0c[li * 256 + c2];
#pragma unroll
    for (int k = 0; k < SDn; ++k)
      acc = fmaf(st[k], C[((size_t)li * SDn + k) * 256 + c2], acc);
    memkv[c2] = acc;
    memkv[256 + c2] = k1c[li * 256 + c2];
  }
  __syncthreads();
  for (int e = tid; e < Hn * CSn; e += 256) {
    const int h = e / CSn, il = e % CSn;
    const float* qp = q + il * Dn + h * DHn;
    float s0 = 0.f, s1 = 0.f;
#pragma unroll
    for (int d = 0; d < DHn; d += 4) {
      const float4 q4 = *reinterpret_cast<const float4*>(qp + d);
      const float4 k0 = *reinterpret_cast<const float4*>(memkv + 0 * 256 + h * DHn + d);
      const float4 k1 = *reinterpret_cast<const float4*>(memkv + 1 * 256 + h * DHn + d);
      s0 += q4.x * k0.x + q4.y * k0.y + q4.z * k0.z + q4.w * k0.w;
      s1 += q4.x * k1.x + q4.y * k1.y + q4.z * k1.z + q4.w * k1.w;
    }
    s0 *= INV_SQRT_DH; s1 *= INV_SQRT_DH;
    const float m = fmaxf(s0, s1);
    const float e0 = expf(s0 - m), e1 = expf(s1 - m);
    const float inv = 1.f / (e0 + e1);
    catt[e * 2] = e0 * inv; catt[e * 2 + 1] = e1 * inv;
  }
  __syncthreads();
  for (int e = tid; e < CSn * Dn; e += 256) {
    const int il = e >> 7, c = e & 127, h = c >> 5;
    const int a = (h * CSn + il) * 2;
    const float v = catt[a]     * memkv[0 * 256 + Dn + c]
                  + catt[a + 1] * memkv[1 * 256 + Dn + c];
    ANP[apos(row0 + il, c, 4)] = f2bf(v);
  }
}

__global__ __launch_bounds__(256) void head_kernel(
    const float* __restrict__ X, const int* __restrict__ plist,
    const int* __restrict__ prow, const int* __restrict__ pexp,
    const float* __restrict__ rwgt, const float* __restrict__ hW,
    const float* __restrict__ hb, float* __restrict__ Rbuf)
{
  __shared__ float xr[CSn * Dn];
  const int i = (int)blockIdx.x;
  const int ex = pexp[i];
  const int orig = plist[i];
  const int row0 = prow[i];
  const float wgt = rwgt[orig];
  for (int e4 = (int)threadIdx.x; e4 < CSn * 32; e4 += 256) {
    const int il = e4 >> 5, c4 = (e4 & 31) * 4;
    *reinterpret_cast<float4*>(xr + il * Dn + c4) =
        *reinterpret_cast<const float4*>(X + (size_t)(row0 + il) * 128 + c4);
  }
  __syncthreads();
  const int e = (int)threadIdx.x;
  if (e < CSn * JDn) {
    const int t = e / JDn, j = e - t * JDn;
    const float* w = hW + ex * Dn * JDn + j;
    float acc = hb[ex * JDn + j];
#pragma unroll 4
    for (int kk = 0; kk < Dn; ++kk) acc = fmaf(xr[t * Dn + kk], w[kk * JDn], acc);
    Rbuf[(size_t)i * 140 + e] = wgt * acc;
  }
}

__global__ void combine_kernel(const float* __restrict__ Rbuf,
                               const int* __restrict__ ppos, float* __restrict__ out)
{
  const int idx = (int)blockIdx.x * 256 + (int)threadIdx.x;
  if (idx >= Bn * 140) return;
  const int b = idx / 140, e = idx - b * 140;
  out[idx] = Rbuf[(size_t)ppos[2 * b] * 140 + e] + Rbuf[(size_t)ppos[2 * b + 1] * 140 + e];
}

// ---------------------------------------------------------------------------
__global__ void qpe_kernel(float* qpe)
{
  const int e = (int)blockIdx.x * 256 + (int)threadIdx.x;
  if (e < CSn * Dn) {
    const int t = e >> 7, d = e & 127;
    const float j  = (float)(d & ~1);
    const float dv = expf(j * (-logf(10000.f) / 128.f));
    const float a  = (float)t * dv;
    qpe[e] = (d & 1) ? cosf(a) : sinf(a);
  }
}

} // namespace

// ---------------------------------------------------------------------------
extern "C" void kernel_launch(void* const* d_in, const int* in_sizes, int n_in,
                              void* d_out, int out_size, void* d_ws, size_t ws_size,
                              hipStream_t stream)
{
  (void)in_sizes; (void)n_in; (void)out_size;

  const int*   ids     = (const int*)  d_in[0];
  const float* state   = (const float*)d_in[1];
  const float* tok_emb = (const float*)d_in[2];
  const float* pos_emb = (const float*)d_in[3];

  // persistent workspace (256B-aligned cursor)
  char* cur = (char*)d_ws;
  auto alloc = [&cur](size_t bytes) -> char* {
    char* p = cur; cur += (bytes + 255) & ~(size_t)255; return p;
  };
  float* qpe    = (float*)alloc(4096 * 4);
  float* intent = (float*)alloc((size_t)Bn * Dn * 4);
  int*   ridx   = (int*)  alloc(PAIRS * 4);
  float* rwgt   = (float*)alloc(PAIRS * 4);
  short* pQ     = (short*)alloc((size_t)36 * 49152 * 2);   // expert packs (single bf16)
  short* pO     = (short*)alloc((size_t)36 * 16384 * 2);
  short* pF1    = (short*)alloc((size_t)18 * 65536 * 2);
  short* pF2    = (short*)alloc((size_t)18 * 65536 * 2);
  short* pbQ    = (short*)alloc((size_t)4 * 98304 * 2);    // BERT packs (split hi/lo)
  short* pbO    = (short*)alloc((size_t)4 * 32768 * 2);
  short* pbW1   = (short*)alloc((size_t)4 * 131072 * 2);
  short* pbW2   = (short*)alloc((size_t)4 * 131072 * 2);
  int*   sch    = (int*)  alloc(2048 * 4);
  int*   plist  = (int*)  alloc(PAIRS * 4);
  int*   prow   = (int*)  alloc(PAIRS * 4);
  int*   pexp   = (int*)  alloc(PAIRS * 4);
  int*   ppos   = (int*)  alloc(PAIRS * 4);
  float* Cmat   = (float*)alloc((size_t)18 * SDn * 256 * 4);  // 294912 B
  float* k0c    = (float*)alloc((size_t)18 * 256 * 4);
  float* k1c    = (float*)alloc((size_t)18 * 256 * 4);
  constexpr size_t ARENA_BYTES = 192806912;
  char* arena = alloc(ARENA_BYTES);
  if ((size_t)(cur - (char*)d_ws) > ws_size) return;  // ws confirmed sufficient R4-R9

  // BERT views
  float* Xb  = (float*)(arena);                          // 25.2 MB
  short* Ah  = (short*)(arena + 25165824);               // 12.6 MB
  short* Al  = (short*)(arena + 37748736);               // 12.6 MB
  float* SBb = (float*)(arena + 50331648);               // QKV fp32 75.5 MB
  short* Hh  = (short*)(arena + 50331648);               // aliases SBb (sequential use)
  short* Hl  = (short*)(arena + 100663296);              // 50.3 MB
  // expert views
  float* X2   = (float*)(arena);                         // 42.3 MB
  short* ANP  = (short*)(arena + 42336256);              // 21.2 MB
  short* SBh  = (short*)(arena + 63504384);              // bf16 QKV/Qc/HP (<=84 MB, KT=16 HP)
  float* Rbuf = (float*)(arena + 190513152);             // 2.3 MB

  qpe_kernel<<<dim3(10), dim3(256), 0, stream>>>(qpe);

  // ---- weight packing + composite cross-attn factors
  {
    const int tq = 36 * 6144;
    pack_kernel<<<dim3((tq + 255) / 256), dim3(256), 0, stream>>>(
        (const float*)d_in[34], pQ, 128, 384, tq);
    const int to = 36 * 2048;
    pack_kernel<<<dim3((to + 255) / 256), dim3(256), 0, stream>>>(
        (const float*)d_in[36], pO, 128, 128, to);
    const int t1c = 18 * 8192;
    pack_kernel<<<dim3((t1c + 255) / 256), dim3(256), 0, stream>>>(
        (const float*)d_in[40], pF1, 128, 512, t1c);
    const int t2c = 18 * 8192;
    pack_kernel<<<dim3((t2c + 255) / 256), dim3(256), 0, stream>>>(
        (const float*)d_in[42], pF2, 512, 128, t2c);
    const int bq = 4 * 6144;
    pack2_kernel<<<dim3((bq + 255) / 256), dim3(256), 0, stream>>>(
        (const float*)d_in[4], pbQ, 128, 384, bq);
    const int bo = 4 * 2048;
    pack2_kernel<<<dim3((bo + 255) / 256), dim3(256), 0, stream>>>(
        (const float*)d_in[6], pbO, 128, 128, bo);
    const int bw1 = 4 * 8192;
    pack2_kernel<<<dim3((bw1 + 255) / 256), dim3(256), 0, stream>>>(
        (const float*)d_in[8], pbW1, 128, 512, bw1);
    const int bw2 = 4 * 8192;
    pack2_kernel<<<dim3((bw2 + 255) / 256), dim3(256), 0, stream>>>(
        (const float*)d_in[10], pbW2, 512, 128, bw2);
    compose_kernel<<<dim3(En * NLDn), dim3(256), 0, stream>>>(
        (const float*)d_in[30], (const float*)d_in[31], (const float*)d_in[33],
        (const float*)d_in[34], (const float*)d_in[35], Cmat, k0c, k1c);
  }

  // ---- BERT phase pipeline
  {
    const float* bq  = (const float*)d_in[5];
    const float* bo  = (const float*)d_in[7];
    const float* b1  = (const float*)d_in[9];
    const float* b2  = (const float*)d_in[11];
    const float* lns = (const float*)d_in[12];
    const float* lnb = (const float*)d_in[13];

    bembed_kernel<<<dim3(ROWSB / 16), dim3(256), 0, stream>>>(
        ids, tok_emb, pos_emb, Xb, Ah, Al);
    for (int l = 0; l < NLBn; ++l) {
      bqkv_kernel<<<dim3(ROWSB / 64, 3), dim3(256), 0, stream>>>(
          Ah, Al, pbQ + (size_t)l * 98304, bq + l * 384, SBb);
      battn_kernel<<<dim3(Bn, Hn), dim3(64), 0, stream>>>(SBb, ids, Ah, Al);
      bo_ln_kernel<<<dim3(ROWSB / 64), dim3(256), 0, stream>>>(
          Ah, Al, pbO + (size_t)l * 32768, bo + l * 128,
          lns + l * 256, lnb + l * 256, Xb, Ah, Al);
      bw1_kernel<<<dim3(ROWSB / 64, 4), dim3(256), 0, stream>>>(
          Ah, Al, pbW1 + (size_t)l * 131072, b1 + l * 512, Hh, Hl);
      bw2_kernel<<<dim3(ROWSB / 64), dim3(512), 0, stream>>>(
          Hh, Hl, pbW2 + (size_t)l * 131072, b2 + l * 128,
          lns + l * 256 + 128, lnb + l * 256 + 128, Xb, Ah, Al);
    }
    bintent_kernel<<<dim3(Bn / 4), dim3(256), 0, stream>>>(
        Xb, (const float*)d_in[14], (const float*)d_in[15], intent);
  }

  // ---- router
  {
    RouterP rp;
    rp.state = state; rp.intent = intent;
    rp.se_W1 = (const float*)d_in[16]; rp.se_b1 = (const float*)d_in[17];
    rp.se_W2 = (const float*)d_in[18]; rp.se_b2 = (const float*)d_in[19];
    rp.se_ln_s = (const float*)d_in[20]; rp.se_ln_b = (const float*)d_in[21];
    rp.r_W1 = (const float*)d_in[22]; rp.r_b1 = (const float*)d_in[23];
    rp.r_W2 = (const float*)d_in[24]; rp.r_b2 = (const float*)d_in[25];
    rp.r_ln_s = (const float*)d_in[26]; rp.r_ln_b = (const float*)d_in[27];
    rp.gate_W = (const float*)d_in[28]; rp.gate_b = (const float*)d_in[29];
    rp.ridx = ridx; rp.rwgt = rwgt;
    router_kernel<<<dim3(Bn), dim3(128), 0, stream>>>(rp);
  }

  const float* ab   = (const float*)d_in[35];
  const float* abo  = (const float*)d_in[37];
  const float* lnsA = (const float*)d_in[38];
  const float* lnbA = (const float*)d_in[39];
  const float* fb1A = (const float*)d_in[41];
  const float* fb2A = (const float*)d_in[43];
  const float* hW   = (const float*)d_in[44];
  const float* hB   = (const float*)d_in[45];

  // ---- expert phase pipeline
  {
    sched_kernel<<<dim3(1), dim3(256), 0, stream>>>(ridx, sch, plist, prow, pexp, ppos);
    xinit_kernel<<<dim3(MPMAX * 32 / 256), dim3(256), 0, stream>>>(qpe, sch, X2);
    ln_pack_kernel<<<dim3(MPMAX / 16), dim3(256), 0, stream>>>(
        X2, ANP, lnsA, lnbA, 0, sch);
    short* HP = SBh;
    for (int l = 0; l < NLDn; ++l) {
      // self-attention block
      gemm_k128<6, 0, true><<<dim3(NBGMAX), dim3(256), 0, stream>>>(
          ANP, pQ + (l * 2 + 0) * 49152, 294912,
          ab + (l * 2 + 0) * 384, 2304, 0,
          SBh, 384, nullptr, nullptr, nullptr, 0, nullptr, sch);
      sattn_kernel<<<dim3(PAIRS, Hn), dim3(64), 0, stream>>>(SBh, prow, ANP);
      gemm_k128<2, 4, true><<<dim3(NBGMAX), dim3(256), 0, stream>>>(
          ANP, pO + (l * 2 + 0) * 16384, 98304,
          abo + (l * 2 + 0) * 128, 768, 0,
          nullptr, 0, ANP, lnsA, lnbA, (l * 3 + 1) * 128, X2, sch);
      // cross-attention block
      gemm_k128<2, 0, true><<<dim3(NBGMAX), dim3(256), 0, stream>>>(
          ANP, pQ + (l * 2 + 1) * 49152, 294912,
          ab + (l * 2 + 1) * 384, 2304, 0,
          SBh, 128, nullptr, nullptr, nullptr, 0, nullptr, sch);
      cattn_kernel<<<dim3(PAIRS), dim3(256), 0, stream>>>(
          SBh, state, Cmat, k0c, k1c, l, plist, prow, pexp, ANP);
      gemm_k128<2, 4, true><<<dim3(NBGMAX), dim3(256), 0, stream>>>(
          ANP, pO + (l * 2 + 1) * 16384, 98304,
          abo + (l * 2 + 1) * 128, 768, 0,
          nullptr, 0, ANP, lnsA, lnbA, (l * 3 + 2) * 128, X2, sch);
      // FFN block: two W1 halves -> KT=16 HP, then one merged K=512 W2
      gemm_k128<4, 3, true><<<dim3(NBGMAX), dim3(256), 0, stream>>>(
          ANP, pF1 + l * 65536, 196608,
          fb1A + l * 512 + 0 * 256, 1536, 0,
          nullptr, 0, HP, nullptr, nullptr, 0, nullptr, sch);
      gemm_k128<4, 3, true><<<dim3(NBGMAX), dim3(256), 0, stream>>>(
          ANP, pF1 + l * 65536, 196608,
          fb1A + l * 512 + 1 * 256, 1536, 16,
          nullptr, 0, HP, nullptr, nullptr, 0, nullptr, sch);
      if (l < NLDn - 1) {
        gemm_k256f<true><<<dim3(NBGMAX), dim3(256), 0, stream>>>(
            HP, pF2 + l * 65536, 196608, fb2A + l * 128, 384,
            X2, ANP, lnsA, lnbA, ((l + 1) * 3 + 0) * 128, sch);
      } else {
        gemm_k256f<false><<<dim3(NBGMAX), dim3(256), 0, stream>>>(
            HP, pF2 + l * 65536, 196608, fb2A + l * 128, 384,
            X2, nullptr, nullptr, nullptr, 0, sch);
      }
    }
    head_kernel<<<dim3(PAIRS), dim3(256), 0, stream>>>(
        X2, plist, prow, pexp, rwgt, hW, hB, Rbuf);
    combine_kernel<<<dim3((Bn * 140 + 255) / 256), dim3(256), 0, stream>>>(
        Rbuf, ppos, (float*)d_out);
  }
}